// Round 10
// baseline (649.817 us; speedup 1.0000x reference)
//
#include <hip/hip_runtime.h>
#include <math.h>

// Problem constants
namespace {
constexpr int B = 2, C = 16, D = 16, H = 128, W = 128;
constexpr int HW   = H * W;        // 16384
constexpr int DHW  = D * HW;       // 262144
constexpr int CDHW = C * DHW;      // 4194304
constexpr float EPSBN = 1e-5f;

// workspace regions (floats). ws = 37,748,736 floats = 151 MB
// R0: X1 / (app2) V / XB16 / —          R1: OWacc / G0
// K/KT/QT/MST small regions             R2: (app1) V / Yt / G1
// R3: VT / G2
constexpr long long OFF_R0  = 0;
constexpr long long OFF_R1  = 8388608;
constexpr long long OFF_K   = 16777216;  // K / WT16 (bf16 gate weights)
constexpr long long OFF_KT  = 17825792;
constexpr long long OFF_QT  = 18874368;
constexpr long long OFF_MST = 19922944;  // s_inner in (I,O) layout
constexpr long long OFF_R2  = 20971520;
constexpr long long OFF_R3  = 29360128;
}

using frag_ab = __attribute__((ext_vector_type(8))) short;  // 8 bf16
using frag_cd = __attribute__((ext_vector_type(4))) float;  // 4 f32

__device__ __forceinline__ unsigned short f2bf(float f) {
  unsigned u = __float_as_uint(f);
  u = (u + 0x7FFF + ((u >> 16) & 1)) >> 16;   // RNE
  return (unsigned short)u;
}

// ---------------------------------------------------------------------------
// K1: conv_pre (1x3x3, pad 0,1,1) + BN + ReLU.   grid(64, D, B), block 256.
// ---------------------------------------------------------------------------
__global__ __launch_bounds__(256) void k_conv_pre(
    const float* __restrict__ x, const float* __restrict__ wp,
    const float* __restrict__ bg, const float* __restrict__ bb,
    const float* __restrict__ bm, const float* __restrict__ bv,
    float* __restrict__ out)
{
  __shared__ float xs[16][18][18];
  __shared__ float sc[16], bi[16];
  const int tid = threadIdx.x;
  const int tile = blockIdx.x;
  const int d = blockIdx.y, b = blockIdx.z;
  const int h0 = (tile >> 3) * 16, w0 = (tile & 7) * 16;

  if (tid < 16) {
    float s = bg[tid] * rsqrtf(bv[tid] + EPSBN);
    sc[tid] = s;
    bi[tid] = bb[tid] - bm[tid] * s;
  }
  const float* xb = x + (long long)b * CDHW + (long long)d * HW;
  for (int idx = tid; idx < 16 * 324; idx += 256) {
    int cin = idx / 324, rem = idx - cin * 324;
    int ph = rem / 18, pw = rem - ph * 18;
    int gh = h0 - 1 + ph, gw = w0 - 1 + pw;
    float v = 0.f;
    if (gh >= 0 && gh < H && gw >= 0 && gw < W)
      v = xb[(long long)cin * DHW + gh * W + gw];
    xs[cin][ph][pw] = v;
  }
  __syncthreads();

  const int ty = tid >> 4, tx = tid & 15;
  float acc[16];
  #pragma unroll
  for (int co = 0; co < 16; ++co) acc[co] = 0.f;

  for (int cin = 0; cin < 16; ++cin) {
    #pragma unroll
    for (int kh = 0; kh < 3; ++kh) {
      #pragma unroll
      for (int kw = 0; kw < 3; ++kw) {
        float xv = xs[cin][ty + kh][tx + kw];
        const int wi = cin * 9 + kh * 3 + kw;
        #pragma unroll
        for (int co = 0; co < 16; ++co)
          acc[co] = fmaf(xv, wp[co * 144 + wi], acc[co]);
      }
    }
  }
  float* ob = out + (long long)b * CDHW + (long long)d * HW + (h0 + ty) * W + (w0 + tx);
  #pragma unroll
  for (int co = 0; co < 16; ++co)
    ob[(long long)co * DHW] = fmaxf(fmaf(acc[co], sc[co], bi[co]), 0.f);
}

// ---------------------------------------------------------------------------
// K2: projections (layout-generic).
// ---------------------------------------------------------------------------
__global__ __launch_bounds__(256) void k_qkv(
    const float* __restrict__ xin, const float* __restrict__ wq,
    const float* __restrict__ wk, const float* __restrict__ wv,
    float* __restrict__ Kp, float* __restrict__ KTp, float* __restrict__ QTp,
    float* __restrict__ Vp, float* __restrict__ VTp)
{
  const int tid = threadIdx.x;
  const int tile = blockIdx.x, d = blockIdx.y, b = blockIdx.z;
  const int h0 = (tile >> 3) * 16, w0 = (tile & 7) * 16;
  const int ty = tid >> 4, tx = tid & 15;
  const int h = h0 + ty, w = w0 + tx;

  const float* xb = xin + (long long)b * CDHW + (long long)d * HW + h * 128 + w;
  float xv[16];
  #pragma unroll
  for (int c = 0; c < 16; ++c) xv[c] = xb[(long long)c * DHW];

  float q0 = 0, q1 = 0, k0 = 0, k1 = 0, v[16];
  #pragma unroll
  for (int c = 0; c < 16; ++c) {
    q0 = fmaf(wq[c], xv[c], q0);
    q1 = fmaf(wq[16 + c], xv[c], q1);
    k0 = fmaf(wk[c], xv[c], k0);
    k1 = fmaf(wk[16 + c], xv[c], k1);
  }
  #pragma unroll
  for (int o = 0; o < 16; ++o) {
    float a = 0;
    #pragma unroll
    for (int c = 0; c < 16; ++c) a = fmaf(wv[o * 16 + c], xv[c], a);
    v[o] = a;
  }

  const int sl = b * 16 + d;
  const long long base2 = (long long)(sl * 2) * HW;
  const long long baseV = (long long)(sl * 16) * HW;
  const int hw = h * 128 + w;
  Kp[base2 + hw] = k0;
  Kp[base2 + HW + hw] = k1;
  #pragma unroll
  for (int o = 0; o < 16; ++o) Vp[baseV + (long long)o * HW + hw] = v[o];

  __shared__ float lsk[2][16][17];
  __shared__ float lsq[2][16][17];
  __shared__ float lsv[16][16][17];
  lsk[0][ty][tx] = k0; lsk[1][ty][tx] = k1;
  lsq[0][ty][tx] = q0; lsq[1][ty][tx] = q1;
  #pragma unroll
  for (int o = 0; o < 16; ++o) lsv[o][ty][tx] = v[o];
  __syncthreads();

  const int wh = (w0 + ty) * 128 + (h0 + tx);
  KTp[base2 + wh]      = lsk[0][tx][ty];
  KTp[base2 + HW + wh] = lsk[1][tx][ty];
  QTp[base2 + wh]      = lsq[0][tx][ty];
  QTp[base2 + HW + wh] = lsq[1][tx][ty];
  #pragma unroll
  for (int o = 0; o < 16; ++o) VTp[baseV + (long long)o * HW + wh] = lsv[o][tx][ty];
}

__device__ __forceinline__ float f4comp(const float4& f, int j) {
  return (j == 0) ? f.x : (j == 1) ? f.y : (j == 2) ? f.z : f.w;
}

// ---------------------------------------------------------------------------
// K3 v4: INNER direction only. Computes inner scores (LDS K-row), exp (no
// max; scores O(1)), accumulates raw oW and s_inner. Outer direction moved
// entirely to k_att_col (which computes those exps anyway).
// Writes OWp (raw acc, normal layout) and s_inner to MST (I,O layout).
// ---------------------------------------------------------------------------
template<bool MASK_INNER>
__global__ __launch_bounds__(256) void k_att_row(
    const float* __restrict__ xin, float* __restrict__ OWp,
    const float* __restrict__ Kp, const float* __restrict__ Vp,
    float* __restrict__ MSTp, const float* __restrict__ wq)
{
  __shared__ float krow[4][2][128];
  const int tid = threadIdx.x;
  const int o0 = blockIdx.x * 4, d = blockIdx.y, b = blockIdx.z;
  const int sl = b * 16 + d;
  const long long base2 = (long long)(sl * 2) * HW;
  const long long baseV = (long long)(sl * 16) * HW;
  const long long baseM = (long long)sl * HW;
  const int hi = tid >> 6;            // orow 0..3 (wave-aligned)
  const int L  = tid & 63;
  const int orow = o0 + hi;
  const long long xbase = (long long)b * CDHW + (long long)d * HW;

  for (int kk = tid; kk < 1024; kk += 256) {
    int col = kk & 127;
    int t = kk >> 7;                  // r2*2 + o
    int r2 = t >> 1, o = t & 1;
    krow[r2][o][col] = Kp[base2 + (long long)o * HW + (o0 + r2) * 128 + col];
  }
  __syncthreads();

  const int ir[2] = {L, L + 64};
  float q0[2] = {0.f, 0.f}, q1[2] = {0.f, 0.f};
  #pragma unroll
  for (int c = 0; c < 16; ++c) {
    const float w0 = wq[c], w1 = wq[16 + c];
    #pragma unroll
    for (int r = 0; r < 2; ++r) {
      float xv = xin[xbase + (long long)c * DHW + orow * 128 + ir[r]];
      q0[r] = fmaf(w0, xv, q0[r]);
      q1[r] = fmaf(w1, xv, q1[r]);
    }
  }

  float s[2] = {0.f, 0.f};
  float acc[2][16];
  #pragma unroll
  for (int r = 0; r < 2; ++r)
    #pragma unroll
    for (int c = 0; c < 16; ++c) acc[r][c] = 0.f;

  for (int v4 = 0; v4 < 32; ++v4) {
    float a[2][4];
    #pragma unroll
    for (int jj = 0; jj < 4; ++jj) {
      const int v = v4 * 4 + jj;
      const float kv0 = krow[hi][0][v], kv1 = krow[hi][1][v];
      #pragma unroll
      for (int r = 0; r < 2; ++r) {
        float e = fmaf(q0[r], kv0, q1[r] * kv1);
        float aa = __expf(e);
        if (MASK_INNER && v == ir[r]) aa = 0.f;
        a[r][jj] = aa;
      }
    }
    #pragma unroll
    for (int jj = 0; jj < 4; ++jj) { s[0] += a[0][jj]; s[1] += a[1][jj]; }

    #pragma unroll
    for (int ch = 0; ch < 2; ++ch) {
      float4 vv[8];
      #pragma unroll
      for (int cc = 0; cc < 8; ++cc)
        vv[cc] = *(const float4*)&Vp[baseV + (long long)(ch * 8 + cc) * HW + orow * 128 + v4 * 4];
      #pragma unroll
      for (int jj = 0; jj < 4; ++jj)
        #pragma unroll
        for (int r = 0; r < 2; ++r)
          #pragma unroll
          for (int cc = 0; cc < 8; ++cc)
            acc[r][ch * 8 + cc] = fmaf(a[r][jj], f4comp(vv[cc], jj), acc[r][ch * 8 + cc]);
    }
  }

  #pragma unroll
  for (int r = 0; r < 2; ++r) {
    MSTp[baseM + ir[r] * 128 + orow] = s[r];
    #pragma unroll
    for (int c = 0; c < 16; ++c)
      OWp[xbase + (long long)c * DHW + orow * 128 + ir[r]] = acc[r][c];
  }
}

// ---------------------------------------------------------------------------
// K4 v3: outer direction + final combine. Computes outer exps (for oH AND
// the outer denominator), inv = 1/(s_inner+s_outer),
// res = x + gamma*inv*(oWacc + oHacc).
// MASK_INNER=false (app1): mask outer diag; writes fp32 transposed -> Yt.
// MASK_INNER=true  (app2): outer unmasked; writes bf16 [pos][16c] Xb16.
// ---------------------------------------------------------------------------
template<bool MASK_INNER>
__global__ __launch_bounds__(128) void k_att_col(
    const float* __restrict__ xin, const float* __restrict__ OWp,
    float* __restrict__ Yt, short* __restrict__ Xb16,
    const float* __restrict__ KTp, const float* __restrict__ QTp,
    const float* __restrict__ VTp, const float* __restrict__ MSTp,
    const float* __restrict__ gp)
{
  __shared__ float kc[4][2][128];
  __shared__ float ii_s[4][128];
  __shared__ float ps[16][128][4];
  const int tid = threadIdx.x;
  const int i0 = blockIdx.x * 4, d = blockIdx.y, b = blockIdx.z;
  const int sl = b * 16 + d;
  const long long base2 = (long long)(sl * 2) * HW;
  const long long baseV = (long long)(sl * 16) * HW;
  const long long baseM = (long long)sl * HW;
  const int wi = tid >> 5, oi = tid & 31;
  const int icol = i0 + wi;
  const long long xbase = (long long)b * CDHW + (long long)d * HW;

  for (int kk = 0; kk < 8; ++kk) {
    int o = kk & 1, r2 = kk >> 1;
    kc[r2][o][tid] = KTp[base2 + (long long)o * HW + (i0 + r2) * 128 + tid];
  }
  for (int kk = 0; kk < 4; ++kk)
    ii_s[kk][tid] = MSTp[baseM + (i0 + kk) * 128 + tid];
  for (int t = tid; t < 2048; t += 128) {
    int c = t >> 7, o = t & 127;
    *(float4*)&ps[c][o][0] =
        *(const float4*)&OWp[xbase + (long long)c * DHW + o * 128 + i0];
  }
  __syncthreads();

  int orr[4];
  float q0[4], q1[4], sout[4];
  #pragma unroll
  for (int r = 0; r < 4; ++r) {
    orr[r] = oi + 32 * r;
    q0[r] = QTp[base2 + icol * 128 + orr[r]];
    q1[r] = QTp[base2 + HW + icol * 128 + orr[r]];
    sout[r] = 0.f;
  }
  float acc[4][16];
  #pragma unroll
  for (int r = 0; r < 4; ++r)
    #pragma unroll
    for (int c = 0; c < 16; ++c) acc[r][c] = 0.f;

  for (int j4 = 0; j4 < 32; ++j4) {
    float4 vv[16];
    #pragma unroll
    for (int c = 0; c < 16; ++c)
      vv[c] = *(const float4*)&VTp[baseV + (long long)c * HW + icol * 128 + j4 * 4];
    #pragma unroll
    for (int jj = 0; jj < 4; ++jj) {
      const int j = j4 * 4 + jj;
      const float k0 = kc[wi][0][j], k1 = kc[wi][1][j];
      #pragma unroll
      for (int r = 0; r < 4; ++r) {
        float e = fmaf(q0[r], k0, q1[r] * k1);
        float a = __expf(e);
        if (!MASK_INNER && j == orr[r]) a = 0.f;
        sout[r] += a;
        #pragma unroll
        for (int c = 0; c < 16; ++c)
          acc[r][c] = fmaf(a, f4comp(vv[c], jj), acc[r][c]);
      }
    }
  }

  const float gamma = gp[0];
  #pragma unroll
  for (int r = 0; r < 4; ++r) {
    float gi = gamma / (ii_s[wi][orr[r]] + sout[r]);
    float res[16];
    #pragma unroll
    for (int c = 0; c < 16; ++c)
      res[c] = fmaf(gi, ps[c][orr[r]][wi] + acc[r][c],
                    xin[xbase + (long long)c * DHW + orr[r] * 128 + icol]);

    if constexpr (!MASK_INNER) {
      #pragma unroll
      for (int c = 0; c < 16; ++c)
        Yt[xbase + (long long)c * DHW + icol * 128 + orr[r]] = res[c];
    } else {
      unsigned pk[8];
      #pragma unroll
      for (int c = 0; c < 8; ++c)
        pk[c] = (unsigned)f2bf(res[2 * c]) | ((unsigned)f2bf(res[2 * c + 1]) << 16);
      short* dst = Xb16 + ((long long)(b * D + d) * HW + icol * 128 + orr[r]) * 16;
      *(uint4*)(dst)     = make_uint4(pk[0], pk[1], pk[2], pk[3]);
      *(uint4*)(dst + 8) = make_uint4(pk[4], pk[5], pk[6], pk[7]);
    }
  }
}

// ---------------------------------------------------------------------------
// K_wt: pack gate weights OIDHW -> bf16 WT16[co64][k448], k = tap*16+cin.
// ---------------------------------------------------------------------------
__global__ __launch_bounds__(256) void k_wt(
    const float* __restrict__ wg, short* __restrict__ WT16)
{
  const int idx = blockIdx.x * 256 + threadIdx.x;   // < 28672
  if (idx >= 64 * 448) return;
  const int co_g = idx / 448;
  const int k = idx - co_g * 448;
  const int tap = k >> 4, cin = k & 15;
  float v = (tap < 27) ? wg[co_g * 432 + cin * 27 + tap] : 0.f;
  WT16[idx] = (short)f2bf(v);
}

// ---------------------------------------------------------------------------
// K5a: conv_gate via MFMA implicit GEMM (bf16 in, f32 acc).
// ---------------------------------------------------------------------------
__global__ __launch_bounds__(256, 2) void k_gates(
    const short* __restrict__ XB16, const short* __restrict__ WT16,
    float* __restrict__ g0, float* __restrict__ g1,
    float* __restrict__ g2, float* __restrict__ g3)
{
  __shared__ short xls[2 * 1584 * 8];   // [half][pos=kd*528+rr*132+col][8c]
  const int tid = threadIdx.x;
  const int rp = blockIdx.x;            // 0..63 (2-row group)
  const int d = blockIdx.y, b = blockIdx.z;
  const int h0 = rp * 2;

  const int lane = tid & 63;
  const int og   = tid >> 6;
  const int p    = lane & 15;
  const int chunk = lane >> 4;

  const short* xb = XB16 + (long long)(b * D) * HW * 16;
  const frag_ab zero8 = {0, 0, 0, 0, 0, 0, 0, 0};
  for (int it = 0; it < 13; ++it) {
    const int ci = it * 256 + tid;
    if (ci < 3168) {
      const int pos = ci >> 1, half = ci & 1;
      const int kd = pos / 528;
      const int rem = pos - kd * 528;
      const int rr = rem / 132;
      const int col = rem - rr * 132;
      const int dd = d - 1 + kd, gh = h0 - 1 + rr, gw = col - 1;
      frag_ab v = zero8;
      if (dd >= 0 && dd < D && gh >= 0 && gh < H && gw >= 0 && gw < W)
        v = *(const frag_ab*)(xb + ((long long)dd * HW + gh * W + gw) * 16 + half * 8);
      *(frag_ab*)&xls[half * 12672 + pos * 8] = v;
    }
  }

  frag_ab a[14];
  {
    const short* wl = WT16 + (og * 16 + p) * 448 + chunk * 8;
    #pragma unroll
    for (int s = 0; s < 14; ++s)
      a[s] = *(const frag_ab*)(wl + s * 32);
  }

  const int t0 = chunk >> 1, half = chunk & 1;
  int offs[14];
  #pragma unroll
  for (int s = 0; s < 14; ++s) {
    int tap = 2 * s + t0;
    if (tap > 26) tap = 0;
    const int kd = (tap * 57) >> 9;
    const int rem = tap - kd * 9;
    const int kh = (rem * 11) >> 5;
    const int kw = rem - kh * 3;
    offs[s] = half * 12672 + ((kd * 4 + kh) * 132 + p + kw) * 8;
  }

  frag_cd acc[2][8];
  #pragma unroll
  for (int r2 = 0; r2 < 2; ++r2)
    #pragma unroll
    for (int pg = 0; pg < 8; ++pg)
      acc[r2][pg] = (frag_cd){0.f, 0.f, 0.f, 0.f};

  __syncthreads();

  #pragma unroll
  for (int s = 0; s < 14; ++s) {
    const frag_ab av = a[s];
    const int base0 = offs[s];
    #pragma unroll
    for (int pg = 0; pg < 8; ++pg) {
      frag_ab b0 = *(const frag_ab*)&xls[base0 + pg * 128];
      acc[0][pg] = __builtin_amdgcn_mfma_f32_16x16x32_bf16(av, b0, acc[0][pg], 0, 0, 0);
      frag_ab b1 = *(const frag_ab*)&xls[base0 + 1056 + pg * 128];
      acc[1][pg] = __builtin_amdgcn_mfma_f32_16x16x32_bf16(av, b1, acc[1][pg], 0, 0, 0);
    }
  }

  float* gbuf = (og == 0) ? g0 : (og == 1) ? g1 : (og == 2) ? g2 : g3;
  const long long base = (long long)b * CDHW + (long long)d * HW + h0 * W;
  #pragma unroll
  for (int r2 = 0; r2 < 2; ++r2)
    #pragma unroll
    for (int pg = 0; pg < 8; ++pg)
      #pragma unroll
      for (int reg = 0; reg < 4; ++reg) {
        const int cc = chunk * 4 + reg;
        gbuf[base + (long long)cc * DHW + r2 * W + pg * 16 + p] = acc[r2][pg][reg];
      }
}

// ---------------------------------------------------------------------------
// K5b: BN + activations + SRU scan over D. One thread per (b,c,h,w).
// ---------------------------------------------------------------------------
__global__ __launch_bounds__(256) void k_scan(
    const float* __restrict__ g0, const float* __restrict__ g1,
    const float* __restrict__ g2, const float* __restrict__ g3,
    const float* __restrict__ bg, const float* __restrict__ bb,
    const float* __restrict__ bm, const float* __restrict__ bv,
    float* __restrict__ out)
{
  const int g = blockIdx.x * 256 + threadIdx.x;   // 0 .. 524287
  const int hw = g & 16383;
  const int cc = (g >> 14) & 15;
  const int b  = g >> 18;

  float sc[4], bi[4];
  #pragma unroll
  for (int gg = 0; gg < 4; ++gg) {
    int ch = gg * 16 + cc;
    float s = bg[ch] * rsqrtf(bv[ch] + EPSBN);
    sc[gg] = s;
    bi[gg] = bb[ch] - bm[ch] * s;
  }

  const long long base = (long long)b * CDHW + (long long)cc * DHW + hw;
  float Ct = 0.f;
  for (int d = 0; d < D; ++d) {
    const long long idx = base + (long long)d * HW;
    float wx = tanhf(fmaf(g0[idx], sc[0], bi[0]));
    float ft = 1.f / (1.f + __expf(-fmaf(g1[idx], sc[1], bi[1])));
    float rt = 1.f / (1.f + __expf(-fmaf(g2[idx], sc[2], bi[2])));
    float xg = tanhf(fmaf(g3[idx], sc[3], bi[3]));
    Ct = (d == 0) ? (1.f - ft) : fmaf(ft, Ct, (1.f - ft) * wx);
    out[idx] = fmaf(rt, Ct, (1.f - rt) * xg);
  }
}

// ---------------------------------------------------------------------------
extern "C" void kernel_launch(void* const* d_in, const int* in_sizes, int n_in,
                              void* d_out, int out_size, void* d_ws, size_t ws_size,
                              hipStream_t stream) {
  const float* x      = (const float*)d_in[0];
  const float* w_pre  = (const float*)d_in[1];
  const float* bnpg   = (const float*)d_in[2];
  const float* bnpb   = (const float*)d_in[3];
  const float* bnpm   = (const float*)d_in[4];
  const float* bnpv   = (const float*)d_in[5];
  const float* wq     = (const float*)d_in[6];
  const float* wk     = (const float*)d_in[7];
  const float* wv     = (const float*)d_in[8];
  const float* gamma  = (const float*)d_in[9];
  const float* w_gate = (const float*)d_in[10];
  const float* bng    = (const float*)d_in[11];
  const float* bnb    = (const float*)d_in[12];
  const float* bnm    = (const float*)d_in[13];
  const float* bnv    = (const float*)d_in[14];

  float* ws  = (float*)d_ws;
  float* R0  = ws + OFF_R0;
  float* R1  = ws + OFF_R1;
  float* Kb  = ws + OFF_K;
  float* KTb = ws + OFF_KT;
  float* QTb = ws + OFF_QT;
  float* MST = ws + OFF_MST;
  float* R2  = ws + OFF_R2;
  float* R3  = ws + OFF_R3;
  short* XB16 = (short*)(ws + OFF_R0);
  short* WT16 = (short*)(ws + OFF_K);
  float* out = (float*)d_out;

  const dim3 gTile(64, D, B), gAtt(32, D, B);

  // stage 1: conv_pre + BN + ReLU -> R0 (X1)
  k_conv_pre<<<gTile, dim3(256), 0, stream>>>(x, w_pre, bnpg, bnpb, bnpm, bnpv, R0);

  // attention application 1 (normal layout, mask on outer=H): R0 -> Yt in R2
  k_qkv<<<gTile, dim3(256), 0, stream>>>(R0, wq, wk, wv, Kb, KTb, QTb, R2, R3);
  k_att_row<false><<<gAtt, dim3(256), 0, stream>>>(R0, R1, Kb, R2, MST, wq);
  k_att_col<false><<<gAtt, dim3(128), 0, stream>>>(R0, R1, R2, nullptr, KTb, QTb, R3, MST, gamma);

  // attention application 2 (transposed layout, mask on inner): R2 -> XB16 in R0
  k_qkv<<<gTile, dim3(256), 0, stream>>>(R2, wq, wk, wv, Kb, KTb, QTb, R0, R3);
  k_att_row<true><<<gAtt, dim3(256), 0, stream>>>(R2, R1, Kb, R0, MST, wq);
  k_att_col<true><<<gAtt, dim3(128), 0, stream>>>(R2, R1, nullptr, XB16, KTb, QTb, R3, MST, gamma);

  // bf16 gate weights (K region free now)
  k_wt<<<dim3(112), dim3(256), 0, stream>>>(w_gate, WT16);

  // stage 3: conv_gate via MFMA (G0->R1, G1->R2, G2->R3, X gate -> d_out)
  k_gates<<<dim3(64, D, B), dim3(256), 0, stream>>>(XB16, WT16, R1, R2, R3, out);

  // stage 4: BN + activations + SRU scan
  k_scan<<<dim3(2048), dim3(256), 0, stream>>>(R1, R2, R3, out, bng, bnb, bnm, bnv, out);
}

// Round 11
// 618.383 us; speedup vs baseline: 1.0508x; 1.0508x over previous
//
#include <hip/hip_runtime.h>
#include <math.h>

// Problem constants
namespace {
constexpr int B = 2, C = 16, D = 16, H = 128, W = 128;
constexpr int HW   = H * W;        // 16384
constexpr int DHW  = D * HW;       // 262144
constexpr int CDHW = C * DHW;      // 4194304
constexpr float EPSBN = 1e-5f;

// workspace regions (floats). ws = 37,748,736 floats = 151 MB
constexpr long long OFF_R0  = 0;
constexpr long long OFF_R1  = 8388608;
constexpr long long OFF_K   = 16777216;  // K / WT16 (bf16 gate weights)
constexpr long long OFF_KT  = 17825792;
constexpr long long OFF_QT  = 18874368;
constexpr long long OFF_MST = 19922944;  // s_inner (I,O); 0.5M used
constexpr long long OFF_SO  = 20447232;  // s_outer (I,O); 0.5M used
constexpr long long OFF_R2  = 20971520;
constexpr long long OFF_R3  = 29360128;
}

using frag_ab = __attribute__((ext_vector_type(8))) short;  // 8 bf16
using frag_cd = __attribute__((ext_vector_type(4))) float;  // 4 f32

__device__ __forceinline__ unsigned short f2bf(float f) {
  unsigned u = __float_as_uint(f);
  u = (u + 0x7FFF + ((u >> 16) & 1)) >> 16;   // RNE
  return (unsigned short)u;
}

// ---------------------------------------------------------------------------
// K1: conv_pre (1x3x3, pad 0,1,1) + BN + ReLU.   grid(64, D, B), block 256.
// ---------------------------------------------------------------------------
__global__ __launch_bounds__(256) void k_conv_pre(
    const float* __restrict__ x, const float* __restrict__ wp,
    const float* __restrict__ bg, const float* __restrict__ bb,
    const float* __restrict__ bm, const float* __restrict__ bv,
    float* __restrict__ out)
{
  __shared__ float xs[16][18][18];
  __shared__ float sc[16], bi[16];
  const int tid = threadIdx.x;
  const int tile = blockIdx.x;
  const int d = blockIdx.y, b = blockIdx.z;
  const int h0 = (tile >> 3) * 16, w0 = (tile & 7) * 16;

  if (tid < 16) {
    float s = bg[tid] * rsqrtf(bv[tid] + EPSBN);
    sc[tid] = s;
    bi[tid] = bb[tid] - bm[tid] * s;
  }
  const float* xb = x + (long long)b * CDHW + (long long)d * HW;
  for (int idx = tid; idx < 16 * 324; idx += 256) {
    int cin = idx / 324, rem = idx - cin * 324;
    int ph = rem / 18, pw = rem - ph * 18;
    int gh = h0 - 1 + ph, gw = w0 - 1 + pw;
    float v = 0.f;
    if (gh >= 0 && gh < H && gw >= 0 && gw < W)
      v = xb[(long long)cin * DHW + gh * W + gw];
    xs[cin][ph][pw] = v;
  }
  __syncthreads();

  const int ty = tid >> 4, tx = tid & 15;
  float acc[16];
  #pragma unroll
  for (int co = 0; co < 16; ++co) acc[co] = 0.f;

  for (int cin = 0; cin < 16; ++cin) {
    #pragma unroll
    for (int kh = 0; kh < 3; ++kh) {
      #pragma unroll
      for (int kw = 0; kw < 3; ++kw) {
        float xv = xs[cin][ty + kh][tx + kw];
        const int wi = cin * 9 + kh * 3 + kw;
        #pragma unroll
        for (int co = 0; co < 16; ++co)
          acc[co] = fmaf(xv, wp[co * 144 + wi], acc[co]);
      }
    }
  }
  float* ob = out + (long long)b * CDHW + (long long)d * HW + (h0 + ty) * W + (w0 + tx);
  #pragma unroll
  for (int co = 0; co < 16; ++co)
    ob[(long long)co * DHW] = fmaxf(fmaf(acc[co], sc[co], bi[co]), 0.f);
}

// ---------------------------------------------------------------------------
// K2: projections (layout-generic).
// ---------------------------------------------------------------------------
__global__ __launch_bounds__(256) void k_qkv(
    const float* __restrict__ xin, const float* __restrict__ wq,
    const float* __restrict__ wk, const float* __restrict__ wv,
    float* __restrict__ Kp, float* __restrict__ KTp, float* __restrict__ QTp,
    float* __restrict__ Vp, float* __restrict__ VTp)
{
  const int tid = threadIdx.x;
  const int tile = blockIdx.x, d = blockIdx.y, b = blockIdx.z;
  const int h0 = (tile >> 3) * 16, w0 = (tile & 7) * 16;
  const int ty = tid >> 4, tx = tid & 15;
  const int h = h0 + ty, w = w0 + tx;

  const float* xb = xin + (long long)b * CDHW + (long long)d * HW + h * 128 + w;
  float xv[16];
  #pragma unroll
  for (int c = 0; c < 16; ++c) xv[c] = xb[(long long)c * DHW];

  float q0 = 0, q1 = 0, k0 = 0, k1 = 0, v[16];
  #pragma unroll
  for (int c = 0; c < 16; ++c) {
    q0 = fmaf(wq[c], xv[c], q0);
    q1 = fmaf(wq[16 + c], xv[c], q1);
    k0 = fmaf(wk[c], xv[c], k0);
    k1 = fmaf(wk[16 + c], xv[c], k1);
  }
  #pragma unroll
  for (int o = 0; o < 16; ++o) {
    float a = 0;
    #pragma unroll
    for (int c = 0; c < 16; ++c) a = fmaf(wv[o * 16 + c], xv[c], a);
    v[o] = a;
  }

  const int sl = b * 16 + d;
  const long long base2 = (long long)(sl * 2) * HW;
  const long long baseV = (long long)(sl * 16) * HW;
  const int hw = h * 128 + w;
  Kp[base2 + hw] = k0;
  Kp[base2 + HW + hw] = k1;
  #pragma unroll
  for (int o = 0; o < 16; ++o) Vp[baseV + (long long)o * HW + hw] = v[o];

  __shared__ float lsk[2][16][17];
  __shared__ float lsq[2][16][17];
  __shared__ float lsv[16][16][17];
  lsk[0][ty][tx] = k0; lsk[1][ty][tx] = k1;
  lsq[0][ty][tx] = q0; lsq[1][ty][tx] = q1;
  #pragma unroll
  for (int o = 0; o < 16; ++o) lsv[o][ty][tx] = v[o];
  __syncthreads();

  const int wh = (w0 + ty) * 128 + (h0 + tx);
  KTp[base2 + wh]      = lsk[0][tx][ty];
  KTp[base2 + HW + wh] = lsk[1][tx][ty];
  QTp[base2 + wh]      = lsq[0][tx][ty];
  QTp[base2 + HW + wh] = lsq[1][tx][ty];
  #pragma unroll
  for (int o = 0; o < 16; ++o) VTp[baseV + (long long)o * HW + wh] = lsv[o][tx][ty];
}

__device__ __forceinline__ float f4comp(const float4& f, int j) {
  return (j == 0) ? f.x : (j == 1) ? f.y : (j == 2) ? f.z : f.w;
}

// ---------------------------------------------------------------------------
// K3: INNER direction. Raw oW acc + s_inner. (round-9 v4, unchanged)
// ---------------------------------------------------------------------------
template<bool MASK_INNER>
__global__ __launch_bounds__(256) void k_att_row(
    const float* __restrict__ xin, float* __restrict__ OWp,
    const float* __restrict__ Kp, const float* __restrict__ Vp,
    float* __restrict__ Sip, const float* __restrict__ wq)
{
  __shared__ float krow[4][2][128];
  const int tid = threadIdx.x;
  const int o0 = blockIdx.x * 4, d = blockIdx.y, b = blockIdx.z;
  const int sl = b * 16 + d;
  const long long base2 = (long long)(sl * 2) * HW;
  const long long baseV = (long long)(sl * 16) * HW;
  const long long baseM = (long long)sl * HW;
  const int hi = tid >> 6;
  const int L  = tid & 63;
  const int orow = o0 + hi;
  const long long xbase = (long long)b * CDHW + (long long)d * HW;

  for (int kk = tid; kk < 1024; kk += 256) {
    int col = kk & 127;
    int t = kk >> 7;
    int r2 = t >> 1, o = t & 1;
    krow[r2][o][col] = Kp[base2 + (long long)o * HW + (o0 + r2) * 128 + col];
  }
  __syncthreads();

  const int ir[2] = {L, L + 64};
  float q0[2] = {0.f, 0.f}, q1[2] = {0.f, 0.f};
  #pragma unroll
  for (int c = 0; c < 16; ++c) {
    const float w0 = wq[c], w1 = wq[16 + c];
    #pragma unroll
    for (int r = 0; r < 2; ++r) {
      float xv = xin[xbase + (long long)c * DHW + orow * 128 + ir[r]];
      q0[r] = fmaf(w0, xv, q0[r]);
      q1[r] = fmaf(w1, xv, q1[r]);
    }
  }

  float s[2] = {0.f, 0.f};
  float acc[2][16];
  #pragma unroll
  for (int r = 0; r < 2; ++r)
    #pragma unroll
    for (int c = 0; c < 16; ++c) acc[r][c] = 0.f;

  for (int v4 = 0; v4 < 32; ++v4) {
    float a[2][4];
    #pragma unroll
    for (int jj = 0; jj < 4; ++jj) {
      const int v = v4 * 4 + jj;
      const float kv0 = krow[hi][0][v], kv1 = krow[hi][1][v];
      #pragma unroll
      for (int r = 0; r < 2; ++r) {
        float e = fmaf(q0[r], kv0, q1[r] * kv1);
        float aa = __expf(e);
        if (MASK_INNER && v == ir[r]) aa = 0.f;
        a[r][jj] = aa;
      }
    }
    #pragma unroll
    for (int jj = 0; jj < 4; ++jj) { s[0] += a[0][jj]; s[1] += a[1][jj]; }

    #pragma unroll
    for (int ch = 0; ch < 2; ++ch) {
      float4 vv[8];
      #pragma unroll
      for (int cc = 0; cc < 8; ++cc)
        vv[cc] = *(const float4*)&Vp[baseV + (long long)(ch * 8 + cc) * HW + orow * 128 + v4 * 4];
      #pragma unroll
      for (int jj = 0; jj < 4; ++jj)
        #pragma unroll
        for (int r = 0; r < 2; ++r)
          #pragma unroll
          for (int cc = 0; cc < 8; ++cc)
            acc[r][ch * 8 + cc] = fmaf(a[r][jj], f4comp(vv[cc], jj), acc[r][ch * 8 + cc]);
    }
  }

  #pragma unroll
  for (int r = 0; r < 2; ++r) {
    Sip[baseM + ir[r] * 128 + orow] = s[r];
    #pragma unroll
    for (int c = 0; c < 16; ++c)
      OWp[xbase + (long long)c * DHW + orow * 128 + ir[r]] = acc[r][c];
  }
}

// ---------------------------------------------------------------------------
// K4 v4: OUTER direction, pure producer. 256 thr = 4 icol-waves, 2 orr/lane.
// Reads KT/QT/VT only (all coalesced / broadcast). Writes raw oH acc OHT
// [c][i*128+o] and s_outer [i*128+o] — both coalesced.
// MASK_INNER=false (app1): mask outer diag. true (app2): no outer mask.
// ---------------------------------------------------------------------------
template<bool MASK_INNER>
__global__ __launch_bounds__(256) void k_att_col(
    const float* __restrict__ KTp, const float* __restrict__ QTp,
    const float* __restrict__ VTp, float* __restrict__ OHTp,
    float* __restrict__ Sop)
{
  __shared__ float kc[4][2][128];
  const int tid = threadIdx.x;
  const int i0 = blockIdx.x * 4, d = blockIdx.y, b = blockIdx.z;
  const int sl = b * 16 + d;
  const long long base2 = (long long)(sl * 2) * HW;
  const long long baseV = (long long)(sl * 16) * HW;
  const long long baseS = (long long)sl * HW;
  const int hi = tid >> 6;            // icol offset (wave-uniform)
  const int L  = tid & 63;
  const int icol = i0 + hi;
  const long long xbase = (long long)b * CDHW + (long long)d * HW;

  for (int kk = tid; kk < 1024; kk += 256) {
    int col = kk & 127;
    int t = kk >> 7;
    int r2 = t >> 1, o = t & 1;
    kc[r2][o][col] = KTp[base2 + (long long)o * HW + (i0 + r2) * 128 + col];
  }
  __syncthreads();

  const int orr[2] = {L, L + 64};
  float q0[2], q1[2];
  #pragma unroll
  for (int r = 0; r < 2; ++r) {
    q0[r] = QTp[base2 + icol * 128 + orr[r]];
    q1[r] = QTp[base2 + HW + icol * 128 + orr[r]];
  }

  float s[2] = {0.f, 0.f};
  float acc[2][16];
  #pragma unroll
  for (int r = 0; r < 2; ++r)
    #pragma unroll
    for (int c = 0; c < 16; ++c) acc[r][c] = 0.f;

  for (int j4 = 0; j4 < 32; ++j4) {
    float a[2][4];
    #pragma unroll
    for (int jj = 0; jj < 4; ++jj) {
      const int j = j4 * 4 + jj;
      const float k0 = kc[hi][0][j], k1 = kc[hi][1][j];
      #pragma unroll
      for (int r = 0; r < 2; ++r) {
        float e = fmaf(q0[r], k0, q1[r] * k1);
        float aa = __expf(e);
        if (!MASK_INNER && j == orr[r]) aa = 0.f;
        a[r][jj] = aa;
      }
    }
    #pragma unroll
    for (int jj = 0; jj < 4; ++jj) { s[0] += a[0][jj]; s[1] += a[1][jj]; }

    #pragma unroll
    for (int ch = 0; ch < 2; ++ch) {
      float4 vv[8];
      #pragma unroll
      for (int cc = 0; cc < 8; ++cc)
        vv[cc] = *(const float4*)&VTp[baseV + (long long)(ch * 8 + cc) * HW + icol * 128 + j4 * 4];
      #pragma unroll
      for (int jj = 0; jj < 4; ++jj)
        #pragma unroll
        for (int r = 0; r < 2; ++r)
          #pragma unroll
          for (int cc = 0; cc < 8; ++cc)
            acc[r][ch * 8 + cc] = fmaf(a[r][jj], f4comp(vv[cc], jj), acc[r][ch * 8 + cc]);
    }
  }

  #pragma unroll
  for (int r = 0; r < 2; ++r) {
    Sop[baseS + icol * 128 + orr[r]] = s[r];
    #pragma unroll
    for (int c = 0; c < 16; ++c)
      OHTp[xbase + (long long)c * DHW + icol * 128 + orr[r]] = acc[r][c];
  }
}

// ---------------------------------------------------------------------------
// K_comb: res = x + gamma/(s_i+s_o) * (oW + oH), written TRANSPOSED.
// 16x16 spatial tile; x/OW transposed through padded LDS; OHT/s read
// coalesced (their layout matches output). TO_BF16: write [pos][16c] bf16.
// ---------------------------------------------------------------------------
template<bool TO_BF16>
__global__ __launch_bounds__(256) void k_comb(
    const float* __restrict__ Xn, const float* __restrict__ OWp,
    const float* __restrict__ OHTp, const float* __restrict__ Sip,
    const float* __restrict__ Sop, const float* __restrict__ gp,
    float* __restrict__ Yt, short* __restrict__ Xb16)
{
  __shared__ float xs[16][16][17], ows[16][16][17];
  const int tid = threadIdx.x;
  const int tile = blockIdx.x, d = blockIdx.y, b = blockIdx.z;
  const int o0 = (tile >> 3) * 16, i0 = (tile & 7) * 16;
  const int sl = b * 16 + d;
  const long long baseM = (long long)sl * HW;
  const long long xbase = (long long)b * CDHW + (long long)d * HW;

  const int to = tid >> 4, ti = tid & 15;
  #pragma unroll
  for (int c = 0; c < 16; ++c) {
    const long long src = xbase + (long long)c * DHW + (o0 + to) * 128 + (i0 + ti);
    xs[c][to][ti]  = Xn[src];
    ows[c][to][ti] = OWp[src];
  }
  __syncthreads();

  const int ti2 = tid >> 4, to2 = tid & 15;
  const int i = i0 + ti2, o = o0 + to2;
  const float si = Sip[baseM + i * 128 + o];
  const float so = Sop[baseM + i * 128 + o];
  const float gi = gp[0] / (si + so);

  float res[16];
  #pragma unroll
  for (int c = 0; c < 16; ++c) {
    float oh = OHTp[xbase + (long long)c * DHW + i * 128 + o];
    res[c] = fmaf(gi, ows[c][to2][ti2] + oh, xs[c][to2][ti2]);
  }

  if constexpr (!TO_BF16) {
    #pragma unroll
    for (int c = 0; c < 16; ++c)
      Yt[xbase + (long long)c * DHW + i * 128 + o] = res[c];
  } else {
    unsigned pk[8];
    #pragma unroll
    for (int c = 0; c < 8; ++c)
      pk[c] = (unsigned)f2bf(res[2 * c]) | ((unsigned)f2bf(res[2 * c + 1]) << 16);
    short* dst = Xb16 + ((long long)(b * D + d) * HW + i * 128 + o) * 16;
    *(uint4*)(dst)     = make_uint4(pk[0], pk[1], pk[2], pk[3]);
    *(uint4*)(dst + 8) = make_uint4(pk[4], pk[5], pk[6], pk[7]);
  }
}

// ---------------------------------------------------------------------------
// K_wt: pack gate weights OIDHW -> bf16 WT16[co64][k448], k = tap*16+cin.
// ---------------------------------------------------------------------------
__global__ __launch_bounds__(256) void k_wt(
    const float* __restrict__ wg, short* __restrict__ WT16)
{
  const int idx = blockIdx.x * 256 + threadIdx.x;   // < 28672
  if (idx >= 64 * 448) return;
  const int co_g = idx / 448;
  const int k = idx - co_g * 448;
  const int tap = k >> 4, cin = k & 15;
  float v = (tap < 27) ? wg[co_g * 432 + cin * 27 + tap] : 0.f;
  WT16[idx] = (short)f2bf(v);
}

// ---------------------------------------------------------------------------
// K5a: conv_gate via MFMA implicit GEMM (bf16 in, f32 acc).
// ---------------------------------------------------------------------------
__global__ __launch_bounds__(256, 2) void k_gates(
    const short* __restrict__ XB16, const short* __restrict__ WT16,
    float* __restrict__ g0, float* __restrict__ g1,
    float* __restrict__ g2, float* __restrict__ g3)
{
  __shared__ short xls[2 * 1584 * 8];   // [half][pos=kd*528+rr*132+col][8c]
  const int tid = threadIdx.x;
  const int rp = blockIdx.x;            // 0..63 (2-row group)
  const int d = blockIdx.y, b = blockIdx.z;
  const int h0 = rp * 2;

  const int lane = tid & 63;
  const int og   = tid >> 6;
  const int p    = lane & 15;
  const int chunk = lane >> 4;

  const short* xb = XB16 + (long long)(b * D) * HW * 16;
  const frag_ab zero8 = {0, 0, 0, 0, 0, 0, 0, 0};
  for (int it = 0; it < 13; ++it) {
    const int ci = it * 256 + tid;
    if (ci < 3168) {
      const int pos = ci >> 1, half = ci & 1;
      const int kd = pos / 528;
      const int rem = pos - kd * 528;
      const int rr = rem / 132;
      const int col = rem - rr * 132;
      const int dd = d - 1 + kd, gh = h0 - 1 + rr, gw = col - 1;
      frag_ab v = zero8;
      if (dd >= 0 && dd < D && gh >= 0 && gh < H && gw >= 0 && gw < W)
        v = *(const frag_ab*)(xb + ((long long)dd * HW + gh * W + gw) * 16 + half * 8);
      *(frag_ab*)&xls[half * 12672 + pos * 8] = v;
    }
  }

  frag_ab a[14];
  {
    const short* wl = WT16 + (og * 16 + p) * 448 + chunk * 8;
    #pragma unroll
    for (int s = 0; s < 14; ++s)
      a[s] = *(const frag_ab*)(wl + s * 32);
  }

  const int t0 = chunk >> 1, half = chunk & 1;
  int offs[14];
  #pragma unroll
  for (int s = 0; s < 14; ++s) {
    int tap = 2 * s + t0;
    if (tap > 26) tap = 0;
    const int kd = (tap * 57) >> 9;
    const int rem = tap - kd * 9;
    const int kh = (rem * 11) >> 5;
    const int kw = rem - kh * 3;
    offs[s] = half * 12672 + ((kd * 4 + kh) * 132 + p + kw) * 8;
  }

  frag_cd acc[2][8];
  #pragma unroll
  for (int r2 = 0; r2 < 2; ++r2)
    #pragma unroll
    for (int pg = 0; pg < 8; ++pg)
      acc[r2][pg] = (frag_cd){0.f, 0.f, 0.f, 0.f};

  __syncthreads();

  #pragma unroll
  for (int s = 0; s < 14; ++s) {
    const frag_ab av = a[s];
    const int base0 = offs[s];
    #pragma unroll
    for (int pg = 0; pg < 8; ++pg) {
      frag_ab b0 = *(const frag_ab*)&xls[base0 + pg * 128];
      acc[0][pg] = __builtin_amdgcn_mfma_f32_16x16x32_bf16(av, b0, acc[0][pg], 0, 0, 0);
      frag_ab b1 = *(const frag_ab*)&xls[base0 + 1056 + pg * 128];
      acc[1][pg] = __builtin_amdgcn_mfma_f32_16x16x32_bf16(av, b1, acc[1][pg], 0, 0, 0);
    }
  }

  float* gbuf = (og == 0) ? g0 : (og == 1) ? g1 : (og == 2) ? g2 : g3;
  const long long base = (long long)b * CDHW + (long long)d * HW + h0 * W;
  #pragma unroll
  for (int r2 = 0; r2 < 2; ++r2)
    #pragma unroll
    for (int pg = 0; pg < 8; ++pg)
      #pragma unroll
      for (int reg = 0; reg < 4; ++reg) {
        const int cc = chunk * 4 + reg;
        gbuf[base + (long long)cc * DHW + r2 * W + pg * 16 + p] = acc[r2][pg][reg];
      }
}

// ---------------------------------------------------------------------------
// K5b: BN + activations + SRU scan over D. One thread per (b,c,h,w).
// ---------------------------------------------------------------------------
__global__ __launch_bounds__(256) void k_scan(
    const float* __restrict__ g0, const float* __restrict__ g1,
    const float* __restrict__ g2, const float* __restrict__ g3,
    const float* __restrict__ bg, const float* __restrict__ bb,
    const float* __restrict__ bm, const float* __restrict__ bv,
    float* __restrict__ out)
{
  const int g = blockIdx.x * 256 + threadIdx.x;   // 0 .. 524287
  const int hw = g & 16383;
  const int cc = (g >> 14) & 15;
  const int b  = g >> 18;

  float sc[4], bi[4];
  #pragma unroll
  for (int gg = 0; gg < 4; ++gg) {
    int ch = gg * 16 + cc;
    float s = bg[ch] * rsqrtf(bv[ch] + EPSBN);
    sc[gg] = s;
    bi[gg] = bb[ch] - bm[ch] * s;
  }

  const long long base = (long long)b * CDHW + (long long)cc * DHW + hw;
  float Ct = 0.f;
  for (int d = 0; d < D; ++d) {
    const long long idx = base + (long long)d * HW;
    float wx = tanhf(fmaf(g0[idx], sc[0], bi[0]));
    float ft = 1.f / (1.f + __expf(-fmaf(g1[idx], sc[1], bi[1])));
    float rt = 1.f / (1.f + __expf(-fmaf(g2[idx], sc[2], bi[2])));
    float xg = tanhf(fmaf(g3[idx], sc[3], bi[3]));
    Ct = (d == 0) ? (1.f - ft) : fmaf(ft, Ct, (1.f - ft) * wx);
    out[idx] = fmaf(rt, Ct, (1.f - rt) * xg);
  }
}

// ---------------------------------------------------------------------------
extern "C" void kernel_launch(void* const* d_in, const int* in_sizes, int n_in,
                              void* d_out, int out_size, void* d_ws, size_t ws_size,
                              hipStream_t stream) {
  const float* x      = (const float*)d_in[0];
  const float* w_pre  = (const float*)d_in[1];
  const float* bnpg   = (const float*)d_in[2];
  const float* bnpb   = (const float*)d_in[3];
  const float* bnpm   = (const float*)d_in[4];
  const float* bnpv   = (const float*)d_in[5];
  const float* wq     = (const float*)d_in[6];
  const float* wk     = (const float*)d_in[7];
  const float* wv     = (const float*)d_in[8];
  const float* gamma  = (const float*)d_in[9];
  const float* w_gate = (const float*)d_in[10];
  const float* bng    = (const float*)d_in[11];
  const float* bnb    = (const float*)d_in[12];
  const float* bnm    = (const float*)d_in[13];
  const float* bnv    = (const float*)d_in[14];

  float* ws  = (float*)d_ws;
  float* R0  = ws + OFF_R0;
  float* R1  = ws + OFF_R1;
  float* Kb  = ws + OFF_K;
  float* KTb = ws + OFF_KT;
  float* QTb = ws + OFF_QT;
  float* SI  = ws + OFF_MST;
  float* SO  = ws + OFF_SO;
  float* R2  = ws + OFF_R2;
  float* R3  = ws + OFF_R3;
  short* XB16 = (short*)(ws + OFF_R1);
  short* WT16 = (short*)(ws + OFF_K);
  float* out = (float*)d_out;

  const dim3 gTile(64, D, B), gAtt(32, D, B);

  // stage 1: conv_pre + BN + ReLU -> R0 (app1 x, normal layout)
  k_conv_pre<<<gTile, dim3(256), 0, stream>>>(x, w_pre, bnpg, bnpb, bnpm, bnpv, R0);

  // attention application 1 (mask on outer): x=R0, V->R2, VT->R3
  k_qkv<<<gTile, dim3(256), 0, stream>>>(R0, wq, wk, wv, Kb, KTb, QTb, R2, R3);
  k_att_row<false><<<gAtt, dim3(256), 0, stream>>>(R0, R1, Kb, R2, SI, wq);       // OW->R1
  k_att_col<false><<<gAtt, dim3(256), 0, stream>>>(KTb, QTb, R3, R2, SO);         // OHT->R2
  k_comb<false><<<gTile, dim3(256), 0, stream>>>(R0, R1, R2, SI, SO, gamma, R3, nullptr); // Y->R3

  // attention application 2 (transposed layout; mask on inner): x=R3
  k_qkv<<<gTile, dim3(256), 0, stream>>>(R3, wq, wk, wv, Kb, KTb, QTb, R0, R1);   // V->R0, VT->R1
  k_att_row<true><<<gAtt, dim3(256), 0, stream>>>(R3, R2, Kb, R0, SI, wq);        // OW->R2
  k_att_col<true><<<gAtt, dim3(256), 0, stream>>>(KTb, QTb, R1, R0, SO);          // OHT->R0
  k_comb<true><<<gTile, dim3(256), 0, stream>>>(R3, R2, R0, SI, SO, gamma, nullptr, XB16); // ->R1

  // bf16 gate weights (K region free now)
  k_wt<<<dim3(112), dim3(256), 0, stream>>>(w_gate, WT16);

  // stage 3: conv_gate via MFMA (G0->R0, G1->R2, G2->R3, X gate -> d_out)
  k_gates<<<dim3(64, D, B), dim3(256), 0, stream>>>(XB16, WT16, R0, R2, R3, out);

  // stage 4: BN + activations + SRU scan
  k_scan<<<dim3(2048), dim3(256), 0, stream>>>(R0, R2, R3, out, bng, bnb, bnm, bnv, out);
}

// Round 12
// 502.094 us; speedup vs baseline: 1.2942x; 1.2316x over previous
//
#include <hip/hip_runtime.h>
#include <math.h>

// Problem constants
namespace {
constexpr int B = 2, C = 16, D = 16, H = 128, W = 128;
constexpr int HW   = H * W;        // 16384
constexpr int DHW  = D * HW;       // 262144
constexpr int CDHW = C * DHW;      // 4194304
constexpr float EPSBN = 1e-5f;

// workspace regions (floats). ws = 37,748,736 floats = 151 MB
constexpr long long OFF_R0  = 0;
constexpr long long OFF_R1  = 8388608;
constexpr long long OFF_K   = 16777216;  // K / WT16 (bf16 gate weights)
constexpr long long OFF_KT  = 17825792;
constexpr long long OFF_QT  = 18874368;
constexpr long long OFF_MST = 19922944;  // s_inner (I,O); 0.5M used
constexpr long long OFF_SO  = 20447232;  // s_outer (I,O); 0.5M used
constexpr long long OFF_R2  = 20971520;
constexpr long long OFF_R3  = 29360128;
}

using frag_ab = __attribute__((ext_vector_type(8))) short;  // 8 bf16
using frag_cd = __attribute__((ext_vector_type(4))) float;  // 4 f32

__device__ __forceinline__ unsigned short f2bf(float f) {
  unsigned u = __float_as_uint(f);
  u = (u + 0x7FFF + ((u >> 16) & 1)) >> 16;   // RNE
  return (unsigned short)u;
}

// ---------------------------------------------------------------------------
// K1: conv_pre (1x3x3, pad 0,1,1) + BN + ReLU.   grid(64, D, B), block 256.
// ---------------------------------------------------------------------------
__global__ __launch_bounds__(256) void k_conv_pre(
    const float* __restrict__ x, const float* __restrict__ wp,
    const float* __restrict__ bg, const float* __restrict__ bb,
    const float* __restrict__ bm, const float* __restrict__ bv,
    float* __restrict__ out)
{
  __shared__ float xs[16][18][18];
  __shared__ float sc[16], bi[16];
  const int tid = threadIdx.x;
  const int tile = blockIdx.x;
  const int d = blockIdx.y, b = blockIdx.z;
  const int h0 = (tile >> 3) * 16, w0 = (tile & 7) * 16;

  if (tid < 16) {
    float s = bg[tid] * rsqrtf(bv[tid] + EPSBN);
    sc[tid] = s;
    bi[tid] = bb[tid] - bm[tid] * s;
  }
  const float* xb = x + (long long)b * CDHW + (long long)d * HW;
  for (int idx = tid; idx < 16 * 324; idx += 256) {
    int cin = idx / 324, rem = idx - cin * 324;
    int ph = rem / 18, pw = rem - ph * 18;
    int gh = h0 - 1 + ph, gw = w0 - 1 + pw;
    float v = 0.f;
    if (gh >= 0 && gh < H && gw >= 0 && gw < W)
      v = xb[(long long)cin * DHW + gh * W + gw];
    xs[cin][ph][pw] = v;
  }
  __syncthreads();

  const int ty = tid >> 4, tx = tid & 15;
  float acc[16];
  #pragma unroll
  for (int co = 0; co < 16; ++co) acc[co] = 0.f;

  for (int cin = 0; cin < 16; ++cin) {
    #pragma unroll
    for (int kh = 0; kh < 3; ++kh) {
      #pragma unroll
      for (int kw = 0; kw < 3; ++kw) {
        float xv = xs[cin][ty + kh][tx + kw];
        const int wi = cin * 9 + kh * 3 + kw;
        #pragma unroll
        for (int co = 0; co < 16; ++co)
          acc[co] = fmaf(xv, wp[co * 144 + wi], acc[co]);
      }
    }
  }
  float* ob = out + (long long)b * CDHW + (long long)d * HW + (h0 + ty) * W + (w0 + tx);
  #pragma unroll
  for (int co = 0; co < 16; ++co)
    ob[(long long)co * DHW] = fmaxf(fmaf(acc[co], sc[co], bi[co]), 0.f);
}

// ---------------------------------------------------------------------------
// K2: projections (layout-generic).
// ---------------------------------------------------------------------------
__global__ __launch_bounds__(256) void k_qkv(
    const float* __restrict__ xin, const float* __restrict__ wq,
    const float* __restrict__ wk, const float* __restrict__ wv,
    float* __restrict__ Kp, float* __restrict__ KTp, float* __restrict__ QTp,
    float* __restrict__ Vp, float* __restrict__ VTp)
{
  const int tid = threadIdx.x;
  const int tile = blockIdx.x, d = blockIdx.y, b = blockIdx.z;
  const int h0 = (tile >> 3) * 16, w0 = (tile & 7) * 16;
  const int ty = tid >> 4, tx = tid & 15;
  const int h = h0 + ty, w = w0 + tx;

  const float* xb = xin + (long long)b * CDHW + (long long)d * HW + h * 128 + w;
  float xv[16];
  #pragma unroll
  for (int c = 0; c < 16; ++c) xv[c] = xb[(long long)c * DHW];

  float q0 = 0, q1 = 0, k0 = 0, k1 = 0, v[16];
  #pragma unroll
  for (int c = 0; c < 16; ++c) {
    q0 = fmaf(wq[c], xv[c], q0);
    q1 = fmaf(wq[16 + c], xv[c], q1);
    k0 = fmaf(wk[c], xv[c], k0);
    k1 = fmaf(wk[16 + c], xv[c], k1);
  }
  #pragma unroll
  for (int o = 0; o < 16; ++o) {
    float a = 0;
    #pragma unroll
    for (int c = 0; c < 16; ++c) a = fmaf(wv[o * 16 + c], xv[c], a);
    v[o] = a;
  }

  const int sl = b * 16 + d;
  const long long base2 = (long long)(sl * 2) * HW;
  const long long baseV = (long long)(sl * 16) * HW;
  const int hw = h * 128 + w;
  Kp[base2 + hw] = k0;
  Kp[base2 + HW + hw] = k1;
  #pragma unroll
  for (int o = 0; o < 16; ++o) Vp[baseV + (long long)o * HW + hw] = v[o];

  __shared__ float lsk[2][16][17];
  __shared__ float lsq[2][16][17];
  __shared__ float lsv[16][16][17];
  lsk[0][ty][tx] = k0; lsk[1][ty][tx] = k1;
  lsq[0][ty][tx] = q0; lsq[1][ty][tx] = q1;
  #pragma unroll
  for (int o = 0; o < 16; ++o) lsv[o][ty][tx] = v[o];
  __syncthreads();

  const int wh = (w0 + ty) * 128 + (h0 + tx);
  KTp[base2 + wh]      = lsk[0][tx][ty];
  KTp[base2 + HW + wh] = lsk[1][tx][ty];
  QTp[base2 + wh]      = lsq[0][tx][ty];
  QTp[base2 + HW + wh] = lsq[1][tx][ty];
  #pragma unroll
  for (int o = 0; o < 16; ++o) VTp[baseV + (long long)o * HW + wh] = lsv[o][tx][ty];
}

__device__ __forceinline__ float f4comp(const float4& f, int j) {
  return (j == 0) ? f.x : (j == 1) ? f.y : (j == 2) ? f.z : f.w;
}

// ---------------------------------------------------------------------------
// K3 v5: INNER direction. V slab staged in LDS (was per-iteration global
// broadcast loads on the critical path). Raw oW acc + s_inner out.
// ---------------------------------------------------------------------------
template<bool MASK_INNER>
__global__ __launch_bounds__(256) void k_att_row(
    const float* __restrict__ xin, float* __restrict__ OWp,
    const float* __restrict__ Kp, const float* __restrict__ Vp,
    float* __restrict__ Sip, const float* __restrict__ wq)
{
  __shared__ float krow[4][2][128];
  __shared__ __align__(16) float vrow[4][16][128];   // 32 KB
  const int tid = threadIdx.x;
  const int o0 = blockIdx.x * 4, d = blockIdx.y, b = blockIdx.z;
  const int sl = b * 16 + d;
  const long long base2 = (long long)(sl * 2) * HW;
  const long long baseV = (long long)(sl * 16) * HW;
  const long long baseM = (long long)sl * HW;
  const int hi = tid >> 6;
  const int L  = tid & 63;
  const int orow = o0 + hi;
  const long long xbase = (long long)b * CDHW + (long long)d * HW;

  for (int kk = tid; kk < 1024; kk += 256) {
    int col = kk & 127;
    int t = kk >> 7;
    int r2 = t >> 1, o = t & 1;
    krow[r2][o][col] = Kp[base2 + (long long)o * HW + (o0 + r2) * 128 + col];
  }
  // stage V slab: 2048 float4 (r2, c, col4)
  for (int idx = tid; idx < 2048; idx += 256) {
    int col4 = idx & 31;
    int t = idx >> 5;
    int c = t & 15, r2 = t >> 4;
    *(float4*)&vrow[r2][c][col4 * 4] =
        *(const float4*)&Vp[baseV + (long long)c * HW + (o0 + r2) * 128 + col4 * 4];
  }
  __syncthreads();

  const int ir[2] = {L, L + 64};
  float q0[2] = {0.f, 0.f}, q1[2] = {0.f, 0.f};
  #pragma unroll
  for (int c = 0; c < 16; ++c) {
    const float w0 = wq[c], w1 = wq[16 + c];
    #pragma unroll
    for (int r = 0; r < 2; ++r) {
      float xv = xin[xbase + (long long)c * DHW + orow * 128 + ir[r]];
      q0[r] = fmaf(w0, xv, q0[r]);
      q1[r] = fmaf(w1, xv, q1[r]);
    }
  }

  float s[2] = {0.f, 0.f};
  float acc[2][16];
  #pragma unroll
  for (int r = 0; r < 2; ++r)
    #pragma unroll
    for (int c = 0; c < 16; ++c) acc[r][c] = 0.f;

  for (int v4 = 0; v4 < 32; ++v4) {
    float a[2][4];
    #pragma unroll
    for (int jj = 0; jj < 4; ++jj) {
      const int v = v4 * 4 + jj;
      const float kv0 = krow[hi][0][v], kv1 = krow[hi][1][v];
      #pragma unroll
      for (int r = 0; r < 2; ++r) {
        float e = fmaf(q0[r], kv0, q1[r] * kv1);
        float aa = __expf(e);
        if (MASK_INNER && v == ir[r]) aa = 0.f;
        a[r][jj] = aa;
      }
    }
    #pragma unroll
    for (int jj = 0; jj < 4; ++jj) { s[0] += a[0][jj]; s[1] += a[1][jj]; }

    #pragma unroll
    for (int cc = 0; cc < 16; ++cc) {
      const float4 vv = *(const float4*)&vrow[hi][cc][v4 * 4];
      #pragma unroll
      for (int jj = 0; jj < 4; ++jj)
        #pragma unroll
        for (int r = 0; r < 2; ++r)
          acc[r][cc] = fmaf(a[r][jj], f4comp(vv, jj), acc[r][cc]);
    }
  }

  #pragma unroll
  for (int r = 0; r < 2; ++r) {
    Sip[baseM + ir[r] * 128 + orow] = s[r];
    #pragma unroll
    for (int c = 0; c < 16; ++c)
      OWp[xbase + (long long)c * DHW + orow * 128 + ir[r]] = acc[r][c];
  }
}

// ---------------------------------------------------------------------------
// K4 v5: OUTER direction, pure producer; VT slab staged in LDS.
// Writes raw oH acc OHT [c][i*128+o] and s_outer [i*128+o] — coalesced.
// ---------------------------------------------------------------------------
template<bool MASK_INNER>
__global__ __launch_bounds__(256) void k_att_col(
    const float* __restrict__ KTp, const float* __restrict__ QTp,
    const float* __restrict__ VTp, float* __restrict__ OHTp,
    float* __restrict__ Sop)
{
  __shared__ float kc[4][2][128];
  __shared__ __align__(16) float vc[4][16][128];   // 32 KB
  const int tid = threadIdx.x;
  const int i0 = blockIdx.x * 4, d = blockIdx.y, b = blockIdx.z;
  const int sl = b * 16 + d;
  const long long base2 = (long long)(sl * 2) * HW;
  const long long baseV = (long long)(sl * 16) * HW;
  const long long baseS = (long long)sl * HW;
  const int hi = tid >> 6;            // icol offset (wave-uniform)
  const int L  = tid & 63;
  const int icol = i0 + hi;
  const long long xbase = (long long)b * CDHW + (long long)d * HW;

  for (int kk = tid; kk < 1024; kk += 256) {
    int col = kk & 127;
    int t = kk >> 7;
    int r2 = t >> 1, o = t & 1;
    kc[r2][o][col] = KTp[base2 + (long long)o * HW + (i0 + r2) * 128 + col];
  }
  for (int idx = tid; idx < 2048; idx += 256) {
    int col4 = idx & 31;
    int t = idx >> 5;
    int c = t & 15, r2 = t >> 4;
    *(float4*)&vc[r2][c][col4 * 4] =
        *(const float4*)&VTp[baseV + (long long)c * HW + (i0 + r2) * 128 + col4 * 4];
  }
  __syncthreads();

  const int orr[2] = {L, L + 64};
  float q0[2], q1[2];
  #pragma unroll
  for (int r = 0; r < 2; ++r) {
    q0[r] = QTp[base2 + icol * 128 + orr[r]];
    q1[r] = QTp[base2 + HW + icol * 128 + orr[r]];
  }

  float s[2] = {0.f, 0.f};
  float acc[2][16];
  #pragma unroll
  for (int r = 0; r < 2; ++r)
    #pragma unroll
    for (int c = 0; c < 16; ++c) acc[r][c] = 0.f;

  for (int j4 = 0; j4 < 32; ++j4) {
    float a[2][4];
    #pragma unroll
    for (int jj = 0; jj < 4; ++jj) {
      const int j = j4 * 4 + jj;
      const float k0 = kc[hi][0][j], k1 = kc[hi][1][j];
      #pragma unroll
      for (int r = 0; r < 2; ++r) {
        float e = fmaf(q0[r], k0, q1[r] * k1);
        float aa = __expf(e);
        if (!MASK_INNER && j == orr[r]) aa = 0.f;
        a[r][jj] = aa;
      }
    }
    #pragma unroll
    for (int jj = 0; jj < 4; ++jj) { s[0] += a[0][jj]; s[1] += a[1][jj]; }

    #pragma unroll
    for (int cc = 0; cc < 16; ++cc) {
      const float4 vv = *(const float4*)&vc[hi][cc][j4 * 4];
      #pragma unroll
      for (int jj = 0; jj < 4; ++jj)
        #pragma unroll
        for (int r = 0; r < 2; ++r)
          acc[r][cc] = fmaf(a[r][jj], f4comp(vv, jj), acc[r][cc]);
    }
  }

  #pragma unroll
  for (int r = 0; r < 2; ++r) {
    Sop[baseS + icol * 128 + orr[r]] = s[r];
    #pragma unroll
    for (int c = 0; c < 16; ++c)
      OHTp[xbase + (long long)c * DHW + icol * 128 + orr[r]] = acc[r][c];
  }
}

// ---------------------------------------------------------------------------
// K_comb: res = x + gamma/(s_i+s_o) * (oW + oH), written TRANSPOSED.
// ---------------------------------------------------------------------------
template<bool TO_BF16>
__global__ __launch_bounds__(256) void k_comb(
    const float* __restrict__ Xn, const float* __restrict__ OWp,
    const float* __restrict__ OHTp, const float* __restrict__ Sip,
    const float* __restrict__ Sop, const float* __restrict__ gp,
    float* __restrict__ Yt, short* __restrict__ Xb16)
{
  __shared__ float xs[16][16][17], ows[16][16][17];
  const int tid = threadIdx.x;
  const int tile = blockIdx.x, d = blockIdx.y, b = blockIdx.z;
  const int o0 = (tile >> 3) * 16, i0 = (tile & 7) * 16;
  const int sl = b * 16 + d;
  const long long baseM = (long long)sl * HW;
  const long long xbase = (long long)b * CDHW + (long long)d * HW;

  const int to = tid >> 4, ti = tid & 15;
  #pragma unroll
  for (int c = 0; c < 16; ++c) {
    const long long src = xbase + (long long)c * DHW + (o0 + to) * 128 + (i0 + ti);
    xs[c][to][ti]  = Xn[src];
    ows[c][to][ti] = OWp[src];
  }
  __syncthreads();

  const int ti2 = tid >> 4, to2 = tid & 15;
  const int i = i0 + ti2, o = o0 + to2;
  const float si = Sip[baseM + i * 128 + o];
  const float so = Sop[baseM + i * 128 + o];
  const float gi = gp[0] / (si + so);

  float res[16];
  #pragma unroll
  for (int c = 0; c < 16; ++c) {
    float oh = OHTp[xbase + (long long)c * DHW + i * 128 + o];
    res[c] = fmaf(gi, ows[c][to2][ti2] + oh, xs[c][to2][ti2]);
  }

  if constexpr (!TO_BF16) {
    #pragma unroll
    for (int c = 0; c < 16; ++c)
      Yt[xbase + (long long)c * DHW + i * 128 + o] = res[c];
  } else {
    unsigned pk[8];
    #pragma unroll
    for (int c = 0; c < 8; ++c)
      pk[c] = (unsigned)f2bf(res[2 * c]) | ((unsigned)f2bf(res[2 * c + 1]) << 16);
    short* dst = Xb16 + ((long long)(b * D + d) * HW + i * 128 + o) * 16;
    *(uint4*)(dst)     = make_uint4(pk[0], pk[1], pk[2], pk[3]);
    *(uint4*)(dst + 8) = make_uint4(pk[4], pk[5], pk[6], pk[7]);
  }
}

// ---------------------------------------------------------------------------
// K_wt: pack gate weights OIDHW -> bf16 WT16[co64][k448], k = tap*16+cin.
// ---------------------------------------------------------------------------
__global__ __launch_bounds__(256) void k_wt(
    const float* __restrict__ wg, short* __restrict__ WT16)
{
  const int idx = blockIdx.x * 256 + threadIdx.x;   // < 28672
  if (idx >= 64 * 448) return;
  const int co_g = idx / 448;
  const int k = idx - co_g * 448;
  const int tap = k >> 4, cin = k & 15;
  float v = (tap < 27) ? wg[co_g * 432 + cin * 27 + tap] : 0.f;
  WT16[idx] = (short)f2bf(v);
}

// ---------------------------------------------------------------------------
// K5a: conv_gate via MFMA implicit GEMM (bf16 in, f32 acc).
// ---------------------------------------------------------------------------
__global__ __launch_bounds__(256, 2) void k_gates(
    const short* __restrict__ XB16, const short* __restrict__ WT16,
    float* __restrict__ g0, float* __restrict__ g1,
    float* __restrict__ g2, float* __restrict__ g3)
{
  __shared__ short xls[2 * 1584 * 8];   // [half][pos=kd*528+rr*132+col][8c]
  const int tid = threadIdx.x;
  const int rp = blockIdx.x;            // 0..63 (2-row group)
  const int d = blockIdx.y, b = blockIdx.z;
  const int h0 = rp * 2;

  const int lane = tid & 63;
  const int og   = tid >> 6;
  const int p    = lane & 15;
  const int chunk = lane >> 4;

  const short* xb = XB16 + (long long)(b * D) * HW * 16;
  const frag_ab zero8 = {0, 0, 0, 0, 0, 0, 0, 0};
  for (int it = 0; it < 13; ++it) {
    const int ci = it * 256 + tid;
    if (ci < 3168) {
      const int pos = ci >> 1, half = ci & 1;
      const int kd = pos / 528;
      const int rem = pos - kd * 528;
      const int rr = rem / 132;
      const int col = rem - rr * 132;
      const int dd = d - 1 + kd, gh = h0 - 1 + rr, gw = col - 1;
      frag_ab v = zero8;
      if (dd >= 0 && dd < D && gh >= 0 && gh < H && gw >= 0 && gw < W)
        v = *(const frag_ab*)(xb + ((long long)dd * HW + gh * W + gw) * 16 + half * 8);
      *(frag_ab*)&xls[half * 12672 + pos * 8] = v;
    }
  }

  frag_ab a[14];
  {
    const short* wl = WT16 + (og * 16 + p) * 448 + chunk * 8;
    #pragma unroll
    for (int s = 0; s < 14; ++s)
      a[s] = *(const frag_ab*)(wl + s * 32);
  }

  const int t0 = chunk >> 1, half = chunk & 1;
  int offs[14];
  #pragma unroll
  for (int s = 0; s < 14; ++s) {
    int tap = 2 * s + t0;
    if (tap > 26) tap = 0;
    const int kd = (tap * 57) >> 9;
    const int rem = tap - kd * 9;
    const int kh = (rem * 11) >> 5;
    const int kw = rem - kh * 3;
    offs[s] = half * 12672 + ((kd * 4 + kh) * 132 + p + kw) * 8;
  }

  frag_cd acc[2][8];
  #pragma unroll
  for (int r2 = 0; r2 < 2; ++r2)
    #pragma unroll
    for (int pg = 0; pg < 8; ++pg)
      acc[r2][pg] = (frag_cd){0.f, 0.f, 0.f, 0.f};

  __syncthreads();

  #pragma unroll
  for (int s = 0; s < 14; ++s) {
    const frag_ab av = a[s];
    const int base0 = offs[s];
    #pragma unroll
    for (int pg = 0; pg < 8; ++pg) {
      frag_ab b0 = *(const frag_ab*)&xls[base0 + pg * 128];
      acc[0][pg] = __builtin_amdgcn_mfma_f32_16x16x32_bf16(av, b0, acc[0][pg], 0, 0, 0);
      frag_ab b1 = *(const frag_ab*)&xls[base0 + 1056 + pg * 128];
      acc[1][pg] = __builtin_amdgcn_mfma_f32_16x16x32_bf16(av, b1, acc[1][pg], 0, 0, 0);
    }
  }

  float* gbuf = (og == 0) ? g0 : (og == 1) ? g1 : (og == 2) ? g2 : g3;
  const long long base = (long long)b * CDHW + (long long)d * HW + h0 * W;
  #pragma unroll
  for (int r2 = 0; r2 < 2; ++r2)
    #pragma unroll
    for (int pg = 0; pg < 8; ++pg)
      #pragma unroll
      for (int reg = 0; reg < 4; ++reg) {
        const int cc = chunk * 4 + reg;
        gbuf[base + (long long)cc * DHW + r2 * W + pg * 16 + p] = acc[r2][pg][reg];
      }
}

// ---------------------------------------------------------------------------
// K5b: BN + activations + SRU scan over D. One thread per (b,c,h,w).
// ---------------------------------------------------------------------------
__global__ __launch_bounds__(256) void k_scan(
    const float* __restrict__ g0, const float* __restrict__ g1,
    const float* __restrict__ g2, const float* __restrict__ g3,
    const float* __restrict__ bg, const float* __restrict__ bb,
    const float* __restrict__ bm, const float* __restrict__ bv,
    float* __restrict__ out)
{
  const int g = blockIdx.x * 256 + threadIdx.x;   // 0 .. 524287
  const int hw = g & 16383;
  const int cc = (g >> 14) & 15;
  const int b  = g >> 18;

  float sc[4], bi[4];
  #pragma unroll
  for (int gg = 0; gg < 4; ++gg) {
    int ch = gg * 16 + cc;
    float s = bg[ch] * rsqrtf(bv[ch] + EPSBN);
    sc[gg] = s;
    bi[gg] = bb[ch] - bm[ch] * s;
  }

  const long long base = (long long)b * CDHW + (long long)cc * DHW + hw;
  float Ct = 0.f;
  for (int d = 0; d < D; ++d) {
    const long long idx = base + (long long)d * HW;
    float wx = tanhf(fmaf(g0[idx], sc[0], bi[0]));
    float ft = 1.f / (1.f + __expf(-fmaf(g1[idx], sc[1], bi[1])));
    float rt = 1.f / (1.f + __expf(-fmaf(g2[idx], sc[2], bi[2])));
    float xg = tanhf(fmaf(g3[idx], sc[3], bi[3]));
    Ct = (d == 0) ? (1.f - ft) : fmaf(ft, Ct, (1.f - ft) * wx);
    out[idx] = fmaf(rt, Ct, (1.f - rt) * xg);
  }
}

// ---------------------------------------------------------------------------
extern "C" void kernel_launch(void* const* d_in, const int* in_sizes, int n_in,
                              void* d_out, int out_size, void* d_ws, size_t ws_size,
                              hipStream_t stream) {
  const float* x      = (const float*)d_in[0];
  const float* w_pre  = (const float*)d_in[1];
  const float* bnpg   = (const float*)d_in[2];
  const float* bnpb   = (const float*)d_in[3];
  const float* bnpm   = (const float*)d_in[4];
  const float* bnpv   = (const float*)d_in[5];
  const float* wq     = (const float*)d_in[6];
  const float* wk     = (const float*)d_in[7];
  const float* wv     = (const float*)d_in[8];
  const float* gamma  = (const float*)d_in[9];
  const float* w_gate = (const float*)d_in[10];
  const float* bng    = (const float*)d_in[11];
  const float* bnb    = (const float*)d_in[12];
  const float* bnm    = (const float*)d_in[13];
  const float* bnv    = (const float*)d_in[14];

  float* ws  = (float*)d_ws;
  float* R0  = ws + OFF_R0;
  float* R1  = ws + OFF_R1;
  float* Kb  = ws + OFF_K;
  float* KTb = ws + OFF_KT;
  float* QTb = ws + OFF_QT;
  float* SI  = ws + OFF_MST;
  float* SO  = ws + OFF_SO;
  float* R2  = ws + OFF_R2;
  float* R3  = ws + OFF_R3;
  short* XB16 = (short*)(ws + OFF_R1);
  short* WT16 = (short*)(ws + OFF_K);
  float* out = (float*)d_out;

  const dim3 gTile(64, D, B), gAtt(32, D, B);

  // stage 1: conv_pre + BN + ReLU -> R0 (app1 x, normal layout)
  k_conv_pre<<<gTile, dim3(256), 0, stream>>>(x, w_pre, bnpg, bnpb, bnpm, bnpv, R0);

  // attention application 1 (mask on outer): x=R0, V->R2, VT->R3
  k_qkv<<<gTile, dim3(256), 0, stream>>>(R0, wq, wk, wv, Kb, KTb, QTb, R2, R3);
  k_att_row<false><<<gAtt, dim3(256), 0, stream>>>(R0, R1, Kb, R2, SI, wq);       // OW->R1
  k_att_col<false><<<gAtt, dim3(256), 0, stream>>>(KTb, QTb, R3, R2, SO);         // OHT->R2
  k_comb<false><<<gTile, dim3(256), 0, stream>>>(R0, R1, R2, SI, SO, gamma, R3, nullptr); // Y->R3

  // attention application 2 (transposed layout; mask on inner): x=R3
  k_qkv<<<gTile, dim3(256), 0, stream>>>(R3, wq, wk, wv, Kb, KTb, QTb, R0, R1);   // V->R0, VT->R1
  k_att_row<true><<<gAtt, dim3(256), 0, stream>>>(R3, R2, Kb, R0, SI, wq);        // OW->R2
  k_att_col<true><<<gAtt, dim3(256), 0, stream>>>(KTb, QTb, R1, R0, SO);          // OHT->R0
  k_comb<true><<<gTile, dim3(256), 0, stream>>>(R3, R2, R0, SI, SO, gamma, nullptr, XB16); // ->R1

  // bf16 gate weights (K region free now)
  k_wt<<<dim3(112), dim3(256), 0, stream>>>(w_gate, WT16);

  // stage 3: conv_gate via MFMA (G0->R0, G1->R2, G2->R3, X gate -> d_out)
  k_gates<<<dim3(64, D, B), dim3(256), 0, stream>>>(XB16, WT16, R0, R2, R3, out);

  // stage 4: BN + activations + SRU scan
  k_scan<<<dim3(2048), dim3(256), 0, stream>>>(R0, R2, R3, out, bng, bnb, bnm, bnv, out);
}

// Round 13
// 463.913 us; speedup vs baseline: 1.4007x; 1.0823x over previous
//
#include <hip/hip_runtime.h>
#include <math.h>

// Problem constants
namespace {
constexpr int B = 2, C = 16, D = 16, H = 128, W = 128;
constexpr int HW   = H * W;        // 16384
constexpr int DHW  = D * HW;       // 262144
constexpr int CDHW = C * DHW;      // 4194304
constexpr float EPSBN = 1e-5f;

// workspace regions (floats). ws = 37,748,736 floats = 151 MB
constexpr long long OFF_R0  = 0;
constexpr long long OFF_R1  = 8388608;
constexpr long long OFF_K   = 16777216;  // K / WT16 (bf16 gate weights)
constexpr long long OFF_KT  = 17825792;
constexpr long long OFF_QT  = 18874368;
constexpr long long OFF_MST = 19922944;  // s_inner (I,O); 0.5M used
constexpr long long OFF_SO  = 20447232;  // s_outer (I,O); 0.5M used; WP16 early
constexpr long long OFF_R2  = 20971520;
constexpr long long OFF_R3  = 29360128;
}

using frag_ab = __attribute__((ext_vector_type(8))) short;  // 8 bf16
using frag_cd = __attribute__((ext_vector_type(4))) float;  // 4 f32

__device__ __forceinline__ unsigned short f2bf(float f) {
  unsigned u = __float_as_uint(f);
  u = (u + 0x7FFF + ((u >> 16) & 1)) >> 16;   // RNE
  return (unsigned short)u;
}

// ---------------------------------------------------------------------------
// K_x16: cast input x (fp32, c-major) -> bf16 [pos][16c]. grid(64, D, B).
// ---------------------------------------------------------------------------
__global__ __launch_bounds__(256) void k_x16(
    const float* __restrict__ x, short* __restrict__ XB0)
{
  const int tid = threadIdx.x;
  const int tile = blockIdx.x, d = blockIdx.y, b = blockIdx.z;
  const int h0 = (tile >> 3) * 16, w0 = (tile & 7) * 16;
  const long long xbase = (long long)b * CDHW + (long long)d * HW;
  const int th = tid >> 4, tw = tid & 15;

  float v[16];
  #pragma unroll
  for (int c = 0; c < 16; ++c)
    v[c] = x[xbase + (long long)c * DHW + (h0 + th) * 128 + (w0 + tw)];

  unsigned pk[8];
  #pragma unroll
  for (int c = 0; c < 8; ++c)
    pk[c] = (unsigned)f2bf(v[2 * c]) | ((unsigned)f2bf(v[2 * c + 1]) << 16);
  short* dst = XB0 + ((long long)(b * D + d) * HW + (h0 + th) * 128 + (w0 + tw)) * 16;
  *(uint4*)(dst)     = make_uint4(pk[0], pk[1], pk[2], pk[3]);
  *(uint4*)(dst + 8) = make_uint4(pk[4], pk[5], pk[6], pk[7]);
}

// ---------------------------------------------------------------------------
// K_wp: pack conv_pre weights [co16][cin16][3][3] -> bf16 WP16[co16][k160],
// k = tap*16 + cin, taps >= 9 zero-padded.
// ---------------------------------------------------------------------------
__global__ __launch_bounds__(256) void k_wp(
    const float* __restrict__ wp, short* __restrict__ WP16)
{
  const int idx = blockIdx.x * 256 + threadIdx.x;   // < 2560
  if (idx >= 16 * 160) return;
  const int co = idx / 160;
  const int k = idx - co * 160;
  const int tap = k >> 4, cin = k & 15;
  float v = (tap < 9) ? wp[co * 144 + cin * 9 + tap] : 0.f;
  WP16[idx] = (short)f2bf(v);
}

// ---------------------------------------------------------------------------
// K1 v2: conv_pre via MFMA implicit GEMM (bf16 in, f32 acc) + BN + ReLU.
// grid(16 rowgroups, D, B), block 256 = 4 waves; wave = 2 rows x 128 cols.
// K = 160 (10 taps x 16 cin, tap 9 pad). LDS: 10 rows x 132 x 16c bf16.
// Same operand layout as k_gates (verified).
// ---------------------------------------------------------------------------
__global__ __launch_bounds__(256) void k_conv_pre16(
    const short* __restrict__ XB0, const short* __restrict__ WP16,
    const float* __restrict__ bg, const float* __restrict__ bb,
    const float* __restrict__ bm, const float* __restrict__ bv,
    float* __restrict__ X1)
{
  __shared__ short xls[10 * 132 * 16];   // 42.2 KB
  const int tid = threadIdx.x;
  const int rg = blockIdx.x;             // 0..15 (8-row group)
  const int d = blockIdx.y, b = blockIdx.z;
  const int h0 = rg * 8;

  const int lane = tid & 63;
  const int wv   = tid >> 6;
  const int p    = lane & 15;            // output col within pg / A row (co)
  const int chunk = lane >> 4;           // k-subchunk 0..3

  // ---- stage x tile: 10 x 132 positions x 2 halves ----
  const short* xb0 = XB0 + (long long)(b * D + d) * HW * 16;
  const frag_ab zero8 = {0, 0, 0, 0, 0, 0, 0, 0};
  for (int idx = tid; idx < 2640; idx += 256) {
    const int pos = idx >> 1, half = idx & 1;
    const int row = pos / 132, col = pos - row * 132;
    const int gh = h0 - 1 + row, gw = col - 1;
    frag_ab v = zero8;
    if (gh >= 0 && gh < H && gw >= 0 && gw < W)
      v = *(const frag_ab*)(xb0 + ((long long)gh * 128 + gw) * 16 + half * 8);
    *(frag_ab*)&xls[(row * 132 + col) * 16 + half * 8] = v;
  }

  // ---- preload A fragments: 5 k-steps ----
  frag_ab a[5];
  {
    const short* wl = WP16 + p * 160 + chunk * 8;
    #pragma unroll
    for (int s = 0; s < 5; ++s)
      a[s] = *(const frag_ab*)(wl + s * 32);
  }

  // ---- per-lane B base offsets (shorts) per k-step ----
  int offs[5];
  #pragma unroll
  for (int s = 0; s < 5; ++s) {
    int tap = 2 * s + (chunk >> 1);
    if (tap > 8) tap = 0;                // padded k (A==0) -> in-bounds addr
    const int kh = tap / 3, kw = tap - kh * 3;
    offs[s] = ((2 * wv + kh) * 132 + p + kw) * 16 + (chunk & 1) * 8;
  }

  frag_cd acc[2][8];
  #pragma unroll
  for (int r2 = 0; r2 < 2; ++r2)
    #pragma unroll
    for (int pg = 0; pg < 8; ++pg)
      acc[r2][pg] = (frag_cd){0.f, 0.f, 0.f, 0.f};

  __syncthreads();

  #pragma unroll
  for (int s = 0; s < 5; ++s) {
    const frag_ab av = a[s];
    const int base0 = offs[s];
    #pragma unroll
    for (int pg = 0; pg < 8; ++pg) {
      frag_ab b0 = *(const frag_ab*)&xls[base0 + pg * 256];
      acc[0][pg] = __builtin_amdgcn_mfma_f32_16x16x32_bf16(av, b0, acc[0][pg], 0, 0, 0);
      frag_ab b1 = *(const frag_ab*)&xls[base0 + 2112 + pg * 256];
      acc[1][pg] = __builtin_amdgcn_mfma_f32_16x16x32_bf16(av, b1, acc[1][pg], 0, 0, 0);
    }
  }

  // ---- epilogue: BN + ReLU; D row = chunk*4+reg (co), col = p ----
  float sc4[4], bi4[4];
  #pragma unroll
  for (int reg = 0; reg < 4; ++reg) {
    const int co = chunk * 4 + reg;
    float s = bg[co] * rsqrtf(bv[co] + EPSBN);
    sc4[reg] = s;
    bi4[reg] = bb[co] - bm[co] * s;
  }
  const long long xbase = (long long)b * CDHW + (long long)d * HW;
  #pragma unroll
  for (int r2 = 0; r2 < 2; ++r2) {
    const int row = h0 + 2 * wv + r2;
    #pragma unroll
    for (int pg = 0; pg < 8; ++pg)
      #pragma unroll
      for (int reg = 0; reg < 4; ++reg) {
        const int co = chunk * 4 + reg;
        float v = fmaxf(fmaf(acc[r2][pg][reg], sc4[reg], bi4[reg]), 0.f);
        X1[xbase + (long long)co * DHW + row * 128 + pg * 16 + p] = v;
      }
  }
}

// ---------------------------------------------------------------------------
// K2: projections (layout-generic).
// ---------------------------------------------------------------------------
__global__ __launch_bounds__(256) void k_qkv(
    const float* __restrict__ xin, const float* __restrict__ wq,
    const float* __restrict__ wk, const float* __restrict__ wv,
    float* __restrict__ Kp, float* __restrict__ KTp, float* __restrict__ QTp,
    float* __restrict__ Vp, float* __restrict__ VTp)
{
  const int tid = threadIdx.x;
  const int tile = blockIdx.x, d = blockIdx.y, b = blockIdx.z;
  const int h0 = (tile >> 3) * 16, w0 = (tile & 7) * 16;
  const int ty = tid >> 4, tx = tid & 15;
  const int h = h0 + ty, w = w0 + tx;

  const float* xb = xin + (long long)b * CDHW + (long long)d * HW + h * 128 + w;
  float xv[16];
  #pragma unroll
  for (int c = 0; c < 16; ++c) xv[c] = xb[(long long)c * DHW];

  float q0 = 0, q1 = 0, k0 = 0, k1 = 0, v[16];
  #pragma unroll
  for (int c = 0; c < 16; ++c) {
    q0 = fmaf(wq[c], xv[c], q0);
    q1 = fmaf(wq[16 + c], xv[c], q1);
    k0 = fmaf(wk[c], xv[c], k0);
    k1 = fmaf(wk[16 + c], xv[c], k1);
  }
  #pragma unroll
  for (int o = 0; o < 16; ++o) {
    float a = 0;
    #pragma unroll
    for (int c = 0; c < 16; ++c) a = fmaf(wv[o * 16 + c], xv[c], a);
    v[o] = a;
  }

  const int sl = b * 16 + d;
  const long long base2 = (long long)(sl * 2) * HW;
  const long long baseV = (long long)(sl * 16) * HW;
  const int hw = h * 128 + w;
  Kp[base2 + hw] = k0;
  Kp[base2 + HW + hw] = k1;
  #pragma unroll
  for (int o = 0; o < 16; ++o) Vp[baseV + (long long)o * HW + hw] = v[o];

  __shared__ float lsk[2][16][17];
  __shared__ float lsq[2][16][17];
  __shared__ float lsv[16][16][17];
  lsk[0][ty][tx] = k0; lsk[1][ty][tx] = k1;
  lsq[0][ty][tx] = q0; lsq[1][ty][tx] = q1;
  #pragma unroll
  for (int o = 0; o < 16; ++o) lsv[o][ty][tx] = v[o];
  __syncthreads();

  const int wh = (w0 + ty) * 128 + (h0 + tx);
  KTp[base2 + wh]      = lsk[0][tx][ty];
  KTp[base2 + HW + wh] = lsk[1][tx][ty];
  QTp[base2 + wh]      = lsq[0][tx][ty];
  QTp[base2 + HW + wh] = lsq[1][tx][ty];
  #pragma unroll
  for (int o = 0; o < 16; ++o) VTp[baseV + (long long)o * HW + wh] = lsv[o][tx][ty];
}

__device__ __forceinline__ float f4comp(const float4& f, int j) {
  return (j == 0) ? f.x : (j == 1) ? f.y : (j == 2) ? f.z : f.w;
}

// ---------------------------------------------------------------------------
// K3 v5: INNER direction. V slab staged in LDS. Raw oW acc + s_inner out.
// ---------------------------------------------------------------------------
template<bool MASK_INNER>
__global__ __launch_bounds__(256) void k_att_row(
    const float* __restrict__ xin, float* __restrict__ OWp,
    const float* __restrict__ Kp, const float* __restrict__ Vp,
    float* __restrict__ Sip, const float* __restrict__ wq)
{
  __shared__ float krow[4][2][128];
  __shared__ __align__(16) float vrow[4][16][128];   // 32 KB
  const int tid = threadIdx.x;
  const int o0 = blockIdx.x * 4, d = blockIdx.y, b = blockIdx.z;
  const int sl = b * 16 + d;
  const long long base2 = (long long)(sl * 2) * HW;
  const long long baseV = (long long)(sl * 16) * HW;
  const long long baseM = (long long)sl * HW;
  const int hi = tid >> 6;
  const int L  = tid & 63;
  const int orow = o0 + hi;
  const long long xbase = (long long)b * CDHW + (long long)d * HW;

  for (int kk = tid; kk < 1024; kk += 256) {
    int col = kk & 127;
    int t = kk >> 7;
    int r2 = t >> 1, o = t & 1;
    krow[r2][o][col] = Kp[base2 + (long long)o * HW + (o0 + r2) * 128 + col];
  }
  for (int idx = tid; idx < 2048; idx += 256) {
    int col4 = idx & 31;
    int t = idx >> 5;
    int c = t & 15, r2 = t >> 4;
    *(float4*)&vrow[r2][c][col4 * 4] =
        *(const float4*)&Vp[baseV + (long long)c * HW + (o0 + r2) * 128 + col4 * 4];
  }
  __syncthreads();

  const int ir[2] = {L, L + 64};
  float q0[2] = {0.f, 0.f}, q1[2] = {0.f, 0.f};
  #pragma unroll
  for (int c = 0; c < 16; ++c) {
    const float w0 = wq[c], w1 = wq[16 + c];
    #pragma unroll
    for (int r = 0; r < 2; ++r) {
      float xv = xin[xbase + (long long)c * DHW + orow * 128 + ir[r]];
      q0[r] = fmaf(w0, xv, q0[r]);
      q1[r] = fmaf(w1, xv, q1[r]);
    }
  }

  float s[2] = {0.f, 0.f};
  float acc[2][16];
  #pragma unroll
  for (int r = 0; r < 2; ++r)
    #pragma unroll
    for (int c = 0; c < 16; ++c) acc[r][c] = 0.f;

  for (int v4 = 0; v4 < 32; ++v4) {
    float a[2][4];
    #pragma unroll
    for (int jj = 0; jj < 4; ++jj) {
      const int v = v4 * 4 + jj;
      const float kv0 = krow[hi][0][v], kv1 = krow[hi][1][v];
      #pragma unroll
      for (int r = 0; r < 2; ++r) {
        float e = fmaf(q0[r], kv0, q1[r] * kv1);
        float aa = __expf(e);
        if (MASK_INNER && v == ir[r]) aa = 0.f;
        a[r][jj] = aa;
      }
    }
    #pragma unroll
    for (int jj = 0; jj < 4; ++jj) { s[0] += a[0][jj]; s[1] += a[1][jj]; }

    #pragma unroll
    for (int cc = 0; cc < 16; ++cc) {
      const float4 vv = *(const float4*)&vrow[hi][cc][v4 * 4];
      #pragma unroll
      for (int jj = 0; jj < 4; ++jj)
        #pragma unroll
        for (int r = 0; r < 2; ++r)
          acc[r][cc] = fmaf(a[r][jj], f4comp(vv, jj), acc[r][cc]);
    }
  }

  #pragma unroll
  for (int r = 0; r < 2; ++r) {
    Sip[baseM + ir[r] * 128 + orow] = s[r];
    #pragma unroll
    for (int c = 0; c < 16; ++c)
      OWp[xbase + (long long)c * DHW + orow * 128 + ir[r]] = acc[r][c];
  }
}

// ---------------------------------------------------------------------------
// K4 v5: OUTER direction, pure producer; VT slab staged in LDS.
// ---------------------------------------------------------------------------
template<bool MASK_INNER>
__global__ __launch_bounds__(256) void k_att_col(
    const float* __restrict__ KTp, const float* __restrict__ QTp,
    const float* __restrict__ VTp, float* __restrict__ OHTp,
    float* __restrict__ Sop)
{
  __shared__ float kc[4][2][128];
  __shared__ __align__(16) float vc[4][16][128];   // 32 KB
  const int tid = threadIdx.x;
  const int i0 = blockIdx.x * 4, d = blockIdx.y, b = blockIdx.z;
  const int sl = b * 16 + d;
  const long long base2 = (long long)(sl * 2) * HW;
  const long long baseV = (long long)(sl * 16) * HW;
  const long long baseS = (long long)sl * HW;
  const int hi = tid >> 6;
  const int L  = tid & 63;
  const int icol = i0 + hi;
  const long long xbase = (long long)b * CDHW + (long long)d * HW;

  for (int kk = tid; kk < 1024; kk += 256) {
    int col = kk & 127;
    int t = kk >> 7;
    int r2 = t >> 1, o = t & 1;
    kc[r2][o][col] = KTp[base2 + (long long)o * HW + (i0 + r2) * 128 + col];
  }
  for (int idx = tid; idx < 2048; idx += 256) {
    int col4 = idx & 31;
    int t = idx >> 5;
    int c = t & 15, r2 = t >> 4;
    *(float4*)&vc[r2][c][col4 * 4] =
        *(const float4*)&VTp[baseV + (long long)c * HW + (i0 + r2) * 128 + col4 * 4];
  }
  __syncthreads();

  const int orr[2] = {L, L + 64};
  float q0[2], q1[2];
  #pragma unroll
  for (int r = 0; r < 2; ++r) {
    q0[r] = QTp[base2 + icol * 128 + orr[r]];
    q1[r] = QTp[base2 + HW + icol * 128 + orr[r]];
  }

  float s[2] = {0.f, 0.f};
  float acc[2][16];
  #pragma unroll
  for (int r = 0; r < 2; ++r)
    #pragma unroll
    for (int c = 0; c < 16; ++c) acc[r][c] = 0.f;

  for (int j4 = 0; j4 < 32; ++j4) {
    float a[2][4];
    #pragma unroll
    for (int jj = 0; jj < 4; ++jj) {
      const int j = j4 * 4 + jj;
      const float k0 = kc[hi][0][j], k1 = kc[hi][1][j];
      #pragma unroll
      for (int r = 0; r < 2; ++r) {
        float e = fmaf(q0[r], k0, q1[r] * k1);
        float aa = __expf(e);
        if (!MASK_INNER && j == orr[r]) aa = 0.f;
        a[r][jj] = aa;
      }
    }
    #pragma unroll
    for (int jj = 0; jj < 4; ++jj) { s[0] += a[0][jj]; s[1] += a[1][jj]; }

    #pragma unroll
    for (int cc = 0; cc < 16; ++cc) {
      const float4 vv = *(const float4*)&vc[hi][cc][j4 * 4];
      #pragma unroll
      for (int jj = 0; jj < 4; ++jj)
        #pragma unroll
        for (int r = 0; r < 2; ++r)
          acc[r][cc] = fmaf(a[r][jj], f4comp(vv, jj), acc[r][cc]);
    }
  }

  #pragma unroll
  for (int r = 0; r < 2; ++r) {
    Sop[baseS + icol * 128 + orr[r]] = s[r];
    #pragma unroll
    for (int c = 0; c < 16; ++c)
      OHTp[xbase + (long long)c * DHW + icol * 128 + orr[r]] = acc[r][c];
  }
}

// ---------------------------------------------------------------------------
// K_comb: res = x + gamma/(s_i+s_o) * (oW + oH), written TRANSPOSED.
// ---------------------------------------------------------------------------
template<bool TO_BF16>
__global__ __launch_bounds__(256) void k_comb(
    const float* __restrict__ Xn, const float* __restrict__ OWp,
    const float* __restrict__ OHTp, const float* __restrict__ Sip,
    const float* __restrict__ Sop, const float* __restrict__ gp,
    float* __restrict__ Yt, short* __restrict__ Xb16)
{
  __shared__ float xs[16][16][17], ows[16][16][17];
  const int tid = threadIdx.x;
  const int tile = blockIdx.x, d = blockIdx.y, b = blockIdx.z;
  const int o0 = (tile >> 3) * 16, i0 = (tile & 7) * 16;
  const int sl = b * 16 + d;
  const long long baseM = (long long)sl * HW;
  const long long xbase = (long long)b * CDHW + (long long)d * HW;

  const int to = tid >> 4, ti = tid & 15;
  #pragma unroll
  for (int c = 0; c < 16; ++c) {
    const long long src = xbase + (long long)c * DHW + (o0 + to) * 128 + (i0 + ti);
    xs[c][to][ti]  = Xn[src];
    ows[c][to][ti] = OWp[src];
  }
  __syncthreads();

  const int ti2 = tid >> 4, to2 = tid & 15;
  const int i = i0 + ti2, o = o0 + to2;
  const float si = Sip[baseM + i * 128 + o];
  const float so = Sop[baseM + i * 128 + o];
  const float gi = gp[0] / (si + so);

  float res[16];
  #pragma unroll
  for (int c = 0; c < 16; ++c) {
    float oh = OHTp[xbase + (long long)c * DHW + i * 128 + o];
    res[c] = fmaf(gi, ows[c][to2][ti2] + oh, xs[c][to2][ti2]);
  }

  if constexpr (!TO_BF16) {
    #pragma unroll
    for (int c = 0; c < 16; ++c)
      Yt[xbase + (long long)c * DHW + i * 128 + o] = res[c];
  } else {
    unsigned pk[8];
    #pragma unroll
    for (int c = 0; c < 8; ++c)
      pk[c] = (unsigned)f2bf(res[2 * c]) | ((unsigned)f2bf(res[2 * c + 1]) << 16);
    short* dst = Xb16 + ((long long)(b * D + d) * HW + i * 128 + o) * 16;
    *(uint4*)(dst)     = make_uint4(pk[0], pk[1], pk[2], pk[3]);
    *(uint4*)(dst + 8) = make_uint4(pk[4], pk[5], pk[6], pk[7]);
  }
}

// ---------------------------------------------------------------------------
// K_wt: pack gate weights OIDHW -> bf16 WT16[co64][k448], k = tap*16+cin.
// ---------------------------------------------------------------------------
__global__ __launch_bounds__(256) void k_wt(
    const float* __restrict__ wg, short* __restrict__ WT16)
{
  const int idx = blockIdx.x * 256 + threadIdx.x;   // < 28672
  if (idx >= 64 * 448) return;
  const int co_g = idx / 448;
  const int k = idx - co_g * 448;
  const int tap = k >> 4, cin = k & 15;
  float v = (tap < 27) ? wg[co_g * 432 + cin * 27 + tap] : 0.f;
  WT16[idx] = (short)f2bf(v);
}

// ---------------------------------------------------------------------------
// K5a: conv_gate via MFMA implicit GEMM (bf16 in, f32 acc).
// ---------------------------------------------------------------------------
__global__ __launch_bounds__(256, 2) void k_gates(
    const short* __restrict__ XB16, const short* __restrict__ WT16,
    float* __restrict__ g0, float* __restrict__ g1,
    float* __restrict__ g2, float* __restrict__ g3)
{
  __shared__ short xls[2 * 1584 * 8];   // [half][pos=kd*528+rr*132+col][8c]
  const int tid = threadIdx.x;
  const int rp = blockIdx.x;            // 0..63 (2-row group)
  const int d = blockIdx.y, b = blockIdx.z;
  const int h0 = rp * 2;

  const int lane = tid & 63;
  const int og   = tid >> 6;
  const int p    = lane & 15;
  const int chunk = lane >> 4;

  const short* xb = XB16 + (long long)(b * D) * HW * 16;
  const frag_ab zero8 = {0, 0, 0, 0, 0, 0, 0, 0};
  for (int it = 0; it < 13; ++it) {
    const int ci = it * 256 + tid;
    if (ci < 3168) {
      const int pos = ci >> 1, half = ci & 1;
      const int kd = pos / 528;
      const int rem = pos - kd * 528;
      const int rr = rem / 132;
      const int col = rem - rr * 132;
      const int dd = d - 1 + kd, gh = h0 - 1 + rr, gw = col - 1;
      frag_ab v = zero8;
      if (dd >= 0 && dd < D && gh >= 0 && gh < H && gw >= 0 && gw < W)
        v = *(const frag_ab*)(xb + ((long long)dd * HW + gh * W + gw) * 16 + half * 8);
      *(frag_ab*)&xls[half * 12672 + pos * 8] = v;
    }
  }

  frag_ab a[14];
  {
    const short* wl = WT16 + (og * 16 + p) * 448 + chunk * 8;
    #pragma unroll
    for (int s = 0; s < 14; ++s)
      a[s] = *(const frag_ab*)(wl + s * 32);
  }

  const int t0 = chunk >> 1, half = chunk & 1;
  int offs[14];
  #pragma unroll
  for (int s = 0; s < 14; ++s) {
    int tap = 2 * s + t0;
    if (tap > 26) tap = 0;
    const int kd = (tap * 57) >> 9;
    const int rem = tap - kd * 9;
    const int kh = (rem * 11) >> 5;
    const int kw = rem - kh * 3;
    offs[s] = half * 12672 + ((kd * 4 + kh) * 132 + p + kw) * 8;
  }

  frag_cd acc[2][8];
  #pragma unroll
  for (int r2 = 0; r2 < 2; ++r2)
    #pragma unroll
    for (int pg = 0; pg < 8; ++pg)
      acc[r2][pg] = (frag_cd){0.f, 0.f, 0.f, 0.f};

  __syncthreads();

  #pragma unroll
  for (int s = 0; s < 14; ++s) {
    const frag_ab av = a[s];
    const int base0 = offs[s];
    #pragma unroll
    for (int pg = 0; pg < 8; ++pg) {
      frag_ab b0 = *(const frag_ab*)&xls[base0 + pg * 128];
      acc[0][pg] = __builtin_amdgcn_mfma_f32_16x16x32_bf16(av, b0, acc[0][pg], 0, 0, 0);
      frag_ab b1 = *(const frag_ab*)&xls[base0 + 1056 + pg * 128];
      acc[1][pg] = __builtin_amdgcn_mfma_f32_16x16x32_bf16(av, b1, acc[1][pg], 0, 0, 0);
    }
  }

  float* gbuf = (og == 0) ? g0 : (og == 1) ? g1 : (og == 2) ? g2 : g3;
  const long long base = (long long)b * CDHW + (long long)d * HW + h0 * W;
  #pragma unroll
  for (int r2 = 0; r2 < 2; ++r2)
    #pragma unroll
    for (int pg = 0; pg < 8; ++pg)
      #pragma unroll
      for (int reg = 0; reg < 4; ++reg) {
        const int cc = chunk * 4 + reg;
        gbuf[base + (long long)cc * DHW + r2 * W + pg * 16 + p] = acc[r2][pg][reg];
      }
}

// ---------------------------------------------------------------------------
// K5b: BN + activations + SRU scan over D. One thread per (b,c,h,w).
// ---------------------------------------------------------------------------
__global__ __launch_bounds__(256) void k_scan(
    const float* __restrict__ g0, const float* __restrict__ g1,
    const float* __restrict__ g2, const float* __restrict__ g3,
    const float* __restrict__ bg, const float* __restrict__ bb,
    const float* __restrict__ bm, const float* __restrict__ bv,
    float* __restrict__ out)
{
  const int g = blockIdx.x * 256 + threadIdx.x;   // 0 .. 524287
  const int hw = g & 16383;
  const int cc = (g >> 14) & 15;
  const int b  = g >> 18;

  float sc[4], bi[4];
  #pragma unroll
  for (int gg = 0; gg < 4; ++gg) {
    int ch = gg * 16 + cc;
    float s = bg[ch] * rsqrtf(bv[ch] + EPSBN);
    sc[gg] = s;
    bi[gg] = bb[ch] - bm[ch] * s;
  }

  const long long base = (long long)b * CDHW + (long long)cc * DHW + hw;
  float Ct = 0.f;
  for (int d = 0; d < D; ++d) {
    const long long idx = base + (long long)d * HW;
    float wx = tanhf(fmaf(g0[idx], sc[0], bi[0]));
    float ft = 1.f / (1.f + __expf(-fmaf(g1[idx], sc[1], bi[1])));
    float rt = 1.f / (1.f + __expf(-fmaf(g2[idx], sc[2], bi[2])));
    float xg = tanhf(fmaf(g3[idx], sc[3], bi[3]));
    Ct = (d == 0) ? (1.f - ft) : fmaf(ft, Ct, (1.f - ft) * wx);
    out[idx] = fmaf(rt, Ct, (1.f - rt) * xg);
  }
}

// ---------------------------------------------------------------------------
extern "C" void kernel_launch(void* const* d_in, const int* in_sizes, int n_in,
                              void* d_out, int out_size, void* d_ws, size_t ws_size,
                              hipStream_t stream) {
  const float* x      = (const float*)d_in[0];
  const float* w_pre  = (const float*)d_in[1];
  const float* bnpg   = (const float*)d_in[2];
  const float* bnpb   = (const float*)d_in[3];
  const float* bnpm   = (const float*)d_in[4];
  const float* bnpv   = (const float*)d_in[5];
  const float* wq     = (const float*)d_in[6];
  const float* wk     = (const float*)d_in[7];
  const float* wv     = (const float*)d_in[8];
  const float* gamma  = (const float*)d_in[9];
  const float* w_gate = (const float*)d_in[10];
  const float* bng    = (const float*)d_in[11];
  const float* bnb    = (const float*)d_in[12];
  const float* bnm    = (const float*)d_in[13];
  const float* bnv    = (const float*)d_in[14];

  float* ws  = (float*)d_ws;
  float* R0  = ws + OFF_R0;
  float* R1  = ws + OFF_R1;
  float* Kb  = ws + OFF_K;
  float* KTb = ws + OFF_KT;
  float* QTb = ws + OFF_QT;
  float* SI  = ws + OFF_MST;
  float* SO  = ws + OFF_SO;
  float* R2  = ws + OFF_R2;
  float* R3  = ws + OFF_R3;
  short* XB0  = (short*)(ws + OFF_R1);  // bf16 input (pre-attention phase)
  short* XB16 = (short*)(ws + OFF_R1);  // bf16 attn output (post-attention)
  short* WP16 = (short*)(ws + OFF_SO);  // bf16 conv_pre weights (early phase)
  short* WT16 = (short*)(ws + OFF_K);   // bf16 gate weights
  float* out = (float*)d_out;

  const dim3 gTile(64, D, B), gAtt(32, D, B);

  // stage 1: conv_pre via MFMA: x -> bf16 pos-major -> X1 (fp32) in R0
  k_wp <<<dim3(10),  dim3(256), 0, stream>>>(w_pre, WP16);
  k_x16<<<gTile,     dim3(256), 0, stream>>>(x, XB0);
  k_conv_pre16<<<dim3(16, D, B), dim3(256), 0, stream>>>(
      XB0, WP16, bnpg, bnpb, bnpm, bnpv, R0);

  // attention application 1 (mask on outer): x=R0, V->R2, VT->R3
  k_qkv<<<gTile, dim3(256), 0, stream>>>(R0, wq, wk, wv, Kb, KTb, QTb, R2, R3);
  k_att_row<false><<<gAtt, dim3(256), 0, stream>>>(R0, R1, Kb, R2, SI, wq);       // OW->R1
  k_att_col<false><<<gAtt, dim3(256), 0, stream>>>(KTb, QTb, R3, R2, SO);         // OHT->R2
  k_comb<false><<<gTile, dim3(256), 0, stream>>>(R0, R1, R2, SI, SO, gamma, R3, nullptr); // Y->R3

  // attention application 2 (transposed layout; mask on inner): x=R3
  k_qkv<<<gTile, dim3(256), 0, stream>>>(R3, wq, wk, wv, Kb, KTb, QTb, R0, R1);   // V->R0, VT->R1
  k_att_row<true><<<gAtt, dim3(256), 0, stream>>>(R3, R2, Kb, R0, SI, wq);        // OW->R2
  k_att_col<true><<<gAtt, dim3(256), 0, stream>>>(KTb, QTb, R1, R0, SO);          // OHT->R0
  k_comb<true><<<gTile, dim3(256), 0, stream>>>(R3, R2, R0, SI, SO, gamma, nullptr, XB16); // ->R1

  // bf16 gate weights (K region free now)
  k_wt<<<dim3(112), dim3(256), 0, stream>>>(w_gate, WT16);

  // stage 3: conv_gate via MFMA (G0->R0, G1->R2, G2->R3, X gate -> d_out)
  k_gates<<<dim3(64, D, B), dim3(256), 0, stream>>>(XB16, WT16, R0, R2, R3, out);

  // stage 4: BN + activations + SRU scan
  k_scan<<<dim3(2048), dim3(256), 0, stream>>>(R0, R2, R3, out, bng, bnb, bnm, bnv, out);
}

// Round 14
// 388.684 us; speedup vs baseline: 1.6718x; 1.1935x over previous
//
#include <hip/hip_runtime.h>
#include <math.h>

// Problem constants
namespace {
constexpr int B = 2, C = 16, D = 16, H = 128, W = 128;
constexpr int HW   = H * W;        // 16384
constexpr int DHW  = D * HW;       // 262144
constexpr int CDHW = C * DHW;      // 4194304
constexpr float EPSBN = 1e-5f;

// workspace regions (floats). ws = 37,748,736 floats = 151 MB
constexpr long long OFF_R0  = 0;
constexpr long long OFF_R1  = 8388608;
constexpr long long OFF_K   = 16777216;  // K / WT16 (bf16 gate weights)
constexpr long long OFF_KT  = 17825792;
constexpr long long OFF_QT  = 18874368;
constexpr long long OFF_MST = 19922944;  // s_inner (I,O); 0.5M used
constexpr long long OFF_SO  = 20447232;  // s_outer (I,O); 0.5M used; WP16 early
constexpr long long OFF_R2  = 20971520;
constexpr long long OFF_R3  = 29360128;
}

using frag_ab = __attribute__((ext_vector_type(8))) short;  // 8 bf16
using frag_cd = __attribute__((ext_vector_type(4))) float;  // 4 f32

__device__ __forceinline__ unsigned short f2bf(float f) {
  unsigned u = __float_as_uint(f);
  u = (u + 0x7FFF + ((u >> 16) & 1)) >> 16;   // RNE
  return (unsigned short)u;
}

__device__ __forceinline__ unsigned cvt_pk_bf16(float lo, float hi) {
  unsigned r;
  asm volatile("v_cvt_pk_bf16_f32 %0, %1, %2" : "=v"(r) : "v"(lo), "v"(hi));
  return r;
}

// ---------------------------------------------------------------------------
// K_x16: cast input x (fp32, c-major) -> bf16 [pos][16c]. grid(64, D, B).
// ---------------------------------------------------------------------------
__global__ __launch_bounds__(256) void k_x16(
    const float* __restrict__ x, short* __restrict__ XB0)
{
  const int tid = threadIdx.x;
  const int tile = blockIdx.x, d = blockIdx.y, b = blockIdx.z;
  const int h0 = (tile >> 3) * 16, w0 = (tile & 7) * 16;
  const long long xbase = (long long)b * CDHW + (long long)d * HW;
  const int th = tid >> 4, tw = tid & 15;

  float v[16];
  #pragma unroll
  for (int c = 0; c < 16; ++c)
    v[c] = x[xbase + (long long)c * DHW + (h0 + th) * 128 + (w0 + tw)];

  unsigned pk[8];
  #pragma unroll
  for (int c = 0; c < 8; ++c)
    pk[c] = (unsigned)f2bf(v[2 * c]) | ((unsigned)f2bf(v[2 * c + 1]) << 16);
  short* dst = XB0 + ((long long)(b * D + d) * HW + (h0 + th) * 128 + (w0 + tw)) * 16;
  *(uint4*)(dst)     = make_uint4(pk[0], pk[1], pk[2], pk[3]);
  *(uint4*)(dst + 8) = make_uint4(pk[4], pk[5], pk[6], pk[7]);
}

// ---------------------------------------------------------------------------
// K_wp: pack conv_pre weights -> bf16 WP16[co16][k160].
// ---------------------------------------------------------------------------
__global__ __launch_bounds__(256) void k_wp(
    const float* __restrict__ wp, short* __restrict__ WP16)
{
  const int idx = blockIdx.x * 256 + threadIdx.x;   // < 2560
  if (idx >= 16 * 160) return;
  const int co = idx / 160;
  const int k = idx - co * 160;
  const int tap = k >> 4, cin = k & 15;
  float v = (tap < 9) ? wp[co * 144 + cin * 9 + tap] : 0.f;
  WP16[idx] = (short)f2bf(v);
}

// ---------------------------------------------------------------------------
// K1 v2: conv_pre via MFMA implicit GEMM + BN + ReLU. (round-13, verified)
// ---------------------------------------------------------------------------
__global__ __launch_bounds__(256) void k_conv_pre16(
    const short* __restrict__ XB0, const short* __restrict__ WP16,
    const float* __restrict__ bg, const float* __restrict__ bb,
    const float* __restrict__ bm, const float* __restrict__ bv,
    float* __restrict__ X1)
{
  __shared__ short xls[10 * 132 * 16];   // 42.2 KB
  const int tid = threadIdx.x;
  const int rg = blockIdx.x;
  const int d = blockIdx.y, b = blockIdx.z;
  const int h0 = rg * 8;

  const int lane = tid & 63;
  const int wv   = tid >> 6;
  const int p    = lane & 15;
  const int chunk = lane >> 4;

  const short* xb0 = XB0 + (long long)(b * D + d) * HW * 16;
  const frag_ab zero8 = {0, 0, 0, 0, 0, 0, 0, 0};
  for (int idx = tid; idx < 2640; idx += 256) {
    const int pos = idx >> 1, half = idx & 1;
    const int row = pos / 132, col = pos - row * 132;
    const int gh = h0 - 1 + row, gw = col - 1;
    frag_ab v = zero8;
    if (gh >= 0 && gh < H && gw >= 0 && gw < W)
      v = *(const frag_ab*)(xb0 + ((long long)gh * 128 + gw) * 16 + half * 8);
    *(frag_ab*)&xls[(row * 132 + col) * 16 + half * 8] = v;
  }

  frag_ab a[5];
  {
    const short* wl = WP16 + p * 160 + chunk * 8;
    #pragma unroll
    for (int s = 0; s < 5; ++s)
      a[s] = *(const frag_ab*)(wl + s * 32);
  }

  int offs[5];
  #pragma unroll
  for (int s = 0; s < 5; ++s) {
    int tap = 2 * s + (chunk >> 1);
    if (tap > 8) tap = 0;
    const int kh = tap / 3, kw = tap - kh * 3;
    offs[s] = ((2 * wv + kh) * 132 + p + kw) * 16 + (chunk & 1) * 8;
  }

  frag_cd acc[2][8];
  #pragma unroll
  for (int r2 = 0; r2 < 2; ++r2)
    #pragma unroll
    for (int pg = 0; pg < 8; ++pg)
      acc[r2][pg] = (frag_cd){0.f, 0.f, 0.f, 0.f};

  __syncthreads();

  #pragma unroll
  for (int s = 0; s < 5; ++s) {
    const frag_ab av = a[s];
    const int base0 = offs[s];
    #pragma unroll
    for (int pg = 0; pg < 8; ++pg) {
      frag_ab b0 = *(const frag_ab*)&xls[base0 + pg * 256];
      acc[0][pg] = __builtin_amdgcn_mfma_f32_16x16x32_bf16(av, b0, acc[0][pg], 0, 0, 0);
      frag_ab b1 = *(const frag_ab*)&xls[base0 + 2112 + pg * 256];
      acc[1][pg] = __builtin_amdgcn_mfma_f32_16x16x32_bf16(av, b1, acc[1][pg], 0, 0, 0);
    }
  }

  float sc4[4], bi4[4];
  #pragma unroll
  for (int reg = 0; reg < 4; ++reg) {
    const int co = chunk * 4 + reg;
    float s = bg[co] * rsqrtf(bv[co] + EPSBN);
    sc4[reg] = s;
    bi4[reg] = bb[co] - bm[co] * s;
  }
  const long long xbase = (long long)b * CDHW + (long long)d * HW;
  #pragma unroll
  for (int r2 = 0; r2 < 2; ++r2) {
    const int row = h0 + 2 * wv + r2;
    #pragma unroll
    for (int pg = 0; pg < 8; ++pg)
      #pragma unroll
      for (int reg = 0; reg < 4; ++reg) {
        const int co = chunk * 4 + reg;
        float v = fmaxf(fmaf(acc[r2][pg][reg], sc4[reg], bi4[reg]), 0.f);
        X1[xbase + (long long)co * DHW + row * 128 + pg * 16 + p] = v;
      }
  }
}

// ---------------------------------------------------------------------------
// K2: projections (layout-generic).
// ---------------------------------------------------------------------------
__global__ __launch_bounds__(256) void k_qkv(
    const float* __restrict__ xin, const float* __restrict__ wq,
    const float* __restrict__ wk, const float* __restrict__ wv,
    float* __restrict__ Kp, float* __restrict__ KTp, float* __restrict__ QTp,
    float* __restrict__ Vp, float* __restrict__ VTp)
{
  const int tid = threadIdx.x;
  const int tile = blockIdx.x, d = blockIdx.y, b = blockIdx.z;
  const int h0 = (tile >> 3) * 16, w0 = (tile & 7) * 16;
  const int ty = tid >> 4, tx = tid & 15;
  const int h = h0 + ty, w = w0 + tx;

  const float* xb = xin + (long long)b * CDHW + (long long)d * HW + h * 128 + w;
  float xv[16];
  #pragma unroll
  for (int c = 0; c < 16; ++c) xv[c] = xb[(long long)c * DHW];

  float q0 = 0, q1 = 0, k0 = 0, k1 = 0, v[16];
  #pragma unroll
  for (int c = 0; c < 16; ++c) {
    q0 = fmaf(wq[c], xv[c], q0);
    q1 = fmaf(wq[16 + c], xv[c], q1);
    k0 = fmaf(wk[c], xv[c], k0);
    k1 = fmaf(wk[16 + c], xv[c], k1);
  }
  #pragma unroll
  for (int o = 0; o < 16; ++o) {
    float a = 0;
    #pragma unroll
    for (int c = 0; c < 16; ++c) a = fmaf(wv[o * 16 + c], xv[c], a);
    v[o] = a;
  }

  const int sl = b * 16 + d;
  const long long base2 = (long long)(sl * 2) * HW;
  const long long baseV = (long long)(sl * 16) * HW;
  const int hw = h * 128 + w;
  Kp[base2 + hw] = k0;
  Kp[base2 + HW + hw] = k1;
  #pragma unroll
  for (int o = 0; o < 16; ++o) Vp[baseV + (long long)o * HW + hw] = v[o];

  __shared__ float lsk[2][16][17];
  __shared__ float lsq[2][16][17];
  __shared__ float lsv[16][16][17];
  lsk[0][ty][tx] = k0; lsk[1][ty][tx] = k1;
  lsq[0][ty][tx] = q0; lsq[1][ty][tx] = q1;
  #pragma unroll
  for (int o = 0; o < 16; ++o) lsv[o][ty][tx] = v[o];
  __syncthreads();

  const int wh = (w0 + ty) * 128 + (h0 + tx);
  KTp[base2 + wh]      = lsk[0][tx][ty];
  KTp[base2 + HW + wh] = lsk[1][tx][ty];
  QTp[base2 + wh]      = lsq[0][tx][ty];
  QTp[base2 + HW + wh] = lsq[1][tx][ty];
  #pragma unroll
  for (int o = 0; o < 16; ++o) VTp[baseV + (long long)o * HW + wh] = lsv[o][tx][ty];
}

__device__ __forceinline__ float f4comp(const float4& f, int j) {
  return (j == 0) ? f.x : (j == 1) ? f.y : (j == 2) ? f.z : f.w;
}

// ---------------------------------------------------------------------------
// K3 v6: INNER direction via MFMA. Block 256 = 4 orow-waves; wave handles
// one orow: scores computed per-lane in MFMA A-layout (row=icol=lane&15,
// kchunk=lane>>4), exp f32, packed bf16 (v_cvt_pk_bf16_f32), PV via
// mfma_f32_16x16x32_bf16 against bf16 V slab in LDS.
// Writes OWn POS-MAJOR [pos][16c] f32 and s_inner (I,O layout).
// ---------------------------------------------------------------------------
template<bool MASK_INNER>
__global__ __launch_bounds__(256) void k_att_row(
    const float* __restrict__ xin, float* __restrict__ OWn,
    const float* __restrict__ Kp, const float* __restrict__ Vp,
    float* __restrict__ Sip, const float* __restrict__ wq)
{
  __shared__ float kr2[4][128][2];                  // (kv0,kv1) pairs, 4 KB
  __shared__ float q0l[4][128], q1l[4][128];        // 4 KB
  __shared__ __align__(16) short v16[4][16][136];   // bf16 V, padded, 17.4 KB
  const int tid = threadIdx.x;
  const int o0 = blockIdx.x * 4, d = blockIdx.y, b = blockIdx.z;
  const int sl = b * 16 + d;
  const long long base2 = (long long)(sl * 2) * HW;
  const long long baseV = (long long)(sl * 16) * HW;
  const long long baseM = (long long)sl * HW;
  const int hi = tid >> 6;            // orow index in block (wave-uniform)
  const int L  = tid & 63;
  const int p  = L & 15;              // A row (icol within tile) / B col (c)
  const int chunk = L >> 4;           // k-subchunk
  const int orow = o0 + hi;
  const long long xbase = (long long)b * CDHW + (long long)d * HW;

  // ---- stage K pairs ----
  for (int kk = tid; kk < 1024; kk += 256) {
    int col = kk & 127;
    int t = kk >> 7;
    int r2 = t >> 1, o = t & 1;
    kr2[r2][col][o] = Kp[base2 + (long long)o * HW + (o0 + r2) * 128 + col];
  }
  // ---- stage V as bf16 (B-fragment layout: [orow][c][v]) ----
  for (int idx = tid; idx < 2048; idx += 256) {
    int v4 = idx & 31;
    int t = idx >> 5;
    int c = t & 15, r2 = t >> 4;
    float4 vv = *(const float4*)&Vp[baseV + (long long)c * HW + (o0 + r2) * 128 + v4 * 4];
    unsigned pa = cvt_pk_bf16(vv.x, vv.y);
    unsigned pb = cvt_pk_bf16(vv.z, vv.w);
    *(uint2*)&v16[r2][c][v4 * 4] = make_uint2(pa, pb);
  }
  // ---- build q for this wave's orow (2 icols per lane) ----
  {
    float q0a = 0.f, q0b = 0.f, q1a = 0.f, q1b = 0.f;
    #pragma unroll
    for (int c = 0; c < 16; ++c) {
      const float w0 = wq[c], w1 = wq[16 + c];
      float xa = xin[xbase + (long long)c * DHW + orow * 128 + L];
      float xb2 = xin[xbase + (long long)c * DHW + orow * 128 + L + 64];
      q0a = fmaf(w0, xa, q0a);  q1a = fmaf(w1, xa, q1a);
      q0b = fmaf(w0, xb2, q0b); q1b = fmaf(w1, xb2, q1b);
    }
    q0l[hi][L] = q0a; q0l[hi][L + 64] = q0b;
    q1l[hi][L] = q1a; q1l[hi][L + 64] = q1b;
  }
  __syncthreads();

  // ---- preload q registers for all 8 icol-tiles ----
  float q0r[8], q1r[8];
  #pragma unroll
  for (int ti = 0; ti < 8; ++ti) {
    q0r[ti] = q0l[hi][ti * 16 + p];
    q1r[ti] = q1l[hi][ti * 16 + p];
  }

  frag_cd acc[8];
  #pragma unroll
  for (int ti = 0; ti < 8; ++ti) acc[ti] = (frag_cd){0.f, 0.f, 0.f, 0.f};
  float ssum[8] = {0.f, 0.f, 0.f, 0.f, 0.f, 0.f, 0.f, 0.f};

  #pragma unroll
  for (int ks = 0; ks < 4; ++ks) {
    const int vb = ks * 32 + chunk * 8;       // this lane's v base
    // kv pairs for 8 v (broadcast within chunk group)
    float2 kv[8];
    const float* kvp = &kr2[hi][vb][0];
    *(float4*)&kv[0] = *(const float4*)(kvp);
    *(float4*)&kv[2] = *(const float4*)(kvp + 4);
    *(float4*)&kv[4] = *(const float4*)(kvp + 8);
    *(float4*)&kv[6] = *(const float4*)(kvp + 12);
    // B fragment: V[v][c=p], 8 consecutive v
    frag_ab bfrag = *(const frag_ab*)&v16[hi][p][vb];

    #pragma unroll
    for (int ti = 0; ti < 8; ++ti) {
      float pv[8];
      #pragma unroll
      for (int j = 0; j < 8; ++j) {
        float e = fmaf(q0r[ti], kv[j].x, q1r[ti] * kv[j].y);
        pv[j] = __expf(e);
      }
      if constexpr (MASK_INNER) {
        const int dj = ti * 16 + p - vb;      // mask v == icol
        #pragma unroll
        for (int j = 0; j < 8; ++j)
          if (j == dj) pv[j] = 0.f;
      }
      float lsum = 0.f;
      #pragma unroll
      for (int j = 0; j < 8; ++j) lsum += pv[j];
      ssum[ti] += lsum;

      union { frag_ab f; unsigned u[4]; } cv;
      cv.u[0] = cvt_pk_bf16(pv[0], pv[1]);
      cv.u[1] = cvt_pk_bf16(pv[2], pv[3]);
      cv.u[2] = cvt_pk_bf16(pv[4], pv[5]);
      cv.u[3] = cvt_pk_bf16(pv[6], pv[7]);
      acc[ti] = __builtin_amdgcn_mfma_f32_16x16x32_bf16(cv.f, bfrag, acc[ti], 0, 0, 0);
    }
  }

  // ---- s_inner: combine chunk groups, store from lanes < 16 ----
  #pragma unroll
  for (int ti = 0; ti < 8; ++ti) {
    ssum[ti] += __shfl_xor(ssum[ti], 16);
    ssum[ti] += __shfl_xor(ssum[ti], 32);
  }
  if (L < 16) {
    #pragma unroll
    for (int ti = 0; ti < 8; ++ti)
      Sip[baseM + (ti * 16 + L) * 128 + orow] = ssum[ti];
  }

  // ---- OW store: pos-major [pos][16c]; D row=chunk*4+reg (icol), col=p (c)
  float* ob = OWn + ((long long)(b * D + d) * HW + orow * 128) * 16;
  #pragma unroll
  for (int ti = 0; ti < 8; ++ti)
    #pragma unroll
    for (int reg = 0; reg < 4; ++reg)
      ob[(ti * 16 + chunk * 4 + reg) * 16 + p] = acc[ti][reg];
}

// ---------------------------------------------------------------------------
// K4 v5: OUTER direction, pure producer; VT slab staged in LDS. (unchanged)
// ---------------------------------------------------------------------------
template<bool MASK_INNER>
__global__ __launch_bounds__(256) void k_att_col(
    const float* __restrict__ KTp, const float* __restrict__ QTp,
    const float* __restrict__ VTp, float* __restrict__ OHTp,
    float* __restrict__ Sop)
{
  __shared__ float kc[4][2][128];
  __shared__ __align__(16) float vc[4][16][128];   // 32 KB
  const int tid = threadIdx.x;
  const int i0 = blockIdx.x * 4, d = blockIdx.y, b = blockIdx.z;
  const int sl = b * 16 + d;
  const long long base2 = (long long)(sl * 2) * HW;
  const long long baseV = (long long)(sl * 16) * HW;
  const long long baseS = (long long)sl * HW;
  const int hi = tid >> 6;
  const int L  = tid & 63;
  const int icol = i0 + hi;
  const long long xbase = (long long)b * CDHW + (long long)d * HW;

  for (int kk = tid; kk < 1024; kk += 256) {
    int col = kk & 127;
    int t = kk >> 7;
    int r2 = t >> 1, o = t & 1;
    kc[r2][o][col] = KTp[base2 + (long long)o * HW + (i0 + r2) * 128 + col];
  }
  for (int idx = tid; idx < 2048; idx += 256) {
    int col4 = idx & 31;
    int t = idx >> 5;
    int c = t & 15, r2 = t >> 4;
    *(float4*)&vc[r2][c][col4 * 4] =
        *(const float4*)&VTp[baseV + (long long)c * HW + (i0 + r2) * 128 + col4 * 4];
  }
  __syncthreads();

  const int orr[2] = {L, L + 64};
  float q0[2], q1[2];
  #pragma unroll
  for (int r = 0; r < 2; ++r) {
    q0[r] = QTp[base2 + icol * 128 + orr[r]];
    q1[r] = QTp[base2 + HW + icol * 128 + orr[r]];
  }

  float s[2] = {0.f, 0.f};
  float acc[2][16];
  #pragma unroll
  for (int r = 0; r < 2; ++r)
    #pragma unroll
    for (int c = 0; c < 16; ++c) acc[r][c] = 0.f;

  for (int j4 = 0; j4 < 32; ++j4) {
    float a[2][4];
    #pragma unroll
    for (int jj = 0; jj < 4; ++jj) {
      const int j = j4 * 4 + jj;
      const float k0 = kc[hi][0][j], k1 = kc[hi][1][j];
      #pragma unroll
      for (int r = 0; r < 2; ++r) {
        float e = fmaf(q0[r], k0, q1[r] * k1);
        float aa = __expf(e);
        if (!MASK_INNER && j == orr[r]) aa = 0.f;
        a[r][jj] = aa;
      }
    }
    #pragma unroll
    for (int jj = 0; jj < 4; ++jj) { s[0] += a[0][jj]; s[1] += a[1][jj]; }

    #pragma unroll
    for (int cc = 0; cc < 16; ++cc) {
      const float4 vv = *(const float4*)&vc[hi][cc][j4 * 4];
      #pragma unroll
      for (int jj = 0; jj < 4; ++jj)
        #pragma unroll
        for (int r = 0; r < 2; ++r)
          acc[r][cc] = fmaf(a[r][jj], f4comp(vv, jj), acc[r][cc]);
    }
  }

  #pragma unroll
  for (int r = 0; r < 2; ++r) {
    Sop[baseS + icol * 128 + orr[r]] = s[r];
    #pragma unroll
    for (int c = 0; c < 16; ++c)
      OHTp[xbase + (long long)c * DHW + icol * 128 + orr[r]] = acc[r][c];
  }
}

// ---------------------------------------------------------------------------
// K_comb: res = x + gamma/(s_i+s_o) * (oW + oH), written TRANSPOSED.
// OWn is POS-MAJOR [pos][16c] f32 now.
// ---------------------------------------------------------------------------
template<bool TO_BF16>
__global__ __launch_bounds__(256) void k_comb(
    const float* __restrict__ Xn, const float* __restrict__ OWn,
    const float* __restrict__ OHTp, const float* __restrict__ Sip,
    const float* __restrict__ Sop, const float* __restrict__ gp,
    float* __restrict__ Yt, short* __restrict__ Xb16)
{
  __shared__ float xs[16][16][17], ows[16][16][17];
  const int tid = threadIdx.x;
  const int tile = blockIdx.x, d = blockIdx.y, b = blockIdx.z;
  const int o0 = (tile >> 3) * 16, i0 = (tile & 7) * 16;
  const int sl = b * 16 + d;
  const long long baseM = (long long)sl * HW;
  const long long xbase = (long long)b * CDHW + (long long)d * HW;

  const int to = tid >> 4, ti = tid & 15;
  #pragma unroll
  for (int c = 0; c < 16; ++c) {
    const long long src = xbase + (long long)c * DHW + (o0 + to) * 128 + (i0 + ti);
    xs[c][to][ti] = Xn[src];
  }
  {
    const float* osrc = OWn + ((long long)(b * D + d) * HW + (o0 + to) * 128 + (i0 + ti)) * 16;
    float4 f0 = *(const float4*)(osrc);
    float4 f1 = *(const float4*)(osrc + 4);
    float4 f2 = *(const float4*)(osrc + 8);
    float4 f3 = *(const float4*)(osrc + 12);
    ows[0][to][ti] = f0.x;  ows[1][to][ti] = f0.y;
    ows[2][to][ti] = f0.z;  ows[3][to][ti] = f0.w;
    ows[4][to][ti] = f1.x;  ows[5][to][ti] = f1.y;
    ows[6][to][ti] = f1.z;  ows[7][to][ti] = f1.w;
    ows[8][to][ti] = f2.x;  ows[9][to][ti] = f2.y;
    ows[10][to][ti] = f2.z; ows[11][to][ti] = f2.w;
    ows[12][to][ti] = f3.x; ows[13][to][ti] = f3.y;
    ows[14][to][ti] = f3.z; ows[15][to][ti] = f3.w;
  }
  __syncthreads();

  const int ti2 = tid >> 4, to2 = tid & 15;
  const int i = i0 + ti2, o = o0 + to2;
  const float si = Sip[baseM + i * 128 + o];
  const float so = Sop[baseM + i * 128 + o];
  const float gi = gp[0] / (si + so);

  float res[16];
  #pragma unroll
  for (int c = 0; c < 16; ++c) {
    float oh = OHTp[xbase + (long long)c * DHW + i * 128 + o];
    res[c] = fmaf(gi, ows[c][to2][ti2] + oh, xs[c][to2][ti2]);
  }

  if constexpr (!TO_BF16) {
    #pragma unroll
    for (int c = 0; c < 16; ++c)
      Yt[xbase + (long long)c * DHW + i * 128 + o] = res[c];
  } else {
    unsigned pk[8];
    #pragma unroll
    for (int c = 0; c < 8; ++c)
      pk[c] = (unsigned)f2bf(res[2 * c]) | ((unsigned)f2bf(res[2 * c + 1]) << 16);
    short* dst = Xb16 + ((long long)(b * D + d) * HW + i * 128 + o) * 16;
    *(uint4*)(dst)     = make_uint4(pk[0], pk[1], pk[2], pk[3]);
    *(uint4*)(dst + 8) = make_uint4(pk[4], pk[5], pk[6], pk[7]);
  }
}

// ---------------------------------------------------------------------------
// K_wt: pack gate weights OIDHW -> bf16 WT16[co64][k448], k = tap*16+cin.
// ---------------------------------------------------------------------------
__global__ __launch_bounds__(256) void k_wt(
    const float* __restrict__ wg, short* __restrict__ WT16)
{
  const int idx = blockIdx.x * 256 + threadIdx.x;   // < 28672
  if (idx >= 64 * 448) return;
  const int co_g = idx / 448;
  const int k = idx - co_g * 448;
  const int tap = k >> 4, cin = k & 15;
  float v = (tap < 27) ? wg[co_g * 432 + cin * 27 + tap] : 0.f;
  WT16[idx] = (short)f2bf(v);
}

// ---------------------------------------------------------------------------
// K5a: conv_gate via MFMA implicit GEMM (bf16 in, f32 acc).
// ---------------------------------------------------------------------------
__global__ __launch_bounds__(256, 2) void k_gates(
    const short* __restrict__ XB16, const short* __restrict__ WT16,
    float* __restrict__ g0, float* __restrict__ g1,
    float* __restrict__ g2, float* __restrict__ g3)
{
  __shared__ short xls[2 * 1584 * 8];   // [half][pos=kd*528+rr*132+col][8c]
  const int tid = threadIdx.x;
  const int rp = blockIdx.x;            // 0..63 (2-row group)
  const int d = blockIdx.y, b = blockIdx.z;
  const int h0 = rp * 2;

  const int lane = tid & 63;
  const int og   = tid >> 6;
  const int p    = lane & 15;
  const int chunk = lane >> 4;

  const short* xb = XB16 + (long long)(b * D) * HW * 16;
  const frag_ab zero8 = {0, 0, 0, 0, 0, 0, 0, 0};
  for (int it = 0; it < 13; ++it) {
    const int ci = it * 256 + tid;
    if (ci < 3168) {
      const int pos = ci >> 1, half = ci & 1;
      const int kd = pos / 528;
      const int rem = pos - kd * 528;
      const int rr = rem / 132;
      const int col = rem - rr * 132;
      const int dd = d - 1 + kd, gh = h0 - 1 + rr, gw = col - 1;
      frag_ab v = zero8;
      if (dd >= 0 && dd < D && gh >= 0 && gh < H && gw >= 0 && gw < W)
        v = *(const frag_ab*)(xb + ((long long)dd * HW + gh * W + gw) * 16 + half * 8);
      *(frag_ab*)&xls[half * 12672 + pos * 8] = v;
    }
  }

  frag_ab a[14];
  {
    const short* wl = WT16 + (og * 16 + p) * 448 + chunk * 8;
    #pragma unroll
    for (int s = 0; s < 14; ++s)
      a[s] = *(const frag_ab*)(wl + s * 32);
  }

  const int t0 = chunk >> 1, half = chunk & 1;
  int offs[14];
  #pragma unroll
  for (int s = 0; s < 14; ++s) {
    int tap = 2 * s + t0;
    if (tap > 26) tap = 0;
    const int kd = (tap * 57) >> 9;
    const int rem = tap - kd * 9;
    const int kh = (rem * 11) >> 5;
    const int kw = rem - kh * 3;
    offs[s] = half * 12672 + ((kd * 4 + kh) * 132 + p + kw) * 8;
  }

  frag_cd acc[2][8];
  #pragma unroll
  for (int r2 = 0; r2 < 2; ++r2)
    #pragma unroll
    for (int pg = 0; pg < 8; ++pg)
      acc[r2][pg] = (frag_cd){0.f, 0.f, 0.f, 0.f};

  __syncthreads();

  #pragma unroll
  for (int s = 0; s < 14; ++s) {
    const frag_ab av = a[s];
    const int base0 = offs[s];
    #pragma unroll
    for (int pg = 0; pg < 8; ++pg) {
      frag_ab b0 = *(const frag_ab*)&xls[base0 + pg * 128];
      acc[0][pg] = __builtin_amdgcn_mfma_f32_16x16x32_bf16(av, b0, acc[0][pg], 0, 0, 0);
      frag_ab b1 = *(const frag_ab*)&xls[base0 + 1056 + pg * 128];
      acc[1][pg] = __builtin_amdgcn_mfma_f32_16x16x32_bf16(av, b1, acc[1][pg], 0, 0, 0);
    }
  }

  float* gbuf = (og == 0) ? g0 : (og == 1) ? g1 : (og == 2) ? g2 : g3;
  const long long base = (long long)b * CDHW + (long long)d * HW + h0 * W;
  #pragma unroll
  for (int r2 = 0; r2 < 2; ++r2)
    #pragma unroll
    for (int pg = 0; pg < 8; ++pg)
      #pragma unroll
      for (int reg = 0; reg < 4; ++reg) {
        const int cc = chunk * 4 + reg;
        gbuf[base + (long long)cc * DHW + r2 * W + pg * 16 + p] = acc[r2][pg][reg];
      }
}

// ---------------------------------------------------------------------------
// K5b: BN + activations + SRU scan over D. One thread per (b,c,h,w).
// ---------------------------------------------------------------------------
__global__ __launch_bounds__(256) void k_scan(
    const float* __restrict__ g0, const float* __restrict__ g1,
    const float* __restrict__ g2, const float* __restrict__ g3,
    const float* __restrict__ bg, const float* __restrict__ bb,
    const float* __restrict__ bm, const float* __restrict__ bv,
    float* __restrict__ out)
{
  const int g = blockIdx.x * 256 + threadIdx.x;   // 0 .. 524287
  const int hw = g & 16383;
  const int cc = (g >> 14) & 15;
  const int b  = g >> 18;

  float sc[4], bi[4];
  #pragma unroll
  for (int gg = 0; gg < 4; ++gg) {
    int ch = gg * 16 + cc;
    float s = bg[ch] * rsqrtf(bv[ch] + EPSBN);
    sc[gg] = s;
    bi[gg] = bb[ch] - bm[ch] * s;
  }

  const long long base = (long long)b * CDHW + (long long)cc * DHW + hw;
  float Ct = 0.f;
  for (int d = 0; d < D; ++d) {
    const long long idx = base + (long long)d * HW;
    float wx = tanhf(fmaf(g0[idx], sc[0], bi[0]));
    float ft = 1.f / (1.f + __expf(-fmaf(g1[idx], sc[1], bi[1])));
    float rt = 1.f / (1.f + __expf(-fmaf(g2[idx], sc[2], bi[2])));
    float xg = tanhf(fmaf(g3[idx], sc[3], bi[3]));
    Ct = (d == 0) ? (1.f - ft) : fmaf(ft, Ct, (1.f - ft) * wx);
    out[idx] = fmaf(rt, Ct, (1.f - rt) * xg);
  }
}

// ---------------------------------------------------------------------------
extern "C" void kernel_launch(void* const* d_in, const int* in_sizes, int n_in,
                              void* d_out, int out_size, void* d_ws, size_t ws_size,
                              hipStream_t stream) {
  const float* x      = (const float*)d_in[0];
  const float* w_pre  = (const float*)d_in[1];
  const float* bnpg   = (const float*)d_in[2];
  const float* bnpb   = (const float*)d_in[3];
  const float* bnpm   = (const float*)d_in[4];
  const float* bnpv   = (const float*)d_in[5];
  const float* wq     = (const float*)d_in[6];
  const float* wk     = (const float*)d_in[7];
  const float* wv     = (const float*)d_in[8];
  const float* gamma  = (const float*)d_in[9];
  const float* w_gate = (const float*)d_in[10];
  const float* bng    = (const float*)d_in[11];
  const float* bnb    = (const float*)d_in[12];
  const float* bnm    = (const float*)d_in[13];
  const float* bnv    = (const float*)d_in[14];

  float* ws  = (float*)d_ws;
  float* R0  = ws + OFF_R0;
  float* R1  = ws + OFF_R1;
  float* Kb  = ws + OFF_K;
  float* KTb = ws + OFF_KT;
  float* QTb = ws + OFF_QT;
  float* SI  = ws + OFF_MST;
  float* SO  = ws + OFF_SO;
  float* R2  = ws + OFF_R2;
  float* R3  = ws + OFF_R3;
  short* XB0  = (short*)(ws + OFF_R1);  // bf16 input (pre-attention phase)
  short* XB16 = (short*)(ws + OFF_R1);  // bf16 attn output (post-attention)
  short* WP16 = (short*)(ws + OFF_SO);  // bf16 conv_pre weights (early phase)
  short* WT16 = (short*)(ws + OFF_K);   // bf16 gate weights
  float* out = (float*)d_out;

  const dim3 gTile(64, D, B), gAtt(32, D, B);

  // stage 1: conv_pre via MFMA: x -> bf16 pos-major -> X1 (fp32) in R0
  k_wp <<<dim3(10),  dim3(256), 0, stream>>>(w_pre, WP16);
  k_x16<<<gTile,     dim3(256), 0, stream>>>(x, XB0);
  k_conv_pre16<<<dim3(16, D, B), dim3(256), 0, stream>>>(
      XB0, WP16, bnpg, bnpb, bnpm, bnpv, R0);

  // attention application 1 (mask on outer): x=R0, V->R2, VT->R3
  k_qkv<<<gTile, dim3(256), 0, stream>>>(R0, wq, wk, wv, Kb, KTb, QTb, R2, R3);
  k_att_row<false><<<gAtt, dim3(256), 0, stream>>>(R0, R1, Kb, R2, SI, wq);       // OWn->R1
  k_att_col<false><<<gAtt, dim3(256), 0, stream>>>(KTb, QTb, R3, R2, SO);         // OHT->R2
  k_comb<false><<<gTile, dim3(256), 0, stream>>>(R0, R1, R2, SI, SO, gamma, R3, nullptr); // Y->R3

  // attention application 2 (transposed layout; mask on inner): x=R3
  k_qkv<<<gTile, dim3(256), 0, stream>>>(R3, wq, wk, wv, Kb, KTb, QTb, R0, R1);   // V->R0, VT->R1
  k_att_row<true><<<gAtt, dim3(256), 0, stream>>>(R3, R2, Kb, R0, SI, wq);        // OWn->R2
  k_att_col<true><<<gAtt, dim3(256), 0, stream>>>(KTb, QTb, R1, R0, SO);          // OHT->R0
  k_comb<true><<<gTile, dim3(256), 0, stream>>>(R3, R2, R0, SI, SO, gamma, nullptr, XB16); // ->R1

  // bf16 gate weights (K region free now)
  k_wt<<<dim3(112), dim3(256), 0, stream>>>(w_gate, WT16);

  // stage 3: conv_gate via MFMA (G0->R0, G1->R2, G2->R3, X gate -> d_out)
  k_gates<<<dim3(64, D, B), dim3(256), 0, stream>>>(XB16, WT16, R0, R2, R3, out);

  // stage 4: BN + activations + SRU scan
  k_scan<<<dim3(2048), dim3(256), 0, stream>>>(R0, R2, R3, out, bng, bnb, bnm, bnv, out);
}

// Round 15
// 320.874 us; speedup vs baseline: 2.0251x; 1.2113x over previous
//
#include <hip/hip_runtime.h>
#include <math.h>

// Problem constants
namespace {
constexpr int B = 2, C = 16, D = 16, H = 128, W = 128;
constexpr int HW   = H * W;        // 16384
constexpr int DHW  = D * HW;       // 262144
constexpr int CDHW = C * DHW;      // 4194304
constexpr float EPSBN = 1e-5f;

// workspace regions (floats). ws = 37,748,736 floats = 151 MB
constexpr long long OFF_R0  = 0;
constexpr long long OFF_R1  = 8388608;
constexpr long long OFF_K   = 16777216;  // K / WT16 (bf16 gate weights)
constexpr long long OFF_KT  = 17825792;
constexpr long long OFF_QT  = 18874368;
constexpr long long OFF_MST = 19922944;  // s_inner (I,O); 0.5M used
constexpr long long OFF_SO  = 20447232;  // s_outer (I,O); 0.5M used; WP16 early
constexpr long long OFF_R2  = 20971520;
constexpr long long OFF_R3  = 29360128;
}

using frag_ab = __attribute__((ext_vector_type(8))) short;  // 8 bf16
using frag_cd = __attribute__((ext_vector_type(4))) float;  // 4 f32

__device__ __forceinline__ unsigned short f2bf(float f) {
  unsigned u = __float_as_uint(f);
  u = (u + 0x7FFF + ((u >> 16) & 1)) >> 16;   // RNE
  return (unsigned short)u;
}

__device__ __forceinline__ unsigned cvt_pk_bf16(float lo, float hi) {
  unsigned r;
  asm volatile("v_cvt_pk_bf16_f32 %0, %1, %2" : "=v"(r) : "v"(lo), "v"(hi));
  return r;
}

// ---------------------------------------------------------------------------
// K_x16: cast input x (fp32, c-major) -> bf16 [pos][16c]. grid(64, D, B).
// ---------------------------------------------------------------------------
__global__ __launch_bounds__(256) void k_x16(
    const float* __restrict__ x, short* __restrict__ XB0)
{
  const int tid = threadIdx.x;
  const int tile = blockIdx.x, d = blockIdx.y, b = blockIdx.z;
  const int h0 = (tile >> 3) * 16, w0 = (tile & 7) * 16;
  const long long xbase = (long long)b * CDHW + (long long)d * HW;
  const int th = tid >> 4, tw = tid & 15;

  float v[16];
  #pragma unroll
  for (int c = 0; c < 16; ++c)
    v[c] = x[xbase + (long long)c * DHW + (h0 + th) * 128 + (w0 + tw)];

  unsigned pk[8];
  #pragma unroll
  for (int c = 0; c < 8; ++c)
    pk[c] = (unsigned)f2bf(v[2 * c]) | ((unsigned)f2bf(v[2 * c + 1]) << 16);
  short* dst = XB0 + ((long long)(b * D + d) * HW + (h0 + th) * 128 + (w0 + tw)) * 16;
  *(uint4*)(dst)     = make_uint4(pk[0], pk[1], pk[2], pk[3]);
  *(uint4*)(dst + 8) = make_uint4(pk[4], pk[5], pk[6], pk[7]);
}

// ---------------------------------------------------------------------------
// K_wp: pack conv_pre weights -> bf16 WP16[co16][k160].
// ---------------------------------------------------------------------------
__global__ __launch_bounds__(256) void k_wp(
    const float* __restrict__ wp, short* __restrict__ WP16)
{
  const int idx = blockIdx.x * 256 + threadIdx.x;   // < 2560
  if (idx >= 16 * 160) return;
  const int co = idx / 160;
  const int k = idx - co * 160;
  const int tap = k >> 4, cin = k & 15;
  float v = (tap < 9) ? wp[co * 144 + cin * 9 + tap] : 0.f;
  WP16[idx] = (short)f2bf(v);
}

// ---------------------------------------------------------------------------
// K1 v2: conv_pre via MFMA implicit GEMM + BN + ReLU. (round-13, verified)
// ---------------------------------------------------------------------------
__global__ __launch_bounds__(256) void k_conv_pre16(
    const short* __restrict__ XB0, const short* __restrict__ WP16,
    const float* __restrict__ bg, const float* __restrict__ bb,
    const float* __restrict__ bm, const float* __restrict__ bv,
    float* __restrict__ X1)
{
  __shared__ short xls[10 * 132 * 16];   // 42.2 KB
  const int tid = threadIdx.x;
  const int rg = blockIdx.x;
  const int d = blockIdx.y, b = blockIdx.z;
  const int h0 = rg * 8;

  const int lane = tid & 63;
  const int wv   = tid >> 6;
  const int p    = lane & 15;
  const int chunk = lane >> 4;

  const short* xb0 = XB0 + (long long)(b * D + d) * HW * 16;
  const frag_ab zero8 = {0, 0, 0, 0, 0, 0, 0, 0};
  for (int idx = tid; idx < 2640; idx += 256) {
    const int pos = idx >> 1, half = idx & 1;
    const int row = pos / 132, col = pos - row * 132;
    const int gh = h0 - 1 + row, gw = col - 1;
    frag_ab v = zero8;
    if (gh >= 0 && gh < H && gw >= 0 && gw < W)
      v = *(const frag_ab*)(xb0 + ((long long)gh * 128 + gw) * 16 + half * 8);
    *(frag_ab*)&xls[(row * 132 + col) * 16 + half * 8] = v;
  }

  frag_ab a[5];
  {
    const short* wl = WP16 + p * 160 + chunk * 8;
    #pragma unroll
    for (int s = 0; s < 5; ++s)
      a[s] = *(const frag_ab*)(wl + s * 32);
  }

  int offs[5];
  #pragma unroll
  for (int s = 0; s < 5; ++s) {
    int tap = 2 * s + (chunk >> 1);
    if (tap > 8) tap = 0;
    const int kh = tap / 3, kw = tap - kh * 3;
    offs[s] = ((2 * wv + kh) * 132 + p + kw) * 16 + (chunk & 1) * 8;
  }

  frag_cd acc[2][8];
  #pragma unroll
  for (int r2 = 0; r2 < 2; ++r2)
    #pragma unroll
    for (int pg = 0; pg < 8; ++pg)
      acc[r2][pg] = (frag_cd){0.f, 0.f, 0.f, 0.f};

  __syncthreads();

  #pragma unroll
  for (int s = 0; s < 5; ++s) {
    const frag_ab av = a[s];
    const int base0 = offs[s];
    #pragma unroll
    for (int pg = 0; pg < 8; ++pg) {
      frag_ab b0 = *(const frag_ab*)&xls[base0 + pg * 256];
      acc[0][pg] = __builtin_amdgcn_mfma_f32_16x16x32_bf16(av, b0, acc[0][pg], 0, 0, 0);
      frag_ab b1 = *(const frag_ab*)&xls[base0 + 2112 + pg * 256];
      acc[1][pg] = __builtin_amdgcn_mfma_f32_16x16x32_bf16(av, b1, acc[1][pg], 0, 0, 0);
    }
  }

  float sc4[4], bi4[4];
  #pragma unroll
  for (int reg = 0; reg < 4; ++reg) {
    const int co = chunk * 4 + reg;
    float s = bg[co] * rsqrtf(bv[co] + EPSBN);
    sc4[reg] = s;
    bi4[reg] = bb[co] - bm[co] * s;
  }
  const long long xbase = (long long)b * CDHW + (long long)d * HW;
  #pragma unroll
  for (int r2 = 0; r2 < 2; ++r2) {
    const int row = h0 + 2 * wv + r2;
    #pragma unroll
    for (int pg = 0; pg < 8; ++pg)
      #pragma unroll
      for (int reg = 0; reg < 4; ++reg) {
        const int co = chunk * 4 + reg;
        float v = fmaxf(fmaf(acc[r2][pg][reg], sc4[reg], bi4[reg]), 0.f);
        X1[xbase + (long long)co * DHW + row * 128 + pg * 16 + p] = v;
      }
  }
}

// ---------------------------------------------------------------------------
// K2: projections (layout-generic).
// ---------------------------------------------------------------------------
__global__ __launch_bounds__(256) void k_qkv(
    const float* __restrict__ xin, const float* __restrict__ wq,
    const float* __restrict__ wk, const float* __restrict__ wv,
    float* __restrict__ Kp, float* __restrict__ KTp, float* __restrict__ QTp,
    float* __restrict__ Vp, float* __restrict__ VTp)
{
  const int tid = threadIdx.x;
  const int tile = blockIdx.x, d = blockIdx.y, b = blockIdx.z;
  const int h0 = (tile >> 3) * 16, w0 = (tile & 7) * 16;
  const int ty = tid >> 4, tx = tid & 15;
  const int h = h0 + ty, w = w0 + tx;

  const float* xb = xin + (long long)b * CDHW + (long long)d * HW + h * 128 + w;
  float xv[16];
  #pragma unroll
  for (int c = 0; c < 16; ++c) xv[c] = xb[(long long)c * DHW];

  float q0 = 0, q1 = 0, k0 = 0, k1 = 0, v[16];
  #pragma unroll
  for (int c = 0; c < 16; ++c) {
    q0 = fmaf(wq[c], xv[c], q0);
    q1 = fmaf(wq[16 + c], xv[c], q1);
    k0 = fmaf(wk[c], xv[c], k0);
    k1 = fmaf(wk[16 + c], xv[c], k1);
  }
  #pragma unroll
  for (int o = 0; o < 16; ++o) {
    float a = 0;
    #pragma unroll
    for (int c = 0; c < 16; ++c) a = fmaf(wv[o * 16 + c], xv[c], a);
    v[o] = a;
  }

  const int sl = b * 16 + d;
  const long long base2 = (long long)(sl * 2) * HW;
  const long long baseV = (long long)(sl * 16) * HW;
  const int hw = h * 128 + w;
  Kp[base2 + hw] = k0;
  Kp[base2 + HW + hw] = k1;
  #pragma unroll
  for (int o = 0; o < 16; ++o) Vp[baseV + (long long)o * HW + hw] = v[o];

  __shared__ float lsk[2][16][17];
  __shared__ float lsq[2][16][17];
  __shared__ float lsv[16][16][17];
  lsk[0][ty][tx] = k0; lsk[1][ty][tx] = k1;
  lsq[0][ty][tx] = q0; lsq[1][ty][tx] = q1;
  #pragma unroll
  for (int o = 0; o < 16; ++o) lsv[o][ty][tx] = v[o];
  __syncthreads();

  const int wh = (w0 + ty) * 128 + (h0 + tx);
  KTp[base2 + wh]      = lsk[0][tx][ty];
  KTp[base2 + HW + wh] = lsk[1][tx][ty];
  QTp[base2 + wh]      = lsq[0][tx][ty];
  QTp[base2 + HW + wh] = lsq[1][tx][ty];
  #pragma unroll
  for (int o = 0; o < 16; ++o) VTp[baseV + (long long)o * HW + wh] = lsv[o][tx][ty];
}

// ---------------------------------------------------------------------------
// K3 v6: INNER direction via MFMA. (round-14, verified)
// Writes OWn POS-MAJOR [orow*128+icol][16c] f32 and s_inner (I,O layout).
// ---------------------------------------------------------------------------
template<bool MASK_INNER>
__global__ __launch_bounds__(256) void k_att_row(
    const float* __restrict__ xin, float* __restrict__ OWn,
    const float* __restrict__ Kp, const float* __restrict__ Vp,
    float* __restrict__ Sip, const float* __restrict__ wq)
{
  __shared__ float kr2[4][128][2];
  __shared__ float q0l[4][128], q1l[4][128];
  __shared__ __align__(16) short v16[4][16][136];
  const int tid = threadIdx.x;
  const int o0 = blockIdx.x * 4, d = blockIdx.y, b = blockIdx.z;
  const int sl = b * 16 + d;
  const long long base2 = (long long)(sl * 2) * HW;
  const long long baseV = (long long)(sl * 16) * HW;
  const long long baseM = (long long)sl * HW;
  const int hi = tid >> 6;
  const int L  = tid & 63;
  const int p  = L & 15;
  const int chunk = L >> 4;
  const int orow = o0 + hi;
  const long long xbase = (long long)b * CDHW + (long long)d * HW;

  for (int kk = tid; kk < 1024; kk += 256) {
    int col = kk & 127;
    int t = kk >> 7;
    int r2 = t >> 1, o = t & 1;
    kr2[r2][col][o] = Kp[base2 + (long long)o * HW + (o0 + r2) * 128 + col];
  }
  for (int idx = tid; idx < 2048; idx += 256) {
    int v4 = idx & 31;
    int t = idx >> 5;
    int c = t & 15, r2 = t >> 4;
    float4 vv = *(const float4*)&Vp[baseV + (long long)c * HW + (o0 + r2) * 128 + v4 * 4];
    unsigned pa = cvt_pk_bf16(vv.x, vv.y);
    unsigned pb = cvt_pk_bf16(vv.z, vv.w);
    *(uint2*)&v16[r2][c][v4 * 4] = make_uint2(pa, pb);
  }
  {
    float q0a = 0.f, q0b = 0.f, q1a = 0.f, q1b = 0.f;
    #pragma unroll
    for (int c = 0; c < 16; ++c) {
      const float w0 = wq[c], w1 = wq[16 + c];
      float xa = xin[xbase + (long long)c * DHW + orow * 128 + L];
      float xb2 = xin[xbase + (long long)c * DHW + orow * 128 + L + 64];
      q0a = fmaf(w0, xa, q0a);  q1a = fmaf(w1, xa, q1a);
      q0b = fmaf(w0, xb2, q0b); q1b = fmaf(w1, xb2, q1b);
    }
    q0l[hi][L] = q0a; q0l[hi][L + 64] = q0b;
    q1l[hi][L] = q1a; q1l[hi][L + 64] = q1b;
  }
  __syncthreads();

  float q0r[8], q1r[8];
  #pragma unroll
  for (int ti = 0; ti < 8; ++ti) {
    q0r[ti] = q0l[hi][ti * 16 + p];
    q1r[ti] = q1l[hi][ti * 16 + p];
  }

  frag_cd acc[8];
  #pragma unroll
  for (int ti = 0; ti < 8; ++ti) acc[ti] = (frag_cd){0.f, 0.f, 0.f, 0.f};
  float ssum[8] = {0.f, 0.f, 0.f, 0.f, 0.f, 0.f, 0.f, 0.f};

  #pragma unroll
  for (int ks = 0; ks < 4; ++ks) {
    const int vb = ks * 32 + chunk * 8;
    float2 kv[8];
    const float* kvp = &kr2[hi][vb][0];
    *(float4*)&kv[0] = *(const float4*)(kvp);
    *(float4*)&kv[2] = *(const float4*)(kvp + 4);
    *(float4*)&kv[4] = *(const float4*)(kvp + 8);
    *(float4*)&kv[6] = *(const float4*)(kvp + 12);
    frag_ab bfrag = *(const frag_ab*)&v16[hi][p][vb];

    #pragma unroll
    for (int ti = 0; ti < 8; ++ti) {
      float pv[8];
      #pragma unroll
      for (int j = 0; j < 8; ++j) {
        float e = fmaf(q0r[ti], kv[j].x, q1r[ti] * kv[j].y);
        pv[j] = __expf(e);
      }
      if constexpr (MASK_INNER) {
        const int dj = ti * 16 + p - vb;
        #pragma unroll
        for (int j = 0; j < 8; ++j)
          if (j == dj) pv[j] = 0.f;
      }
      float lsum = 0.f;
      #pragma unroll
      for (int j = 0; j < 8; ++j) lsum += pv[j];
      ssum[ti] += lsum;

      union { frag_ab f; unsigned u[4]; } cv;
      cv.u[0] = cvt_pk_bf16(pv[0], pv[1]);
      cv.u[1] = cvt_pk_bf16(pv[2], pv[3]);
      cv.u[2] = cvt_pk_bf16(pv[4], pv[5]);
      cv.u[3] = cvt_pk_bf16(pv[6], pv[7]);
      acc[ti] = __builtin_amdgcn_mfma_f32_16x16x32_bf16(cv.f, bfrag, acc[ti], 0, 0, 0);
    }
  }

  #pragma unroll
  for (int ti = 0; ti < 8; ++ti) {
    ssum[ti] += __shfl_xor(ssum[ti], 16);
    ssum[ti] += __shfl_xor(ssum[ti], 32);
  }
  if (L < 16) {
    #pragma unroll
    for (int ti = 0; ti < 8; ++ti)
      Sip[baseM + (ti * 16 + L) * 128 + orow] = ssum[ti];
  }

  float* ob = OWn + ((long long)(b * D + d) * HW + orow * 128) * 16;
  #pragma unroll
  for (int ti = 0; ti < 8; ++ti)
    #pragma unroll
    for (int reg = 0; reg < 4; ++reg)
      ob[(ti * 16 + chunk * 4 + reg) * 16 + p] = acc[ti][reg];
}

// ---------------------------------------------------------------------------
// K4 v6: OUTER direction via MFMA (clone of att_row v6 under orow<->icol).
// Wave = one icol; scores over outer j in A-layout; VT slab bf16 B-frags.
// Writes OHn POS-MAJOR [icol*128+orr][16c] f32 (matches k_comb output
// indexing (i*128+o)) and s_outer [icol*128+orr].
// MASK_INNER=false (app1): mask j==orr. true (app2): no outer mask.
// ---------------------------------------------------------------------------
template<bool MASK_INNER>
__global__ __launch_bounds__(256) void k_att_col(
    const float* __restrict__ KTp, const float* __restrict__ QTp,
    const float* __restrict__ VTp, float* __restrict__ OHn,
    float* __restrict__ Sop)
{
  __shared__ float kr2[4][128][2];
  __shared__ __align__(16) short v16[4][16][136];
  const int tid = threadIdx.x;
  const int i0 = blockIdx.x * 4, d = blockIdx.y, b = blockIdx.z;
  const int sl = b * 16 + d;
  const long long base2 = (long long)(sl * 2) * HW;
  const long long baseV = (long long)(sl * 16) * HW;
  const long long baseS = (long long)sl * HW;
  const int hi = tid >> 6;            // icol index in block (wave-uniform)
  const int L  = tid & 63;
  const int p  = L & 15;              // A row (orr within tile) / B col (c)
  const int chunk = L >> 4;
  const int icol = i0 + hi;

  for (int kk = tid; kk < 1024; kk += 256) {
    int col = kk & 127;
    int t = kk >> 7;
    int r2 = t >> 1, o = t & 1;
    kr2[r2][col][o] = KTp[base2 + (long long)o * HW + (i0 + r2) * 128 + col];
  }
  for (int idx = tid; idx < 2048; idx += 256) {
    int j4 = idx & 31;
    int t = idx >> 5;
    int c = t & 15, r2 = t >> 4;
    float4 vv = *(const float4*)&VTp[baseV + (long long)c * HW + (i0 + r2) * 128 + j4 * 4];
    unsigned pa = cvt_pk_bf16(vv.x, vv.y);
    unsigned pb = cvt_pk_bf16(vv.z, vv.w);
    *(uint2*)&v16[r2][c][j4 * 4] = make_uint2(pa, pb);
  }
  __syncthreads();

  // q per orr (direct from QT: [icol*128 + orr])
  float q0r[8], q1r[8];
  #pragma unroll
  for (int ti = 0; ti < 8; ++ti) {
    q0r[ti] = QTp[base2 + icol * 128 + ti * 16 + p];
    q1r[ti] = QTp[base2 + HW + icol * 128 + ti * 16 + p];
  }

  frag_cd acc[8];
  #pragma unroll
  for (int ti = 0; ti < 8; ++ti) acc[ti] = (frag_cd){0.f, 0.f, 0.f, 0.f};
  float ssum[8] = {0.f, 0.f, 0.f, 0.f, 0.f, 0.f, 0.f, 0.f};

  #pragma unroll
  for (int ks = 0; ks < 4; ++ks) {
    const int vb = ks * 32 + chunk * 8;
    float2 kv[8];
    const float* kvp = &kr2[hi][vb][0];
    *(float4*)&kv[0] = *(const float4*)(kvp);
    *(float4*)&kv[2] = *(const float4*)(kvp + 4);
    *(float4*)&kv[4] = *(const float4*)(kvp + 8);
    *(float4*)&kv[6] = *(const float4*)(kvp + 12);
    frag_ab bfrag = *(const frag_ab*)&v16[hi][p][vb];

    #pragma unroll
    for (int ti = 0; ti < 8; ++ti) {
      float pv[8];
      #pragma unroll
      for (int j = 0; j < 8; ++j) {
        float e = fmaf(q0r[ti], kv[j].x, q1r[ti] * kv[j].y);
        pv[j] = __expf(e);
      }
      if constexpr (!MASK_INNER) {
        const int dj = ti * 16 + p - vb;    // mask j == orr
        #pragma unroll
        for (int j = 0; j < 8; ++j)
          if (j == dj) pv[j] = 0.f;
      }
      float lsum = 0.f;
      #pragma unroll
      for (int j = 0; j < 8; ++j) lsum += pv[j];
      ssum[ti] += lsum;

      union { frag_ab f; unsigned u[4]; } cv;
      cv.u[0] = cvt_pk_bf16(pv[0], pv[1]);
      cv.u[1] = cvt_pk_bf16(pv[2], pv[3]);
      cv.u[2] = cvt_pk_bf16(pv[4], pv[5]);
      cv.u[3] = cvt_pk_bf16(pv[6], pv[7]);
      acc[ti] = __builtin_amdgcn_mfma_f32_16x16x32_bf16(cv.f, bfrag, acc[ti], 0, 0, 0);
    }
  }

  #pragma unroll
  for (int ti = 0; ti < 8; ++ti) {
    ssum[ti] += __shfl_xor(ssum[ti], 16);
    ssum[ti] += __shfl_xor(ssum[ti], 32);
  }
  if (L < 16) {
    #pragma unroll
    for (int ti = 0; ti < 8; ++ti)
      Sop[baseS + icol * 128 + ti * 16 + L] = ssum[ti];
  }

  float* ob = OHn + ((long long)(b * D + d) * HW + icol * 128) * 16;
  #pragma unroll
  for (int ti = 0; ti < 8; ++ti)
    #pragma unroll
    for (int reg = 0; reg < 4; ++reg)
      ob[(ti * 16 + chunk * 4 + reg) * 16 + p] = acc[ti][reg];
}

// ---------------------------------------------------------------------------
// K_comb: res = x + gamma/(s_i+s_o) * (oW + oH), written TRANSPOSED.
// OWn pos-major [o*128+i][16c]; OHn pos-major [i*128+o][16c] (direct read).
// ---------------------------------------------------------------------------
template<bool TO_BF16>
__global__ __launch_bounds__(256) void k_comb(
    const float* __restrict__ Xn, const float* __restrict__ OWn,
    const float* __restrict__ OHn, const float* __restrict__ Sip,
    const float* __restrict__ Sop, const float* __restrict__ gp,
    float* __restrict__ Yt, short* __restrict__ Xb16)
{
  __shared__ float xs[16][16][17], ows[16][16][17];
  const int tid = threadIdx.x;
  const int tile = blockIdx.x, d = blockIdx.y, b = blockIdx.z;
  const int o0 = (tile >> 3) * 16, i0 = (tile & 7) * 16;
  const int sl = b * 16 + d;
  const long long baseM = (long long)sl * HW;
  const long long xbase = (long long)b * CDHW + (long long)d * HW;

  const int to = tid >> 4, ti = tid & 15;
  #pragma unroll
  for (int c = 0; c < 16; ++c) {
    const long long src = xbase + (long long)c * DHW + (o0 + to) * 128 + (i0 + ti);
    xs[c][to][ti] = Xn[src];
  }
  {
    const float* osrc = OWn + ((long long)(b * D + d) * HW + (o0 + to) * 128 + (i0 + ti)) * 16;
    float4 f0 = *(const float4*)(osrc);
    float4 f1 = *(const float4*)(osrc + 4);
    float4 f2 = *(const float4*)(osrc + 8);
    float4 f3 = *(const float4*)(osrc + 12);
    ows[0][to][ti] = f0.x;  ows[1][to][ti] = f0.y;
    ows[2][to][ti] = f0.z;  ows[3][to][ti] = f0.w;
    ows[4][to][ti] = f1.x;  ows[5][to][ti] = f1.y;
    ows[6][to][ti] = f1.z;  ows[7][to][ti] = f1.w;
    ows[8][to][ti] = f2.x;  ows[9][to][ti] = f2.y;
    ows[10][to][ti] = f2.z; ows[11][to][ti] = f2.w;
    ows[12][to][ti] = f3.x; ows[13][to][ti] = f3.y;
    ows[14][to][ti] = f3.z; ows[15][to][ti] = f3.w;
  }
  __syncthreads();

  const int ti2 = tid >> 4, to2 = tid & 15;
  const int i = i0 + ti2, o = o0 + to2;
  const float si = Sip[baseM + i * 128 + o];
  const float so = Sop[baseM + i * 128 + o];
  const float gi = gp[0] / (si + so);

  float oh[16];
  {
    const float* osrc = OHn + ((long long)(b * D + d) * HW + i * 128 + o) * 16;
    float4 f0 = *(const float4*)(osrc);
    float4 f1 = *(const float4*)(osrc + 4);
    float4 f2 = *(const float4*)(osrc + 8);
    float4 f3 = *(const float4*)(osrc + 12);
    oh[0] = f0.x;  oh[1] = f0.y;  oh[2] = f0.z;  oh[3] = f0.w;
    oh[4] = f1.x;  oh[5] = f1.y;  oh[6] = f1.z;  oh[7] = f1.w;
    oh[8] = f2.x;  oh[9] = f2.y;  oh[10] = f2.z; oh[11] = f2.w;
    oh[12] = f3.x; oh[13] = f3.y; oh[14] = f3.z; oh[15] = f3.w;
  }

  float res[16];
  #pragma unroll
  for (int c = 0; c < 16; ++c)
    res[c] = fmaf(gi, ows[c][to2][ti2] + oh[c], xs[c][to2][ti2]);

  if constexpr (!TO_BF16) {
    #pragma unroll
    for (int c = 0; c < 16; ++c)
      Yt[xbase + (long long)c * DHW + i * 128 + o] = res[c];
  } else {
    unsigned pk[8];
    #pragma unroll
    for (int c = 0; c < 8; ++c)
      pk[c] = (unsigned)f2bf(res[2 * c]) | ((unsigned)f2bf(res[2 * c + 1]) << 16);
    short* dst = Xb16 + ((long long)(b * D + d) * HW + i * 128 + o) * 16;
    *(uint4*)(dst)     = make_uint4(pk[0], pk[1], pk[2], pk[3]);
    *(uint4*)(dst + 8) = make_uint4(pk[4], pk[5], pk[6], pk[7]);
  }
}

// ---------------------------------------------------------------------------
// K_wt: pack gate weights OIDHW -> bf16 WT16[co64][k448], k = tap*16+cin.
// ---------------------------------------------------------------------------
__global__ __launch_bounds__(256) void k_wt(
    const float* __restrict__ wg, short* __restrict__ WT16)
{
  const int idx = blockIdx.x * 256 + threadIdx.x;   // < 28672
  if (idx >= 64 * 448) return;
  const int co_g = idx / 448;
  const int k = idx - co_g * 448;
  const int tap = k >> 4, cin = k & 15;
  float v = (tap < 27) ? wg[co_g * 432 + cin * 27 + tap] : 0.f;
  WT16[idx] = (short)f2bf(v);
}

// ---------------------------------------------------------------------------
// K5a: conv_gate via MFMA implicit GEMM (bf16 in, f32 acc).
// ---------------------------------------------------------------------------
__global__ __launch_bounds__(256, 2) void k_gates(
    const short* __restrict__ XB16, const short* __restrict__ WT16,
    float* __restrict__ g0, float* __restrict__ g1,
    float* __restrict__ g2, float* __restrict__ g3)
{
  __shared__ short xls[2 * 1584 * 8];   // [half][pos=kd*528+rr*132+col][8c]
  const int tid = threadIdx.x;
  const int rp = blockIdx.x;            // 0..63 (2-row group)
  const int d = blockIdx.y, b = blockIdx.z;
  const int h0 = rp * 2;

  const int lane = tid & 63;
  const int og   = tid >> 6;
  const int p    = lane & 15;
  const int chunk = lane >> 4;

  const short* xb = XB16 + (long long)(b * D) * HW * 16;
  const frag_ab zero8 = {0, 0, 0, 0, 0, 0, 0, 0};
  for (int it = 0; it < 13; ++it) {
    const int ci = it * 256 + tid;
    if (ci < 3168) {
      const int pos = ci >> 1, half = ci & 1;
      const int kd = pos / 528;
      const int rem = pos - kd * 528;
      const int rr = rem / 132;
      const int col = rem - rr * 132;
      const int dd = d - 1 + kd, gh = h0 - 1 + rr, gw = col - 1;
      frag_ab v = zero8;
      if (dd >= 0 && dd < D && gh >= 0 && gh < H && gw >= 0 && gw < W)
        v = *(const frag_ab*)(xb + ((long long)dd * HW + gh * W + gw) * 16 + half * 8);
      *(frag_ab*)&xls[half * 12672 + pos * 8] = v;
    }
  }

  frag_ab a[14];
  {
    const short* wl = WT16 + (og * 16 + p) * 448 + chunk * 8;
    #pragma unroll
    for (int s = 0; s < 14; ++s)
      a[s] = *(const frag_ab*)(wl + s * 32);
  }

  const int t0 = chunk >> 1, half = chunk & 1;
  int offs[14];
  #pragma unroll
  for (int s = 0; s < 14; ++s) {
    int tap = 2 * s + t0;
    if (tap > 26) tap = 0;
    const int kd = (tap * 57) >> 9;
    const int rem = tap - kd * 9;
    const int kh = (rem * 11) >> 5;
    const int kw = rem - kh * 3;
    offs[s] = half * 12672 + ((kd * 4 + kh) * 132 + p + kw) * 8;
  }

  frag_cd acc[2][8];
  #pragma unroll
  for (int r2 = 0; r2 < 2; ++r2)
    #pragma unroll
    for (int pg = 0; pg < 8; ++pg)
      acc[r2][pg] = (frag_cd){0.f, 0.f, 0.f, 0.f};

  __syncthreads();

  #pragma unroll
  for (int s = 0; s < 14; ++s) {
    const frag_ab av = a[s];
    const int base0 = offs[s];
    #pragma unroll
    for (int pg = 0; pg < 8; ++pg) {
      frag_ab b0 = *(const frag_ab*)&xls[base0 + pg * 128];
      acc[0][pg] = __builtin_amdgcn_mfma_f32_16x16x32_bf16(av, b0, acc[0][pg], 0, 0, 0);
      frag_ab b1 = *(const frag_ab*)&xls[base0 + 1056 + pg * 128];
      acc[1][pg] = __builtin_amdgcn_mfma_f32_16x16x32_bf16(av, b1, acc[1][pg], 0, 0, 0);
    }
  }

  float* gbuf = (og == 0) ? g0 : (og == 1) ? g1 : (og == 2) ? g2 : g3;
  const long long base = (long long)b * CDHW + (long long)d * HW + h0 * W;
  #pragma unroll
  for (int r2 = 0; r2 < 2; ++r2)
    #pragma unroll
    for (int pg = 0; pg < 8; ++pg)
      #pragma unroll
      for (int reg = 0; reg < 4; ++reg) {
        const int cc = chunk * 4 + reg;
        gbuf[base + (long long)cc * DHW + r2 * W + pg * 16 + p] = acc[r2][pg][reg];
      }
}

// ---------------------------------------------------------------------------
// K5b: BN + activations + SRU scan over D. One thread per (b,c,h,w).
// ---------------------------------------------------------------------------
__global__ __launch_bounds__(256) void k_scan(
    const float* __restrict__ g0, const float* __restrict__ g1,
    const float* __restrict__ g2, const float* __restrict__ g3,
    const float* __restrict__ bg, const float* __restrict__ bb,
    const float* __restrict__ bm, const float* __restrict__ bv,
    float* __restrict__ out)
{
  const int g = blockIdx.x * 256 + threadIdx.x;   // 0 .. 524287
  const int hw = g & 16383;
  const int cc = (g >> 14) & 15;
  const int b  = g >> 18;

  float sc[4], bi[4];
  #pragma unroll
  for (int gg = 0; gg < 4; ++gg) {
    int ch = gg * 16 + cc;
    float s = bg[ch] * rsqrtf(bv[ch] + EPSBN);
    sc[gg] = s;
    bi[gg] = bb[ch] - bm[ch] * s;
  }

  const long long base = (long long)b * CDHW + (long long)cc * DHW + hw;
  float Ct = 0.f;
  for (int d = 0; d < D; ++d) {
    const long long idx = base + (long long)d * HW;
    float wx = tanhf(fmaf(g0[idx], sc[0], bi[0]));
    float ft = 1.f / (1.f + __expf(-fmaf(g1[idx], sc[1], bi[1])));
    float rt = 1.f / (1.f + __expf(-fmaf(g2[idx], sc[2], bi[2])));
    float xg = tanhf(fmaf(g3[idx], sc[3], bi[3]));
    Ct = (d == 0) ? (1.f - ft) : fmaf(ft, Ct, (1.f - ft) * wx);
    out[idx] = fmaf(rt, Ct, (1.f - rt) * xg);
  }
}

// ---------------------------------------------------------------------------
extern "C" void kernel_launch(void* const* d_in, const int* in_sizes, int n_in,
                              void* d_out, int out_size, void* d_ws, size_t ws_size,
                              hipStream_t stream) {
  const float* x      = (const float*)d_in[0];
  const float* w_pre  = (const float*)d_in[1];
  const float* bnpg   = (const float*)d_in[2];
  const float* bnpb   = (const float*)d_in[3];
  const float* bnpm   = (const float*)d_in[4];
  const float* bnpv   = (const float*)d_in[5];
  const float* wq     = (const float*)d_in[6];
  const float* wk     = (const float*)d_in[7];
  const float* wv     = (const float*)d_in[8];
  const float* gamma  = (const float*)d_in[9];
  const float* w_gate = (const float*)d_in[10];
  const float* bng    = (const float*)d_in[11];
  const float* bnb    = (const float*)d_in[12];
  const float* bnm    = (const float*)d_in[13];
  const float* bnv    = (const float*)d_in[14];

  float* ws  = (float*)d_ws;
  float* R0  = ws + OFF_R0;
  float* R1  = ws + OFF_R1;
  float* Kb  = ws + OFF_K;
  float* KTb = ws + OFF_KT;
  float* QTb = ws + OFF_QT;
  float* SI  = ws + OFF_MST;
  float* SO  = ws + OFF_SO;
  float* R2  = ws + OFF_R2;
  float* R3  = ws + OFF_R3;
  short* XB0  = (short*)(ws + OFF_R1);  // bf16 input (pre-attention phase)
  short* XB16 = (short*)(ws + OFF_R1);  // bf16 attn output (post-attention)
  short* WP16 = (short*)(ws + OFF_SO);  // bf16 conv_pre weights (early phase)
  short* WT16 = (short*)(ws + OFF_K);   // bf16 gate weights
  float* out = (float*)d_out;

  const dim3 gTile(64, D, B), gAtt(32, D, B);

  // stage 1: conv_pre via MFMA: x -> bf16 pos-major -> X1 (fp32) in R0
  k_wp <<<dim3(10),  dim3(256), 0, stream>>>(w_pre, WP16);
  k_x16<<<gTile,     dim3(256), 0, stream>>>(x, XB0);
  k_conv_pre16<<<dim3(16, D, B), dim3(256), 0, stream>>>(
      XB0, WP16, bnpg, bnpb, bnpm, bnpv, R0);

  // attention application 1 (mask on outer): x=R0, V->R2, VT->R3
  k_qkv<<<gTile, dim3(256), 0, stream>>>(R0, wq, wk, wv, Kb, KTb, QTb, R2, R3);
  k_att_row<false><<<gAtt, dim3(256), 0, stream>>>(R0, R1, Kb, R2, SI, wq);       // OWn->R1
  k_att_col<false><<<gAtt, dim3(256), 0, stream>>>(KTb, QTb, R3, R2, SO);         // OHn->R2
  k_comb<false><<<gTile, dim3(256), 0, stream>>>(R0, R1, R2, SI, SO, gamma, R3, nullptr); // Y->R3

  // attention application 2 (transposed layout; mask on inner): x=R3
  k_qkv<<<gTile, dim3(256), 0, stream>>>(R3, wq, wk, wv, Kb, KTb, QTb, R0, R1);   // V->R0, VT->R1
  k_att_row<true><<<gAtt, dim3(256), 0, stream>>>(R3, R2, Kb, R0, SI, wq);        // OWn->R2
  k_att_col<true><<<gAtt, dim3(256), 0, stream>>>(KTb, QTb, R1, R0, SO);          // OHn->R0
  k_comb<true><<<gTile, dim3(256), 0, stream>>>(R3, R2, R0, SI, SO, gamma, nullptr, XB16); // ->R1

  // bf16 gate weights (K region free now)
  k_wt<<<dim3(112), dim3(256), 0, stream>>>(w_gate, WT16);

  // stage 3: conv_gate via MFMA (G0->R0, G1->R2, G2->R3, X gate -> d_out)
  k_gates<<<dim3(64, D, B), dim3(256), 0, stream>>>(XB16, WT16, R0, R2, R3, out);

  // stage 4: BN + activations + SRU scan
  k_scan<<<dim3(2048), dim3(256), 0, stream>>>(R0, R2, R3, out, bng, bnb, bnm, bnv, out);
}

// Round 16
// 300.820 us; speedup vs baseline: 2.1601x; 1.0667x over previous
//
#include <hip/hip_runtime.h>
#include <math.h>

// Problem constants
namespace {
constexpr int B = 2, C = 16, D = 16, H = 128, W = 128;
constexpr int HW   = H * W;        // 16384
constexpr int DHW  = D * HW;       // 262144
constexpr int CDHW = C * DHW;      // 4194304
constexpr float EPSBN = 1e-5f;

// workspace regions (floats). ws = 37,748,736 floats = 151 MB
constexpr long long OFF_R0  = 0;
constexpr long long OFF_R1  = 8388608;
constexpr long long OFF_K   = 16777216;  // K / WT16 (bf16 gate weights)
constexpr long long OFF_KT  = 17825792;
constexpr long long OFF_QT  = 18874368;
constexpr long long OFF_MST = 19922944;  // s_inner (I,O); 0.5M used
constexpr long long OFF_SO  = 20447232;  // s_outer (I,O); 0.5M used; WP16 early
constexpr long long OFF_R2  = 20971520;
constexpr long long OFF_R3  = 29360128;
}

using frag_ab = __attribute__((ext_vector_type(8))) short;  // 8 bf16
using frag_cd = __attribute__((ext_vector_type(4))) float;  // 4 f32

__device__ __forceinline__ unsigned short f2bf(float f) {
  unsigned u = __float_as_uint(f);
  u = (u + 0x7FFF + ((u >> 16) & 1)) >> 16;   // RNE
  return (unsigned short)u;
}
__device__ __forceinline__ float bf2f(short s) {
  return __uint_as_float(((unsigned)(unsigned short)s) << 16);
}
__device__ __forceinline__ unsigned cvt_pk_bf16(float lo, float hi) {
  unsigned r;
  asm volatile("v_cvt_pk_bf16_f32 %0, %1, %2" : "=v"(r) : "v"(lo), "v"(hi));
  return r;
}

// ---------------------------------------------------------------------------
// K_x16: cast input x (fp32, c-major) -> bf16 [pos][16c]. grid(64, D, B).
// ---------------------------------------------------------------------------
__global__ __launch_bounds__(256) void k_x16(
    const float* __restrict__ x, short* __restrict__ XB0)
{
  const int tid = threadIdx.x;
  const int tile = blockIdx.x, d = blockIdx.y, b = blockIdx.z;
  const int h0 = (tile >> 3) * 16, w0 = (tile & 7) * 16;
  const long long xbase = (long long)b * CDHW + (long long)d * HW;
  const int th = tid >> 4, tw = tid & 15;

  float v[16];
  #pragma unroll
  for (int c = 0; c < 16; ++c)
    v[c] = x[xbase + (long long)c * DHW + (h0 + th) * 128 + (w0 + tw)];

  unsigned pk[8];
  #pragma unroll
  for (int c = 0; c < 8; ++c)
    pk[c] = (unsigned)f2bf(v[2 * c]) | ((unsigned)f2bf(v[2 * c + 1]) << 16);
  short* dst = XB0 + ((long long)(b * D + d) * HW + (h0 + th) * 128 + (w0 + tw)) * 16;
  *(uint4*)(dst)     = make_uint4(pk[0], pk[1], pk[2], pk[3]);
  *(uint4*)(dst + 8) = make_uint4(pk[4], pk[5], pk[6], pk[7]);
}

// ---------------------------------------------------------------------------
// K_wp: pack conv_pre weights -> bf16 WP16[co16][k160].
// ---------------------------------------------------------------------------
__global__ __launch_bounds__(256) void k_wp(
    const float* __restrict__ wp, short* __restrict__ WP16)
{
  const int idx = blockIdx.x * 256 + threadIdx.x;   // < 2560
  if (idx >= 16 * 160) return;
  const int co = idx / 160;
  const int k = idx - co * 160;
  const int tap = k >> 4, cin = k & 15;
  float v = (tap < 9) ? wp[co * 144 + cin * 9 + tap] : 0.f;
  WP16[idx] = (short)f2bf(v);
}

// ---------------------------------------------------------------------------
// K1 v2: conv_pre via MFMA implicit GEMM + BN + ReLU. (round-13, verified)
// ---------------------------------------------------------------------------
__global__ __launch_bounds__(256) void k_conv_pre16(
    const short* __restrict__ XB0, const short* __restrict__ WP16,
    const float* __restrict__ bg, const float* __restrict__ bb,
    const float* __restrict__ bm, const float* __restrict__ bv,
    float* __restrict__ X1)
{
  __shared__ short xls[10 * 132 * 16];   // 42.2 KB
  const int tid = threadIdx.x;
  const int rg = blockIdx.x;
  const int d = blockIdx.y, b = blockIdx.z;
  const int h0 = rg * 8;

  const int lane = tid & 63;
  const int wv   = tid >> 6;
  const int p    = lane & 15;
  const int chunk = lane >> 4;

  const short* xb0 = XB0 + (long long)(b * D + d) * HW * 16;
  const frag_ab zero8 = {0, 0, 0, 0, 0, 0, 0, 0};
  for (int idx = tid; idx < 2640; idx += 256) {
    const int pos = idx >> 1, half = idx & 1;
    const int row = pos / 132, col = pos - row * 132;
    const int gh = h0 - 1 + row, gw = col - 1;
    frag_ab v = zero8;
    if (gh >= 0 && gh < H && gw >= 0 && gw < W)
      v = *(const frag_ab*)(xb0 + ((long long)gh * 128 + gw) * 16 + half * 8);
    *(frag_ab*)&xls[(row * 132 + col) * 16 + half * 8] = v;
  }

  frag_ab a[5];
  {
    const short* wl = WP16 + p * 160 + chunk * 8;
    #pragma unroll
    for (int s = 0; s < 5; ++s)
      a[s] = *(const frag_ab*)(wl + s * 32);
  }

  int offs[5];
  #pragma unroll
  for (int s = 0; s < 5; ++s) {
    int tap = 2 * s + (chunk >> 1);
    if (tap > 8) tap = 0;
    const int kh = tap / 3, kw = tap - kh * 3;
    offs[s] = ((2 * wv + kh) * 132 + p + kw) * 16 + (chunk & 1) * 8;
  }

  frag_cd acc[2][8];
  #pragma unroll
  for (int r2 = 0; r2 < 2; ++r2)
    #pragma unroll
    for (int pg = 0; pg < 8; ++pg)
      acc[r2][pg] = (frag_cd){0.f, 0.f, 0.f, 0.f};

  __syncthreads();

  #pragma unroll
  for (int s = 0; s < 5; ++s) {
    const frag_ab av = a[s];
    const int base0 = offs[s];
    #pragma unroll
    for (int pg = 0; pg < 8; ++pg) {
      frag_ab b0 = *(const frag_ab*)&xls[base0 + pg * 256];
      acc[0][pg] = __builtin_amdgcn_mfma_f32_16x16x32_bf16(av, b0, acc[0][pg], 0, 0, 0);
      frag_ab b1 = *(const frag_ab*)&xls[base0 + 2112 + pg * 256];
      acc[1][pg] = __builtin_amdgcn_mfma_f32_16x16x32_bf16(av, b1, acc[1][pg], 0, 0, 0);
    }
  }

  float sc4[4], bi4[4];
  #pragma unroll
  for (int reg = 0; reg < 4; ++reg) {
    const int co = chunk * 4 + reg;
    float s = bg[co] * rsqrtf(bv[co] + EPSBN);
    sc4[reg] = s;
    bi4[reg] = bb[co] - bm[co] * s;
  }
  const long long xbase = (long long)b * CDHW + (long long)d * HW;
  #pragma unroll
  for (int r2 = 0; r2 < 2; ++r2) {
    const int row = h0 + 2 * wv + r2;
    #pragma unroll
    for (int pg = 0; pg < 8; ++pg)
      #pragma unroll
      for (int reg = 0; reg < 4; ++reg) {
        const int co = chunk * 4 + reg;
        float v = fmaxf(fmaf(acc[r2][pg][reg], sc4[reg], bi4[reg]), 0.f);
        X1[xbase + (long long)co * DHW + row * 128 + pg * 16 + p] = v;
      }
  }
}

// ---------------------------------------------------------------------------
// K2: projections. V/VT now stored bf16 (PV consumes bf16 anyway).
// ---------------------------------------------------------------------------
__global__ __launch_bounds__(256) void k_qkv(
    const float* __restrict__ xin, const float* __restrict__ wq,
    const float* __restrict__ wk, const float* __restrict__ wv,
    float* __restrict__ Kp, float* __restrict__ KTp, float* __restrict__ QTp,
    short* __restrict__ Vp16, short* __restrict__ VTp16)
{
  const int tid = threadIdx.x;
  const int tile = blockIdx.x, d = blockIdx.y, b = blockIdx.z;
  const int h0 = (tile >> 3) * 16, w0 = (tile & 7) * 16;
  const int ty = tid >> 4, tx = tid & 15;
  const int h = h0 + ty, w = w0 + tx;

  const float* xb = xin + (long long)b * CDHW + (long long)d * HW + h * 128 + w;
  float xv[16];
  #pragma unroll
  for (int c = 0; c < 16; ++c) xv[c] = xb[(long long)c * DHW];

  float q0 = 0, q1 = 0, k0 = 0, k1 = 0, v[16];
  #pragma unroll
  for (int c = 0; c < 16; ++c) {
    q0 = fmaf(wq[c], xv[c], q0);
    q1 = fmaf(wq[16 + c], xv[c], q1);
    k0 = fmaf(wk[c], xv[c], k0);
    k1 = fmaf(wk[16 + c], xv[c], k1);
  }
  #pragma unroll
  for (int o = 0; o < 16; ++o) {
    float a = 0;
    #pragma unroll
    for (int c = 0; c < 16; ++c) a = fmaf(wv[o * 16 + c], xv[c], a);
    v[o] = a;
  }

  const int sl = b * 16 + d;
  const long long base2 = (long long)(sl * 2) * HW;
  const long long baseV = (long long)(sl * 16) * HW;
  const int hw = h * 128 + w;
  Kp[base2 + hw] = k0;
  Kp[base2 + HW + hw] = k1;
  #pragma unroll
  for (int o = 0; o < 16; ++o)
    Vp16[baseV + (long long)o * HW + hw] = (short)f2bf(v[o]);

  __shared__ float lsk[2][16][17];
  __shared__ float lsq[2][16][17];
  __shared__ float lsv[16][16][17];
  lsk[0][ty][tx] = k0; lsk[1][ty][tx] = k1;
  lsq[0][ty][tx] = q0; lsq[1][ty][tx] = q1;
  #pragma unroll
  for (int o = 0; o < 16; ++o) lsv[o][ty][tx] = v[o];
  __syncthreads();

  const int wh = (w0 + ty) * 128 + (h0 + tx);
  KTp[base2 + wh]      = lsk[0][tx][ty];
  KTp[base2 + HW + wh] = lsk[1][tx][ty];
  QTp[base2 + wh]      = lsq[0][tx][ty];
  QTp[base2 + HW + wh] = lsq[1][tx][ty];
  #pragma unroll
  for (int o = 0; o < 16; ++o)
    VTp16[baseV + (long long)o * HW + wh] = (short)f2bf(lsv[o][tx][ty]);
}

// ---------------------------------------------------------------------------
// K3 v6: INNER direction via MFMA. V slab copied bf16 directly.
// Writes OWn POS-MAJOR [orow*128+icol][16c] f32 and s_inner (I,O layout).
// ---------------------------------------------------------------------------
template<bool MASK_INNER>
__global__ __launch_bounds__(256) void k_att_row(
    const float* __restrict__ xin, float* __restrict__ OWn,
    const float* __restrict__ Kp, const short* __restrict__ Vp16,
    float* __restrict__ Sip, const float* __restrict__ wq)
{
  __shared__ float kr2[4][128][2];
  __shared__ float q0l[4][128], q1l[4][128];
  __shared__ __align__(16) short v16[4][16][136];
  const int tid = threadIdx.x;
  const int o0 = blockIdx.x * 4, d = blockIdx.y, b = blockIdx.z;
  const int sl = b * 16 + d;
  const long long base2 = (long long)(sl * 2) * HW;
  const long long baseV = (long long)(sl * 16) * HW;
  const long long baseM = (long long)sl * HW;
  const int hi = tid >> 6;
  const int L  = tid & 63;
  const int p  = L & 15;
  const int chunk = L >> 4;
  const int orow = o0 + hi;
  const long long xbase = (long long)b * CDHW + (long long)d * HW;

  for (int kk = tid; kk < 1024; kk += 256) {
    int col = kk & 127;
    int t = kk >> 7;
    int r2 = t >> 1, o = t & 1;
    kr2[r2][col][o] = Kp[base2 + (long long)o * HW + (o0 + r2) * 128 + col];
  }
  for (int idx = tid; idx < 2048; idx += 256) {
    int v4 = idx & 31;
    int t = idx >> 5;
    int c = t & 15, r2 = t >> 4;
    *(uint2*)&v16[r2][c][v4 * 4] =
        *(const uint2*)&Vp16[baseV + (long long)c * HW + (o0 + r2) * 128 + v4 * 4];
  }
  {
    float q0a = 0.f, q0b = 0.f, q1a = 0.f, q1b = 0.f;
    #pragma unroll
    for (int c = 0; c < 16; ++c) {
      const float w0 = wq[c], w1 = wq[16 + c];
      float xa = xin[xbase + (long long)c * DHW + orow * 128 + L];
      float xb2 = xin[xbase + (long long)c * DHW + orow * 128 + L + 64];
      q0a = fmaf(w0, xa, q0a);  q1a = fmaf(w1, xa, q1a);
      q0b = fmaf(w0, xb2, q0b); q1b = fmaf(w1, xb2, q1b);
    }
    q0l[hi][L] = q0a; q0l[hi][L + 64] = q0b;
    q1l[hi][L] = q1a; q1l[hi][L + 64] = q1b;
  }
  __syncthreads();

  float q0r[8], q1r[8];
  #pragma unroll
  for (int ti = 0; ti < 8; ++ti) {
    q0r[ti] = q0l[hi][ti * 16 + p];
    q1r[ti] = q1l[hi][ti * 16 + p];
  }

  frag_cd acc[8];
  #pragma unroll
  for (int ti = 0; ti < 8; ++ti) acc[ti] = (frag_cd){0.f, 0.f, 0.f, 0.f};
  float ssum[8] = {0.f, 0.f, 0.f, 0.f, 0.f, 0.f, 0.f, 0.f};

  #pragma unroll
  for (int ks = 0; ks < 4; ++ks) {
    const int vb = ks * 32 + chunk * 8;
    float2 kv[8];
    const float* kvp = &kr2[hi][vb][0];
    *(float4*)&kv[0] = *(const float4*)(kvp);
    *(float4*)&kv[2] = *(const float4*)(kvp + 4);
    *(float4*)&kv[4] = *(const float4*)(kvp + 8);
    *(float4*)&kv[6] = *(const float4*)(kvp + 12);
    frag_ab bfrag = *(const frag_ab*)&v16[hi][p][vb];

    #pragma unroll
    for (int ti = 0; ti < 8; ++ti) {
      float pv[8];
      #pragma unroll
      for (int j = 0; j < 8; ++j) {
        float e = fmaf(q0r[ti], kv[j].x, q1r[ti] * kv[j].y);
        pv[j] = __expf(e);
      }
      if constexpr (MASK_INNER) {
        const int dj = ti * 16 + p - vb;
        #pragma unroll
        for (int j = 0; j < 8; ++j)
          if (j == dj) pv[j] = 0.f;
      }
      float lsum = 0.f;
      #pragma unroll
      for (int j = 0; j < 8; ++j) lsum += pv[j];
      ssum[ti] += lsum;

      union { frag_ab f; unsigned u[4]; } cv;
      cv.u[0] = cvt_pk_bf16(pv[0], pv[1]);
      cv.u[1] = cvt_pk_bf16(pv[2], pv[3]);
      cv.u[2] = cvt_pk_bf16(pv[4], pv[5]);
      cv.u[3] = cvt_pk_bf16(pv[6], pv[7]);
      acc[ti] = __builtin_amdgcn_mfma_f32_16x16x32_bf16(cv.f, bfrag, acc[ti], 0, 0, 0);
    }
  }

  #pragma unroll
  for (int ti = 0; ti < 8; ++ti) {
    ssum[ti] += __shfl_xor(ssum[ti], 16);
    ssum[ti] += __shfl_xor(ssum[ti], 32);
  }
  if (L < 16) {
    #pragma unroll
    for (int ti = 0; ti < 8; ++ti)
      Sip[baseM + (ti * 16 + L) * 128 + orow] = ssum[ti];
  }

  float* ob = OWn + ((long long)(b * D + d) * HW + orow * 128) * 16;
  #pragma unroll
  for (int ti = 0; ti < 8; ++ti)
    #pragma unroll
    for (int reg = 0; reg < 4; ++reg)
      ob[(ti * 16 + chunk * 4 + reg) * 16 + p] = acc[ti][reg];
}

// ---------------------------------------------------------------------------
// K4 v6: OUTER direction via MFMA. VT slab copied bf16 directly.
// Writes OHn POS-MAJOR [icol*128+orr][16c] f32, s_outer [icol*128+orr].
// ---------------------------------------------------------------------------
template<bool MASK_INNER>
__global__ __launch_bounds__(256) void k_att_col(
    const float* __restrict__ KTp, const float* __restrict__ QTp,
    const short* __restrict__ VTp16, float* __restrict__ OHn,
    float* __restrict__ Sop)
{
  __shared__ float kr2[4][128][2];
  __shared__ __align__(16) short v16[4][16][136];
  const int tid = threadIdx.x;
  const int i0 = blockIdx.x * 4, d = blockIdx.y, b = blockIdx.z;
  const int sl = b * 16 + d;
  const long long base2 = (long long)(sl * 2) * HW;
  const long long baseV = (long long)(sl * 16) * HW;
  const long long baseS = (long long)sl * HW;
  const int hi = tid >> 6;
  const int L  = tid & 63;
  const int p  = L & 15;
  const int chunk = L >> 4;
  const int icol = i0 + hi;

  for (int kk = tid; kk < 1024; kk += 256) {
    int col = kk & 127;
    int t = kk >> 7;
    int r2 = t >> 1, o = t & 1;
    kr2[r2][col][o] = KTp[base2 + (long long)o * HW + (i0 + r2) * 128 + col];
  }
  for (int idx = tid; idx < 2048; idx += 256) {
    int j4 = idx & 31;
    int t = idx >> 5;
    int c = t & 15, r2 = t >> 4;
    *(uint2*)&v16[r2][c][j4 * 4] =
        *(const uint2*)&VTp16[baseV + (long long)c * HW + (i0 + r2) * 128 + j4 * 4];
  }
  __syncthreads();

  float q0r[8], q1r[8];
  #pragma unroll
  for (int ti = 0; ti < 8; ++ti) {
    q0r[ti] = QTp[base2 + icol * 128 + ti * 16 + p];
    q1r[ti] = QTp[base2 + HW + icol * 128 + ti * 16 + p];
  }

  frag_cd acc[8];
  #pragma unroll
  for (int ti = 0; ti < 8; ++ti) acc[ti] = (frag_cd){0.f, 0.f, 0.f, 0.f};
  float ssum[8] = {0.f, 0.f, 0.f, 0.f, 0.f, 0.f, 0.f, 0.f};

  #pragma unroll
  for (int ks = 0; ks < 4; ++ks) {
    const int vb = ks * 32 + chunk * 8;
    float2 kv[8];
    const float* kvp = &kr2[hi][vb][0];
    *(float4*)&kv[0] = *(const float4*)(kvp);
    *(float4*)&kv[2] = *(const float4*)(kvp + 4);
    *(float4*)&kv[4] = *(const float4*)(kvp + 8);
    *(float4*)&kv[6] = *(const float4*)(kvp + 12);
    frag_ab bfrag = *(const frag_ab*)&v16[hi][p][vb];

    #pragma unroll
    for (int ti = 0; ti < 8; ++ti) {
      float pv[8];
      #pragma unroll
      for (int j = 0; j < 8; ++j) {
        float e = fmaf(q0r[ti], kv[j].x, q1r[ti] * kv[j].y);
        pv[j] = __expf(e);
      }
      if constexpr (!MASK_INNER) {
        const int dj = ti * 16 + p - vb;    // mask j == orr
        #pragma unroll
        for (int j = 0; j < 8; ++j)
          if (j == dj) pv[j] = 0.f;
      }
      float lsum = 0.f;
      #pragma unroll
      for (int j = 0; j < 8; ++j) lsum += pv[j];
      ssum[ti] += lsum;

      union { frag_ab f; unsigned u[4]; } cv;
      cv.u[0] = cvt_pk_bf16(pv[0], pv[1]);
      cv.u[1] = cvt_pk_bf16(pv[2], pv[3]);
      cv.u[2] = cvt_pk_bf16(pv[4], pv[5]);
      cv.u[3] = cvt_pk_bf16(pv[6], pv[7]);
      acc[ti] = __builtin_amdgcn_mfma_f32_16x16x32_bf16(cv.f, bfrag, acc[ti], 0, 0, 0);
    }
  }

  #pragma unroll
  for (int ti = 0; ti < 8; ++ti) {
    ssum[ti] += __shfl_xor(ssum[ti], 16);
    ssum[ti] += __shfl_xor(ssum[ti], 32);
  }
  if (L < 16) {
    #pragma unroll
    for (int ti = 0; ti < 8; ++ti)
      Sop[baseS + icol * 128 + ti * 16 + L] = ssum[ti];
  }

  float* ob = OHn + ((long long)(b * D + d) * HW + icol * 128) * 16;
  #pragma unroll
  for (int ti = 0; ti < 8; ++ti)
    #pragma unroll
    for (int reg = 0; reg < 4; ++reg)
      ob[(ti * 16 + chunk * 4 + reg) * 16 + p] = acc[ti][reg];
}

// ---------------------------------------------------------------------------
// K_comb: res = x + gamma/(s_i+s_o) * (oW + oH), written TRANSPOSED.
// ---------------------------------------------------------------------------
template<bool TO_BF16>
__global__ __launch_bounds__(256) void k_comb(
    const float* __restrict__ Xn, const float* __restrict__ OWn,
    const float* __restrict__ OHn, const float* __restrict__ Sip,
    const float* __restrict__ Sop, const float* __restrict__ gp,
    float* __restrict__ Yt, short* __restrict__ Xb16)
{
  __shared__ float xs[16][16][17], ows[16][16][17];
  const int tid = threadIdx.x;
  const int tile = blockIdx.x, d = blockIdx.y, b = blockIdx.z;
  const int o0 = (tile >> 3) * 16, i0 = (tile & 7) * 16;
  const int sl = b * 16 + d;
  const long long baseM = (long long)sl * HW;
  const long long xbase = (long long)b * CDHW + (long long)d * HW;

  const int to = tid >> 4, ti = tid & 15;
  #pragma unroll
  for (int c = 0; c < 16; ++c) {
    const long long src = xbase + (long long)c * DHW + (o0 + to) * 128 + (i0 + ti);
    xs[c][to][ti] = Xn[src];
  }
  {
    const float* osrc = OWn + ((long long)(b * D + d) * HW + (o0 + to) * 128 + (i0 + ti)) * 16;
    float4 f0 = *(const float4*)(osrc);
    float4 f1 = *(const float4*)(osrc + 4);
    float4 f2 = *(const float4*)(osrc + 8);
    float4 f3 = *(const float4*)(osrc + 12);
    ows[0][to][ti] = f0.x;  ows[1][to][ti] = f0.y;
    ows[2][to][ti] = f0.z;  ows[3][to][ti] = f0.w;
    ows[4][to][ti] = f1.x;  ows[5][to][ti] = f1.y;
    ows[6][to][ti] = f1.z;  ows[7][to][ti] = f1.w;
    ows[8][to][ti] = f2.x;  ows[9][to][ti] = f2.y;
    ows[10][to][ti] = f2.z; ows[11][to][ti] = f2.w;
    ows[12][to][ti] = f3.x; ows[13][to][ti] = f3.y;
    ows[14][to][ti] = f3.z; ows[15][to][ti] = f3.w;
  }
  __syncthreads();

  const int ti2 = tid >> 4, to2 = tid & 15;
  const int i = i0 + ti2, o = o0 + to2;
  const float si = Sip[baseM + i * 128 + o];
  const float so = Sop[baseM + i * 128 + o];
  const float gi = gp[0] / (si + so);

  float oh[16];
  {
    const float* osrc = OHn + ((long long)(b * D + d) * HW + i * 128 + o) * 16;
    float4 f0 = *(const float4*)(osrc);
    float4 f1 = *(const float4*)(osrc + 4);
    float4 f2 = *(const float4*)(osrc + 8);
    float4 f3 = *(const float4*)(osrc + 12);
    oh[0] = f0.x;  oh[1] = f0.y;  oh[2] = f0.z;  oh[3] = f0.w;
    oh[4] = f1.x;  oh[5] = f1.y;  oh[6] = f1.z;  oh[7] = f1.w;
    oh[8] = f2.x;  oh[9] = f2.y;  oh[10] = f2.z; oh[11] = f2.w;
    oh[12] = f3.x; oh[13] = f3.y; oh[14] = f3.z; oh[15] = f3.w;
  }

  float res[16];
  #pragma unroll
  for (int c = 0; c < 16; ++c)
    res[c] = fmaf(gi, ows[c][to2][ti2] + oh[c], xs[c][to2][ti2]);

  if constexpr (!TO_BF16) {
    #pragma unroll
    for (int c = 0; c < 16; ++c)
      Yt[xbase + (long long)c * DHW + i * 128 + o] = res[c];
  } else {
    unsigned pk[8];
    #pragma unroll
    for (int c = 0; c < 8; ++c)
      pk[c] = (unsigned)f2bf(res[2 * c]) | ((unsigned)f2bf(res[2 * c + 1]) << 16);
    short* dst = Xb16 + ((long long)(b * D + d) * HW + i * 128 + o) * 16;
    *(uint4*)(dst)     = make_uint4(pk[0], pk[1], pk[2], pk[3]);
    *(uint4*)(dst + 8) = make_uint4(pk[4], pk[5], pk[6], pk[7]);
  }
}

// ---------------------------------------------------------------------------
// K_wt: pack gate weights OIDHW -> bf16 WT16[co64][k448], k = tap*16+cin.
// ---------------------------------------------------------------------------
__global__ __launch_bounds__(256) void k_wt(
    const float* __restrict__ wg, short* __restrict__ WT16)
{
  const int idx = blockIdx.x * 256 + threadIdx.x;   // < 28672
  if (idx >= 64 * 448) return;
  const int co_g = idx / 448;
  const int k = idx - co_g * 448;
  const int tap = k >> 4, cin = k & 15;
  float v = (tap < 27) ? wg[co_g * 432 + cin * 27 + tap] : 0.f;
  WT16[idx] = (short)f2bf(v);
}

// ---------------------------------------------------------------------------
// K5a: conv_gate via MFMA implicit GEMM; gates stored bf16.
// ---------------------------------------------------------------------------
__global__ __launch_bounds__(256, 2) void k_gates(
    const short* __restrict__ XB16, const short* __restrict__ WT16,
    short* __restrict__ g0, short* __restrict__ g1,
    short* __restrict__ g2, short* __restrict__ g3)
{
  __shared__ short xls[2 * 1584 * 8];   // [half][pos=kd*528+rr*132+col][8c]
  const int tid = threadIdx.x;
  const int rp = blockIdx.x;            // 0..63 (2-row group)
  const int d = blockIdx.y, b = blockIdx.z;
  const int h0 = rp * 2;

  const int lane = tid & 63;
  const int og   = tid >> 6;
  const int p    = lane & 15;
  const int chunk = lane >> 4;

  const short* xb = XB16 + (long long)(b * D) * HW * 16;
  const frag_ab zero8 = {0, 0, 0, 0, 0, 0, 0, 0};
  for (int it = 0; it < 13; ++it) {
    const int ci = it * 256 + tid;
    if (ci < 3168) {
      const int pos = ci >> 1, half = ci & 1;
      const int kd = pos / 528;
      const int rem = pos - kd * 528;
      const int rr = rem / 132;
      const int col = rem - rr * 132;
      const int dd = d - 1 + kd, gh = h0 - 1 + rr, gw = col - 1;
      frag_ab v = zero8;
      if (dd >= 0 && dd < D && gh >= 0 && gh < H && gw >= 0 && gw < W)
        v = *(const frag_ab*)(xb + ((long long)dd * HW + gh * W + gw) * 16 + half * 8);
      *(frag_ab*)&xls[half * 12672 + pos * 8] = v;
    }
  }

  frag_ab a[14];
  {
    const short* wl = WT16 + (og * 16 + p) * 448 + chunk * 8;
    #pragma unroll
    for (int s = 0; s < 14; ++s)
      a[s] = *(const frag_ab*)(wl + s * 32);
  }

  const int t0 = chunk >> 1, half = chunk & 1;
  int offs[14];
  #pragma unroll
  for (int s = 0; s < 14; ++s) {
    int tap = 2 * s + t0;
    if (tap > 26) tap = 0;
    const int kd = (tap * 57) >> 9;
    const int rem = tap - kd * 9;
    const int kh = (rem * 11) >> 5;
    const int kw = rem - kh * 3;
    offs[s] = half * 12672 + ((kd * 4 + kh) * 132 + p + kw) * 8;
  }

  frag_cd acc[2][8];
  #pragma unroll
  for (int r2 = 0; r2 < 2; ++r2)
    #pragma unroll
    for (int pg = 0; pg < 8; ++pg)
      acc[r2][pg] = (frag_cd){0.f, 0.f, 0.f, 0.f};

  __syncthreads();

  #pragma unroll
  for (int s = 0; s < 14; ++s) {
    const frag_ab av = a[s];
    const int base0 = offs[s];
    #pragma unroll
    for (int pg = 0; pg < 8; ++pg) {
      frag_ab b0 = *(const frag_ab*)&xls[base0 + pg * 128];
      acc[0][pg] = __builtin_amdgcn_mfma_f32_16x16x32_bf16(av, b0, acc[0][pg], 0, 0, 0);
      frag_ab b1 = *(const frag_ab*)&xls[base0 + 1056 + pg * 128];
      acc[1][pg] = __builtin_amdgcn_mfma_f32_16x16x32_bf16(av, b1, acc[1][pg], 0, 0, 0);
    }
  }

  short* gbuf = (og == 0) ? g0 : (og == 1) ? g1 : (og == 2) ? g2 : g3;
  const long long base = (long long)b * CDHW + (long long)d * HW + h0 * W;
  #pragma unroll
  for (int r2 = 0; r2 < 2; ++r2)
    #pragma unroll
    for (int pg = 0; pg < 8; ++pg)
      #pragma unroll
      for (int reg = 0; reg < 4; ++reg) {
        const int cc = chunk * 4 + reg;
        gbuf[base + (long long)cc * DHW + r2 * W + pg * 16 + p] =
            (short)f2bf(acc[r2][pg][reg]);
      }
}

// ---------------------------------------------------------------------------
// K5b: BN + activations + SRU scan over D. Gates read as bf16.
// ---------------------------------------------------------------------------
__global__ __launch_bounds__(256) void k_scan(
    const short* __restrict__ g0, const short* __restrict__ g1,
    const short* __restrict__ g2, const short* __restrict__ g3,
    const float* __restrict__ bg, const float* __restrict__ bb,
    const float* __restrict__ bm, const float* __restrict__ bv,
    float* __restrict__ out)
{
  const int g = blockIdx.x * 256 + threadIdx.x;   // 0 .. 524287
  const int hw = g & 16383;
  const int cc = (g >> 14) & 15;
  const int b  = g >> 18;

  float sc[4], bi[4];
  #pragma unroll
  for (int gg = 0; gg < 4; ++gg) {
    int ch = gg * 16 + cc;
    float s = bg[ch] * rsqrtf(bv[ch] + EPSBN);
    sc[gg] = s;
    bi[gg] = bb[ch] - bm[ch] * s;
  }

  const long long base = (long long)b * CDHW + (long long)cc * DHW + hw;
  float Ct = 0.f;
  for (int d = 0; d < D; ++d) {
    const long long idx = base + (long long)d * HW;
    float wx = tanhf(fmaf(bf2f(g0[idx]), sc[0], bi[0]));
    float ft = 1.f / (1.f + __expf(-fmaf(bf2f(g1[idx]), sc[1], bi[1])));
    float rt = 1.f / (1.f + __expf(-fmaf(bf2f(g2[idx]), sc[2], bi[2])));
    float xg = tanhf(fmaf(bf2f(g3[idx]), sc[3], bi[3]));
    Ct = (d == 0) ? (1.f - ft) : fmaf(ft, Ct, (1.f - ft) * wx);
    out[idx] = fmaf(rt, Ct, (1.f - rt) * xg);
  }
}

// ---------------------------------------------------------------------------
extern "C" void kernel_launch(void* const* d_in, const int* in_sizes, int n_in,
                              void* d_out, int out_size, void* d_ws, size_t ws_size,
                              hipStream_t stream) {
  const float* x      = (const float*)d_in[0];
  const float* w_pre  = (const float*)d_in[1];
  const float* bnpg   = (const float*)d_in[2];
  const float* bnpb   = (const float*)d_in[3];
  const float* bnpm   = (const float*)d_in[4];
  const float* bnpv   = (const float*)d_in[5];
  const float* wq     = (const float*)d_in[6];
  const float* wk     = (const float*)d_in[7];
  const float* wv     = (const float*)d_in[8];
  const float* gamma  = (const float*)d_in[9];
  const float* w_gate = (const float*)d_in[10];
  const float* bng    = (const float*)d_in[11];
  const float* bnb    = (const float*)d_in[12];
  const float* bnm    = (const float*)d_in[13];
  const float* bnv    = (const float*)d_in[14];

  float* ws  = (float*)d_ws;
  float* R0  = ws + OFF_R0;
  float* R1  = ws + OFF_R1;
  float* Kb  = ws + OFF_K;
  float* KTb = ws + OFF_KT;
  float* QTb = ws + OFF_QT;
  float* SI  = ws + OFF_MST;
  float* SO  = ws + OFF_SO;
  float* R2  = ws + OFF_R2;
  float* R3  = ws + OFF_R3;
  short* XB0  = (short*)(ws + OFF_R1);  // bf16 input (pre-attention phase)
  short* XB16 = (short*)(ws + OFF_R1);  // bf16 attn output (post-attention)
  short* WP16 = (short*)(ws + OFF_SO);  // bf16 conv_pre weights (early phase)
  short* WT16 = (short*)(ws + OFF_K);   // bf16 gate weights
  // bf16 V/VT per app (each 8.4M shorts = half a region)
  short* V1b  = (short*)(ws + OFF_R2);
  short* VT1b = (short*)(ws + OFF_R3);
  short* V2b  = (short*)(ws + OFF_R0);
  short* VT2b = (short*)(ws + OFF_R1) + 8388608;  // upper half of R1 (XB16 uses lower)
  // bf16 gate buffers: two per region
  short* G0b = (short*)(ws + OFF_R0);
  short* G1b = (short*)(ws + OFF_R0) + 8388608;
  short* G2b = (short*)(ws + OFF_R2);
  short* G3b = (short*)(ws + OFF_R2) + 8388608;
  float* out = (float*)d_out;

  const dim3 gTile(64, D, B), gAtt(32, D, B);

  // stage 1: conv_pre via MFMA: x -> bf16 pos-major -> X1 (fp32) in R0
  k_wp <<<dim3(10),  dim3(256), 0, stream>>>(w_pre, WP16);
  k_x16<<<gTile,     dim3(256), 0, stream>>>(x, XB0);
  k_conv_pre16<<<dim3(16, D, B), dim3(256), 0, stream>>>(
      XB0, WP16, bnpg, bnpb, bnpm, bnpv, R0);

  // attention application 1 (mask on outer): x=R0, V16->R2, VT16->R3
  k_qkv<<<gTile, dim3(256), 0, stream>>>(R0, wq, wk, wv, Kb, KTb, QTb, V1b, VT1b);
  k_att_row<false><<<gAtt, dim3(256), 0, stream>>>(R0, R1, Kb, V1b, SI, wq);      // OWn->R1
  k_att_col<false><<<gAtt, dim3(256), 0, stream>>>(KTb, QTb, VT1b, R2, SO);       // OHn->R2
  k_comb<false><<<gTile, dim3(256), 0, stream>>>(R0, R1, R2, SI, SO, gamma, R3, nullptr); // Y->R3

  // attention application 2 (transposed layout; mask on inner): x=R3
  k_qkv<<<gTile, dim3(256), 0, stream>>>(R3, wq, wk, wv, Kb, KTb, QTb, V2b, VT2b);
  k_att_row<true><<<gAtt, dim3(256), 0, stream>>>(R3, R2, Kb, V2b, SI, wq);       // OWn->R2
  k_att_col<true><<<gAtt, dim3(256), 0, stream>>>(KTb, QTb, VT2b, R0, SO);        // OHn->R0
  k_comb<true><<<gTile, dim3(256), 0, stream>>>(R3, R2, R0, SI, SO, gamma, nullptr, XB16); // ->R1 lower

  // bf16 gate weights (K region free now)
  k_wt<<<dim3(112), dim3(256), 0, stream>>>(w_gate, WT16);

  // stage 3: conv_gate via MFMA -> bf16 gates (G0,G1 in R0; G2,G3 in R2)
  k_gates<<<dim3(64, D, B), dim3(256), 0, stream>>>(XB16, WT16, G0b, G1b, G2b, G3b);

  // stage 4: BN + activations + SRU scan -> out
  k_scan<<<dim3(2048), dim3(256), 0, stream>>>(G0b, G1b, G2b, G3b, bng, bnb, bnm, bnv, out);
}

// Round 17
// 297.980 us; speedup vs baseline: 2.1807x; 1.0095x over previous
//
#include <hip/hip_runtime.h>
#include <math.h>

// Problem constants
namespace {
constexpr int B = 2, C = 16, D = 16, H = 128, W = 128;
constexpr int HW   = H * W;        // 16384
constexpr int DHW  = D * HW;       // 262144
constexpr int CDHW = C * DHW;      // 4194304
constexpr float EPSBN = 1e-5f;

// workspace regions (floats). ws = 37,748,736 floats = 151 MB
constexpr long long OFF_R0  = 0;
constexpr long long OFF_R1  = 8388608;
constexpr long long OFF_K   = 16777216;  // K / WT16 (bf16 gate weights)
constexpr long long OFF_KT  = 17825792;
constexpr long long OFF_QT  = 18874368;
constexpr long long OFF_MST = 19922944;  // s_inner (I,O); 0.5M used
constexpr long long OFF_SO  = 20447232;  // s_outer (I,O); 0.5M used; WP16 early
constexpr long long OFF_R2  = 20971520;
constexpr long long OFF_R3  = 29360128;
}

using frag_ab = __attribute__((ext_vector_type(8))) short;  // 8 bf16
using frag_cd = __attribute__((ext_vector_type(4))) float;  // 4 f32

__device__ __forceinline__ unsigned short f2bf(float f) {
  unsigned u = __float_as_uint(f);
  u = (u + 0x7FFF + ((u >> 16) & 1)) >> 16;   // RNE
  return (unsigned short)u;
}
__device__ __forceinline__ float bf2f(short s) {
  return __uint_as_float(((unsigned)(unsigned short)s) << 16);
}
__device__ __forceinline__ unsigned cvt_pk_bf16(float lo, float hi) {
  unsigned r;
  asm volatile("v_cvt_pk_bf16_f32 %0, %1, %2" : "=v"(r) : "v"(lo), "v"(hi));
  return r;
}

// ---------------------------------------------------------------------------
// K_x16: cast input x (fp32, c-major) -> bf16 [pos][16c]. grid(64, D, B).
// ---------------------------------------------------------------------------
__global__ __launch_bounds__(256) void k_x16(
    const float* __restrict__ x, short* __restrict__ XB0)
{
  const int tid = threadIdx.x;
  const int tile = blockIdx.x, d = blockIdx.y, b = blockIdx.z;
  const int h0 = (tile >> 3) * 16, w0 = (tile & 7) * 16;
  const long long xbase = (long long)b * CDHW + (long long)d * HW;
  const int th = tid >> 4, tw = tid & 15;

  float v[16];
  #pragma unroll
  for (int c = 0; c < 16; ++c)
    v[c] = x[xbase + (long long)c * DHW + (h0 + th) * 128 + (w0 + tw)];

  unsigned pk[8];
  #pragma unroll
  for (int c = 0; c < 8; ++c)
    pk[c] = (unsigned)f2bf(v[2 * c]) | ((unsigned)f2bf(v[2 * c + 1]) << 16);
  short* dst = XB0 + ((long long)(b * D + d) * HW + (h0 + th) * 128 + (w0 + tw)) * 16;
  *(uint4*)(dst)     = make_uint4(pk[0], pk[1], pk[2], pk[3]);
  *(uint4*)(dst + 8) = make_uint4(pk[4], pk[5], pk[6], pk[7]);
}

// ---------------------------------------------------------------------------
// K_wp: pack conv_pre weights -> bf16 per-half layout:
// WP16[(half*16+co)*96 + ks*32 + t*8 + c8], tap = ks*4+t (taps>=9 zero).
// ---------------------------------------------------------------------------
__global__ __launch_bounds__(256) void k_wp(
    const float* __restrict__ wp, short* __restrict__ WP16)
{
  const int idx = blockIdx.x * 256 + threadIdx.x;   // < 3072
  if (idx >= 2 * 16 * 96) return;
  const int u = idx / 96;            // half*16 + co
  const int k = idx - u * 96;
  const int ks = k >> 5, rem = k & 31;
  const int t = rem >> 3, c8 = rem & 7;
  const int tap = ks * 4 + t;
  const int half = u >> 4, co = u & 15;
  const int cin = half * 8 + c8;
  float v = (tap < 9) ? wp[co * 144 + cin * 9 + tap] : 0.f;
  WP16[idx] = (short)f2bf(v);
}

// ---------------------------------------------------------------------------
// K1 v3: conv_pre via MFMA, cin-halves processed sequentially (LDS 21 KB).
// grid(16 rowgroups, D, B), block 256 = 4 waves; wave = 2 rows x 128 cols.
// Per half: stage 10 rows x 132 x 8c bf16, 3 k-steps (4 taps x 8 cin each).
// ---------------------------------------------------------------------------
__global__ __launch_bounds__(256) void k_conv_pre16(
    const short* __restrict__ XB0, const short* __restrict__ WP16,
    const float* __restrict__ bg, const float* __restrict__ bb,
    const float* __restrict__ bm, const float* __restrict__ bv,
    float* __restrict__ X1)
{
  __shared__ short xls[10 * 132 * 8];   // 21.1 KB
  const int tid = threadIdx.x;
  const int rg = blockIdx.x;
  const int d = blockIdx.y, b = blockIdx.z;
  const int h0 = rg * 8;

  const int lane = tid & 63;
  const int wv   = tid >> 6;
  const int p    = lane & 15;
  const int chunk = lane >> 4;

  const short* xb0 = XB0 + (long long)(b * D + d) * HW * 16;
  const frag_ab zero8 = {0, 0, 0, 0, 0, 0, 0, 0};

  frag_cd acc[2][8];
  #pragma unroll
  for (int r2 = 0; r2 < 2; ++r2)
    #pragma unroll
    for (int pg = 0; pg < 8; ++pg)
      acc[r2][pg] = (frag_cd){0.f, 0.f, 0.f, 0.f};

  // per-lane B offsets (independent of half)
  int offs[3];
  #pragma unroll
  for (int s = 0; s < 3; ++s) {
    int tap = s * 4 + chunk;
    if (tap > 8) tap = 0;               // padded (A==0) -> in-bounds addr
    const int kh = (tap * 11) >> 5;     // tap/3
    const int kw = tap - kh * 3;
    offs[s] = ((2 * wv + kh) * 132 + p + kw) * 8;
  }

  for (int half = 0; half < 2; ++half) {
    // stage this half's slab: 10 x 132 positions x 8c
    for (int idx = tid; idx < 1320; idx += 256) {
      const int row = idx / 132, col = idx - row * 132;
      const int gh = h0 - 1 + row, gw = col - 1;
      frag_ab v = zero8;
      if (gh >= 0 && gh < H && gw >= 0 && gw < W)
        v = *(const frag_ab*)(xb0 + ((long long)gh * 128 + gw) * 16 + half * 8);
      *(frag_ab*)&xls[idx * 8] = v;
    }
    __syncthreads();

    frag_ab a[3];
    {
      const short* wl = WP16 + ((half << 4) + p) * 96 + chunk * 8;
      #pragma unroll
      for (int s = 0; s < 3; ++s)
        a[s] = *(const frag_ab*)(wl + s * 32);
    }

    #pragma unroll
    for (int s = 0; s < 3; ++s) {
      const frag_ab av = a[s];
      const int base0 = offs[s];
      #pragma unroll
      for (int pg = 0; pg < 8; ++pg) {
        frag_ab b0 = *(const frag_ab*)&xls[base0 + pg * 128];
        acc[0][pg] = __builtin_amdgcn_mfma_f32_16x16x32_bf16(av, b0, acc[0][pg], 0, 0, 0);
        frag_ab b1 = *(const frag_ab*)&xls[base0 + 1056 + pg * 128];
        acc[1][pg] = __builtin_amdgcn_mfma_f32_16x16x32_bf16(av, b1, acc[1][pg], 0, 0, 0);
      }
    }
    __syncthreads();   // before restage
  }

  float sc4[4], bi4[4];
  #pragma unroll
  for (int reg = 0; reg < 4; ++reg) {
    const int co = chunk * 4 + reg;
    float s = bg[co] * rsqrtf(bv[co] + EPSBN);
    sc4[reg] = s;
    bi4[reg] = bb[co] - bm[co] * s;
  }
  const long long xbase = (long long)b * CDHW + (long long)d * HW;
  #pragma unroll
  for (int r2 = 0; r2 < 2; ++r2) {
    const int row = h0 + 2 * wv + r2;
    #pragma unroll
    for (int pg = 0; pg < 8; ++pg)
      #pragma unroll
      for (int reg = 0; reg < 4; ++reg) {
        const int co = chunk * 4 + reg;
        float v = fmaxf(fmaf(acc[r2][pg][reg], sc4[reg], bi4[reg]), 0.f);
        X1[xbase + (long long)co * DHW + row * 128 + pg * 16 + p] = v;
      }
  }
}

// ---------------------------------------------------------------------------
// K2: projections. V/VT stored bf16.
// ---------------------------------------------------------------------------
__global__ __launch_bounds__(256) void k_qkv(
    const float* __restrict__ xin, const float* __restrict__ wq,
    const float* __restrict__ wk, const float* __restrict__ wv,
    float* __restrict__ Kp, float* __restrict__ KTp, float* __restrict__ QTp,
    short* __restrict__ Vp16, short* __restrict__ VTp16)
{
  const int tid = threadIdx.x;
  const int tile = blockIdx.x, d = blockIdx.y, b = blockIdx.z;
  const int h0 = (tile >> 3) * 16, w0 = (tile & 7) * 16;
  const int ty = tid >> 4, tx = tid & 15;
  const int h = h0 + ty, w = w0 + tx;

  const float* xb = xin + (long long)b * CDHW + (long long)d * HW + h * 128 + w;
  float xv[16];
  #pragma unroll
  for (int c = 0; c < 16; ++c) xv[c] = xb[(long long)c * DHW];

  float q0 = 0, q1 = 0, k0 = 0, k1 = 0, v[16];
  #pragma unroll
  for (int c = 0; c < 16; ++c) {
    q0 = fmaf(wq[c], xv[c], q0);
    q1 = fmaf(wq[16 + c], xv[c], q1);
    k0 = fmaf(wk[c], xv[c], k0);
    k1 = fmaf(wk[16 + c], xv[c], k1);
  }
  #pragma unroll
  for (int o = 0; o < 16; ++o) {
    float a = 0;
    #pragma unroll
    for (int c = 0; c < 16; ++c) a = fmaf(wv[o * 16 + c], xv[c], a);
    v[o] = a;
  }

  const int sl = b * 16 + d;
  const long long base2 = (long long)(sl * 2) * HW;
  const long long baseV = (long long)(sl * 16) * HW;
  const int hw = h * 128 + w;
  Kp[base2 + hw] = k0;
  Kp[base2 + HW + hw] = k1;
  #pragma unroll
  for (int o = 0; o < 16; ++o)
    Vp16[baseV + (long long)o * HW + hw] = (short)f2bf(v[o]);

  __shared__ float lsk[2][16][17];
  __shared__ float lsq[2][16][17];
  __shared__ float lsv[16][16][17];
  lsk[0][ty][tx] = k0; lsk[1][ty][tx] = k1;
  lsq[0][ty][tx] = q0; lsq[1][ty][tx] = q1;
  #pragma unroll
  for (int o = 0; o < 16; ++o) lsv[o][ty][tx] = v[o];
  __syncthreads();

  const int wh = (w0 + ty) * 128 + (h0 + tx);
  KTp[base2 + wh]      = lsk[0][tx][ty];
  KTp[base2 + HW + wh] = lsk[1][tx][ty];
  QTp[base2 + wh]      = lsq[0][tx][ty];
  QTp[base2 + HW + wh] = lsq[1][tx][ty];
  #pragma unroll
  for (int o = 0; o < 16; ++o)
    VTp16[baseV + (long long)o * HW + wh] = (short)f2bf(lsv[o][tx][ty]);
}

// ---------------------------------------------------------------------------
// K3 v6: INNER direction via MFMA. V slab copied bf16 directly.
// ---------------------------------------------------------------------------
template<bool MASK_INNER>
__global__ __launch_bounds__(256) void k_att_row(
    const float* __restrict__ xin, float* __restrict__ OWn,
    const float* __restrict__ Kp, const short* __restrict__ Vp16,
    float* __restrict__ Sip, const float* __restrict__ wq)
{
  __shared__ float kr2[4][128][2];
  __shared__ float q0l[4][128], q1l[4][128];
  __shared__ __align__(16) short v16[4][16][136];
  const int tid = threadIdx.x;
  const int o0 = blockIdx.x * 4, d = blockIdx.y, b = blockIdx.z;
  const int sl = b * 16 + d;
  const long long base2 = (long long)(sl * 2) * HW;
  const long long baseV = (long long)(sl * 16) * HW;
  const long long baseM = (long long)sl * HW;
  const int hi = tid >> 6;
  const int L  = tid & 63;
  const int p  = L & 15;
  const int chunk = L >> 4;
  const int orow = o0 + hi;
  const long long xbase = (long long)b * CDHW + (long long)d * HW;

  for (int kk = tid; kk < 1024; kk += 256) {
    int col = kk & 127;
    int t = kk >> 7;
    int r2 = t >> 1, o = t & 1;
    kr2[r2][col][o] = Kp[base2 + (long long)o * HW + (o0 + r2) * 128 + col];
  }
  for (int idx = tid; idx < 2048; idx += 256) {
    int v4 = idx & 31;
    int t = idx >> 5;
    int c = t & 15, r2 = t >> 4;
    *(uint2*)&v16[r2][c][v4 * 4] =
        *(const uint2*)&Vp16[baseV + (long long)c * HW + (o0 + r2) * 128 + v4 * 4];
  }
  {
    float q0a = 0.f, q0b = 0.f, q1a = 0.f, q1b = 0.f;
    #pragma unroll
    for (int c = 0; c < 16; ++c) {
      const float w0 = wq[c], w1 = wq[16 + c];
      float xa = xin[xbase + (long long)c * DHW + orow * 128 + L];
      float xb2 = xin[xbase + (long long)c * DHW + orow * 128 + L + 64];
      q0a = fmaf(w0, xa, q0a);  q1a = fmaf(w1, xa, q1a);
      q0b = fmaf(w0, xb2, q0b); q1b = fmaf(w1, xb2, q1b);
    }
    q0l[hi][L] = q0a; q0l[hi][L + 64] = q0b;
    q1l[hi][L] = q1a; q1l[hi][L + 64] = q1b;
  }
  __syncthreads();

  float q0r[8], q1r[8];
  #pragma unroll
  for (int ti = 0; ti < 8; ++ti) {
    q0r[ti] = q0l[hi][ti * 16 + p];
    q1r[ti] = q1l[hi][ti * 16 + p];
  }

  frag_cd acc[8];
  #pragma unroll
  for (int ti = 0; ti < 8; ++ti) acc[ti] = (frag_cd){0.f, 0.f, 0.f, 0.f};
  float ssum[8] = {0.f, 0.f, 0.f, 0.f, 0.f, 0.f, 0.f, 0.f};

  #pragma unroll
  for (int ks = 0; ks < 4; ++ks) {
    const int vb = ks * 32 + chunk * 8;
    float2 kv[8];
    const float* kvp = &kr2[hi][vb][0];
    *(float4*)&kv[0] = *(const float4*)(kvp);
    *(float4*)&kv[2] = *(const float4*)(kvp + 4);
    *(float4*)&kv[4] = *(const float4*)(kvp + 8);
    *(float4*)&kv[6] = *(const float4*)(kvp + 12);
    frag_ab bfrag = *(const frag_ab*)&v16[hi][p][vb];

    #pragma unroll
    for (int ti = 0; ti < 8; ++ti) {
      float pv[8];
      #pragma unroll
      for (int j = 0; j < 8; ++j) {
        float e = fmaf(q0r[ti], kv[j].x, q1r[ti] * kv[j].y);
        pv[j] = __expf(e);
      }
      if constexpr (MASK_INNER) {
        const int dj = ti * 16 + p - vb;
        #pragma unroll
        for (int j = 0; j < 8; ++j)
          if (j == dj) pv[j] = 0.f;
      }
      float lsum = 0.f;
      #pragma unroll
      for (int j = 0; j < 8; ++j) lsum += pv[j];
      ssum[ti] += lsum;

      union { frag_ab f; unsigned u[4]; } cv;
      cv.u[0] = cvt_pk_bf16(pv[0], pv[1]);
      cv.u[1] = cvt_pk_bf16(pv[2], pv[3]);
      cv.u[2] = cvt_pk_bf16(pv[4], pv[5]);
      cv.u[3] = cvt_pk_bf16(pv[6], pv[7]);
      acc[ti] = __builtin_amdgcn_mfma_f32_16x16x32_bf16(cv.f, bfrag, acc[ti], 0, 0, 0);
    }
  }

  #pragma unroll
  for (int ti = 0; ti < 8; ++ti) {
    ssum[ti] += __shfl_xor(ssum[ti], 16);
    ssum[ti] += __shfl_xor(ssum[ti], 32);
  }
  if (L < 16) {
    #pragma unroll
    for (int ti = 0; ti < 8; ++ti)
      Sip[baseM + (ti * 16 + L) * 128 + orow] = ssum[ti];
  }

  float* ob = OWn + ((long long)(b * D + d) * HW + orow * 128) * 16;
  #pragma unroll
  for (int ti = 0; ti < 8; ++ti)
    #pragma unroll
    for (int reg = 0; reg < 4; ++reg)
      ob[(ti * 16 + chunk * 4 + reg) * 16 + p] = acc[ti][reg];
}

// ---------------------------------------------------------------------------
// K4 v6: OUTER direction via MFMA. VT slab copied bf16 directly.
// ---------------------------------------------------------------------------
template<bool MASK_INNER>
__global__ __launch_bounds__(256) void k_att_col(
    const float* __restrict__ KTp, const float* __restrict__ QTp,
    const short* __restrict__ VTp16, float* __restrict__ OHn,
    float* __restrict__ Sop)
{
  __shared__ float kr2[4][128][2];
  __shared__ __align__(16) short v16[4][16][136];
  const int tid = threadIdx.x;
  const int i0 = blockIdx.x * 4, d = blockIdx.y, b = blockIdx.z;
  const int sl = b * 16 + d;
  const long long base2 = (long long)(sl * 2) * HW;
  const long long baseV = (long long)(sl * 16) * HW;
  const long long baseS = (long long)sl * HW;
  const int hi = tid >> 6;
  const int L  = tid & 63;
  const int p  = L & 15;
  const int chunk = L >> 4;
  const int icol = i0 + hi;

  for (int kk = tid; kk < 1024; kk += 256) {
    int col = kk & 127;
    int t = kk >> 7;
    int r2 = t >> 1, o = t & 1;
    kr2[r2][col][o] = KTp[base2 + (long long)o * HW + (i0 + r2) * 128 + col];
  }
  for (int idx = tid; idx < 2048; idx += 256) {
    int j4 = idx & 31;
    int t = idx >> 5;
    int c = t & 15, r2 = t >> 4;
    *(uint2*)&v16[r2][c][j4 * 4] =
        *(const uint2*)&VTp16[baseV + (long long)c * HW + (i0 + r2) * 128 + j4 * 4];
  }
  __syncthreads();

  float q0r[8], q1r[8];
  #pragma unroll
  for (int ti = 0; ti < 8; ++ti) {
    q0r[ti] = QTp[base2 + icol * 128 + ti * 16 + p];
    q1r[ti] = QTp[base2 + HW + icol * 128 + ti * 16 + p];
  }

  frag_cd acc[8];
  #pragma unroll
  for (int ti = 0; ti < 8; ++ti) acc[ti] = (frag_cd){0.f, 0.f, 0.f, 0.f};
  float ssum[8] = {0.f, 0.f, 0.f, 0.f, 0.f, 0.f, 0.f, 0.f};

  #pragma unroll
  for (int ks = 0; ks < 4; ++ks) {
    const int vb = ks * 32 + chunk * 8;
    float2 kv[8];
    const float* kvp = &kr2[hi][vb][0];
    *(float4*)&kv[0] = *(const float4*)(kvp);
    *(float4*)&kv[2] = *(const float4*)(kvp + 4);
    *(float4*)&kv[4] = *(const float4*)(kvp + 8);
    *(float4*)&kv[6] = *(const float4*)(kvp + 12);
    frag_ab bfrag = *(const frag_ab*)&v16[hi][p][vb];

    #pragma unroll
    for (int ti = 0; ti < 8; ++ti) {
      float pv[8];
      #pragma unroll
      for (int j = 0; j < 8; ++j) {
        float e = fmaf(q0r[ti], kv[j].x, q1r[ti] * kv[j].y);
        pv[j] = __expf(e);
      }
      if constexpr (!MASK_INNER) {
        const int dj = ti * 16 + p - vb;    // mask j == orr
        #pragma unroll
        for (int j = 0; j < 8; ++j)
          if (j == dj) pv[j] = 0.f;
      }
      float lsum = 0.f;
      #pragma unroll
      for (int j = 0; j < 8; ++j) lsum += pv[j];
      ssum[ti] += lsum;

      union { frag_ab f; unsigned u[4]; } cv;
      cv.u[0] = cvt_pk_bf16(pv[0], pv[1]);
      cv.u[1] = cvt_pk_bf16(pv[2], pv[3]);
      cv.u[2] = cvt_pk_bf16(pv[4], pv[5]);
      cv.u[3] = cvt_pk_bf16(pv[6], pv[7]);
      acc[ti] = __builtin_amdgcn_mfma_f32_16x16x32_bf16(cv.f, bfrag, acc[ti], 0, 0, 0);
    }
  }

  #pragma unroll
  for (int ti = 0; ti < 8; ++ti) {
    ssum[ti] += __shfl_xor(ssum[ti], 16);
    ssum[ti] += __shfl_xor(ssum[ti], 32);
  }
  if (L < 16) {
    #pragma unroll
    for (int ti = 0; ti < 8; ++ti)
      Sop[baseS + icol * 128 + ti * 16 + L] = ssum[ti];
  }

  float* ob = OHn + ((long long)(b * D + d) * HW + icol * 128) * 16;
  #pragma unroll
  for (int ti = 0; ti < 8; ++ti)
    #pragma unroll
    for (int reg = 0; reg < 4; ++reg)
      ob[(ti * 16 + chunk * 4 + reg) * 16 + p] = acc[ti][reg];
}

// ---------------------------------------------------------------------------
// K_comb: res = x + gamma/(s_i+s_o) * (oW + oH), written TRANSPOSED.
// ---------------------------------------------------------------------------
template<bool TO_BF16>
__global__ __launch_bounds__(256) void k_comb(
    const float* __restrict__ Xn, const float* __restrict__ OWn,
    const float* __restrict__ OHn, const float* __restrict__ Sip,
    const float* __restrict__ Sop, const float* __restrict__ gp,
    float* __restrict__ Yt, short* __restrict__ Xb16)
{
  __shared__ float xs[16][16][17], ows[16][16][17];
  const int tid = threadIdx.x;
  const int tile = blockIdx.x, d = blockIdx.y, b = blockIdx.z;
  const int o0 = (tile >> 3) * 16, i0 = (tile & 7) * 16;
  const int sl = b * 16 + d;
  const long long baseM = (long long)sl * HW;
  const long long xbase = (long long)b * CDHW + (long long)d * HW;

  const int to = tid >> 4, ti = tid & 15;
  #pragma unroll
  for (int c = 0; c < 16; ++c) {
    const long long src = xbase + (long long)c * DHW + (o0 + to) * 128 + (i0 + ti);
    xs[c][to][ti] = Xn[src];
  }
  {
    const float* osrc = OWn + ((long long)(b * D + d) * HW + (o0 + to) * 128 + (i0 + ti)) * 16;
    float4 f0 = *(const float4*)(osrc);
    float4 f1 = *(const float4*)(osrc + 4);
    float4 f2 = *(const float4*)(osrc + 8);
    float4 f3 = *(const float4*)(osrc + 12);
    ows[0][to][ti] = f0.x;  ows[1][to][ti] = f0.y;
    ows[2][to][ti] = f0.z;  ows[3][to][ti] = f0.w;
    ows[4][to][ti] = f1.x;  ows[5][to][ti] = f1.y;
    ows[6][to][ti] = f1.z;  ows[7][to][ti] = f1.w;
    ows[8][to][ti] = f2.x;  ows[9][to][ti] = f2.y;
    ows[10][to][ti] = f2.z; ows[11][to][ti] = f2.w;
    ows[12][to][ti] = f3.x; ows[13][to][ti] = f3.y;
    ows[14][to][ti] = f3.z; ows[15][to][ti] = f3.w;
  }
  __syncthreads();

  const int ti2 = tid >> 4, to2 = tid & 15;
  const int i = i0 + ti2, o = o0 + to2;
  const float si = Sip[baseM + i * 128 + o];
  const float so = Sop[baseM + i * 128 + o];
  const float gi = gp[0] / (si + so);

  float oh[16];
  {
    const float* osrc = OHn + ((long long)(b * D + d) * HW + i * 128 + o) * 16;
    float4 f0 = *(const float4*)(osrc);
    float4 f1 = *(const float4*)(osrc + 4);
    float4 f2 = *(const float4*)(osrc + 8);
    float4 f3 = *(const float4*)(osrc + 12);
    oh[0] = f0.x;  oh[1] = f0.y;  oh[2] = f0.z;  oh[3] = f0.w;
    oh[4] = f1.x;  oh[5] = f1.y;  oh[6] = f1.z;  oh[7] = f1.w;
    oh[8] = f2.x;  oh[9] = f2.y;  oh[10] = f2.z; oh[11] = f2.w;
    oh[12] = f3.x; oh[13] = f3.y; oh[14] = f3.z; oh[15] = f3.w;
  }

  float res[16];
  #pragma unroll
  for (int c = 0; c < 16; ++c)
    res[c] = fmaf(gi, ows[c][to2][ti2] + oh[c], xs[c][to2][ti2]);

  if constexpr (!TO_BF16) {
    #pragma unroll
    for (int c = 0; c < 16; ++c)
      Yt[xbase + (long long)c * DHW + i * 128 + o] = res[c];
  } else {
    unsigned pk[8];
    #pragma unroll
    for (int c = 0; c < 8; ++c)
      pk[c] = (unsigned)f2bf(res[2 * c]) | ((unsigned)f2bf(res[2 * c + 1]) << 16);
    short* dst = Xb16 + ((long long)(b * D + d) * HW + i * 128 + o) * 16;
    *(uint4*)(dst)     = make_uint4(pk[0], pk[1], pk[2], pk[3]);
    *(uint4*)(dst + 8) = make_uint4(pk[4], pk[5], pk[6], pk[7]);
  }
}

// ---------------------------------------------------------------------------
// K_wt: pack gate weights -> bf16 per-half layout:
// WT16[(half*64+co)*224 + ks*32 + t*8 + c8], tap = ks*4+t (tap 27 zero).
// ---------------------------------------------------------------------------
__global__ __launch_bounds__(256) void k_wt(
    const float* __restrict__ wg, short* __restrict__ WT16)
{
  const int idx = blockIdx.x * 256 + threadIdx.x;   // < 28672
  if (idx >= 2 * 64 * 224) return;
  const int u = idx / 224;           // half*64 + co
  const int k = idx - u * 224;
  const int ks = k >> 5, rem = k & 31;
  const int t = rem >> 3, c8 = rem & 7;
  const int tap = ks * 4 + t;
  const int half = u >> 6, co = u & 63;
  const int cin = half * 8 + c8;
  float v = (tap < 27) ? wg[co * 432 + cin * 27 + tap] : 0.f;
  WT16[idx] = (short)f2bf(v);
}

// ---------------------------------------------------------------------------
// K5a v2: conv_gate via MFMA, cin-halves sequential (LDS 25.3 KB).
// Per half: stage [kd3][rr4][col132][8c], 7 k-steps (4 taps x 8 cin each).
// Gates stored bf16.
// ---------------------------------------------------------------------------
__global__ __launch_bounds__(256, 2) void k_gates(
    const short* __restrict__ XB16, const short* __restrict__ WT16,
    short* __restrict__ g0, short* __restrict__ g1,
    short* __restrict__ g2, short* __restrict__ g3)
{
  __shared__ short xls[1584 * 8];       // 25.3 KB
  const int tid = threadIdx.x;
  const int rp = blockIdx.x;            // 0..63 (2-row group)
  const int d = blockIdx.y, b = blockIdx.z;
  const int h0 = rp * 2;

  const int lane = tid & 63;
  const int og   = tid >> 6;
  const int p    = lane & 15;
  const int chunk = lane >> 4;

  const short* xb = XB16 + (long long)(b * D) * HW * 16;
  const frag_ab zero8 = {0, 0, 0, 0, 0, 0, 0, 0};

  frag_cd acc[2][8];
  #pragma unroll
  for (int r2 = 0; r2 < 2; ++r2)
    #pragma unroll
    for (int pg = 0; pg < 8; ++pg)
      acc[r2][pg] = (frag_cd){0.f, 0.f, 0.f, 0.f};

  int offs[7];
  #pragma unroll
  for (int s = 0; s < 7; ++s) {
    int tap = s * 4 + chunk;
    if (tap > 26) tap = 0;              // pad (A==0)
    const int kd = (tap * 57) >> 9;     // tap/9
    const int rem = tap - kd * 9;
    const int kh = (rem * 11) >> 5;     // rem/3
    const int kw = rem - kh * 3;
    offs[s] = ((kd * 4 + kh) * 132 + p + kw) * 8;
  }

  for (int half = 0; half < 2; ++half) {
    // stage: 3 kd x 4 rows x 132 cols x 8c
    for (int idx = tid; idx < 1584; idx += 256) {
      const int kd = idx / 528;
      const int rem = idx - kd * 528;
      const int rr = rem / 132;
      const int col = rem - rr * 132;
      const int dd = d - 1 + kd, gh = h0 - 1 + rr, gw = col - 1;
      frag_ab v = zero8;
      if (dd >= 0 && dd < D && gh >= 0 && gh < H && gw >= 0 && gw < W)
        v = *(const frag_ab*)(xb + ((long long)dd * HW + gh * W + gw) * 16 + half * 8);
      *(frag_ab*)&xls[idx * 8] = v;
    }
    __syncthreads();

    frag_ab a[7];
    {
      const short* wl = WT16 + ((half << 6) + og * 16 + p) * 224 + chunk * 8;
      #pragma unroll
      for (int s = 0; s < 7; ++s)
        a[s] = *(const frag_ab*)(wl + s * 32);
    }

    #pragma unroll
    for (int s = 0; s < 7; ++s) {
      const frag_ab av = a[s];
      const int base0 = offs[s];
      #pragma unroll
      for (int pg = 0; pg < 8; ++pg) {
        frag_ab b0 = *(const frag_ab*)&xls[base0 + pg * 128];
        acc[0][pg] = __builtin_amdgcn_mfma_f32_16x16x32_bf16(av, b0, acc[0][pg], 0, 0, 0);
        frag_ab b1 = *(const frag_ab*)&xls[base0 + 1056 + pg * 128];
        acc[1][pg] = __builtin_amdgcn_mfma_f32_16x16x32_bf16(av, b1, acc[1][pg], 0, 0, 0);
      }
    }
    __syncthreads();   // before restage
  }

  short* gbuf = (og == 0) ? g0 : (og == 1) ? g1 : (og == 2) ? g2 : g3;
  const long long base = (long long)b * CDHW + (long long)d * HW + h0 * W;
  #pragma unroll
  for (int r2 = 0; r2 < 2; ++r2)
    #pragma unroll
    for (int pg = 0; pg < 8; ++pg)
      #pragma unroll
      for (int reg = 0; reg < 4; ++reg) {
        const int cc = chunk * 4 + reg;
        gbuf[base + (long long)cc * DHW + r2 * W + pg * 16 + p] =
            (short)f2bf(acc[r2][pg][reg]);
      }
}

// ---------------------------------------------------------------------------
// K5b: BN + activations + SRU scan over D. Gates read as bf16.
// ---------------------------------------------------------------------------
__global__ __launch_bounds__(256) void k_scan(
    const short* __restrict__ g0, const short* __restrict__ g1,
    const short* __restrict__ g2, const short* __restrict__ g3,
    const float* __restrict__ bg, const float* __restrict__ bb,
    const float* __restrict__ bm, const float* __restrict__ bv,
    float* __restrict__ out)
{
  const int g = blockIdx.x * 256 + threadIdx.x;   // 0 .. 524287
  const int hw = g & 16383;
  const int cc = (g >> 14) & 15;
  const int b  = g >> 18;

  float sc[4], bi[4];
  #pragma unroll
  for (int gg = 0; gg < 4; ++gg) {
    int ch = gg * 16 + cc;
    float s = bg[ch] * rsqrtf(bv[ch] + EPSBN);
    sc[gg] = s;
    bi[gg] = bb[ch] - bm[ch] * s;
  }

  const long long base = (long long)b * CDHW + (long long)cc * DHW + hw;
  float Ct = 0.f;
  for (int d = 0; d < D; ++d) {
    const long long idx = base + (long long)d * HW;
    float wx = tanhf(fmaf(bf2f(g0[idx]), sc[0], bi[0]));
    float ft = 1.f / (1.f + __expf(-fmaf(bf2f(g1[idx]), sc[1], bi[1])));
    float rt = 1.f / (1.f + __expf(-fmaf(bf2f(g2[idx]), sc[2], bi[2])));
    float xg = tanhf(fmaf(bf2f(g3[idx]), sc[3], bi[3]));
    Ct = (d == 0) ? (1.f - ft) : fmaf(ft, Ct, (1.f - ft) * wx);
    out[idx] = fmaf(rt, Ct, (1.f - rt) * xg);
  }
}

// ---------------------------------------------------------------------------
extern "C" void kernel_launch(void* const* d_in, const int* in_sizes, int n_in,
                              void* d_out, int out_size, void* d_ws, size_t ws_size,
                              hipStream_t stream) {
  const float* x      = (const float*)d_in[0];
  const float* w_pre  = (const float*)d_in[1];
  const float* bnpg   = (const float*)d_in[2];
  const float* bnpb   = (const float*)d_in[3];
  const float* bnpm   = (const float*)d_in[4];
  const float* bnpv   = (const float*)d_in[5];
  const float* wq     = (const float*)d_in[6];
  const float* wk     = (const float*)d_in[7];
  const float* wv     = (const float*)d_in[8];
  const float* gamma  = (const float*)d_in[9];
  const float* w_gate = (const float*)d_in[10];
  const float* bng    = (const float*)d_in[11];
  const float* bnb    = (const float*)d_in[12];
  const float* bnm    = (const float*)d_in[13];
  const float* bnv    = (const float*)d_in[14];

  float* ws  = (float*)d_ws;
  float* R0  = ws + OFF_R0;
  float* R1  = ws + OFF_R1;
  float* Kb  = ws + OFF_K;
  float* KTb = ws + OFF_KT;
  float* QTb = ws + OFF_QT;
  float* SI  = ws + OFF_MST;
  float* SO  = ws + OFF_SO;
  float* R2  = ws + OFF_R2;
  float* R3  = ws + OFF_R3;
  short* XB0  = (short*)(ws + OFF_R1);  // bf16 input (pre-attention phase)
  short* XB16 = (short*)(ws + OFF_R1);  // bf16 attn output (post-attention)
  short* WP16 = (short*)(ws + OFF_SO);  // bf16 conv_pre weights (early phase)
  short* WT16 = (short*)(ws + OFF_K);   // bf16 gate weights
  // bf16 V/VT per app
  short* V1b  = (short*)(ws + OFF_R2);
  short* VT1b = (short*)(ws + OFF_R3);
  short* V2b  = (short*)(ws + OFF_R0);
  short* VT2b = (short*)(ws + OFF_R1) + 8388608;  // upper half of R1
  // bf16 gate buffers: two per region
  short* G0b = (short*)(ws + OFF_R0);
  short* G1b = (short*)(ws + OFF_R0) + 8388608;
  short* G2b = (short*)(ws + OFF_R2);
  short* G3b = (short*)(ws + OFF_R2) + 8388608;
  float* out = (float*)d_out;

  const dim3 gTile(64, D, B), gAtt(32, D, B);

  // stage 1: conv_pre via MFMA: x -> bf16 pos-major -> X1 (fp32) in R0
  k_wp <<<dim3(12),  dim3(256), 0, stream>>>(w_pre, WP16);
  k_x16<<<gTile,     dim3(256), 0, stream>>>(x, XB0);
  k_conv_pre16<<<dim3(16, D, B), dim3(256), 0, stream>>>(
      XB0, WP16, bnpg, bnpb, bnpm, bnpv, R0);

  // attention application 1 (mask on outer): x=R0, V16->R2, VT16->R3
  k_qkv<<<gTile, dim3(256), 0, stream>>>(R0, wq, wk, wv, Kb, KTb, QTb, V1b, VT1b);
  k_att_row<false><<<gAtt, dim3(256), 0, stream>>>(R0, R1, Kb, V1b, SI, wq);      // OWn->R1
  k_att_col<false><<<gAtt, dim3(256), 0, stream>>>(KTb, QTb, VT1b, R2, SO);       // OHn->R2
  k_comb<false><<<gTile, dim3(256), 0, stream>>>(R0, R1, R2, SI, SO, gamma, R3, nullptr); // Y->R3

  // attention application 2 (transposed layout; mask on inner): x=R3
  k_qkv<<<gTile, dim3(256), 0, stream>>>(R3, wq, wk, wv, Kb, KTb, QTb, V2b, VT2b);
  k_att_row<true><<<gAtt, dim3(256), 0, stream>>>(R3, R2, Kb, V2b, SI, wq);       // OWn->R2
  k_att_col<true><<<gAtt, dim3(256), 0, stream>>>(KTb, QTb, VT2b, R0, SO);        // OHn->R0
  k_comb<true><<<gTile, dim3(256), 0, stream>>>(R3, R2, R0, SI, SO, gamma, nullptr, XB16); // ->R1 lower

  // bf16 gate weights (K region free now)
  k_wt<<<dim3(112), dim3(256), 0, stream>>>(w_gate, WT16);

  // stage 3: conv_gate via MFMA -> bf16 gates (G0,G1 in R0; G2,G3 in R2)
  k_gates<<<dim3(64, D, B), dim3(256), 0, stream>>>(XB16, WT16, G0b, G1b, G2b, G3b);

  // stage 4: BN + activations + SRU scan -> out
  k_scan<<<dim3(2048), dim3(256), 0, stream>>>(G0b, G1b, G2b, G3b, bng, bnb, bnm, bnv, out);
}

// Round 18
// 297.776 us; speedup vs baseline: 2.1822x; 1.0007x over previous
//
#include <hip/hip_runtime.h>
#include <math.h>

// Problem constants
namespace {
constexpr int B = 2, C = 16, D = 16, H = 128, W = 128;
constexpr int HW   = H * W;        // 16384
constexpr int DHW  = D * HW;       // 262144
constexpr int CDHW = C * DHW;      // 4194304
constexpr float EPSBN = 1e-5f;

// workspace regions (floats). ws = 37,748,736 floats = 151 MB
constexpr long long OFF_R0  = 0;
constexpr long long OFF_R1  = 8388608;
constexpr long long OFF_K   = 16777216;  // K / WT16 (bf16 gate weights)
constexpr long long OFF_KT  = 17825792;
constexpr long long OFF_QT  = 18874368;
constexpr long long OFF_MST = 19922944;  // s_inner (I,O); 0.5M used
constexpr long long OFF_SO  = 20447232;  // s_outer (I,O); 0.5M used; WP16 early
constexpr long long OFF_R2  = 20971520;
constexpr long long OFF_R3  = 29360128;
}

using frag_ab = __attribute__((ext_vector_type(8))) short;  // 8 bf16
using frag_cd = __attribute__((ext_vector_type(4))) float;  // 4 f32

__device__ __forceinline__ unsigned short f2bf(float f) {
  unsigned u = __float_as_uint(f);
  u = (u + 0x7FFF + ((u >> 16) & 1)) >> 16;   // RNE
  return (unsigned short)u;
}
__device__ __forceinline__ float bf2f(short s) {
  return __uint_as_float(((unsigned)(unsigned short)s) << 16);
}
__device__ __forceinline__ unsigned cvt_pk_bf16(float lo, float hi) {
  unsigned r;
  asm volatile("v_cvt_pk_bf16_f32 %0, %1, %2" : "=v"(r) : "v"(lo), "v"(hi));
  return r;
}

// ---------------------------------------------------------------------------
// K_x16: cast input x (fp32, c-major) -> bf16 [pos][16c]. grid(64, D, B).
// ---------------------------------------------------------------------------
__global__ __launch_bounds__(256) void k_x16(
    const float* __restrict__ x, short* __restrict__ XB0)
{
  const int tid = threadIdx.x;
  const int tile = blockIdx.x, d = blockIdx.y, b = blockIdx.z;
  const int h0 = (tile >> 3) * 16, w0 = (tile & 7) * 16;
  const long long xbase = (long long)b * CDHW + (long long)d * HW;
  const int th = tid >> 4, tw = tid & 15;

  float v[16];
  #pragma unroll
  for (int c = 0; c < 16; ++c)
    v[c] = x[xbase + (long long)c * DHW + (h0 + th) * 128 + (w0 + tw)];

  unsigned pk[8];
  #pragma unroll
  for (int c = 0; c < 8; ++c)
    pk[c] = (unsigned)f2bf(v[2 * c]) | ((unsigned)f2bf(v[2 * c + 1]) << 16);
  short* dst = XB0 + ((long long)(b * D + d) * HW + (h0 + th) * 128 + (w0 + tw)) * 16;
  *(uint4*)(dst)     = make_uint4(pk[0], pk[1], pk[2], pk[3]);
  *(uint4*)(dst + 8) = make_uint4(pk[4], pk[5], pk[6], pk[7]);
}

// ---------------------------------------------------------------------------
// K_wp: pack conv_pre weights -> bf16 per-half layout:
// WP16[(half*16+co)*96 + ks*32 + t*8 + c8], tap = ks*4+t (taps>=9 zero).
// ---------------------------------------------------------------------------
__global__ __launch_bounds__(256) void k_wp(
    const float* __restrict__ wp, short* __restrict__ WP16)
{
  const int idx = blockIdx.x * 256 + threadIdx.x;   // < 3072
  if (idx >= 2 * 16 * 96) return;
  const int u = idx / 96;            // half*16 + co
  const int k = idx - u * 96;
  const int ks = k >> 5, rem = k & 31;
  const int t = rem >> 3, c8 = rem & 7;
  const int tap = ks * 4 + t;
  const int half = u >> 4, co = u & 15;
  const int cin = half * 8 + c8;
  float v = (tap < 9) ? wp[co * 144 + cin * 9 + tap] : 0.f;
  WP16[idx] = (short)f2bf(v);
}

// ---------------------------------------------------------------------------
// K1 v3: conv_pre via MFMA, cin-halves processed sequentially (LDS 21 KB).
// grid(16 rowgroups, D, B), block 256 = 4 waves; wave = 2 rows x 128 cols.
// Per half: stage 10 rows x 132 x 8c bf16, 3 k-steps (4 taps x 8 cin each).
// ---------------------------------------------------------------------------
__global__ __launch_bounds__(256) void k_conv_pre16(
    const short* __restrict__ XB0, const short* __restrict__ WP16,
    const float* __restrict__ bg, const float* __restrict__ bb,
    const float* __restrict__ bm, const float* __restrict__ bv,
    float* __restrict__ X1)
{
  __shared__ short xls[10 * 132 * 8];   // 21.1 KB
  const int tid = threadIdx.x;
  const int rg = blockIdx.x;
  const int d = blockIdx.y, b = blockIdx.z;
  const int h0 = rg * 8;

  const int lane = tid & 63;
  const int wv   = tid >> 6;
  const int p    = lane & 15;
  const int chunk = lane >> 4;

  const short* xb0 = XB0 + (long long)(b * D + d) * HW * 16;
  const frag_ab zero8 = {0, 0, 0, 0, 0, 0, 0, 0};

  frag_cd acc[2][8];
  #pragma unroll
  for (int r2 = 0; r2 < 2; ++r2)
    #pragma unroll
    for (int pg = 0; pg < 8; ++pg)
      acc[r2][pg] = (frag_cd){0.f, 0.f, 0.f, 0.f};

  // per-lane B offsets (independent of half)
  int offs[3];
  #pragma unroll
  for (int s = 0; s < 3; ++s) {
    int tap = s * 4 + chunk;
    if (tap > 8) tap = 0;               // padded (A==0) -> in-bounds addr
    const int kh = (tap * 11) >> 5;     // tap/3
    const int kw = tap - kh * 3;
    offs[s] = ((2 * wv + kh) * 132 + p + kw) * 8;
  }

  for (int half = 0; half < 2; ++half) {
    // stage this half's slab: 10 x 132 positions x 8c
    for (int idx = tid; idx < 1320; idx += 256) {
      const int row = idx / 132, col = idx - row * 132;
      const int gh = h0 - 1 + row, gw = col - 1;
      frag_ab v = zero8;
      if (gh >= 0 && gh < H && gw >= 0 && gw < W)
        v = *(const frag_ab*)(xb0 + ((long long)gh * 128 + gw) * 16 + half * 8);
      *(frag_ab*)&xls[idx * 8] = v;
    }
    __syncthreads();

    frag_ab a[3];
    {
      const short* wl = WP16 + ((half << 4) + p) * 96 + chunk * 8;
      #pragma unroll
      for (int s = 0; s < 3; ++s)
        a[s] = *(const frag_ab*)(wl + s * 32);
    }

    #pragma unroll
    for (int s = 0; s < 3; ++s) {
      const frag_ab av = a[s];
      const int base0 = offs[s];
      #pragma unroll
      for (int pg = 0; pg < 8; ++pg) {
        frag_ab b0 = *(const frag_ab*)&xls[base0 + pg * 128];
        acc[0][pg] = __builtin_amdgcn_mfma_f32_16x16x32_bf16(av, b0, acc[0][pg], 0, 0, 0);
        frag_ab b1 = *(const frag_ab*)&xls[base0 + 1056 + pg * 128];
        acc[1][pg] = __builtin_amdgcn_mfma_f32_16x16x32_bf16(av, b1, acc[1][pg], 0, 0, 0);
      }
    }
    __syncthreads();   // before restage
  }

  float sc4[4], bi4[4];
  #pragma unroll
  for (int reg = 0; reg < 4; ++reg) {
    const int co = chunk * 4 + reg;
    float s = bg[co] * rsqrtf(bv[co] + EPSBN);
    sc4[reg] = s;
    bi4[reg] = bb[co] - bm[co] * s;
  }
  const long long xbase = (long long)b * CDHW + (long long)d * HW;
  #pragma unroll
  for (int r2 = 0; r2 < 2; ++r2) {
    const int row = h0 + 2 * wv + r2;
    #pragma unroll
    for (int pg = 0; pg < 8; ++pg)
      #pragma unroll
      for (int reg = 0; reg < 4; ++reg) {
        const int co = chunk * 4 + reg;
        float v = fmaxf(fmaf(acc[r2][pg][reg], sc4[reg], bi4[reg]), 0.f);
        X1[xbase + (long long)co * DHW + row * 128 + pg * 16 + p] = v;
      }
  }
}

// ---------------------------------------------------------------------------
// K2: projections. V/VT stored bf16.
// ---------------------------------------------------------------------------
__global__ __launch_bounds__(256) void k_qkv(
    const float* __restrict__ xin, const float* __restrict__ wq,
    const float* __restrict__ wk, const float* __restrict__ wv,
    float* __restrict__ Kp, float* __restrict__ KTp, float* __restrict__ QTp,
    short* __restrict__ Vp16, short* __restrict__ VTp16)
{
  const int tid = threadIdx.x;
  const int tile = blockIdx.x, d = blockIdx.y, b = blockIdx.z;
  const int h0 = (tile >> 3) * 16, w0 = (tile & 7) * 16;
  const int ty = tid >> 4, tx = tid & 15;
  const int h = h0 + ty, w = w0 + tx;

  const float* xb = xin + (long long)b * CDHW + (long long)d * HW + h * 128 + w;
  float xv[16];
  #pragma unroll
  for (int c = 0; c < 16; ++c) xv[c] = xb[(long long)c * DHW];

  float q0 = 0, q1 = 0, k0 = 0, k1 = 0, v[16];
  #pragma unroll
  for (int c = 0; c < 16; ++c) {
    q0 = fmaf(wq[c], xv[c], q0);
    q1 = fmaf(wq[16 + c], xv[c], q1);
    k0 = fmaf(wk[c], xv[c], k0);
    k1 = fmaf(wk[16 + c], xv[c], k1);
  }
  #pragma unroll
  for (int o = 0; o < 16; ++o) {
    float a = 0;
    #pragma unroll
    for (int c = 0; c < 16; ++c) a = fmaf(wv[o * 16 + c], xv[c], a);
    v[o] = a;
  }

  const int sl = b * 16 + d;
  const long long base2 = (long long)(sl * 2) * HW;
  const long long baseV = (long long)(sl * 16) * HW;
  const int hw = h * 128 + w;
  Kp[base2 + hw] = k0;
  Kp[base2 + HW + hw] = k1;
  #pragma unroll
  for (int o = 0; o < 16; ++o)
    Vp16[baseV + (long long)o * HW + hw] = (short)f2bf(v[o]);

  __shared__ float lsk[2][16][17];
  __shared__ float lsq[2][16][17];
  __shared__ float lsv[16][16][17];
  lsk[0][ty][tx] = k0; lsk[1][ty][tx] = k1;
  lsq[0][ty][tx] = q0; lsq[1][ty][tx] = q1;
  #pragma unroll
  for (int o = 0; o < 16; ++o) lsv[o][ty][tx] = v[o];
  __syncthreads();

  const int wh = (w0 + ty) * 128 + (h0 + tx);
  KTp[base2 + wh]      = lsk[0][tx][ty];
  KTp[base2 + HW + wh] = lsk[1][tx][ty];
  QTp[base2 + wh]      = lsq[0][tx][ty];
  QTp[base2 + HW + wh] = lsq[1][tx][ty];
  #pragma unroll
  for (int o = 0; o < 16; ++o)
    VTp16[baseV + (long long)o * HW + wh] = (short)f2bf(lsv[o][tx][ty]);
}

// ---------------------------------------------------------------------------
// K3 v6: INNER direction via MFMA. V slab copied bf16 directly.
// ---------------------------------------------------------------------------
template<bool MASK_INNER>
__global__ __launch_bounds__(256) void k_att_row(
    const float* __restrict__ xin, float* __restrict__ OWn,
    const float* __restrict__ Kp, const short* __restrict__ Vp16,
    float* __restrict__ Sip, const float* __restrict__ wq)
{
  __shared__ float kr2[4][128][2];
  __shared__ float q0l[4][128], q1l[4][128];
  __shared__ __align__(16) short v16[4][16][136];
  const int tid = threadIdx.x;
  const int o0 = blockIdx.x * 4, d = blockIdx.y, b = blockIdx.z;
  const int sl = b * 16 + d;
  const long long base2 = (long long)(sl * 2) * HW;
  const long long baseV = (long long)(sl * 16) * HW;
  const long long baseM = (long long)sl * HW;
  const int hi = tid >> 6;
  const int L  = tid & 63;
  const int p  = L & 15;
  const int chunk = L >> 4;
  const int orow = o0 + hi;
  const long long xbase = (long long)b * CDHW + (long long)d * HW;

  for (int kk = tid; kk < 1024; kk += 256) {
    int col = kk & 127;
    int t = kk >> 7;
    int r2 = t >> 1, o = t & 1;
    kr2[r2][col][o] = Kp[base2 + (long long)o * HW + (o0 + r2) * 128 + col];
  }
  for (int idx = tid; idx < 2048; idx += 256) {
    int v4 = idx & 31;
    int t = idx >> 5;
    int c = t & 15, r2 = t >> 4;
    *(uint2*)&v16[r2][c][v4 * 4] =
        *(const uint2*)&Vp16[baseV + (long long)c * HW + (o0 + r2) * 128 + v4 * 4];
  }
  {
    float q0a = 0.f, q0b = 0.f, q1a = 0.f, q1b = 0.f;
    #pragma unroll
    for (int c = 0; c < 16; ++c) {
      const float w0 = wq[c], w1 = wq[16 + c];
      float xa = xin[xbase + (long long)c * DHW + orow * 128 + L];
      float xb2 = xin[xbase + (long long)c * DHW + orow * 128 + L + 64];
      q0a = fmaf(w0, xa, q0a);  q1a = fmaf(w1, xa, q1a);
      q0b = fmaf(w0, xb2, q0b); q1b = fmaf(w1, xb2, q1b);
    }
    q0l[hi][L] = q0a; q0l[hi][L + 64] = q0b;
    q1l[hi][L] = q1a; q1l[hi][L + 64] = q1b;
  }
  __syncthreads();

  float q0r[8], q1r[8];
  #pragma unroll
  for (int ti = 0; ti < 8; ++ti) {
    q0r[ti] = q0l[hi][ti * 16 + p];
    q1r[ti] = q1l[hi][ti * 16 + p];
  }

  frag_cd acc[8];
  #pragma unroll
  for (int ti = 0; ti < 8; ++ti) acc[ti] = (frag_cd){0.f, 0.f, 0.f, 0.f};
  float ssum[8] = {0.f, 0.f, 0.f, 0.f, 0.f, 0.f, 0.f, 0.f};

  #pragma unroll
  for (int ks = 0; ks < 4; ++ks) {
    const int vb = ks * 32 + chunk * 8;
    float2 kv[8];
    const float* kvp = &kr2[hi][vb][0];
    *(float4*)&kv[0] = *(const float4*)(kvp);
    *(float4*)&kv[2] = *(const float4*)(kvp + 4);
    *(float4*)&kv[4] = *(const float4*)(kvp + 8);
    *(float4*)&kv[6] = *(const float4*)(kvp + 12);
    frag_ab bfrag = *(const frag_ab*)&v16[hi][p][vb];

    #pragma unroll
    for (int ti = 0; ti < 8; ++ti) {
      float pv[8];
      #pragma unroll
      for (int j = 0; j < 8; ++j) {
        float e = fmaf(q0r[ti], kv[j].x, q1r[ti] * kv[j].y);
        pv[j] = __expf(e);
      }
      if constexpr (MASK_INNER) {
        const int dj = ti * 16 + p - vb;
        #pragma unroll
        for (int j = 0; j < 8; ++j)
          if (j == dj) pv[j] = 0.f;
      }
      float lsum = 0.f;
      #pragma unroll
      for (int j = 0; j < 8; ++j) lsum += pv[j];
      ssum[ti] += lsum;

      union { frag_ab f; unsigned u[4]; } cv;
      cv.u[0] = cvt_pk_bf16(pv[0], pv[1]);
      cv.u[1] = cvt_pk_bf16(pv[2], pv[3]);
      cv.u[2] = cvt_pk_bf16(pv[4], pv[5]);
      cv.u[3] = cvt_pk_bf16(pv[6], pv[7]);
      acc[ti] = __builtin_amdgcn_mfma_f32_16x16x32_bf16(cv.f, bfrag, acc[ti], 0, 0, 0);
    }
  }

  #pragma unroll
  for (int ti = 0; ti < 8; ++ti) {
    ssum[ti] += __shfl_xor(ssum[ti], 16);
    ssum[ti] += __shfl_xor(ssum[ti], 32);
  }
  if (L < 16) {
    #pragma unroll
    for (int ti = 0; ti < 8; ++ti)
      Sip[baseM + (ti * 16 + L) * 128 + orow] = ssum[ti];
  }

  float* ob = OWn + ((long long)(b * D + d) * HW + orow * 128) * 16;
  #pragma unroll
  for (int ti = 0; ti < 8; ++ti)
    #pragma unroll
    for (int reg = 0; reg < 4; ++reg)
      ob[(ti * 16 + chunk * 4 + reg) * 16 + p] = acc[ti][reg];
}

// ---------------------------------------------------------------------------
// K4 v6: OUTER direction via MFMA. VT slab copied bf16 directly.
// ---------------------------------------------------------------------------
template<bool MASK_INNER>
__global__ __launch_bounds__(256) void k_att_col(
    const float* __restrict__ KTp, const float* __restrict__ QTp,
    const short* __restrict__ VTp16, float* __restrict__ OHn,
    float* __restrict__ Sop)
{
  __shared__ float kr2[4][128][2];
  __shared__ __align__(16) short v16[4][16][136];
  const int tid = threadIdx.x;
  const int i0 = blockIdx.x * 4, d = blockIdx.y, b = blockIdx.z;
  const int sl = b * 16 + d;
  const long long base2 = (long long)(sl * 2) * HW;
  const long long baseV = (long long)(sl * 16) * HW;
  const long long baseS = (long long)sl * HW;
  const int hi = tid >> 6;
  const int L  = tid & 63;
  const int p  = L & 15;
  const int chunk = L >> 4;
  const int icol = i0 + hi;

  for (int kk = tid; kk < 1024; kk += 256) {
    int col = kk & 127;
    int t = kk >> 7;
    int r2 = t >> 1, o = t & 1;
    kr2[r2][col][o] = KTp[base2 + (long long)o * HW + (i0 + r2) * 128 + col];
  }
  for (int idx = tid; idx < 2048; idx += 256) {
    int j4 = idx & 31;
    int t = idx >> 5;
    int c = t & 15, r2 = t >> 4;
    *(uint2*)&v16[r2][c][j4 * 4] =
        *(const uint2*)&VTp16[baseV + (long long)c * HW + (i0 + r2) * 128 + j4 * 4];
  }
  __syncthreads();

  float q0r[8], q1r[8];
  #pragma unroll
  for (int ti = 0; ti < 8; ++ti) {
    q0r[ti] = QTp[base2 + icol * 128 + ti * 16 + p];
    q1r[ti] = QTp[base2 + HW + icol * 128 + ti * 16 + p];
  }

  frag_cd acc[8];
  #pragma unroll
  for (int ti = 0; ti < 8; ++ti) acc[ti] = (frag_cd){0.f, 0.f, 0.f, 0.f};
  float ssum[8] = {0.f, 0.f, 0.f, 0.f, 0.f, 0.f, 0.f, 0.f};

  #pragma unroll
  for (int ks = 0; ks < 4; ++ks) {
    const int vb = ks * 32 + chunk * 8;
    float2 kv[8];
    const float* kvp = &kr2[hi][vb][0];
    *(float4*)&kv[0] = *(const float4*)(kvp);
    *(float4*)&kv[2] = *(const float4*)(kvp + 4);
    *(float4*)&kv[4] = *(const float4*)(kvp + 8);
    *(float4*)&kv[6] = *(const float4*)(kvp + 12);
    frag_ab bfrag = *(const frag_ab*)&v16[hi][p][vb];

    #pragma unroll
    for (int ti = 0; ti < 8; ++ti) {
      float pv[8];
      #pragma unroll
      for (int j = 0; j < 8; ++j) {
        float e = fmaf(q0r[ti], kv[j].x, q1r[ti] * kv[j].y);
        pv[j] = __expf(e);
      }
      if constexpr (!MASK_INNER) {
        const int dj = ti * 16 + p - vb;    // mask j == orr
        #pragma unroll
        for (int j = 0; j < 8; ++j)
          if (j == dj) pv[j] = 0.f;
      }
      float lsum = 0.f;
      #pragma unroll
      for (int j = 0; j < 8; ++j) lsum += pv[j];
      ssum[ti] += lsum;

      union { frag_ab f; unsigned u[4]; } cv;
      cv.u[0] = cvt_pk_bf16(pv[0], pv[1]);
      cv.u[1] = cvt_pk_bf16(pv[2], pv[3]);
      cv.u[2] = cvt_pk_bf16(pv[4], pv[5]);
      cv.u[3] = cvt_pk_bf16(pv[6], pv[7]);
      acc[ti] = __builtin_amdgcn_mfma_f32_16x16x32_bf16(cv.f, bfrag, acc[ti], 0, 0, 0);
    }
  }

  #pragma unroll
  for (int ti = 0; ti < 8; ++ti) {
    ssum[ti] += __shfl_xor(ssum[ti], 16);
    ssum[ti] += __shfl_xor(ssum[ti], 32);
  }
  if (L < 16) {
    #pragma unroll
    for (int ti = 0; ti < 8; ++ti)
      Sop[baseS + icol * 128 + ti * 16 + L] = ssum[ti];
  }

  float* ob = OHn + ((long long)(b * D + d) * HW + icol * 128) * 16;
  #pragma unroll
  for (int ti = 0; ti < 8; ++ti)
    #pragma unroll
    for (int reg = 0; reg < 4; ++reg)
      ob[(ti * 16 + chunk * 4 + reg) * 16 + p] = acc[ti][reg];
}

// ---------------------------------------------------------------------------
// K_comb: res = x + gamma/(s_i+s_o) * (oW + oH), written TRANSPOSED.
// ---------------------------------------------------------------------------
template<bool TO_BF16>
__global__ __launch_bounds__(256) void k_comb(
    const float* __restrict__ Xn, const float* __restrict__ OWn,
    const float* __restrict__ OHn, const float* __restrict__ Sip,
    const float* __restrict__ Sop, const float* __restrict__ gp,
    float* __restrict__ Yt, short* __restrict__ Xb16)
{
  __shared__ float xs[16][16][17], ows[16][16][17];
  const int tid = threadIdx.x;
  const int tile = blockIdx.x, d = blockIdx.y, b = blockIdx.z;
  const int o0 = (tile >> 3) * 16, i0 = (tile & 7) * 16;
  const int sl = b * 16 + d;
  const long long baseM = (long long)sl * HW;
  const long long xbase = (long long)b * CDHW + (long long)d * HW;

  const int to = tid >> 4, ti = tid & 15;
  #pragma unroll
  for (int c = 0; c < 16; ++c) {
    const long long src = xbase + (long long)c * DHW + (o0 + to) * 128 + (i0 + ti);
    xs[c][to][ti] = Xn[src];
  }
  {
    const float* osrc = OWn + ((long long)(b * D + d) * HW + (o0 + to) * 128 + (i0 + ti)) * 16;
    float4 f0 = *(const float4*)(osrc);
    float4 f1 = *(const float4*)(osrc + 4);
    float4 f2 = *(const float4*)(osrc + 8);
    float4 f3 = *(const float4*)(osrc + 12);
    ows[0][to][ti] = f0.x;  ows[1][to][ti] = f0.y;
    ows[2][to][ti] = f0.z;  ows[3][to][ti] = f0.w;
    ows[4][to][ti] = f1.x;  ows[5][to][ti] = f1.y;
    ows[6][to][ti] = f1.z;  ows[7][to][ti] = f1.w;
    ows[8][to][ti] = f2.x;  ows[9][to][ti] = f2.y;
    ows[10][to][ti] = f2.z; ows[11][to][ti] = f2.w;
    ows[12][to][ti] = f3.x; ows[13][to][ti] = f3.y;
    ows[14][to][ti] = f3.z; ows[15][to][ti] = f3.w;
  }
  __syncthreads();

  const int ti2 = tid >> 4, to2 = tid & 15;
  const int i = i0 + ti2, o = o0 + to2;
  const float si = Sip[baseM + i * 128 + o];
  const float so = Sop[baseM + i * 128 + o];
  const float gi = gp[0] / (si + so);

  float oh[16];
  {
    const float* osrc = OHn + ((long long)(b * D + d) * HW + i * 128 + o) * 16;
    float4 f0 = *(const float4*)(osrc);
    float4 f1 = *(const float4*)(osrc + 4);
    float4 f2 = *(const float4*)(osrc + 8);
    float4 f3 = *(const float4*)(osrc + 12);
    oh[0] = f0.x;  oh[1] = f0.y;  oh[2] = f0.z;  oh[3] = f0.w;
    oh[4] = f1.x;  oh[5] = f1.y;  oh[6] = f1.z;  oh[7] = f1.w;
    oh[8] = f2.x;  oh[9] = f2.y;  oh[10] = f2.z; oh[11] = f2.w;
    oh[12] = f3.x; oh[13] = f3.y; oh[14] = f3.z; oh[15] = f3.w;
  }

  float res[16];
  #pragma unroll
  for (int c = 0; c < 16; ++c)
    res[c] = fmaf(gi, ows[c][to2][ti2] + oh[c], xs[c][to2][ti2]);

  if constexpr (!TO_BF16) {
    #pragma unroll
    for (int c = 0; c < 16; ++c)
      Yt[xbase + (long long)c * DHW + i * 128 + o] = res[c];
  } else {
    unsigned pk[8];
    #pragma unroll
    for (int c = 0; c < 8; ++c)
      pk[c] = (unsigned)f2bf(res[2 * c]) | ((unsigned)f2bf(res[2 * c + 1]) << 16);
    short* dst = Xb16 + ((long long)(b * D + d) * HW + i * 128 + o) * 16;
    *(uint4*)(dst)     = make_uint4(pk[0], pk[1], pk[2], pk[3]);
    *(uint4*)(dst + 8) = make_uint4(pk[4], pk[5], pk[6], pk[7]);
  }
}

// ---------------------------------------------------------------------------
// K_wt: pack gate weights -> bf16 per-half layout:
// WT16[(half*64+co)*224 + ks*32 + t*8 + c8], tap = ks*4+t (tap 27 zero).
// ---------------------------------------------------------------------------
__global__ __launch_bounds__(256) void k_wt(
    const float* __restrict__ wg, short* __restrict__ WT16)
{
  const int idx = blockIdx.x * 256 + threadIdx.x;   // < 28672
  if (idx >= 2 * 64 * 224) return;
  const int u = idx / 224;           // half*64 + co
  const int k = idx - u * 224;
  const int ks = k >> 5, rem = k & 31;
  const int t = rem >> 3, c8 = rem & 7;
  const int tap = ks * 4 + t;
  const int half = u >> 6, co = u & 63;
  const int cin = half * 8 + c8;
  float v = (tap < 27) ? wg[co * 432 + cin * 27 + tap] : 0.f;
  WT16[idx] = (short)f2bf(v);
}

// ---------------------------------------------------------------------------
// K5a v2: conv_gate via MFMA, cin-halves sequential (LDS 25.3 KB).
// Per half: stage [kd3][rr4][col132][8c], 7 k-steps (4 taps x 8 cin each).
// Gates stored bf16.
// ---------------------------------------------------------------------------
__global__ __launch_bounds__(256, 2) void k_gates(
    const short* __restrict__ XB16, const short* __restrict__ WT16,
    short* __restrict__ g0, short* __restrict__ g1,
    short* __restrict__ g2, short* __restrict__ g3)
{
  __shared__ short xls[1584 * 8];       // 25.3 KB
  const int tid = threadIdx.x;
  const int rp = blockIdx.x;            // 0..63 (2-row group)
  const int d = blockIdx.y, b = blockIdx.z;
  const int h0 = rp * 2;

  const int lane = tid & 63;
  const int og   = tid >> 6;
  const int p    = lane & 15;
  const int chunk = lane >> 4;

  const short* xb = XB16 + (long long)(b * D) * HW * 16;
  const frag_ab zero8 = {0, 0, 0, 0, 0, 0, 0, 0};

  frag_cd acc[2][8];
  #pragma unroll
  for (int r2 = 0; r2 < 2; ++r2)
    #pragma unroll
    for (int pg = 0; pg < 8; ++pg)
      acc[r2][pg] = (frag_cd){0.f, 0.f, 0.f, 0.f};

  int offs[7];
  #pragma unroll
  for (int s = 0; s < 7; ++s) {
    int tap = s * 4 + chunk;
    if (tap > 26) tap = 0;              // pad (A==0)
    const int kd = (tap * 57) >> 9;     // tap/9
    const int rem = tap - kd * 9;
    const int kh = (rem * 11) >> 5;     // rem/3
    const int kw = rem - kh * 3;
    offs[s] = ((kd * 4 + kh) * 132 + p + kw) * 8;
  }

  for (int half = 0; half < 2; ++half) {
    // stage: 3 kd x 4 rows x 132 cols x 8c
    for (int idx = tid; idx < 1584; idx += 256) {
      const int kd = idx / 528;
      const int rem = idx - kd * 528;
      const int rr = rem / 132;
      const int col = rem - rr * 132;
      const int dd = d - 1 + kd, gh = h0 - 1 + rr, gw = col - 1;
      frag_ab v = zero8;
      if (dd >= 0 && dd < D && gh >= 0 && gh < H && gw >= 0 && gw < W)
        v = *(const frag_ab*)(xb + ((long long)dd * HW + gh * W + gw) * 16 + half * 8);
      *(frag_ab*)&xls[idx * 8] = v;
    }
    __syncthreads();

    frag_ab a[7];
    {
      const short* wl = WT16 + ((half << 6) + og * 16 + p) * 224 + chunk * 8;
      #pragma unroll
      for (int s = 0; s < 7; ++s)
        a[s] = *(const frag_ab*)(wl + s * 32);
    }

    #pragma unroll
    for (int s = 0; s < 7; ++s) {
      const frag_ab av = a[s];
      const int base0 = offs[s];
      #pragma unroll
      for (int pg = 0; pg < 8; ++pg) {
        frag_ab b0 = *(const frag_ab*)&xls[base0 + pg * 128];
        acc[0][pg] = __builtin_amdgcn_mfma_f32_16x16x32_bf16(av, b0, acc[0][pg], 0, 0, 0);
        frag_ab b1 = *(const frag_ab*)&xls[base0 + 1056 + pg * 128];
        acc[1][pg] = __builtin_amdgcn_mfma_f32_16x16x32_bf16(av, b1, acc[1][pg], 0, 0, 0);
      }
    }
    __syncthreads();   // before restage
  }

  short* gbuf = (og == 0) ? g0 : (og == 1) ? g1 : (og == 2) ? g2 : g3;
  const long long base = (long long)b * CDHW + (long long)d * HW + h0 * W;
  #pragma unroll
  for (int r2 = 0; r2 < 2; ++r2)
    #pragma unroll
    for (int pg = 0; pg < 8; ++pg)
      #pragma unroll
      for (int reg = 0; reg < 4; ++reg) {
        const int cc = chunk * 4 + reg;
        gbuf[base + (long long)cc * DHW + r2 * W + pg * 16 + p] =
            (short)f2bf(acc[r2][pg][reg]);
      }
}

// ---------------------------------------------------------------------------
// K5b: BN + activations + SRU scan over D. Gates read as bf16.
// ---------------------------------------------------------------------------
__global__ __launch_bounds__(256) void k_scan(
    const short* __restrict__ g0, const short* __restrict__ g1,
    const short* __restrict__ g2, const short* __restrict__ g3,
    const float* __restrict__ bg, const float* __restrict__ bb,
    const float* __restrict__ bm, const float* __restrict__ bv,
    float* __restrict__ out)
{
  const int g = blockIdx.x * 256 + threadIdx.x;   // 0 .. 524287
  const int hw = g & 16383;
  const int cc = (g >> 14) & 15;
  const int b  = g >> 18;

  float sc[4], bi[4];
  #pragma unroll
  for (int gg = 0; gg < 4; ++gg) {
    int ch = gg * 16 + cc;
    float s = bg[ch] * rsqrtf(bv[ch] + EPSBN);
    sc[gg] = s;
    bi[gg] = bb[ch] - bm[ch] * s;
  }

  const long long base = (long long)b * CDHW + (long long)cc * DHW + hw;
  float Ct = 0.f;
  for (int d = 0; d < D; ++d) {
    const long long idx = base + (long long)d * HW;
    float wx = tanhf(fmaf(bf2f(g0[idx]), sc[0], bi[0]));
    float ft = 1.f / (1.f + __expf(-fmaf(bf2f(g1[idx]), sc[1], bi[1])));
    float rt = 1.f / (1.f + __expf(-fmaf(bf2f(g2[idx]), sc[2], bi[2])));
    float xg = tanhf(fmaf(bf2f(g3[idx]), sc[3], bi[3]));
    Ct = (d == 0) ? (1.f - ft) : fmaf(ft, Ct, (1.f - ft) * wx);
    out[idx] = fmaf(rt, Ct, (1.f - rt) * xg);
  }
}

// ---------------------------------------------------------------------------
extern "C" void kernel_launch(void* const* d_in, const int* in_sizes, int n_in,
                              void* d_out, int out_size, void* d_ws, size_t ws_size,
                              hipStream_t stream) {
  const float* x      = (const float*)d_in[0];
  const float* w_pre  = (const float*)d_in[1];
  const float* bnpg   = (const float*)d_in[2];
  const float* bnpb   = (const float*)d_in[3];
  const float* bnpm   = (const float*)d_in[4];
  const float* bnpv   = (const float*)d_in[5];
  const float* wq     = (const float*)d_in[6];
  const float* wk     = (const float*)d_in[7];
  const float* wv     = (const float*)d_in[8];
  const float* gamma  = (const float*)d_in[9];
  const float* w_gate = (const float*)d_in[10];
  const float* bng    = (const float*)d_in[11];
  const float* bnb    = (const float*)d_in[12];
  const float* bnm    = (const float*)d_in[13];
  const float* bnv    = (const float*)d_in[14];

  float* ws  = (float*)d_ws;
  float* R0  = ws + OFF_R0;
  float* R1  = ws + OFF_R1;
  float* Kb  = ws + OFF_K;
  float* KTb = ws + OFF_KT;
  float* QTb = ws + OFF_QT;
  float* SI  = ws + OFF_MST;
  float* SO  = ws + OFF_SO;
  float* R2  = ws + OFF_R2;
  float* R3  = ws + OFF_R3;
  short* XB0  = (short*)(ws + OFF_R1);  // bf16 input (pre-attention phase)
  short* XB16 = (short*)(ws + OFF_R1);  // bf16 attn output (post-attention)
  short* WP16 = (short*)(ws + OFF_SO);  // bf16 conv_pre weights (early phase)
  short* WT16 = (short*)(ws + OFF_K);   // bf16 gate weights
  // bf16 V/VT per app
  short* V1b  = (short*)(ws + OFF_R2);
  short* VT1b = (short*)(ws + OFF_R3);
  short* V2b  = (short*)(ws + OFF_R0);
  short* VT2b = (short*)(ws + OFF_R1) + 8388608;  // upper half of R1
  // bf16 gate buffers: two per region
  short* G0b = (short*)(ws + OFF_R0);
  short* G1b = (short*)(ws + OFF_R0) + 8388608;
  short* G2b = (short*)(ws + OFF_R2);
  short* G3b = (short*)(ws + OFF_R2) + 8388608;
  float* out = (float*)d_out;

  const dim3 gTile(64, D, B), gAtt(32, D, B);

  // stage 1: conv_pre via MFMA: x -> bf16 pos-major -> X1 (fp32) in R0
  k_wp <<<dim3(12),  dim3(256), 0, stream>>>(w_pre, WP16);
  k_x16<<<gTile,     dim3(256), 0, stream>>>(x, XB0);
  k_conv_pre16<<<dim3(16, D, B), dim3(256), 0, stream>>>(
      XB0, WP16, bnpg, bnpb, bnpm, bnpv, R0);

  // attention application 1 (mask on outer): x=R0, V16->R2, VT16->R3
  k_qkv<<<gTile, dim3(256), 0, stream>>>(R0, wq, wk, wv, Kb, KTb, QTb, V1b, VT1b);
  k_att_row<false><<<gAtt, dim3(256), 0, stream>>>(R0, R1, Kb, V1b, SI, wq);      // OWn->R1
  k_att_col<false><<<gAtt, dim3(256), 0, stream>>>(KTb, QTb, VT1b, R2, SO);       // OHn->R2
  k_comb<false><<<gTile, dim3(256), 0, stream>>>(R0, R1, R2, SI, SO, gamma, R3, nullptr); // Y->R3

  // attention application 2 (transposed layout; mask on inner): x=R3
  k_qkv<<<gTile, dim3(256), 0, stream>>>(R3, wq, wk, wv, Kb, KTb, QTb, V2b, VT2b);
  k_att_row<true><<<gAtt, dim3(256), 0, stream>>>(R3, R2, Kb, V2b, SI, wq);       // OWn->R2
  k_att_col<true><<<gAtt, dim3(256), 0, stream>>>(KTb, QTb, VT2b, R0, SO);        // OHn->R0
  k_comb<true><<<gTile, dim3(256), 0, stream>>>(R3, R2, R0, SI, SO, gamma, nullptr, XB16); // ->R1 lower

  // bf16 gate weights (K region free now)
  k_wt<<<dim3(112), dim3(256), 0, stream>>>(w_gate, WT16);

  // stage 3: conv_gate via MFMA -> bf16 gates (G0,G1 in R0; G2,G3 in R2)
  k_gates<<<dim3(64, D, B), dim3(256), 0, stream>>>(XB16, WT16, G0b, G1b, G2b, G3b);

  // stage 4: BN + activations + SRU scan -> out
  k_scan<<<dim3(2048), dim3(256), 0, stream>>>(G0b, G1b, G2b, G3b, bng, bnb, bnm, bnv, out);
}

// Round 19
// 295.686 us; speedup vs baseline: 2.1977x; 1.0071x over previous
//
#include <hip/hip_runtime.h>
#include <math.h>

// Problem constants
namespace {
constexpr int B = 2, C = 16, D = 16, H = 128, W = 128;
constexpr int HW   = H * W;        // 16384
constexpr int DHW  = D * HW;       // 262144
constexpr int CDHW = C * DHW;      // 4194304
constexpr float EPSBN = 1e-5f;

// workspace regions (floats). ws = 37,748,736 floats = 151 MB
constexpr long long OFF_R0  = 0;
constexpr long long OFF_R1  = 8388608;
constexpr long long OFF_K   = 16777216;  // K / WT16 (bf16 gate weights)
constexpr long long OFF_KT  = 17825792;
constexpr long long OFF_QT  = 18874368;
constexpr long long OFF_MST = 19922944;  // s_inner (I,O); 0.5M used
constexpr long long OFF_SO  = 20447232;  // s_outer (I,O); 0.5M used; WP16 early
constexpr long long OFF_R2  = 20971520;
constexpr long long OFF_R3  = 29360128;
}

using frag_ab = __attribute__((ext_vector_type(8))) short;  // 8 bf16
using frag_cd = __attribute__((ext_vector_type(4))) float;  // 4 f32

__device__ __forceinline__ unsigned short f2bf(float f) {
  unsigned u = __float_as_uint(f);
  u = (u + 0x7FFF + ((u >> 16) & 1)) >> 16;   // RNE
  return (unsigned short)u;
}
__device__ __forceinline__ float bf2f(short s) {
  return __uint_as_float(((unsigned)(unsigned short)s) << 16);
}
__device__ __forceinline__ unsigned cvt_pk_bf16(float lo, float hi) {
  unsigned r;
  asm volatile("v_cvt_pk_bf16_f32 %0, %1, %2" : "=v"(r) : "v"(lo), "v"(hi));
  return r;
}

// ---------------------------------------------------------------------------
// K_x16: cast input x (fp32, c-major) -> bf16 [pos][16c]. grid(64, D, B).
// ---------------------------------------------------------------------------
__global__ __launch_bounds__(256) void k_x16(
    const float* __restrict__ x, short* __restrict__ XB0)
{
  const int tid = threadIdx.x;
  const int tile = blockIdx.x, d = blockIdx.y, b = blockIdx.z;
  const int h0 = (tile >> 3) * 16, w0 = (tile & 7) * 16;
  const long long xbase = (long long)b * CDHW + (long long)d * HW;
  const int th = tid >> 4, tw = tid & 15;

  float v[16];
  #pragma unroll
  for (int c = 0; c < 16; ++c)
    v[c] = x[xbase + (long long)c * DHW + (h0 + th) * 128 + (w0 + tw)];

  unsigned pk[8];
  #pragma unroll
  for (int c = 0; c < 8; ++c)
    pk[c] = (unsigned)f2bf(v[2 * c]) | ((unsigned)f2bf(v[2 * c + 1]) << 16);
  short* dst = XB0 + ((long long)(b * D + d) * HW + (h0 + th) * 128 + (w0 + tw)) * 16;
  *(uint4*)(dst)     = make_uint4(pk[0], pk[1], pk[2], pk[3]);
  *(uint4*)(dst + 8) = make_uint4(pk[4], pk[5], pk[6], pk[7]);
}

// ---------------------------------------------------------------------------
// K_wp: pack conv_pre weights -> bf16 per-half layout:
// WP16[(half*16+co)*96 + ks*32 + t*8 + c8], tap = ks*4+t (taps>=9 zero).
// ---------------------------------------------------------------------------
__global__ __launch_bounds__(256) void k_wp(
    const float* __restrict__ wp, short* __restrict__ WP16)
{
  const int idx = blockIdx.x * 256 + threadIdx.x;   // < 3072
  if (idx >= 2 * 16 * 96) return;
  const int u = idx / 96;            // half*16 + co
  const int k = idx - u * 96;
  const int ks = k >> 5, rem = k & 31;
  const int t = rem >> 3, c8 = rem & 7;
  const int tap = ks * 4 + t;
  const int half = u >> 4, co = u & 15;
  const int cin = half * 8 + c8;
  float v = (tap < 9) ? wp[co * 144 + cin * 9 + tap] : 0.f;
  WP16[idx] = (short)f2bf(v);
}

// ---------------------------------------------------------------------------
// K1 v3: conv_pre via MFMA, cin-halves processed sequentially (LDS 21 KB).
// grid(16 rowgroups, D, B), block 256 = 4 waves; wave = 2 rows x 128 cols.
// Per half: stage 10 rows x 132 x 8c bf16, 3 k-steps (4 taps x 8 cin each).
// ---------------------------------------------------------------------------
__global__ __launch_bounds__(256) void k_conv_pre16(
    const short* __restrict__ XB0, const short* __restrict__ WP16,
    const float* __restrict__ bg, const float* __restrict__ bb,
    const float* __restrict__ bm, const float* __restrict__ bv,
    float* __restrict__ X1)
{
  __shared__ short xls[10 * 132 * 8];   // 21.1 KB
  const int tid = threadIdx.x;
  const int rg = blockIdx.x;
  const int d = blockIdx.y, b = blockIdx.z;
  const int h0 = rg * 8;

  const int lane = tid & 63;
  const int wv   = tid >> 6;
  const int p    = lane & 15;
  const int chunk = lane >> 4;

  const short* xb0 = XB0 + (long long)(b * D + d) * HW * 16;
  const frag_ab zero8 = {0, 0, 0, 0, 0, 0, 0, 0};

  frag_cd acc[2][8];
  #pragma unroll
  for (int r2 = 0; r2 < 2; ++r2)
    #pragma unroll
    for (int pg = 0; pg < 8; ++pg)
      acc[r2][pg] = (frag_cd){0.f, 0.f, 0.f, 0.f};

  // per-lane B offsets (independent of half)
  int offs[3];
  #pragma unroll
  for (int s = 0; s < 3; ++s) {
    int tap = s * 4 + chunk;
    if (tap > 8) tap = 0;               // padded (A==0) -> in-bounds addr
    const int kh = (tap * 11) >> 5;     // tap/3
    const int kw = tap - kh * 3;
    offs[s] = ((2 * wv + kh) * 132 + p + kw) * 8;
  }

  for (int half = 0; half < 2; ++half) {
    // stage this half's slab: 10 x 132 positions x 8c
    for (int idx = tid; idx < 1320; idx += 256) {
      const int row = idx / 132, col = idx - row * 132;
      const int gh = h0 - 1 + row, gw = col - 1;
      frag_ab v = zero8;
      if (gh >= 0 && gh < H && gw >= 0 && gw < W)
        v = *(const frag_ab*)(xb0 + ((long long)gh * 128 + gw) * 16 + half * 8);
      *(frag_ab*)&xls[idx * 8] = v;
    }
    __syncthreads();

    frag_ab a[3];
    {
      const short* wl = WP16 + ((half << 4) + p) * 96 + chunk * 8;
      #pragma unroll
      for (int s = 0; s < 3; ++s)
        a[s] = *(const frag_ab*)(wl + s * 32);
    }

    #pragma unroll
    for (int s = 0; s < 3; ++s) {
      const frag_ab av = a[s];
      const int base0 = offs[s];
      #pragma unroll
      for (int pg = 0; pg < 8; ++pg) {
        frag_ab b0 = *(const frag_ab*)&xls[base0 + pg * 128];
        acc[0][pg] = __builtin_amdgcn_mfma_f32_16x16x32_bf16(av, b0, acc[0][pg], 0, 0, 0);
        frag_ab b1 = *(const frag_ab*)&xls[base0 + 1056 + pg * 128];
        acc[1][pg] = __builtin_amdgcn_mfma_f32_16x16x32_bf16(av, b1, acc[1][pg], 0, 0, 0);
      }
    }
    __syncthreads();   // before restage
  }

  float sc4[4], bi4[4];
  #pragma unroll
  for (int reg = 0; reg < 4; ++reg) {
    const int co = chunk * 4 + reg;
    float s = bg[co] * rsqrtf(bv[co] + EPSBN);
    sc4[reg] = s;
    bi4[reg] = bb[co] - bm[co] * s;
  }
  const long long xbase = (long long)b * CDHW + (long long)d * HW;
  #pragma unroll
  for (int r2 = 0; r2 < 2; ++r2) {
    const int row = h0 + 2 * wv + r2;
    #pragma unroll
    for (int pg = 0; pg < 8; ++pg)
      #pragma unroll
      for (int reg = 0; reg < 4; ++reg) {
        const int co = chunk * 4 + reg;
        float v = fmaxf(fmaf(acc[r2][pg][reg], sc4[reg], bi4[reg]), 0.f);
        X1[xbase + (long long)co * DHW + row * 128 + pg * 16 + p] = v;
      }
  }
}

// ---------------------------------------------------------------------------
// K2: projections. V/VT stored bf16.
// ---------------------------------------------------------------------------
__global__ __launch_bounds__(256) void k_qkv(
    const float* __restrict__ xin, const float* __restrict__ wq,
    const float* __restrict__ wk, const float* __restrict__ wv,
    float* __restrict__ Kp, float* __restrict__ KTp, float* __restrict__ QTp,
    short* __restrict__ Vp16, short* __restrict__ VTp16)
{
  const int tid = threadIdx.x;
  const int tile = blockIdx.x, d = blockIdx.y, b = blockIdx.z;
  const int h0 = (tile >> 3) * 16, w0 = (tile & 7) * 16;
  const int ty = tid >> 4, tx = tid & 15;
  const int h = h0 + ty, w = w0 + tx;

  const float* xb = xin + (long long)b * CDHW + (long long)d * HW + h * 128 + w;
  float xv[16];
  #pragma unroll
  for (int c = 0; c < 16; ++c) xv[c] = xb[(long long)c * DHW];

  float q0 = 0, q1 = 0, k0 = 0, k1 = 0, v[16];
  #pragma unroll
  for (int c = 0; c < 16; ++c) {
    q0 = fmaf(wq[c], xv[c], q0);
    q1 = fmaf(wq[16 + c], xv[c], q1);
    k0 = fmaf(wk[c], xv[c], k0);
    k1 = fmaf(wk[16 + c], xv[c], k1);
  }
  #pragma unroll
  for (int o = 0; o < 16; ++o) {
    float a = 0;
    #pragma unroll
    for (int c = 0; c < 16; ++c) a = fmaf(wv[o * 16 + c], xv[c], a);
    v[o] = a;
  }

  const int sl = b * 16 + d;
  const long long base2 = (long long)(sl * 2) * HW;
  const long long baseV = (long long)(sl * 16) * HW;
  const int hw = h * 128 + w;
  Kp[base2 + hw] = k0;
  Kp[base2 + HW + hw] = k1;
  #pragma unroll
  for (int o = 0; o < 16; ++o)
    Vp16[baseV + (long long)o * HW + hw] = (short)f2bf(v[o]);

  __shared__ float lsk[2][16][17];
  __shared__ float lsq[2][16][17];
  __shared__ float lsv[16][16][17];
  lsk[0][ty][tx] = k0; lsk[1][ty][tx] = k1;
  lsq[0][ty][tx] = q0; lsq[1][ty][tx] = q1;
  #pragma unroll
  for (int o = 0; o < 16; ++o) lsv[o][ty][tx] = v[o];
  __syncthreads();

  const int wh = (w0 + ty) * 128 + (h0 + tx);
  KTp[base2 + wh]      = lsk[0][tx][ty];
  KTp[base2 + HW + wh] = lsk[1][tx][ty];
  QTp[base2 + wh]      = lsq[0][tx][ty];
  QTp[base2 + HW + wh] = lsq[1][tx][ty];
  #pragma unroll
  for (int o = 0; o < 16; ++o)
    VTp16[baseV + (long long)o * HW + wh] = (short)f2bf(lsv[o][tx][ty]);
}

// ---------------------------------------------------------------------------
// K3 v6: INNER direction via MFMA. V slab copied bf16 directly.
// ---------------------------------------------------------------------------
template<bool MASK_INNER>
__global__ __launch_bounds__(256) void k_att_row(
    const float* __restrict__ xin, float* __restrict__ OWn,
    const float* __restrict__ Kp, const short* __restrict__ Vp16,
    float* __restrict__ Sip, const float* __restrict__ wq)
{
  __shared__ float kr2[4][128][2];
  __shared__ float q0l[4][128], q1l[4][128];
  __shared__ __align__(16) short v16[4][16][136];
  const int tid = threadIdx.x;
  const int o0 = blockIdx.x * 4, d = blockIdx.y, b = blockIdx.z;
  const int sl = b * 16 + d;
  const long long base2 = (long long)(sl * 2) * HW;
  const long long baseV = (long long)(sl * 16) * HW;
  const long long baseM = (long long)sl * HW;
  const int hi = tid >> 6;
  const int L  = tid & 63;
  const int p  = L & 15;
  const int chunk = L >> 4;
  const int orow = o0 + hi;
  const long long xbase = (long long)b * CDHW + (long long)d * HW;

  for (int kk = tid; kk < 1024; kk += 256) {
    int col = kk & 127;
    int t = kk >> 7;
    int r2 = t >> 1, o = t & 1;
    kr2[r2][col][o] = Kp[base2 + (long long)o * HW + (o0 + r2) * 128 + col];
  }
  for (int idx = tid; idx < 2048; idx += 256) {
    int v4 = idx & 31;
    int t = idx >> 5;
    int c = t & 15, r2 = t >> 4;
    *(uint2*)&v16[r2][c][v4 * 4] =
        *(const uint2*)&Vp16[baseV + (long long)c * HW + (o0 + r2) * 128 + v4 * 4];
  }
  {
    float q0a = 0.f, q0b = 0.f, q1a = 0.f, q1b = 0.f;
    #pragma unroll
    for (int c = 0; c < 16; ++c) {
      const float w0 = wq[c], w1 = wq[16 + c];
      float xa = xin[xbase + (long long)c * DHW + orow * 128 + L];
      float xb2 = xin[xbase + (long long)c * DHW + orow * 128 + L + 64];
      q0a = fmaf(w0, xa, q0a);  q1a = fmaf(w1, xa, q1a);
      q0b = fmaf(w0, xb2, q0b); q1b = fmaf(w1, xb2, q1b);
    }
    q0l[hi][L] = q0a; q0l[hi][L + 64] = q0b;
    q1l[hi][L] = q1a; q1l[hi][L + 64] = q1b;
  }
  __syncthreads();

  float q0r[8], q1r[8];
  #pragma unroll
  for (int ti = 0; ti < 8; ++ti) {
    q0r[ti] = q0l[hi][ti * 16 + p];
    q1r[ti] = q1l[hi][ti * 16 + p];
  }

  frag_cd acc[8];
  #pragma unroll
  for (int ti = 0; ti < 8; ++ti) acc[ti] = (frag_cd){0.f, 0.f, 0.f, 0.f};
  float ssum[8] = {0.f, 0.f, 0.f, 0.f, 0.f, 0.f, 0.f, 0.f};

  #pragma unroll
  for (int ks = 0; ks < 4; ++ks) {
    const int vb = ks * 32 + chunk * 8;
    float2 kv[8];
    const float* kvp = &kr2[hi][vb][0];
    *(float4*)&kv[0] = *(const float4*)(kvp);
    *(float4*)&kv[2] = *(const float4*)(kvp + 4);
    *(float4*)&kv[4] = *(const float4*)(kvp + 8);
    *(float4*)&kv[6] = *(const float4*)(kvp + 12);
    frag_ab bfrag = *(const frag_ab*)&v16[hi][p][vb];

    #pragma unroll
    for (int ti = 0; ti < 8; ++ti) {
      float pv[8];
      #pragma unroll
      for (int j = 0; j < 8; ++j) {
        float e = fmaf(q0r[ti], kv[j].x, q1r[ti] * kv[j].y);
        pv[j] = __expf(e);
      }
      if constexpr (MASK_INNER) {
        const int dj = ti * 16 + p - vb;
        #pragma unroll
        for (int j = 0; j < 8; ++j)
          if (j == dj) pv[j] = 0.f;
      }
      float lsum = 0.f;
      #pragma unroll
      for (int j = 0; j < 8; ++j) lsum += pv[j];
      ssum[ti] += lsum;

      union { frag_ab f; unsigned u[4]; } cv;
      cv.u[0] = cvt_pk_bf16(pv[0], pv[1]);
      cv.u[1] = cvt_pk_bf16(pv[2], pv[3]);
      cv.u[2] = cvt_pk_bf16(pv[4], pv[5]);
      cv.u[3] = cvt_pk_bf16(pv[6], pv[7]);
      acc[ti] = __builtin_amdgcn_mfma_f32_16x16x32_bf16(cv.f, bfrag, acc[ti], 0, 0, 0);
    }
  }

  #pragma unroll
  for (int ti = 0; ti < 8; ++ti) {
    ssum[ti] += __shfl_xor(ssum[ti], 16);
    ssum[ti] += __shfl_xor(ssum[ti], 32);
  }
  if (L < 16) {
    #pragma unroll
    for (int ti = 0; ti < 8; ++ti)
      Sip[baseM + (ti * 16 + L) * 128 + orow] = ssum[ti];
  }

  float* ob = OWn + ((long long)(b * D + d) * HW + orow * 128) * 16;
  #pragma unroll
  for (int ti = 0; ti < 8; ++ti)
    #pragma unroll
    for (int reg = 0; reg < 4; ++reg)
      ob[(ti * 16 + chunk * 4 + reg) * 16 + p] = acc[ti][reg];
}

// ---------------------------------------------------------------------------
// K4 v6: OUTER direction via MFMA. VT slab copied bf16 directly.
// ---------------------------------------------------------------------------
template<bool MASK_INNER>
__global__ __launch_bounds__(256) void k_att_col(
    const float* __restrict__ KTp, const float* __restrict__ QTp,
    const short* __restrict__ VTp16, float* __restrict__ OHn,
    float* __restrict__ Sop)
{
  __shared__ float kr2[4][128][2];
  __shared__ __align__(16) short v16[4][16][136];
  const int tid = threadIdx.x;
  const int i0 = blockIdx.x * 4, d = blockIdx.y, b = blockIdx.z;
  const int sl = b * 16 + d;
  const long long base2 = (long long)(sl * 2) * HW;
  const long long baseV = (long long)(sl * 16) * HW;
  const long long baseS = (long long)sl * HW;
  const int hi = tid >> 6;
  const int L  = tid & 63;
  const int p  = L & 15;
  const int chunk = L >> 4;
  const int icol = i0 + hi;

  for (int kk = tid; kk < 1024; kk += 256) {
    int col = kk & 127;
    int t = kk >> 7;
    int r2 = t >> 1, o = t & 1;
    kr2[r2][col][o] = KTp[base2 + (long long)o * HW + (i0 + r2) * 128 + col];
  }
  for (int idx = tid; idx < 2048; idx += 256) {
    int j4 = idx & 31;
    int t = idx >> 5;
    int c = t & 15, r2 = t >> 4;
    *(uint2*)&v16[r2][c][j4 * 4] =
        *(const uint2*)&VTp16[baseV + (long long)c * HW + (i0 + r2) * 128 + j4 * 4];
  }
  __syncthreads();

  float q0r[8], q1r[8];
  #pragma unroll
  for (int ti = 0; ti < 8; ++ti) {
    q0r[ti] = QTp[base2 + icol * 128 + ti * 16 + p];
    q1r[ti] = QTp[base2 + HW + icol * 128 + ti * 16 + p];
  }

  frag_cd acc[8];
  #pragma unroll
  for (int ti = 0; ti < 8; ++ti) acc[ti] = (frag_cd){0.f, 0.f, 0.f, 0.f};
  float ssum[8] = {0.f, 0.f, 0.f, 0.f, 0.f, 0.f, 0.f, 0.f};

  #pragma unroll
  for (int ks = 0; ks < 4; ++ks) {
    const int vb = ks * 32 + chunk * 8;
    float2 kv[8];
    const float* kvp = &kr2[hi][vb][0];
    *(float4*)&kv[0] = *(const float4*)(kvp);
    *(float4*)&kv[2] = *(const float4*)(kvp + 4);
    *(float4*)&kv[4] = *(const float4*)(kvp + 8);
    *(float4*)&kv[6] = *(const float4*)(kvp + 12);
    frag_ab bfrag = *(const frag_ab*)&v16[hi][p][vb];

    #pragma unroll
    for (int ti = 0; ti < 8; ++ti) {
      float pv[8];
      #pragma unroll
      for (int j = 0; j < 8; ++j) {
        float e = fmaf(q0r[ti], kv[j].x, q1r[ti] * kv[j].y);
        pv[j] = __expf(e);
      }
      if constexpr (!MASK_INNER) {
        const int dj = ti * 16 + p - vb;    // mask j == orr
        #pragma unroll
        for (int j = 0; j < 8; ++j)
          if (j == dj) pv[j] = 0.f;
      }
      float lsum = 0.f;
      #pragma unroll
      for (int j = 0; j < 8; ++j) lsum += pv[j];
      ssum[ti] += lsum;

      union { frag_ab f; unsigned u[4]; } cv;
      cv.u[0] = cvt_pk_bf16(pv[0], pv[1]);
      cv.u[1] = cvt_pk_bf16(pv[2], pv[3]);
      cv.u[2] = cvt_pk_bf16(pv[4], pv[5]);
      cv.u[3] = cvt_pk_bf16(pv[6], pv[7]);
      acc[ti] = __builtin_amdgcn_mfma_f32_16x16x32_bf16(cv.f, bfrag, acc[ti], 0, 0, 0);
    }
  }

  #pragma unroll
  for (int ti = 0; ti < 8; ++ti) {
    ssum[ti] += __shfl_xor(ssum[ti], 16);
    ssum[ti] += __shfl_xor(ssum[ti], 32);
  }
  if (L < 16) {
    #pragma unroll
    for (int ti = 0; ti < 8; ++ti)
      Sop[baseS + icol * 128 + ti * 16 + L] = ssum[ti];
  }

  float* ob = OHn + ((long long)(b * D + d) * HW + icol * 128) * 16;
  #pragma unroll
  for (int ti = 0; ti < 8; ++ti)
    #pragma unroll
    for (int reg = 0; reg < 4; ++reg)
      ob[(ti * 16 + chunk * 4 + reg) * 16 + p] = acc[ti][reg];
}

// ---------------------------------------------------------------------------
// K_comb: res = x + gamma/(s_i+s_o) * (oW + oH), written TRANSPOSED.
// ---------------------------------------------------------------------------
template<bool TO_BF16>
__global__ __launch_bounds__(256) void k_comb(
    const float* __restrict__ Xn, const float* __restrict__ OWn,
    const float* __restrict__ OHn, const float* __restrict__ Sip,
    const float* __restrict__ Sop, const float* __restrict__ gp,
    float* __restrict__ Yt, short* __restrict__ Xb16)
{
  __shared__ float xs[16][16][17], ows[16][16][17];
  const int tid = threadIdx.x;
  const int tile = blockIdx.x, d = blockIdx.y, b = blockIdx.z;
  const int o0 = (tile >> 3) * 16, i0 = (tile & 7) * 16;
  const int sl = b * 16 + d;
  const long long baseM = (long long)sl * HW;
  const long long xbase = (long long)b * CDHW + (long long)d * HW;

  const int to = tid >> 4, ti = tid & 15;
  #pragma unroll
  for (int c = 0; c < 16; ++c) {
    const long long src = xbase + (long long)c * DHW + (o0 + to) * 128 + (i0 + ti);
    xs[c][to][ti] = Xn[src];
  }
  {
    const float* osrc = OWn + ((long long)(b * D + d) * HW + (o0 + to) * 128 + (i0 + ti)) * 16;
    float4 f0 = *(const float4*)(osrc);
    float4 f1 = *(const float4*)(osrc + 4);
    float4 f2 = *(const float4*)(osrc + 8);
    float4 f3 = *(const float4*)(osrc + 12);
    ows[0][to][ti] = f0.x;  ows[1][to][ti] = f0.y;
    ows[2][to][ti] = f0.z;  ows[3][to][ti] = f0.w;
    ows[4][to][ti] = f1.x;  ows[5][to][ti] = f1.y;
    ows[6][to][ti] = f1.z;  ows[7][to][ti] = f1.w;
    ows[8][to][ti] = f2.x;  ows[9][to][ti] = f2.y;
    ows[10][to][ti] = f2.z; ows[11][to][ti] = f2.w;
    ows[12][to][ti] = f3.x; ows[13][to][ti] = f3.y;
    ows[14][to][ti] = f3.z; ows[15][to][ti] = f3.w;
  }
  __syncthreads();

  const int ti2 = tid >> 4, to2 = tid & 15;
  const int i = i0 + ti2, o = o0 + to2;
  const float si = Sip[baseM + i * 128 + o];
  const float so = Sop[baseM + i * 128 + o];
  const float gi = gp[0] / (si + so);

  float oh[16];
  {
    const float* osrc = OHn + ((long long)(b * D + d) * HW + i * 128 + o) * 16;
    float4 f0 = *(const float4*)(osrc);
    float4 f1 = *(const float4*)(osrc + 4);
    float4 f2 = *(const float4*)(osrc + 8);
    float4 f3 = *(const float4*)(osrc + 12);
    oh[0] = f0.x;  oh[1] = f0.y;  oh[2] = f0.z;  oh[3] = f0.w;
    oh[4] = f1.x;  oh[5] = f1.y;  oh[6] = f1.z;  oh[7] = f1.w;
    oh[8] = f2.x;  oh[9] = f2.y;  oh[10] = f2.z; oh[11] = f2.w;
    oh[12] = f3.x; oh[13] = f3.y; oh[14] = f3.z; oh[15] = f3.w;
  }

  float res[16];
  #pragma unroll
  for (int c = 0; c < 16; ++c)
    res[c] = fmaf(gi, ows[c][to2][ti2] + oh[c], xs[c][to2][ti2]);

  if constexpr (!TO_BF16) {
    #pragma unroll
    for (int c = 0; c < 16; ++c)
      Yt[xbase + (long long)c * DHW + i * 128 + o] = res[c];
  } else {
    unsigned pk[8];
    #pragma unroll
    for (int c = 0; c < 8; ++c)
      pk[c] = (unsigned)f2bf(res[2 * c]) | ((unsigned)f2bf(res[2 * c + 1]) << 16);
    short* dst = Xb16 + ((long long)(b * D + d) * HW + i * 128 + o) * 16;
    *(uint4*)(dst)     = make_uint4(pk[0], pk[1], pk[2], pk[3]);
    *(uint4*)(dst + 8) = make_uint4(pk[4], pk[5], pk[6], pk[7]);
  }
}

// ---------------------------------------------------------------------------
// K_wt: pack gate weights -> bf16 per-half layout:
// WT16[(half*64+co)*224 + ks*32 + t*8 + c8], tap = ks*4+t (tap 27 zero).
// ---------------------------------------------------------------------------
__global__ __launch_bounds__(256) void k_wt(
    const float* __restrict__ wg, short* __restrict__ WT16)
{
  const int idx = blockIdx.x * 256 + threadIdx.x;   // < 28672
  if (idx >= 2 * 64 * 224) return;
  const int u = idx / 224;           // half*64 + co
  const int k = idx - u * 224;
  const int ks = k >> 5, rem = k & 31;
  const int t = rem >> 3, c8 = rem & 7;
  const int tap = ks * 4 + t;
  const int half = u >> 6, co = u & 63;
  const int cin = half * 8 + c8;
  float v = (tap < 27) ? wg[co * 432 + cin * 27 + tap] : 0.f;
  WT16[idx] = (short)f2bf(v);
}

// ---------------------------------------------------------------------------
// K5a v2: conv_gate via MFMA, cin-halves sequential (LDS 25.3 KB).
// Per half: stage [kd3][rr4][col132][8c], 7 k-steps (4 taps x 8 cin each).
// Gates stored bf16.
// ---------------------------------------------------------------------------
__global__ __launch_bounds__(256, 2) void k_gates(
    const short* __restrict__ XB16, const short* __restrict__ WT16,
    short* __restrict__ g0, short* __restrict__ g1,
    short* __restrict__ g2, short* __restrict__ g3)
{
  __shared__ short xls[1584 * 8];       // 25.3 KB
  const int tid = threadIdx.x;
  const int rp = blockIdx.x;            // 0..63 (2-row group)
  const int d = blockIdx.y, b = blockIdx.z;
  const int h0 = rp * 2;

  const int lane = tid & 63;
  const int og   = tid >> 6;
  const int p    = lane & 15;
  const int chunk = lane >> 4;

  const short* xb = XB16 + (long long)(b * D) * HW * 16;
  const frag_ab zero8 = {0, 0, 0, 0, 0, 0, 0, 0};

  frag_cd acc[2][8];
  #pragma unroll
  for (int r2 = 0; r2 < 2; ++r2)
    #pragma unroll
    for (int pg = 0; pg < 8; ++pg)
      acc[r2][pg] = (frag_cd){0.f, 0.f, 0.f, 0.f};

  int offs[7];
  #pragma unroll
  for (int s = 0; s < 7; ++s) {
    int tap = s * 4 + chunk;
    if (tap > 26) tap = 0;              // pad (A==0)
    const int kd = (tap * 57) >> 9;     // tap/9
    const int rem = tap - kd * 9;
    const int kh = (rem * 11) >> 5;     // rem/3
    const int kw = rem - kh * 3;
    offs[s] = ((kd * 4 + kh) * 132 + p + kw) * 8;
  }

  for (int half = 0; half < 2; ++half) {
    // stage: 3 kd x 4 rows x 132 cols x 8c
    for (int idx = tid; idx < 1584; idx += 256) {
      const int kd = idx / 528;
      const int rem = idx - kd * 528;
      const int rr = rem / 132;
      const int col = rem - rr * 132;
      const int dd = d - 1 + kd, gh = h0 - 1 + rr, gw = col - 1;
      frag_ab v = zero8;
      if (dd >= 0 && dd < D && gh >= 0 && gh < H && gw >= 0 && gw < W)
        v = *(const frag_ab*)(xb + ((long long)dd * HW + gh * W + gw) * 16 + half * 8);
      *(frag_ab*)&xls[idx * 8] = v;
    }
    __syncthreads();

    frag_ab a[7];
    {
      const short* wl = WT16 + ((half << 6) + og * 16 + p) * 224 + chunk * 8;
      #pragma unroll
      for (int s = 0; s < 7; ++s)
        a[s] = *(const frag_ab*)(wl + s * 32);
    }

    #pragma unroll
    for (int s = 0; s < 7; ++s) {
      const frag_ab av = a[s];
      const int base0 = offs[s];
      #pragma unroll
      for (int pg = 0; pg < 8; ++pg) {
        frag_ab b0 = *(const frag_ab*)&xls[base0 + pg * 128];
        acc[0][pg] = __builtin_amdgcn_mfma_f32_16x16x32_bf16(av, b0, acc[0][pg], 0, 0, 0);
        frag_ab b1 = *(const frag_ab*)&xls[base0 + 1056 + pg * 128];
        acc[1][pg] = __builtin_amdgcn_mfma_f32_16x16x32_bf16(av, b1, acc[1][pg], 0, 0, 0);
      }
    }
    __syncthreads();   // before restage
  }

  short* gbuf = (og == 0) ? g0 : (og == 1) ? g1 : (og == 2) ? g2 : g3;
  const long long base = (long long)b * CDHW + (long long)d * HW + h0 * W;
  #pragma unroll
  for (int r2 = 0; r2 < 2; ++r2)
    #pragma unroll
    for (int pg = 0; pg < 8; ++pg)
      #pragma unroll
      for (int reg = 0; reg < 4; ++reg) {
        const int cc = chunk * 4 + reg;
        gbuf[base + (long long)cc * DHW + r2 * W + pg * 16 + p] =
            (short)f2bf(acc[r2][pg][reg]);
      }
}

// ---------------------------------------------------------------------------
// K5b: BN + activations + SRU scan over D. Gates read as bf16.
// ---------------------------------------------------------------------------
__global__ __launch_bounds__(256) void k_scan(
    const short* __restrict__ g0, const short* __restrict__ g1,
    const short* __restrict__ g2, const short* __restrict__ g3,
    const float* __restrict__ bg, const float* __restrict__ bb,
    const float* __restrict__ bm, const float* __restrict__ bv,
    float* __restrict__ out)
{
  const int g = blockIdx.x * 256 + threadIdx.x;   // 0 .. 524287
  const int hw = g & 16383;
  const int cc = (g >> 14) & 15;
  const int b  = g >> 18;

  float sc[4], bi[4];
  #pragma unroll
  for (int gg = 0; gg < 4; ++gg) {
    int ch = gg * 16 + cc;
    float s = bg[ch] * rsqrtf(bv[ch] + EPSBN);
    sc[gg] = s;
    bi[gg] = bb[ch] - bm[ch] * s;
  }

  const long long base = (long long)b * CDHW + (long long)cc * DHW + hw;
  float Ct = 0.f;
  for (int d = 0; d < D; ++d) {
    const long long idx = base + (long long)d * HW;
    float wx = tanhf(fmaf(bf2f(g0[idx]), sc[0], bi[0]));
    float ft = 1.f / (1.f + __expf(-fmaf(bf2f(g1[idx]), sc[1], bi[1])));
    float rt = 1.f / (1.f + __expf(-fmaf(bf2f(g2[idx]), sc[2], bi[2])));
    float xg = tanhf(fmaf(bf2f(g3[idx]), sc[3], bi[3]));
    Ct = (d == 0) ? (1.f - ft) : fmaf(ft, Ct, (1.f - ft) * wx);
    out[idx] = fmaf(rt, Ct, (1.f - rt) * xg);
  }
}

// ---------------------------------------------------------------------------
extern "C" void kernel_launch(void* const* d_in, const int* in_sizes, int n_in,
                              void* d_out, int out_size, void* d_ws, size_t ws_size,
                              hipStream_t stream) {
  const float* x      = (const float*)d_in[0];
  const float* w_pre  = (const float*)d_in[1];
  const float* bnpg   = (const float*)d_in[2];
  const float* bnpb   = (const float*)d_in[3];
  const float* bnpm   = (const float*)d_in[4];
  const float* bnpv   = (const float*)d_in[5];
  const float* wq     = (const float*)d_in[6];
  const float* wk     = (const float*)d_in[7];
  const float* wv     = (const float*)d_in[8];
  const float* gamma  = (const float*)d_in[9];
  const float* w_gate = (const float*)d_in[10];
  const float* bng    = (const float*)d_in[11];
  const float* bnb    = (const float*)d_in[12];
  const float* bnm    = (const float*)d_in[13];
  const float* bnv    = (const float*)d_in[14];

  float* ws  = (float*)d_ws;
  float* R0  = ws + OFF_R0;
  float* R1  = ws + OFF_R1;
  float* Kb  = ws + OFF_K;
  float* KTb = ws + OFF_KT;
  float* QTb = ws + OFF_QT;
  float* SI  = ws + OFF_MST;
  float* SO  = ws + OFF_SO;
  float* R2  = ws + OFF_R2;
  float* R3  = ws + OFF_R3;
  short* XB0  = (short*)(ws + OFF_R1);  // bf16 input (pre-attention phase)
  short* XB16 = (short*)(ws + OFF_R1);  // bf16 attn output (post-attention)
  short* WP16 = (short*)(ws + OFF_SO);  // bf16 conv_pre weights (early phase)
  short* WT16 = (short*)(ws + OFF_K);   // bf16 gate weights
  // bf16 V/VT per app
  short* V1b  = (short*)(ws + OFF_R2);
  short* VT1b = (short*)(ws + OFF_R3);
  short* V2b  = (short*)(ws + OFF_R0);
  short* VT2b = (short*)(ws + OFF_R1) + 8388608;  // upper half of R1
  // bf16 gate buffers: two per region
  short* G0b = (short*)(ws + OFF_R0);
  short* G1b = (short*)(ws + OFF_R0) + 8388608;
  short* G2b = (short*)(ws + OFF_R2);
  short* G3b = (short*)(ws + OFF_R2) + 8388608;
  float* out = (float*)d_out;

  const dim3 gTile(64, D, B), gAtt(32, D, B);

  // stage 1: conv_pre via MFMA: x -> bf16 pos-major -> X1 (fp32) in R0
  k_wp <<<dim3(12),  dim3(256), 0, stream>>>(w_pre, WP16);
  k_x16<<<gTile,     dim3(256), 0, stream>>>(x, XB0);
  k_conv_pre16<<<dim3(16, D, B), dim3(256), 0, stream>>>(
      XB0, WP16, bnpg, bnpb, bnpm, bnpv, R0);

  // attention application 1 (mask on outer): x=R0, V16->R2, VT16->R3
  k_qkv<<<gTile, dim3(256), 0, stream>>>(R0, wq, wk, wv, Kb, KTb, QTb, V1b, VT1b);
  k_att_row<false><<<gAtt, dim3(256), 0, stream>>>(R0, R1, Kb, V1b, SI, wq);      // OWn->R1
  k_att_col<false><<<gAtt, dim3(256), 0, stream>>>(KTb, QTb, VT1b, R2, SO);       // OHn->R2
  k_comb<false><<<gTile, dim3(256), 0, stream>>>(R0, R1, R2, SI, SO, gamma, R3, nullptr); // Y->R3

  // attention application 2 (transposed layout; mask on inner): x=R3
  k_qkv<<<gTile, dim3(256), 0, stream>>>(R3, wq, wk, wv, Kb, KTb, QTb, V2b, VT2b);
  k_att_row<true><<<gAtt, dim3(256), 0, stream>>>(R3, R2, Kb, V2b, SI, wq);       // OWn->R2
  k_att_col<true><<<gAtt, dim3(256), 0, stream>>>(KTb, QTb, VT2b, R0, SO);        // OHn->R0
  k_comb<true><<<gTile, dim3(256), 0, stream>>>(R3, R2, R0, SI, SO, gamma, nullptr, XB16); // ->R1 lower

  // bf16 gate weights (K region free now)
  k_wt<<<dim3(112), dim3(256), 0, stream>>>(w_gate, WT16);

  // stage 3: conv_gate via MFMA -> bf16 gates (G0,G1 in R0; G2,G3 in R2)
  k_gates<<<dim3(64, D, B), dim3(256), 0, stream>>>(XB16, WT16, G0b, G1b, G2b, G3b);

  // stage 4: BN + activations + SRU scan -> out
  k_scan<<<dim3(2048), dim3(256), 0, stream>>>(G0b, G1b, G2b, G3b, bng, bnb, bnm, bnv, out);
}

// Round 20
// 282.875 us; speedup vs baseline: 2.2972x; 1.0453x over previous
//
#include <hip/hip_runtime.h>
#include <math.h>

// Problem constants
namespace {
constexpr int B = 2, C = 16, D = 16, H = 128, W = 128;
constexpr int HW   = H * W;        // 16384
constexpr int DHW  = D * HW;       // 262144
constexpr int CDHW = C * DHW;      // 4194304
constexpr float EPSBN = 1e-5f;

// workspace regions (floats). ws = 37,748,736 floats = 151 MB
constexpr long long OFF_R0  = 0;
constexpr long long OFF_R1  = 8388608;
constexpr long long OFF_K   = 16777216;  // K / WT16 (bf16 gate weights)
constexpr long long OFF_KT  = 17825792;
constexpr long long OFF_QT  = 18874368;
constexpr long long OFF_MST = 19922944;  // s_inner (I,O); 0.5M used
constexpr long long OFF_SO  = 20447232;  // s_outer (I,O); 0.5M used; WP16 early
constexpr long long OFF_R2  = 20971520;
constexpr long long OFF_R3  = 29360128;
}

using frag_ab = __attribute__((ext_vector_type(8))) short;  // 8 bf16
using frag_cd = __attribute__((ext_vector_type(4))) float;  // 4 f32

__device__ __forceinline__ unsigned short f2bf(float f) {
  unsigned u = __float_as_uint(f);
  u = (u + 0x7FFF + ((u >> 16) & 1)) >> 16;   // RNE
  return (unsigned short)u;
}
__device__ __forceinline__ float bf2f(short s) {
  return __uint_as_float(((unsigned)(unsigned short)s) << 16);
}
__device__ __forceinline__ unsigned cvt_pk_bf16(float lo, float hi) {
  unsigned r;
  asm volatile("v_cvt_pk_bf16_f32 %0, %1, %2" : "=v"(r) : "v"(lo), "v"(hi));
  return r;
}

// ---------------------------------------------------------------------------
// K_x16: cast input x (fp32, c-major) -> bf16 [pos][16c]. grid(64, D, B).
// ---------------------------------------------------------------------------
__global__ __launch_bounds__(256) void k_x16(
    const float* __restrict__ x, short* __restrict__ XB0)
{
  const int tid = threadIdx.x;
  const int tile = blockIdx.x, d = blockIdx.y, b = blockIdx.z;
  const int h0 = (tile >> 3) * 16, w0 = (tile & 7) * 16;
  const long long xbase = (long long)b * CDHW + (long long)d * HW;
  const int th = tid >> 4, tw = tid & 15;

  float v[16];
  #pragma unroll
  for (int c = 0; c < 16; ++c)
    v[c] = x[xbase + (long long)c * DHW + (h0 + th) * 128 + (w0 + tw)];

  unsigned pk[8];
  #pragma unroll
  for (int c = 0; c < 8; ++c)
    pk[c] = (unsigned)f2bf(v[2 * c]) | ((unsigned)f2bf(v[2 * c + 1]) << 16);
  short* dst = XB0 + ((long long)(b * D + d) * HW + (h0 + th) * 128 + (w0 + tw)) * 16;
  *(uint4*)(dst)     = make_uint4(pk[0], pk[1], pk[2], pk[3]);
  *(uint4*)(dst + 8) = make_uint4(pk[4], pk[5], pk[6], pk[7]);
}

// ---------------------------------------------------------------------------
// K_wp: pack conv_pre weights -> bf16 per-half layout.
// ---------------------------------------------------------------------------
__global__ __launch_bounds__(256) void k_wp(
    const float* __restrict__ wp, short* __restrict__ WP16)
{
  const int idx = blockIdx.x * 256 + threadIdx.x;   // < 3072
  if (idx >= 2 * 16 * 96) return;
  const int u = idx / 96;            // half*16 + co
  const int k = idx - u * 96;
  const int ks = k >> 5, rem = k & 31;
  const int t = rem >> 3, c8 = rem & 7;
  const int tap = ks * 4 + t;
  const int half = u >> 4, co = u & 15;
  const int cin = half * 8 + c8;
  float v = (tap < 9) ? wp[co * 144 + cin * 9 + tap] : 0.f;
  WP16[idx] = (short)f2bf(v);
}

// ---------------------------------------------------------------------------
// K1 v3: conv_pre via MFMA, cin-halves sequential (LDS 21 KB). (verified)
// ---------------------------------------------------------------------------
__global__ __launch_bounds__(256) void k_conv_pre16(
    const short* __restrict__ XB0, const short* __restrict__ WP16,
    const float* __restrict__ bg, const float* __restrict__ bb,
    const float* __restrict__ bm, const float* __restrict__ bv,
    float* __restrict__ X1)
{
  __shared__ short xls[10 * 132 * 8];   // 21.1 KB
  const int tid = threadIdx.x;
  const int rg = blockIdx.x;
  const int d = blockIdx.y, b = blockIdx.z;
  const int h0 = rg * 8;

  const int lane = tid & 63;
  const int wv   = tid >> 6;
  const int p    = lane & 15;
  const int chunk = lane >> 4;

  const short* xb0 = XB0 + (long long)(b * D + d) * HW * 16;
  const frag_ab zero8 = {0, 0, 0, 0, 0, 0, 0, 0};

  frag_cd acc[2][8];
  #pragma unroll
  for (int r2 = 0; r2 < 2; ++r2)
    #pragma unroll
    for (int pg = 0; pg < 8; ++pg)
      acc[r2][pg] = (frag_cd){0.f, 0.f, 0.f, 0.f};

  int offs[3];
  #pragma unroll
  for (int s = 0; s < 3; ++s) {
    int tap = s * 4 + chunk;
    if (tap > 8) tap = 0;
    const int kh = (tap * 11) >> 5;
    const int kw = tap - kh * 3;
    offs[s] = ((2 * wv + kh) * 132 + p + kw) * 8;
  }

  for (int half = 0; half < 2; ++half) {
    for (int idx = tid; idx < 1320; idx += 256) {
      const int row = idx / 132, col = idx - row * 132;
      const int gh = h0 - 1 + row, gw = col - 1;
      frag_ab v = zero8;
      if (gh >= 0 && gh < H && gw >= 0 && gw < W)
        v = *(const frag_ab*)(xb0 + ((long long)gh * 128 + gw) * 16 + half * 8);
      *(frag_ab*)&xls[idx * 8] = v;
    }
    __syncthreads();

    frag_ab a[3];
    {
      const short* wl = WP16 + ((half << 4) + p) * 96 + chunk * 8;
      #pragma unroll
      for (int s = 0; s < 3; ++s)
        a[s] = *(const frag_ab*)(wl + s * 32);
    }

    #pragma unroll
    for (int s = 0; s < 3; ++s) {
      const frag_ab av = a[s];
      const int base0 = offs[s];
      #pragma unroll
      for (int pg = 0; pg < 8; ++pg) {
        frag_ab b0 = *(const frag_ab*)&xls[base0 + pg * 128];
        acc[0][pg] = __builtin_amdgcn_mfma_f32_16x16x32_bf16(av, b0, acc[0][pg], 0, 0, 0);
        frag_ab b1 = *(const frag_ab*)&xls[base0 + 1056 + pg * 128];
        acc[1][pg] = __builtin_amdgcn_mfma_f32_16x16x32_bf16(av, b1, acc[1][pg], 0, 0, 0);
      }
    }
    __syncthreads();
  }

  float sc4[4], bi4[4];
  #pragma unroll
  for (int reg = 0; reg < 4; ++reg) {
    const int co = chunk * 4 + reg;
    float s = bg[co] * rsqrtf(bv[co] + EPSBN);
    sc4[reg] = s;
    bi4[reg] = bb[co] - bm[co] * s;
  }
  const long long xbase = (long long)b * CDHW + (long long)d * HW;
  #pragma unroll
  for (int r2 = 0; r2 < 2; ++r2) {
    const int row = h0 + 2 * wv + r2;
    #pragma unroll
    for (int pg = 0; pg < 8; ++pg)
      #pragma unroll
      for (int reg = 0; reg < 4; ++reg) {
        const int co = chunk * 4 + reg;
        float v = fmaxf(fmaf(acc[r2][pg][reg], sc4[reg], bi4[reg]), 0.f);
        X1[xbase + (long long)co * DHW + row * 128 + pg * 16 + p] = v;
      }
  }
}

// ---------------------------------------------------------------------------
// K2: projections (app1 only). V/VT stored bf16.
// ---------------------------------------------------------------------------
__global__ __launch_bounds__(256) void k_qkv(
    const float* __restrict__ xin, const float* __restrict__ wq,
    const float* __restrict__ wk, const float* __restrict__ wv,
    float* __restrict__ Kp, float* __restrict__ KTp, float* __restrict__ QTp,
    short* __restrict__ Vp16, short* __restrict__ VTp16)
{
  const int tid = threadIdx.x;
  const int tile = blockIdx.x, d = blockIdx.y, b = blockIdx.z;
  const int h0 = (tile >> 3) * 16, w0 = (tile & 7) * 16;
  const int ty = tid >> 4, tx = tid & 15;
  const int h = h0 + ty, w = w0 + tx;

  const float* xb = xin + (long long)b * CDHW + (long long)d * HW + h * 128 + w;
  float xv[16];
  #pragma unroll
  for (int c = 0; c < 16; ++c) xv[c] = xb[(long long)c * DHW];

  float q0 = 0, q1 = 0, k0 = 0, k1 = 0, v[16];
  #pragma unroll
  for (int c = 0; c < 16; ++c) {
    q0 = fmaf(wq[c], xv[c], q0);
    q1 = fmaf(wq[16 + c], xv[c], q1);
    k0 = fmaf(wk[c], xv[c], k0);
    k1 = fmaf(wk[16 + c], xv[c], k1);
  }
  #pragma unroll
  for (int o = 0; o < 16; ++o) {
    float a = 0;
    #pragma unroll
    for (int c = 0; c < 16; ++c) a = fmaf(wv[o * 16 + c], xv[c], a);
    v[o] = a;
  }

  const int sl = b * 16 + d;
  const long long base2 = (long long)(sl * 2) * HW;
  const long long baseV = (long long)(sl * 16) * HW;
  const int hw = h * 128 + w;
  Kp[base2 + hw] = k0;
  Kp[base2 + HW + hw] = k1;
  #pragma unroll
  for (int o = 0; o < 16; ++o)
    Vp16[baseV + (long long)o * HW + hw] = (short)f2bf(v[o]);

  __shared__ float lsk[2][16][17];
  __shared__ float lsq[2][16][17];
  __shared__ float lsv[16][16][17];
  lsk[0][ty][tx] = k0; lsk[1][ty][tx] = k1;
  lsq[0][ty][tx] = q0; lsq[1][ty][tx] = q1;
  #pragma unroll
  for (int o = 0; o < 16; ++o) lsv[o][ty][tx] = v[o];
  __syncthreads();

  const int wh = (w0 + ty) * 128 + (h0 + tx);
  KTp[base2 + wh]      = lsk[0][tx][ty];
  KTp[base2 + HW + wh] = lsk[1][tx][ty];
  QTp[base2 + wh]      = lsq[0][tx][ty];
  QTp[base2 + HW + wh] = lsq[1][tx][ty];
  #pragma unroll
  for (int o = 0; o < 16; ++o)
    VTp16[baseV + (long long)o * HW + wh] = (short)f2bf(lsv[o][tx][ty]);
}

// ---------------------------------------------------------------------------
// K3 v7: INNER direction via MFMA. OWn stored bf16 [pos][16c].
// ---------------------------------------------------------------------------
template<bool MASK_INNER>
__global__ __launch_bounds__(256) void k_att_row(
    const float* __restrict__ xin, short* __restrict__ OWn16,
    const float* __restrict__ Kp, const short* __restrict__ Vp16,
    float* __restrict__ Sip, const float* __restrict__ wq)
{
  __shared__ float kr2[4][128][2];
  __shared__ float q0l[4][128], q1l[4][128];
  __shared__ __align__(16) short v16[4][16][136];
  const int tid = threadIdx.x;
  const int o0 = blockIdx.x * 4, d = blockIdx.y, b = blockIdx.z;
  const int sl = b * 16 + d;
  const long long base2 = (long long)(sl * 2) * HW;
  const long long baseV = (long long)(sl * 16) * HW;
  const long long baseM = (long long)sl * HW;
  const int hi = tid >> 6;
  const int L  = tid & 63;
  const int p  = L & 15;
  const int chunk = L >> 4;
  const int orow = o0 + hi;
  const long long xbase = (long long)b * CDHW + (long long)d * HW;

  for (int kk = tid; kk < 1024; kk += 256) {
    int col = kk & 127;
    int t = kk >> 7;
    int r2 = t >> 1, o = t & 1;
    kr2[r2][col][o] = Kp[base2 + (long long)o * HW + (o0 + r2) * 128 + col];
  }
  for (int idx = tid; idx < 2048; idx += 256) {
    int v4 = idx & 31;
    int t = idx >> 5;
    int c = t & 15, r2 = t >> 4;
    *(uint2*)&v16[r2][c][v4 * 4] =
        *(const uint2*)&Vp16[baseV + (long long)c * HW + (o0 + r2) * 128 + v4 * 4];
  }
  {
    float q0a = 0.f, q0b = 0.f, q1a = 0.f, q1b = 0.f;
    #pragma unroll
    for (int c = 0; c < 16; ++c) {
      const float w0 = wq[c], w1 = wq[16 + c];
      float xa = xin[xbase + (long long)c * DHW + orow * 128 + L];
      float xb2 = xin[xbase + (long long)c * DHW + orow * 128 + L + 64];
      q0a = fmaf(w0, xa, q0a);  q1a = fmaf(w1, xa, q1a);
      q0b = fmaf(w0, xb2, q0b); q1b = fmaf(w1, xb2, q1b);
    }
    q0l[hi][L] = q0a; q0l[hi][L + 64] = q0b;
    q1l[hi][L] = q1a; q1l[hi][L + 64] = q1b;
  }
  __syncthreads();

  float q0r[8], q1r[8];
  #pragma unroll
  for (int ti = 0; ti < 8; ++ti) {
    q0r[ti] = q0l[hi][ti * 16 + p];
    q1r[ti] = q1l[hi][ti * 16 + p];
  }

  frag_cd acc[8];
  #pragma unroll
  for (int ti = 0; ti < 8; ++ti) acc[ti] = (frag_cd){0.f, 0.f, 0.f, 0.f};
  float ssum[8] = {0.f, 0.f, 0.f, 0.f, 0.f, 0.f, 0.f, 0.f};

  #pragma unroll
  for (int ks = 0; ks < 4; ++ks) {
    const int vb = ks * 32 + chunk * 8;
    float2 kv[8];
    const float* kvp = &kr2[hi][vb][0];
    *(float4*)&kv[0] = *(const float4*)(kvp);
    *(float4*)&kv[2] = *(const float4*)(kvp + 4);
    *(float4*)&kv[4] = *(const float4*)(kvp + 8);
    *(float4*)&kv[6] = *(const float4*)(kvp + 12);
    frag_ab bfrag = *(const frag_ab*)&v16[hi][p][vb];

    #pragma unroll
    for (int ti = 0; ti < 8; ++ti) {
      float pv[8];
      #pragma unroll
      for (int j = 0; j < 8; ++j) {
        float e = fmaf(q0r[ti], kv[j].x, q1r[ti] * kv[j].y);
        pv[j] = __expf(e);
      }
      if constexpr (MASK_INNER) {
        const int dj = ti * 16 + p - vb;
        #pragma unroll
        for (int j = 0; j < 8; ++j)
          if (j == dj) pv[j] = 0.f;
      }
      float lsum = 0.f;
      #pragma unroll
      for (int j = 0; j < 8; ++j) lsum += pv[j];
      ssum[ti] += lsum;

      union { frag_ab f; unsigned u[4]; } cv;
      cv.u[0] = cvt_pk_bf16(pv[0], pv[1]);
      cv.u[1] = cvt_pk_bf16(pv[2], pv[3]);
      cv.u[2] = cvt_pk_bf16(pv[4], pv[5]);
      cv.u[3] = cvt_pk_bf16(pv[6], pv[7]);
      acc[ti] = __builtin_amdgcn_mfma_f32_16x16x32_bf16(cv.f, bfrag, acc[ti], 0, 0, 0);
    }
  }

  #pragma unroll
  for (int ti = 0; ti < 8; ++ti) {
    ssum[ti] += __shfl_xor(ssum[ti], 16);
    ssum[ti] += __shfl_xor(ssum[ti], 32);
  }
  if (L < 16) {
    #pragma unroll
    for (int ti = 0; ti < 8; ++ti)
      Sip[baseM + (ti * 16 + L) * 128 + orow] = ssum[ti];
  }

  short* ob = OWn16 + ((long long)(b * D + d) * HW + orow * 128) * 16;
  #pragma unroll
  for (int ti = 0; ti < 8; ++ti)
    #pragma unroll
    for (int reg = 0; reg < 4; ++reg)
      ob[(ti * 16 + chunk * 4 + reg) * 16 + p] = (short)f2bf(acc[ti][reg]);
}

// ---------------------------------------------------------------------------
// K4 v7: OUTER direction via MFMA. OHn stored bf16 [pos][16c].
// ---------------------------------------------------------------------------
template<bool MASK_INNER>
__global__ __launch_bounds__(256) void k_att_col(
    const float* __restrict__ KTp, const float* __restrict__ QTp,
    const short* __restrict__ VTp16, short* __restrict__ OHn16,
    float* __restrict__ Sop)
{
  __shared__ float kr2[4][128][2];
  __shared__ __align__(16) short v16[4][16][136];
  const int tid = threadIdx.x;
  const int i0 = blockIdx.x * 4, d = blockIdx.y, b = blockIdx.z;
  const int sl = b * 16 + d;
  const long long base2 = (long long)(sl * 2) * HW;
  const long long baseV = (long long)(sl * 16) * HW;
  const long long baseS = (long long)sl * HW;
  const int hi = tid >> 6;
  const int L  = tid & 63;
  const int p  = L & 15;
  const int chunk = L >> 4;
  const int icol = i0 + hi;

  for (int kk = tid; kk < 1024; kk += 256) {
    int col = kk & 127;
    int t = kk >> 7;
    int r2 = t >> 1, o = t & 1;
    kr2[r2][col][o] = KTp[base2 + (long long)o * HW + (i0 + r2) * 128 + col];
  }
  for (int idx = tid; idx < 2048; idx += 256) {
    int j4 = idx & 31;
    int t = idx >> 5;
    int c = t & 15, r2 = t >> 4;
    *(uint2*)&v16[r2][c][j4 * 4] =
        *(const uint2*)&VTp16[baseV + (long long)c * HW + (i0 + r2) * 128 + j4 * 4];
  }
  __syncthreads();

  float q0r[8], q1r[8];
  #pragma unroll
  for (int ti = 0; ti < 8; ++ti) {
    q0r[ti] = QTp[base2 + icol * 128 + ti * 16 + p];
    q1r[ti] = QTp[base2 + HW + icol * 128 + ti * 16 + p];
  }

  frag_cd acc[8];
  #pragma unroll
  for (int ti = 0; ti < 8; ++ti) acc[ti] = (frag_cd){0.f, 0.f, 0.f, 0.f};
  float ssum[8] = {0.f, 0.f, 0.f, 0.f, 0.f, 0.f, 0.f, 0.f};

  #pragma unroll
  for (int ks = 0; ks < 4; ++ks) {
    const int vb = ks * 32 + chunk * 8;
    float2 kv[8];
    const float* kvp = &kr2[hi][vb][0];
    *(float4*)&kv[0] = *(const float4*)(kvp);
    *(float4*)&kv[2] = *(const float4*)(kvp + 4);
    *(float4*)&kv[4] = *(const float4*)(kvp + 8);
    *(float4*)&kv[6] = *(const float4*)(kvp + 12);
    frag_ab bfrag = *(const frag_ab*)&v16[hi][p][vb];

    #pragma unroll
    for (int ti = 0; ti < 8; ++ti) {
      float pv[8];
      #pragma unroll
      for (int j = 0; j < 8; ++j) {
        float e = fmaf(q0r[ti], kv[j].x, q1r[ti] * kv[j].y);
        pv[j] = __expf(e);
      }
      if constexpr (!MASK_INNER) {
        const int dj = ti * 16 + p - vb;    // mask j == orr
        #pragma unroll
        for (int j = 0; j < 8; ++j)
          if (j == dj) pv[j] = 0.f;
      }
      float lsum = 0.f;
      #pragma unroll
      for (int j = 0; j < 8; ++j) lsum += pv[j];
      ssum[ti] += lsum;

      union { frag_ab f; unsigned u[4]; } cv;
      cv.u[0] = cvt_pk_bf16(pv[0], pv[1]);
      cv.u[1] = cvt_pk_bf16(pv[2], pv[3]);
      cv.u[2] = cvt_pk_bf16(pv[4], pv[5]);
      cv.u[3] = cvt_pk_bf16(pv[6], pv[7]);
      acc[ti] = __builtin_amdgcn_mfma_f32_16x16x32_bf16(cv.f, bfrag, acc[ti], 0, 0, 0);
    }
  }

  #pragma unroll
  for (int ti = 0; ti < 8; ++ti) {
    ssum[ti] += __shfl_xor(ssum[ti], 16);
    ssum[ti] += __shfl_xor(ssum[ti], 32);
  }
  if (L < 16) {
    #pragma unroll
    for (int ti = 0; ti < 8; ++ti)
      Sop[baseS + icol * 128 + ti * 16 + L] = ssum[ti];
  }

  short* ob = OHn16 + ((long long)(b * D + d) * HW + icol * 128) * 16;
  #pragma unroll
  for (int ti = 0; ti < 8; ++ti)
    #pragma unroll
    for (int reg = 0; reg < 4; ++reg)
      ob[(ti * 16 + chunk * 4 + reg) * 16 + p] = (short)f2bf(acc[ti][reg]);
}

// ---------------------------------------------------------------------------
// K_comb_qkv: app1 combine + app2 projections, fused.
// res = x + gamma/(si+so)*(oW+oH); writes Yt (fp32, transposed frame) and
// projections of res in app2's frame: K, KT, QT (fp32), V/VT (bf16).
// ---------------------------------------------------------------------------
__global__ __launch_bounds__(256) void k_comb_qkv(
    const float* __restrict__ Xn, const short* __restrict__ OWn16,
    const short* __restrict__ OHn16, const float* __restrict__ Sip,
    const float* __restrict__ Sop, const float* __restrict__ gp,
    const float* __restrict__ wq, const float* __restrict__ wk,
    const float* __restrict__ wv,
    float* __restrict__ Yt, float* __restrict__ Kp, float* __restrict__ KTp,
    float* __restrict__ QTp, short* __restrict__ Vp16, short* __restrict__ VTp16)
{
  __shared__ float xs[16][16][17];    // x tile; later reused for v transpose
  __shared__ float ows[16][16][17];
  __shared__ float lsk[2][16][17], lsq[2][16][17];
  const int tid = threadIdx.x;
  const int tile = blockIdx.x, d = blockIdx.y, b = blockIdx.z;
  const int o0 = (tile >> 3) * 16, i0 = (tile & 7) * 16;
  const int sl = b * 16 + d;
  const long long baseM = (long long)sl * HW;
  const long long base2 = (long long)(sl * 2) * HW;
  const long long baseV = (long long)(sl * 16) * HW;
  const long long xbase = (long long)b * CDHW + (long long)d * HW;

  const int to = tid >> 4, ti = tid & 15;
  #pragma unroll
  for (int c = 0; c < 16; ++c) {
    const long long src = xbase + (long long)c * DHW + (o0 + to) * 128 + (i0 + ti);
    xs[c][to][ti] = Xn[src];
  }
  {
    const short* osrc = OWn16 + ((long long)(b * D + d) * HW + (o0 + to) * 128 + (i0 + ti)) * 16;
    frag_ab f0 = *(const frag_ab*)(osrc);
    frag_ab f1 = *(const frag_ab*)(osrc + 8);
    #pragma unroll
    for (int c = 0; c < 8; ++c) {
      ows[c][to][ti]     = bf2f(f0[c]);
      ows[c + 8][to][ti] = bf2f(f1[c]);
    }
  }
  __syncthreads();

  const int ti2 = tid >> 4, to2 = tid & 15;
  const int i = i0 + ti2, o = o0 + to2;
  const float si = Sip[baseM + i * 128 + o];
  const float so = Sop[baseM + i * 128 + o];
  const float gi = gp[0] / (si + so);

  float oh[16];
  {
    const short* osrc = OHn16 + ((long long)(b * D + d) * HW + i * 128 + o) * 16;
    frag_ab f0 = *(const frag_ab*)(osrc);
    frag_ab f1 = *(const frag_ab*)(osrc + 8);
    #pragma unroll
    for (int c = 0; c < 8; ++c) { oh[c] = bf2f(f0[c]); oh[c + 8] = bf2f(f1[c]); }
  }

  float res[16];
  #pragma unroll
  for (int c = 0; c < 16; ++c)
    res[c] = fmaf(gi, ows[c][to2][ti2] + oh[c], xs[c][to2][ti2]);

  // Yt (fp32, app2's normal-layout input)
  #pragma unroll
  for (int c = 0; c < 16; ++c)
    Yt[xbase + (long long)c * DHW + i * 128 + o] = res[c];

  // projections of res (app2 frame pixel (h=i, w=o))
  float q0 = 0, q1 = 0, k0 = 0, k1 = 0, v[16];
  #pragma unroll
  for (int c = 0; c < 16; ++c) {
    q0 = fmaf(wq[c], res[c], q0);
    q1 = fmaf(wq[16 + c], res[c], q1);
    k0 = fmaf(wk[c], res[c], k0);
    k1 = fmaf(wk[16 + c], res[c], k1);
  }
  #pragma unroll
  for (int oo = 0; oo < 16; ++oo) {
    float a = 0;
    #pragma unroll
    for (int c = 0; c < 16; ++c) a = fmaf(wv[oo * 16 + c], res[c], a);
    v[oo] = a;
  }

  const int hw = i * 128 + o;
  Kp[base2 + hw] = k0;
  Kp[base2 + HW + hw] = k1;
  #pragma unroll
  for (int oo = 0; oo < 16; ++oo)
    Vp16[baseV + (long long)oo * HW + hw] = (short)f2bf(v[oo]);

  // transposed outputs: write with [o-idx][i-idx] indexing
  lsk[0][to2][ti2] = k0; lsk[1][to2][ti2] = k1;
  lsq[0][to2][ti2] = q0; lsq[1][to2][ti2] = q1;
  __syncthreads();   // also guards xs reads above

  // reuse xs for v transpose
  #pragma unroll
  for (int c = 0; c < 16; ++c) xs[c][to2][ti2] = v[c];

  {
    const int a = tid >> 4, bb2 = tid & 15;   // a = o-idx, bb2 = i-idx
    const long long wh = (long long)(o0 + a) * 128 + (i0 + bb2);
    KTp[base2 + wh]      = lsk[0][a][bb2];
    KTp[base2 + HW + wh] = lsk[1][a][bb2];
    QTp[base2 + wh]      = lsq[0][a][bb2];
    QTp[base2 + HW + wh] = lsq[1][a][bb2];
  }
  __syncthreads();
  {
    const int a = tid >> 4, bb2 = tid & 15;
    const long long wh = (long long)(o0 + a) * 128 + (i0 + bb2);
    #pragma unroll
    for (int c = 0; c < 16; ++c)
      VTp16[baseV + (long long)c * HW + wh] = (short)f2bf(xs[c][a][bb2]);
  }
}

// ---------------------------------------------------------------------------
// K_comb (app2 final): bf16 OW/OH inputs; writes bf16 [pos][16c] Xb16.
// ---------------------------------------------------------------------------
__global__ __launch_bounds__(256) void k_comb_bf(
    const float* __restrict__ Xn, const short* __restrict__ OWn16,
    const short* __restrict__ OHn16, const float* __restrict__ Sip,
    const float* __restrict__ Sop, const float* __restrict__ gp,
    short* __restrict__ Xb16)
{
  __shared__ float xs[16][16][17], ows[16][16][17];
  const int tid = threadIdx.x;
  const int tile = blockIdx.x, d = blockIdx.y, b = blockIdx.z;
  const int o0 = (tile >> 3) * 16, i0 = (tile & 7) * 16;
  const int sl = b * 16 + d;
  const long long baseM = (long long)sl * HW;
  const long long xbase = (long long)b * CDHW + (long long)d * HW;

  const int to = tid >> 4, ti = tid & 15;
  #pragma unroll
  for (int c = 0; c < 16; ++c) {
    const long long src = xbase + (long long)c * DHW + (o0 + to) * 128 + (i0 + ti);
    xs[c][to][ti] = Xn[src];
  }
  {
    const short* osrc = OWn16 + ((long long)(b * D + d) * HW + (o0 + to) * 128 + (i0 + ti)) * 16;
    frag_ab f0 = *(const frag_ab*)(osrc);
    frag_ab f1 = *(const frag_ab*)(osrc + 8);
    #pragma unroll
    for (int c = 0; c < 8; ++c) {
      ows[c][to][ti]     = bf2f(f0[c]);
      ows[c + 8][to][ti] = bf2f(f1[c]);
    }
  }
  __syncthreads();

  const int ti2 = tid >> 4, to2 = tid & 15;
  const int i = i0 + ti2, o = o0 + to2;
  const float si = Sip[baseM + i * 128 + o];
  const float so = Sop[baseM + i * 128 + o];
  const float gi = gp[0] / (si + so);

  float oh[16];
  {
    const short* osrc = OHn16 + ((long long)(b * D + d) * HW + i * 128 + o) * 16;
    frag_ab f0 = *(const frag_ab*)(osrc);
    frag_ab f1 = *(const frag_ab*)(osrc + 8);
    #pragma unroll
    for (int c = 0; c < 8; ++c) { oh[c] = bf2f(f0[c]); oh[c + 8] = bf2f(f1[c]); }
  }

  float res[16];
  #pragma unroll
  for (int c = 0; c < 16; ++c)
    res[c] = fmaf(gi, ows[c][to2][ti2] + oh[c], xs[c][to2][ti2]);

  unsigned pk[8];
  #pragma unroll
  for (int c = 0; c < 8; ++c)
    pk[c] = (unsigned)f2bf(res[2 * c]) | ((unsigned)f2bf(res[2 * c + 1]) << 16);
  short* dst = Xb16 + ((long long)(b * D + d) * HW + i * 128 + o) * 16;
  *(uint4*)(dst)     = make_uint4(pk[0], pk[1], pk[2], pk[3]);
  *(uint4*)(dst + 8) = make_uint4(pk[4], pk[5], pk[6], pk[7]);
}

// ---------------------------------------------------------------------------
// K_wt: pack gate weights -> bf16 per-half layout.
// ---------------------------------------------------------------------------
__global__ __launch_bounds__(256) void k_wt(
    const float* __restrict__ wg, short* __restrict__ WT16)
{
  const int idx = blockIdx.x * 256 + threadIdx.x;   // < 28672
  if (idx >= 2 * 64 * 224) return;
  const int u = idx / 224;           // half*64 + co
  const int k = idx - u * 224;
  const int ks = k >> 5, rem = k & 31;
  const int t = rem >> 3, c8 = rem & 7;
  const int tap = ks * 4 + t;
  const int half = u >> 6, co = u & 63;
  const int cin = half * 8 + c8;
  float v = (tap < 27) ? wg[co * 432 + cin * 27 + tap] : 0.f;
  WT16[idx] = (short)f2bf(v);
}

// ---------------------------------------------------------------------------
// K5a v2: conv_gate via MFMA, cin-halves sequential. Gates stored bf16.
// ---------------------------------------------------------------------------
__global__ __launch_bounds__(256, 2) void k_gates(
    const short* __restrict__ XB16, const short* __restrict__ WT16,
    short* __restrict__ g0, short* __restrict__ g1,
    short* __restrict__ g2, short* __restrict__ g3)
{
  __shared__ short xls[1584 * 8];       // 25.3 KB
  const int tid = threadIdx.x;
  const int rp = blockIdx.x;
  const int d = blockIdx.y, b = blockIdx.z;
  const int h0 = rp * 2;

  const int lane = tid & 63;
  const int og   = tid >> 6;
  const int p    = lane & 15;
  const int chunk = lane >> 4;

  const short* xb = XB16 + (long long)(b * D) * HW * 16;
  const frag_ab zero8 = {0, 0, 0, 0, 0, 0, 0, 0};

  frag_cd acc[2][8];
  #pragma unroll
  for (int r2 = 0; r2 < 2; ++r2)
    #pragma unroll
    for (int pg = 0; pg < 8; ++pg)
      acc[r2][pg] = (frag_cd){0.f, 0.f, 0.f, 0.f};

  int offs[7];
  #pragma unroll
  for (int s = 0; s < 7; ++s) {
    int tap = s * 4 + chunk;
    if (tap > 26) tap = 0;
    const int kd = (tap * 57) >> 9;
    const int rem = tap - kd * 9;
    const int kh = (rem * 11) >> 5;
    const int kw = rem - kh * 3;
    offs[s] = ((kd * 4 + kh) * 132 + p + kw) * 8;
  }

  for (int half = 0; half < 2; ++half) {
    for (int idx = tid; idx < 1584; idx += 256) {
      const int kd = idx / 528;
      const int rem = idx - kd * 528;
      const int rr = rem / 132;
      const int col = rem - rr * 132;
      const int dd = d - 1 + kd, gh = h0 - 1 + rr, gw = col - 1;
      frag_ab v = zero8;
      if (dd >= 0 && dd < D && gh >= 0 && gh < H && gw >= 0 && gw < W)
        v = *(const frag_ab*)(xb + ((long long)dd * HW + gh * W + gw) * 16 + half * 8);
      *(frag_ab*)&xls[idx * 8] = v;
    }
    __syncthreads();

    frag_ab a[7];
    {
      const short* wl = WT16 + ((half << 6) + og * 16 + p) * 224 + chunk * 8;
      #pragma unroll
      for (int s = 0; s < 7; ++s)
        a[s] = *(const frag_ab*)(wl + s * 32);
    }

    #pragma unroll
    for (int s = 0; s < 7; ++s) {
      const frag_ab av = a[s];
      const int base0 = offs[s];
      #pragma unroll
      for (int pg = 0; pg < 8; ++pg) {
        frag_ab b0 = *(const frag_ab*)&xls[base0 + pg * 128];
        acc[0][pg] = __builtin_amdgcn_mfma_f32_16x16x32_bf16(av, b0, acc[0][pg], 0, 0, 0);
        frag_ab b1 = *(const frag_ab*)&xls[base0 + 1056 + pg * 128];
        acc[1][pg] = __builtin_amdgcn_mfma_f32_16x16x32_bf16(av, b1, acc[1][pg], 0, 0, 0);
      }
    }
    __syncthreads();
  }

  short* gbuf = (og == 0) ? g0 : (og == 1) ? g1 : (og == 2) ? g2 : g3;
  const long long base = (long long)b * CDHW + (long long)d * HW + h0 * W;
  #pragma unroll
  for (int r2 = 0; r2 < 2; ++r2)
    #pragma unroll
    for (int pg = 0; pg < 8; ++pg)
      #pragma unroll
      for (int reg = 0; reg < 4; ++reg) {
        const int cc = chunk * 4 + reg;
        gbuf[base + (long long)cc * DHW + r2 * W + pg * 16 + p] =
            (short)f2bf(acc[r2][pg][reg]);
      }
}

// ---------------------------------------------------------------------------
// K5b: BN + activations + SRU scan over D. Gates read as bf16.
// ---------------------------------------------------------------------------
__global__ __launch_bounds__(256) void k_scan(
    const short* __restrict__ g0, const short* __restrict__ g1,
    const short* __restrict__ g2, const short* __restrict__ g3,
    const float* __restrict__ bg, const float* __restrict__ bb,
    const float* __restrict__ bm, const float* __restrict__ bv,
    float* __restrict__ out)
{
  const int g = blockIdx.x * 256 + threadIdx.x;   // 0 .. 524287
  const int hw = g & 16383;
  const int cc = (g >> 14) & 15;
  const int b  = g >> 18;

  float sc[4], bi[4];
  #pragma unroll
  for (int gg = 0; gg < 4; ++gg) {
    int ch = gg * 16 + cc;
    float s = bg[ch] * rsqrtf(bv[ch] + EPSBN);
    sc[gg] = s;
    bi[gg] = bb[ch] - bm[ch] * s;
  }

  const long long base = (long long)b * CDHW + (long long)cc * DHW + hw;
  float Ct = 0.f;
  for (int d = 0; d < D; ++d) {
    const long long idx = base + (long long)d * HW;
    float wx = tanhf(fmaf(bf2f(g0[idx]), sc[0], bi[0]));
    float ft = 1.f / (1.f + __expf(-fmaf(bf2f(g1[idx]), sc[1], bi[1])));
    float rt = 1.f / (1.f + __expf(-fmaf(bf2f(g2[idx]), sc[2], bi[2])));
    float xg = tanhf(fmaf(bf2f(g3[idx]), sc[3], bi[3]));
    Ct = (d == 0) ? (1.f - ft) : fmaf(ft, Ct, (1.f - ft) * wx);
    out[idx] = fmaf(rt, Ct, (1.f - rt) * xg);
  }
}

// ---------------------------------------------------------------------------
extern "C" void kernel_launch(void* const* d_in, const int* in_sizes, int n_in,
                              void* d_out, int out_size, void* d_ws, size_t ws_size,
                              hipStream_t stream) {
  const float* x      = (const float*)d_in[0];
  const float* w_pre  = (const float*)d_in[1];
  const float* bnpg   = (const float*)d_in[2];
  const float* bnpb   = (const float*)d_in[3];
  const float* bnpm   = (const float*)d_in[4];
  const float* bnpv   = (const float*)d_in[5];
  const float* wq     = (const float*)d_in[6];
  const float* wk     = (const float*)d_in[7];
  const float* wv     = (const float*)d_in[8];
  const float* gamma  = (const float*)d_in[9];
  const float* w_gate = (const float*)d_in[10];
  const float* bng    = (const float*)d_in[11];
  const float* bnb    = (const float*)d_in[12];
  const float* bnm    = (const float*)d_in[13];
  const float* bnv    = (const float*)d_in[14];

  float* ws  = (float*)d_ws;
  float* R0  = ws + OFF_R0;
  float* R3  = ws + OFF_R3;
  float* Kb  = ws + OFF_K;
  float* KTb = ws + OFF_KT;
  float* QTb = ws + OFF_QT;
  float* SI  = ws + OFF_MST;
  float* SO  = ws + OFF_SO;

  short* XB0   = (short*)(ws + OFF_R1);            // bf16 input (early)
  short* WP16  = (short*)(ws + OFF_SO);            // conv_pre weights (early)
  short* WT16  = (short*)(ws + OFF_K);             // gate weights (late)
  // app1
  short* V1b   = (short*)(ws + OFF_R2);            // R2 lower
  short* VT1b  = (short*)(ws + OFF_R3);            // R3 lower
  short* OW1   = (short*)(ws + OFF_R1);            // R1 lower
  short* OH1   = (short*)(ws + OFF_R2);            // R2 lower
  // app2 (fused producer)
  short* V2b   = (short*)(ws + OFF_R2) + 8388608;  // R2 upper
  short* VT2b  = (short*)(ws + OFF_R1) + 8388608;  // R1 upper
  short* OW2   = (short*)(ws + OFF_R0);            // R0 lower
  short* OH2   = (short*)(ws + OFF_R2);            // R2 lower
  short* XB16  = (short*)(ws + OFF_R1);            // R1 lower
  // gates
  short* G0b = (short*)(ws + OFF_R0);
  short* G1b = (short*)(ws + OFF_R0) + 8388608;
  short* G2b = (short*)(ws + OFF_R2);
  short* G3b = (short*)(ws + OFF_R2) + 8388608;
  float* out = (float*)d_out;

  const dim3 gTile(64, D, B), gAtt(32, D, B);

  // stage 1: conv_pre via MFMA: x -> bf16 pos-major -> X1 (fp32) in R0
  k_wp <<<dim3(12),  dim3(256), 0, stream>>>(w_pre, WP16);
  k_x16<<<gTile,     dim3(256), 0, stream>>>(x, XB0);
  k_conv_pre16<<<dim3(16, D, B), dim3(256), 0, stream>>>(
      XB0, WP16, bnpg, bnpb, bnpm, bnpv, R0);

  // attention application 1 (mask on outer)
  k_qkv<<<gTile, dim3(256), 0, stream>>>(R0, wq, wk, wv, Kb, KTb, QTb, V1b, VT1b);
  k_att_row<false><<<gAtt, dim3(256), 0, stream>>>(R0, OW1, Kb, V1b, SI, wq);
  k_att_col<false><<<gAtt, dim3(256), 0, stream>>>(KTb, QTb, VT1b, OH1, SO);
  // fused: combine app1 + projections for app2 (Yt->R3, K/KT/QT, V2b/VT2b)
  k_comb_qkv<<<gTile, dim3(256), 0, stream>>>(
      R0, OW1, OH1, SI, SO, gamma, wq, wk, wv,
      R3, Kb, KTb, QTb, V2b, VT2b);

  // attention application 2 (transposed layout; mask on inner): x=R3
  k_att_row<true><<<gAtt, dim3(256), 0, stream>>>(R3, OW2, Kb, V2b, SI, wq);
  k_att_col<true><<<gAtt, dim3(256), 0, stream>>>(KTb, QTb, VT2b, OH2, SO);
  k_comb_bf<<<gTile, dim3(256), 0, stream>>>(R3, OW2, OH2, SI, SO, gamma, XB16);

  // bf16 gate weights (K region free now)
  k_wt<<<dim3(112), dim3(256), 0, stream>>>(w_gate, WT16);

  // stage 3: conv_gate via MFMA -> bf16 gates (G0,G1 in R0; G2,G3 in R2)
  k_gates<<<dim3(64, D, B), dim3(256), 0, stream>>>(XB16, WT16, G0b, G1b, G2b, G3b);

  // stage 4: BN + activations + SRU scan -> out
  k_scan<<<dim3(2048), dim3(256), 0, stream>>>(G0b, G1b, G2b, G3b, bng, bnb, bnm, bnv, out);
}

// Round 21
// 280.127 us; speedup vs baseline: 2.3197x; 1.0098x over previous
//
#include <hip/hip_runtime.h>
#include <math.h>

// Problem constants
namespace {
constexpr int B = 2, C = 16, D = 16, H = 128, W = 128;
constexpr int HW   = H * W;        // 16384
constexpr int DHW  = D * HW;       // 262144
constexpr int CDHW = C * DHW;      // 4194304
constexpr float EPSBN = 1e-5f;

// workspace regions (floats). ws = 37,748,736 floats = 151 MB
constexpr long long OFF_R0  = 0;
constexpr long long OFF_R1  = 8388608;
constexpr long long OFF_K   = 16777216;  // K / WT16 (bf16 gate weights)
constexpr long long OFF_KT  = 17825792;
constexpr long long OFF_QT  = 18874368;
constexpr long long OFF_MST = 19922944;  // s_inner (I,O); 0.5M used
constexpr long long OFF_SO  = 20447232;  // s_outer (I,O); 0.5M used; WP16 early
constexpr long long OFF_R2  = 20971520;
constexpr long long OFF_R3  = 29360128;
}

using frag_ab = __attribute__((ext_vector_type(8))) short;  // 8 bf16
using frag_cd = __attribute__((ext_vector_type(4))) float;  // 4 f32

__device__ __forceinline__ unsigned short f2bf(float f) {
  unsigned u = __float_as_uint(f);
  u = (u + 0x7FFF + ((u >> 16) & 1)) >> 16;   // RNE
  return (unsigned short)u;
}
__device__ __forceinline__ float bf2f(short s) {
  return __uint_as_float(((unsigned)(unsigned short)s) << 16);
}
__device__ __forceinline__ unsigned cvt_pk_bf16(float lo, float hi) {
  unsigned r;
  asm volatile("v_cvt_pk_bf16_f32 %0, %1, %2" : "=v"(r) : "v"(lo), "v"(hi));
  return r;
}

// ---------------------------------------------------------------------------
// K_x16: cast input x (fp32, c-major) -> bf16 [pos][16c]. grid(64, D, B).
// ---------------------------------------------------------------------------
__global__ __launch_bounds__(256) void k_x16(
    const float* __restrict__ x, short* __restrict__ XB0)
{
  const int tid = threadIdx.x;
  const int tile = blockIdx.x, d = blockIdx.y, b = blockIdx.z;
  const int h0 = (tile >> 3) * 16, w0 = (tile & 7) * 16;
  const long long xbase = (long long)b * CDHW + (long long)d * HW;
  const int th = tid >> 4, tw = tid & 15;

  float v[16];
  #pragma unroll
  for (int c = 0; c < 16; ++c)
    v[c] = x[xbase + (long long)c * DHW + (h0 + th) * 128 + (w0 + tw)];

  unsigned pk[8];
  #pragma unroll
  for (int c = 0; c < 8; ++c)
    pk[c] = (unsigned)f2bf(v[2 * c]) | ((unsigned)f2bf(v[2 * c + 1]) << 16);
  short* dst = XB0 + ((long long)(b * D + d) * HW + (h0 + th) * 128 + (w0 + tw)) * 16;
  *(uint4*)(dst)     = make_uint4(pk[0], pk[1], pk[2], pk[3]);
  *(uint4*)(dst + 8) = make_uint4(pk[4], pk[5], pk[6], pk[7]);
}

// ---------------------------------------------------------------------------
// K_wp: pack conv_pre weights -> bf16 per-half layout.
// ---------------------------------------------------------------------------
__global__ __launch_bounds__(256) void k_wp(
    const float* __restrict__ wp, short* __restrict__ WP16)
{
  const int idx = blockIdx.x * 256 + threadIdx.x;   // < 3072
  if (idx >= 2 * 16 * 96) return;
  const int u = idx / 96;            // half*16 + co
  const int k = idx - u * 96;
  const int ks = k >> 5, rem = k & 31;
  const int t = rem >> 3, c8 = rem & 7;
  const int tap = ks * 4 + t;
  const int half = u >> 4, co = u & 15;
  const int cin = half * 8 + c8;
  float v = (tap < 9) ? wp[co * 144 + cin * 9 + tap] : 0.f;
  WP16[idx] = (short)f2bf(v);
}

// ---------------------------------------------------------------------------
// K1 v3: conv_pre via MFMA, cin-halves sequential (LDS 21 KB). (verified)
// ---------------------------------------------------------------------------
__global__ __launch_bounds__(256) void k_conv_pre16(
    const short* __restrict__ XB0, const short* __restrict__ WP16,
    const float* __restrict__ bg, const float* __restrict__ bb,
    const float* __restrict__ bm, const float* __restrict__ bv,
    float* __restrict__ X1)
{
  __shared__ short xls[10 * 132 * 8];   // 21.1 KB
  const int tid = threadIdx.x;
  const int rg = blockIdx.x;
  const int d = blockIdx.y, b = blockIdx.z;
  const int h0 = rg * 8;

  const int lane = tid & 63;
  const int wv   = tid >> 6;
  const int p    = lane & 15;
  const int chunk = lane >> 4;

  const short* xb0 = XB0 + (long long)(b * D + d) * HW * 16;
  const frag_ab zero8 = {0, 0, 0, 0, 0, 0, 0, 0};

  frag_cd acc[2][8];
  #pragma unroll
  for (int r2 = 0; r2 < 2; ++r2)
    #pragma unroll
    for (int pg = 0; pg < 8; ++pg)
      acc[r2][pg] = (frag_cd){0.f, 0.f, 0.f, 0.f};

  int offs[3];
  #pragma unroll
  for (int s = 0; s < 3; ++s) {
    int tap = s * 4 + chunk;
    if (tap > 8) tap = 0;
    const int kh = (tap * 11) >> 5;
    const int kw = tap - kh * 3;
    offs[s] = ((2 * wv + kh) * 132 + p + kw) * 8;
  }

  for (int half = 0; half < 2; ++half) {
    for (int idx = tid; idx < 1320; idx += 256) {
      const int row = idx / 132, col = idx - row * 132;
      const int gh = h0 - 1 + row, gw = col - 1;
      frag_ab v = zero8;
      if (gh >= 0 && gh < H && gw >= 0 && gw < W)
        v = *(const frag_ab*)(xb0 + ((long long)gh * 128 + gw) * 16 + half * 8);
      *(frag_ab*)&xls[idx * 8] = v;
    }
    __syncthreads();

    frag_ab a[3];
    {
      const short* wl = WP16 + ((half << 4) + p) * 96 + chunk * 8;
      #pragma unroll
      for (int s = 0; s < 3; ++s)
        a[s] = *(const frag_ab*)(wl + s * 32);
    }

    #pragma unroll
    for (int s = 0; s < 3; ++s) {
      const frag_ab av = a[s];
      const int base0 = offs[s];
      #pragma unroll
      for (int pg = 0; pg < 8; ++pg) {
        frag_ab b0 = *(const frag_ab*)&xls[base0 + pg * 128];
        acc[0][pg] = __builtin_amdgcn_mfma_f32_16x16x32_bf16(av, b0, acc[0][pg], 0, 0, 0);
        frag_ab b1 = *(const frag_ab*)&xls[base0 + 1056 + pg * 128];
        acc[1][pg] = __builtin_amdgcn_mfma_f32_16x16x32_bf16(av, b1, acc[1][pg], 0, 0, 0);
      }
    }
    __syncthreads();
  }

  float sc4[4], bi4[4];
  #pragma unroll
  for (int reg = 0; reg < 4; ++reg) {
    const int co = chunk * 4 + reg;
    float s = bg[co] * rsqrtf(bv[co] + EPSBN);
    sc4[reg] = s;
    bi4[reg] = bb[co] - bm[co] * s;
  }
  const long long xbase = (long long)b * CDHW + (long long)d * HW;
  #pragma unroll
  for (int r2 = 0; r2 < 2; ++r2) {
    const int row = h0 + 2 * wv + r2;
    #pragma unroll
    for (int pg = 0; pg < 8; ++pg)
      #pragma unroll
      for (int reg = 0; reg < 4; ++reg) {
        const int co = chunk * 4 + reg;
        float v = fmaxf(fmaf(acc[r2][pg][reg], sc4[reg], bi4[reg]), 0.f);
        X1[xbase + (long long)co * DHW + row * 128 + pg * 16 + p] = v;
      }
  }
}

// ---------------------------------------------------------------------------
// K2: projections (app1 only). V/VT stored bf16.
// ---------------------------------------------------------------------------
__global__ __launch_bounds__(256) void k_qkv(
    const float* __restrict__ xin, const float* __restrict__ wq,
    const float* __restrict__ wk, const float* __restrict__ wv,
    float* __restrict__ Kp, float* __restrict__ KTp, float* __restrict__ QTp,
    short* __restrict__ Vp16, short* __restrict__ VTp16)
{
  const int tid = threadIdx.x;
  const int tile = blockIdx.x, d = blockIdx.y, b = blockIdx.z;
  const int h0 = (tile >> 3) * 16, w0 = (tile & 7) * 16;
  const int ty = tid >> 4, tx = tid & 15;
  const int h = h0 + ty, w = w0 + tx;

  const float* xb = xin + (long long)b * CDHW + (long long)d * HW + h * 128 + w;
  float xv[16];
  #pragma unroll
  for (int c = 0; c < 16; ++c) xv[c] = xb[(long long)c * DHW];

  float q0 = 0, q1 = 0, k0 = 0, k1 = 0, v[16];
  #pragma unroll
  for (int c = 0; c < 16; ++c) {
    q0 = fmaf(wq[c], xv[c], q0);
    q1 = fmaf(wq[16 + c], xv[c], q1);
    k0 = fmaf(wk[c], xv[c], k0);
    k1 = fmaf(wk[16 + c], xv[c], k1);
  }
  #pragma unroll
  for (int o = 0; o < 16; ++o) {
    float a = 0;
    #pragma unroll
    for (int c = 0; c < 16; ++c) a = fmaf(wv[o * 16 + c], xv[c], a);
    v[o] = a;
  }

  const int sl = b * 16 + d;
  const long long base2 = (long long)(sl * 2) * HW;
  const long long baseV = (long long)(sl * 16) * HW;
  const int hw = h * 128 + w;
  Kp[base2 + hw] = k0;
  Kp[base2 + HW + hw] = k1;
  #pragma unroll
  for (int o = 0; o < 16; ++o)
    Vp16[baseV + (long long)o * HW + hw] = (short)f2bf(v[o]);

  __shared__ float lsk[2][16][17];
  __shared__ float lsq[2][16][17];
  __shared__ float lsv[16][16][17];
  lsk[0][ty][tx] = k0; lsk[1][ty][tx] = k1;
  lsq[0][ty][tx] = q0; lsq[1][ty][tx] = q1;
  #pragma unroll
  for (int o = 0; o < 16; ++o) lsv[o][ty][tx] = v[o];
  __syncthreads();

  const int wh = (w0 + ty) * 128 + (h0 + tx);
  KTp[base2 + wh]      = lsk[0][tx][ty];
  KTp[base2 + HW + wh] = lsk[1][tx][ty];
  QTp[base2 + wh]      = lsq[0][tx][ty];
  QTp[base2 + HW + wh] = lsq[1][tx][ty];
  #pragma unroll
  for (int o = 0; o < 16; ++o)
    VTp16[baseV + (long long)o * HW + wh] = (short)f2bf(lsv[o][tx][ty]);
}

// ---------------------------------------------------------------------------
// K3 v7: INNER direction via MFMA. OWn stored bf16 [pos][16c].
// ---------------------------------------------------------------------------
template<bool MASK_INNER>
__global__ __launch_bounds__(256) void k_att_row(
    const float* __restrict__ xin, short* __restrict__ OWn16,
    const float* __restrict__ Kp, const short* __restrict__ Vp16,
    float* __restrict__ Sip, const float* __restrict__ wq)
{
  __shared__ float kr2[4][128][2];
  __shared__ float q0l[4][128], q1l[4][128];
  __shared__ __align__(16) short v16[4][16][136];
  const int tid = threadIdx.x;
  const int o0 = blockIdx.x * 4, d = blockIdx.y, b = blockIdx.z;
  const int sl = b * 16 + d;
  const long long base2 = (long long)(sl * 2) * HW;
  const long long baseV = (long long)(sl * 16) * HW;
  const long long baseM = (long long)sl * HW;
  const int hi = tid >> 6;
  const int L  = tid & 63;
  const int p  = L & 15;
  const int chunk = L >> 4;
  const int orow = o0 + hi;
  const long long xbase = (long long)b * CDHW + (long long)d * HW;

  for (int kk = tid; kk < 1024; kk += 256) {
    int col = kk & 127;
    int t = kk >> 7;
    int r2 = t >> 1, o = t & 1;
    kr2[r2][col][o] = Kp[base2 + (long long)o * HW + (o0 + r2) * 128 + col];
  }
  for (int idx = tid; idx < 2048; idx += 256) {
    int v4 = idx & 31;
    int t = idx >> 5;
    int c = t & 15, r2 = t >> 4;
    *(uint2*)&v16[r2][c][v4 * 4] =
        *(const uint2*)&Vp16[baseV + (long long)c * HW + (o0 + r2) * 128 + v4 * 4];
  }
  {
    float q0a = 0.f, q0b = 0.f, q1a = 0.f, q1b = 0.f;
    #pragma unroll
    for (int c = 0; c < 16; ++c) {
      const float w0 = wq[c], w1 = wq[16 + c];
      float xa = xin[xbase + (long long)c * DHW + orow * 128 + L];
      float xb2 = xin[xbase + (long long)c * DHW + orow * 128 + L + 64];
      q0a = fmaf(w0, xa, q0a);  q1a = fmaf(w1, xa, q1a);
      q0b = fmaf(w0, xb2, q0b); q1b = fmaf(w1, xb2, q1b);
    }
    q0l[hi][L] = q0a; q0l[hi][L + 64] = q0b;
    q1l[hi][L] = q1a; q1l[hi][L + 64] = q1b;
  }
  __syncthreads();

  float q0r[8], q1r[8];
  #pragma unroll
  for (int ti = 0; ti < 8; ++ti) {
    q0r[ti] = q0l[hi][ti * 16 + p];
    q1r[ti] = q1l[hi][ti * 16 + p];
  }

  frag_cd acc[8];
  #pragma unroll
  for (int ti = 0; ti < 8; ++ti) acc[ti] = (frag_cd){0.f, 0.f, 0.f, 0.f};
  float ssum[8] = {0.f, 0.f, 0.f, 0.f, 0.f, 0.f, 0.f, 0.f};

  #pragma unroll
  for (int ks = 0; ks < 4; ++ks) {
    const int vb = ks * 32 + chunk * 8;
    float2 kv[8];
    const float* kvp = &kr2[hi][vb][0];
    *(float4*)&kv[0] = *(const float4*)(kvp);
    *(float4*)&kv[2] = *(const float4*)(kvp + 4);
    *(float4*)&kv[4] = *(const float4*)(kvp + 8);
    *(float4*)&kv[6] = *(const float4*)(kvp + 12);
    frag_ab bfrag = *(const frag_ab*)&v16[hi][p][vb];

    #pragma unroll
    for (int ti = 0; ti < 8; ++ti) {
      float pv[8];
      #pragma unroll
      for (int j = 0; j < 8; ++j) {
        float e = fmaf(q0r[ti], kv[j].x, q1r[ti] * kv[j].y);
        pv[j] = __expf(e);
      }
      if constexpr (MASK_INNER) {
        const int dj = ti * 16 + p - vb;
        #pragma unroll
        for (int j = 0; j < 8; ++j)
          if (j == dj) pv[j] = 0.f;
      }
      float lsum = 0.f;
      #pragma unroll
      for (int j = 0; j < 8; ++j) lsum += pv[j];
      ssum[ti] += lsum;

      union { frag_ab f; unsigned u[4]; } cv;
      cv.u[0] = cvt_pk_bf16(pv[0], pv[1]);
      cv.u[1] = cvt_pk_bf16(pv[2], pv[3]);
      cv.u[2] = cvt_pk_bf16(pv[4], pv[5]);
      cv.u[3] = cvt_pk_bf16(pv[6], pv[7]);
      acc[ti] = __builtin_amdgcn_mfma_f32_16x16x32_bf16(cv.f, bfrag, acc[ti], 0, 0, 0);
    }
  }

  #pragma unroll
  for (int ti = 0; ti < 8; ++ti) {
    ssum[ti] += __shfl_xor(ssum[ti], 16);
    ssum[ti] += __shfl_xor(ssum[ti], 32);
  }
  if (L < 16) {
    #pragma unroll
    for (int ti = 0; ti < 8; ++ti)
      Sip[baseM + (ti * 16 + L) * 128 + orow] = ssum[ti];
  }

  short* ob = OWn16 + ((long long)(b * D + d) * HW + orow * 128) * 16;
  #pragma unroll
  for (int ti = 0; ti < 8; ++ti)
    #pragma unroll
    for (int reg = 0; reg < 4; ++reg)
      ob[(ti * 16 + chunk * 4 + reg) * 16 + p] = (short)f2bf(acc[ti][reg]);
}

// ---------------------------------------------------------------------------
// K4 v7: OUTER direction via MFMA. OHn stored bf16 [pos][16c].
// ---------------------------------------------------------------------------
template<bool MASK_INNER>
__global__ __launch_bounds__(256) void k_att_col(
    const float* __restrict__ KTp, const float* __restrict__ QTp,
    const short* __restrict__ VTp16, short* __restrict__ OHn16,
    float* __restrict__ Sop)
{
  __shared__ float kr2[4][128][2];
  __shared__ __align__(16) short v16[4][16][136];
  const int tid = threadIdx.x;
  const int i0 = blockIdx.x * 4, d = blockIdx.y, b = blockIdx.z;
  const int sl = b * 16 + d;
  const long long base2 = (long long)(sl * 2) * HW;
  const long long baseV = (long long)(sl * 16) * HW;
  const long long baseS = (long long)sl * HW;
  const int hi = tid >> 6;
  const int L  = tid & 63;
  const int p  = L & 15;
  const int chunk = L >> 4;
  const int icol = i0 + hi;

  for (int kk = tid; kk < 1024; kk += 256) {
    int col = kk & 127;
    int t = kk >> 7;
    int r2 = t >> 1, o = t & 1;
    kr2[r2][col][o] = KTp[base2 + (long long)o * HW + (i0 + r2) * 128 + col];
  }
  for (int idx = tid; idx < 2048; idx += 256) {
    int j4 = idx & 31;
    int t = idx >> 5;
    int c = t & 15, r2 = t >> 4;
    *(uint2*)&v16[r2][c][j4 * 4] =
        *(const uint2*)&VTp16[baseV + (long long)c * HW + (i0 + r2) * 128 + j4 * 4];
  }
  __syncthreads();

  float q0r[8], q1r[8];
  #pragma unroll
  for (int ti = 0; ti < 8; ++ti) {
    q0r[ti] = QTp[base2 + icol * 128 + ti * 16 + p];
    q1r[ti] = QTp[base2 + HW + icol * 128 + ti * 16 + p];
  }

  frag_cd acc[8];
  #pragma unroll
  for (int ti = 0; ti < 8; ++ti) acc[ti] = (frag_cd){0.f, 0.f, 0.f, 0.f};
  float ssum[8] = {0.f, 0.f, 0.f, 0.f, 0.f, 0.f, 0.f, 0.f};

  #pragma unroll
  for (int ks = 0; ks < 4; ++ks) {
    const int vb = ks * 32 + chunk * 8;
    float2 kv[8];
    const float* kvp = &kr2[hi][vb][0];
    *(float4*)&kv[0] = *(const float4*)(kvp);
    *(float4*)&kv[2] = *(const float4*)(kvp + 4);
    *(float4*)&kv[4] = *(const float4*)(kvp + 8);
    *(float4*)&kv[6] = *(const float4*)(kvp + 12);
    frag_ab bfrag = *(const frag_ab*)&v16[hi][p][vb];

    #pragma unroll
    for (int ti = 0; ti < 8; ++ti) {
      float pv[8];
      #pragma unroll
      for (int j = 0; j < 8; ++j) {
        float e = fmaf(q0r[ti], kv[j].x, q1r[ti] * kv[j].y);
        pv[j] = __expf(e);
      }
      if constexpr (!MASK_INNER) {
        const int dj = ti * 16 + p - vb;    // mask j == orr
        #pragma unroll
        for (int j = 0; j < 8; ++j)
          if (j == dj) pv[j] = 0.f;
      }
      float lsum = 0.f;
      #pragma unroll
      for (int j = 0; j < 8; ++j) lsum += pv[j];
      ssum[ti] += lsum;

      union { frag_ab f; unsigned u[4]; } cv;
      cv.u[0] = cvt_pk_bf16(pv[0], pv[1]);
      cv.u[1] = cvt_pk_bf16(pv[2], pv[3]);
      cv.u[2] = cvt_pk_bf16(pv[4], pv[5]);
      cv.u[3] = cvt_pk_bf16(pv[6], pv[7]);
      acc[ti] = __builtin_amdgcn_mfma_f32_16x16x32_bf16(cv.f, bfrag, acc[ti], 0, 0, 0);
    }
  }

  #pragma unroll
  for (int ti = 0; ti < 8; ++ti) {
    ssum[ti] += __shfl_xor(ssum[ti], 16);
    ssum[ti] += __shfl_xor(ssum[ti], 32);
  }
  if (L < 16) {
    #pragma unroll
    for (int ti = 0; ti < 8; ++ti)
      Sop[baseS + icol * 128 + ti * 16 + L] = ssum[ti];
  }

  short* ob = OHn16 + ((long long)(b * D + d) * HW + icol * 128) * 16;
  #pragma unroll
  for (int ti = 0; ti < 8; ++ti)
    #pragma unroll
    for (int reg = 0; reg < 4; ++reg)
      ob[(ti * 16 + chunk * 4 + reg) * 16 + p] = (short)f2bf(acc[ti][reg]);
}

// ---------------------------------------------------------------------------
// K_comb_qkv: app1 combine + app2 projections, fused.
// res = x + gamma/(si+so)*(oW+oH); writes Yt (fp32, transposed frame) and
// projections of res in app2's frame: K, KT, QT (fp32), V/VT (bf16).
// ---------------------------------------------------------------------------
__global__ __launch_bounds__(256) void k_comb_qkv(
    const float* __restrict__ Xn, const short* __restrict__ OWn16,
    const short* __restrict__ OHn16, const float* __restrict__ Sip,
    const float* __restrict__ Sop, const float* __restrict__ gp,
    const float* __restrict__ wq, const float* __restrict__ wk,
    const float* __restrict__ wv,
    float* __restrict__ Yt, float* __restrict__ Kp, float* __restrict__ KTp,
    float* __restrict__ QTp, short* __restrict__ Vp16, short* __restrict__ VTp16)
{
  __shared__ float xs[16][16][17];    // x tile; later reused for v transpose
  __shared__ float ows[16][16][17];
  __shared__ float lsk[2][16][17], lsq[2][16][17];
  const int tid = threadIdx.x;
  const int tile = blockIdx.x, d = blockIdx.y, b = blockIdx.z;
  const int o0 = (tile >> 3) * 16, i0 = (tile & 7) * 16;
  const int sl = b * 16 + d;
  const long long baseM = (long long)sl * HW;
  const long long base2 = (long long)(sl * 2) * HW;
  const long long baseV = (long long)(sl * 16) * HW;
  const long long xbase = (long long)b * CDHW + (long long)d * HW;

  const int to = tid >> 4, ti = tid & 15;
  #pragma unroll
  for (int c = 0; c < 16; ++c) {
    const long long src = xbase + (long long)c * DHW + (o0 + to) * 128 + (i0 + ti);
    xs[c][to][ti] = Xn[src];
  }
  {
    const short* osrc = OWn16 + ((long long)(b * D + d) * HW + (o0 + to) * 128 + (i0 + ti)) * 16;
    frag_ab f0 = *(const frag_ab*)(osrc);
    frag_ab f1 = *(const frag_ab*)(osrc + 8);
    #pragma unroll
    for (int c = 0; c < 8; ++c) {
      ows[c][to][ti]     = bf2f(f0[c]);
      ows[c + 8][to][ti] = bf2f(f1[c]);
    }
  }
  __syncthreads();

  const int ti2 = tid >> 4, to2 = tid & 15;
  const int i = i0 + ti2, o = o0 + to2;
  const float si = Sip[baseM + i * 128 + o];
  const float so = Sop[baseM + i * 128 + o];
  const float gi = gp[0] / (si + so);

  float oh[16];
  {
    const short* osrc = OHn16 + ((long long)(b * D + d) * HW + i * 128 + o) * 16;
    frag_ab f0 = *(const frag_ab*)(osrc);
    frag_ab f1 = *(const frag_ab*)(osrc + 8);
    #pragma unroll
    for (int c = 0; c < 8; ++c) { oh[c] = bf2f(f0[c]); oh[c + 8] = bf2f(f1[c]); }
  }

  float res[16];
  #pragma unroll
  for (int c = 0; c < 16; ++c)
    res[c] = fmaf(gi, ows[c][to2][ti2] + oh[c], xs[c][to2][ti2]);

  // Yt (fp32, app2's normal-layout input)
  #pragma unroll
  for (int c = 0; c < 16; ++c)
    Yt[xbase + (long long)c * DHW + i * 128 + o] = res[c];

  // projections of res (app2 frame pixel (h=i, w=o))
  float q0 = 0, q1 = 0, k0 = 0, k1 = 0, v[16];
  #pragma unroll
  for (int c = 0; c < 16; ++c) {
    q0 = fmaf(wq[c], res[c], q0);
    q1 = fmaf(wq[16 + c], res[c], q1);
    k0 = fmaf(wk[c], res[c], k0);
    k1 = fmaf(wk[16 + c], res[c], k1);
  }
  #pragma unroll
  for (int oo = 0; oo < 16; ++oo) {
    float a = 0;
    #pragma unroll
    for (int c = 0; c < 16; ++c) a = fmaf(wv[oo * 16 + c], res[c], a);
    v[oo] = a;
  }

  const int hw = i * 128 + o;
  Kp[base2 + hw] = k0;
  Kp[base2 + HW + hw] = k1;
  #pragma unroll
  for (int oo = 0; oo < 16; ++oo)
    Vp16[baseV + (long long)oo * HW + hw] = (short)f2bf(v[oo]);

  // transposed outputs: write with [o-idx][i-idx] indexing
  lsk[0][to2][ti2] = k0; lsk[1][to2][ti2] = k1;
  lsq[0][to2][ti2] = q0; lsq[1][to2][ti2] = q1;
  __syncthreads();   // also guards xs reads above

  // reuse xs for v transpose
  #pragma unroll
  for (int c = 0; c < 16; ++c) xs[c][to2][ti2] = v[c];

  {
    const int a = tid >> 4, bb2 = tid & 15;   // a = o-idx, bb2 = i-idx
    const long long wh = (long long)(o0 + a) * 128 + (i0 + bb2);
    KTp[base2 + wh]      = lsk[0][a][bb2];
    KTp[base2 + HW + wh] = lsk[1][a][bb2];
    QTp[base2 + wh]      = lsq[0][a][bb2];
    QTp[base2 + HW + wh] = lsq[1][a][bb2];
  }
  __syncthreads();
  {
    const int a = tid >> 4, bb2 = tid & 15;
    const long long wh = (long long)(o0 + a) * 128 + (i0 + bb2);
    #pragma unroll
    for (int c = 0; c < 16; ++c)
      VTp16[baseV + (long long)c * HW + wh] = (short)f2bf(xs[c][a][bb2]);
  }
}

// ---------------------------------------------------------------------------
// K_comb (app2 final): bf16 OW/OH inputs; writes bf16 [pos][16c] Xb16.
// ---------------------------------------------------------------------------
__global__ __launch_bounds__(256) void k_comb_bf(
    const float* __restrict__ Xn, const short* __restrict__ OWn16,
    const short* __restrict__ OHn16, const float* __restrict__ Sip,
    const float* __restrict__ Sop, const float* __restrict__ gp,
    short* __restrict__ Xb16)
{
  __shared__ float xs[16][16][17], ows[16][16][17];
  const int tid = threadIdx.x;
  const int tile = blockIdx.x, d = blockIdx.y, b = blockIdx.z;
  const int o0 = (tile >> 3) * 16, i0 = (tile & 7) * 16;
  const int sl = b * 16 + d;
  const long long baseM = (long long)sl * HW;
  const long long xbase = (long long)b * CDHW + (long long)d * HW;

  const int to = tid >> 4, ti = tid & 15;
  #pragma unroll
  for (int c = 0; c < 16; ++c) {
    const long long src = xbase + (long long)c * DHW + (o0 + to) * 128 + (i0 + ti);
    xs[c][to][ti] = Xn[src];
  }
  {
    const short* osrc = OWn16 + ((long long)(b * D + d) * HW + (o0 + to) * 128 + (i0 + ti)) * 16;
    frag_ab f0 = *(const frag_ab*)(osrc);
    frag_ab f1 = *(const frag_ab*)(osrc + 8);
    #pragma unroll
    for (int c = 0; c < 8; ++c) {
      ows[c][to][ti]     = bf2f(f0[c]);
      ows[c + 8][to][ti] = bf2f(f1[c]);
    }
  }
  __syncthreads();

  const int ti2 = tid >> 4, to2 = tid & 15;
  const int i = i0 + ti2, o = o0 + to2;
  const float si = Sip[baseM + i * 128 + o];
  const float so = Sop[baseM + i * 128 + o];
  const float gi = gp[0] / (si + so);

  float oh[16];
  {
    const short* osrc = OHn16 + ((long long)(b * D + d) * HW + i * 128 + o) * 16;
    frag_ab f0 = *(const frag_ab*)(osrc);
    frag_ab f1 = *(const frag_ab*)(osrc + 8);
    #pragma unroll
    for (int c = 0; c < 8; ++c) { oh[c] = bf2f(f0[c]); oh[c + 8] = bf2f(f1[c]); }
  }

  float res[16];
  #pragma unroll
  for (int c = 0; c < 16; ++c)
    res[c] = fmaf(gi, ows[c][to2][ti2] + oh[c], xs[c][to2][ti2]);

  unsigned pk[8];
  #pragma unroll
  for (int c = 0; c < 8; ++c)
    pk[c] = (unsigned)f2bf(res[2 * c]) | ((unsigned)f2bf(res[2 * c + 1]) << 16);
  short* dst = Xb16 + ((long long)(b * D + d) * HW + i * 128 + o) * 16;
  *(uint4*)(dst)     = make_uint4(pk[0], pk[1], pk[2], pk[3]);
  *(uint4*)(dst + 8) = make_uint4(pk[4], pk[5], pk[6], pk[7]);
}

// ---------------------------------------------------------------------------
// K_wt: pack gate weights -> bf16 per-half layout.
// ---------------------------------------------------------------------------
__global__ __launch_bounds__(256) void k_wt(
    const float* __restrict__ wg, short* __restrict__ WT16)
{
  const int idx = blockIdx.x * 256 + threadIdx.x;   // < 28672
  if (idx >= 2 * 64 * 224) return;
  const int u = idx / 224;           // half*64 + co
  const int k = idx - u * 224;
  const int ks = k >> 5, rem = k & 31;
  const int t = rem >> 3, c8 = rem & 7;
  const int tap = ks * 4 + t;
  const int half = u >> 6, co = u & 63;
  const int cin = half * 8 + c8;
  float v = (tap < 27) ? wg[co * 432 + cin * 27 + tap] : 0.f;
  WT16[idx] = (short)f2bf(v);
}

// ---------------------------------------------------------------------------
// K5a v2: conv_gate via MFMA, cin-halves sequential. Gates stored bf16.
// ---------------------------------------------------------------------------
__global__ __launch_bounds__(256, 2) void k_gates(
    const short* __restrict__ XB16, const short* __restrict__ WT16,
    short* __restrict__ g0, short* __restrict__ g1,
    short* __restrict__ g2, short* __restrict__ g3)
{
  __shared__ short xls[1584 * 8];       // 25.3 KB
  const int tid = threadIdx.x;
  const int rp = blockIdx.x;
  const int d = blockIdx.y, b = blockIdx.z;
  const int h0 = rp * 2;

  const int lane = tid & 63;
  const int og   = tid >> 6;
  const int p    = lane & 15;
  const int chunk = lane >> 4;

  const short* xb = XB16 + (long long)(b * D) * HW * 16;
  const frag_ab zero8 = {0, 0, 0, 0, 0, 0, 0, 0};

  frag_cd acc[2][8];
  #pragma unroll
  for (int r2 = 0; r2 < 2; ++r2)
    #pragma unroll
    for (int pg = 0; pg < 8; ++pg)
      acc[r2][pg] = (frag_cd){0.f, 0.f, 0.f, 0.f};

  int offs[7];
  #pragma unroll
  for (int s = 0; s < 7; ++s) {
    int tap = s * 4 + chunk;
    if (tap > 26) tap = 0;
    const int kd = (tap * 57) >> 9;
    const int rem = tap - kd * 9;
    const int kh = (rem * 11) >> 5;
    const int kw = rem - kh * 3;
    offs[s] = ((kd * 4 + kh) * 132 + p + kw) * 8;
  }

  for (int half = 0; half < 2; ++half) {
    for (int idx = tid; idx < 1584; idx += 256) {
      const int kd = idx / 528;
      const int rem = idx - kd * 528;
      const int rr = rem / 132;
      const int col = rem - rr * 132;
      const int dd = d - 1 + kd, gh = h0 - 1 + rr, gw = col - 1;
      frag_ab v = zero8;
      if (dd >= 0 && dd < D && gh >= 0 && gh < H && gw >= 0 && gw < W)
        v = *(const frag_ab*)(xb + ((long long)dd * HW + gh * W + gw) * 16 + half * 8);
      *(frag_ab*)&xls[idx * 8] = v;
    }
    __syncthreads();

    frag_ab a[7];
    {
      const short* wl = WT16 + ((half << 6) + og * 16 + p) * 224 + chunk * 8;
      #pragma unroll
      for (int s = 0; s < 7; ++s)
        a[s] = *(const frag_ab*)(wl + s * 32);
    }

    #pragma unroll
    for (int s = 0; s < 7; ++s) {
      const frag_ab av = a[s];
      const int base0 = offs[s];
      #pragma unroll
      for (int pg = 0; pg < 8; ++pg) {
        frag_ab b0 = *(const frag_ab*)&xls[base0 + pg * 128];
        acc[0][pg] = __builtin_amdgcn_mfma_f32_16x16x32_bf16(av, b0, acc[0][pg], 0, 0, 0);
        frag_ab b1 = *(const frag_ab*)&xls[base0 + 1056 + pg * 128];
        acc[1][pg] = __builtin_amdgcn_mfma_f32_16x16x32_bf16(av, b1, acc[1][pg], 0, 0, 0);
      }
    }
    __syncthreads();
  }

  short* gbuf = (og == 0) ? g0 : (og == 1) ? g1 : (og == 2) ? g2 : g3;
  const long long base = (long long)b * CDHW + (long long)d * HW + h0 * W;
  #pragma unroll
  for (int r2 = 0; r2 < 2; ++r2)
    #pragma unroll
    for (int pg = 0; pg < 8; ++pg)
      #pragma unroll
      for (int reg = 0; reg < 4; ++reg) {
        const int cc = chunk * 4 + reg;
        gbuf[base + (long long)cc * DHW + r2 * W + pg * 16 + p] =
            (short)f2bf(acc[r2][pg][reg]);
      }
}

// ---------------------------------------------------------------------------
// K5b: BN + activations + SRU scan over D. Gates read as bf16.
// ---------------------------------------------------------------------------
__global__ __launch_bounds__(256) void k_scan(
    const short* __restrict__ g0, const short* __restrict__ g1,
    const short* __restrict__ g2, const short* __restrict__ g3,
    const float* __restrict__ bg, const float* __restrict__ bb,
    const float* __restrict__ bm, const float* __restrict__ bv,
    float* __restrict__ out)
{
  const int g = blockIdx.x * 256 + threadIdx.x;   // 0 .. 524287
  const int hw = g & 16383;
  const int cc = (g >> 14) & 15;
  const int b  = g >> 18;

  float sc[4], bi[4];
  #pragma unroll
  for (int gg = 0; gg < 4; ++gg) {
    int ch = gg * 16 + cc;
    float s = bg[ch] * rsqrtf(bv[ch] + EPSBN);
    sc[gg] = s;
    bi[gg] = bb[ch] - bm[ch] * s;
  }

  const long long base = (long long)b * CDHW + (long long)cc * DHW + hw;
  float Ct = 0.f;
  for (int d = 0; d < D; ++d) {
    const long long idx = base + (long long)d * HW;
    float wx = tanhf(fmaf(bf2f(g0[idx]), sc[0], bi[0]));
    float ft = 1.f / (1.f + __expf(-fmaf(bf2f(g1[idx]), sc[1], bi[1])));
    float rt = 1.f / (1.f + __expf(-fmaf(bf2f(g2[idx]), sc[2], bi[2])));
    float xg = tanhf(fmaf(bf2f(g3[idx]), sc[3], bi[3]));
    Ct = (d == 0) ? (1.f - ft) : fmaf(ft, Ct, (1.f - ft) * wx);
    out[idx] = fmaf(rt, Ct, (1.f - rt) * xg);
  }
}

// ---------------------------------------------------------------------------
extern "C" void kernel_launch(void* const* d_in, const int* in_sizes, int n_in,
                              void* d_out, int out_size, void* d_ws, size_t ws_size,
                              hipStream_t stream) {
  const float* x      = (const float*)d_in[0];
  const float* w_pre  = (const float*)d_in[1];
  const float* bnpg   = (const float*)d_in[2];
  const float* bnpb   = (const float*)d_in[3];
  const float* bnpm   = (const float*)d_in[4];
  const float* bnpv   = (const float*)d_in[5];
  const float* wq     = (const float*)d_in[6];
  const float* wk     = (const float*)d_in[7];
  const float* wv     = (const float*)d_in[8];
  const float* gamma  = (const float*)d_in[9];
  const float* w_gate = (const float*)d_in[10];
  const float* bng    = (const float*)d_in[11];
  const float* bnb    = (const float*)d_in[12];
  const float* bnm    = (const float*)d_in[13];
  const float* bnv    = (const float*)d_in[14];

  float* ws  = (float*)d_ws;
  float* R0  = ws + OFF_R0;
  float* R3  = ws + OFF_R3;
  float* Kb  = ws + OFF_K;
  float* KTb = ws + OFF_KT;
  float* QTb = ws + OFF_QT;
  float* SI  = ws + OFF_MST;
  float* SO  = ws + OFF_SO;

  short* XB0   = (short*)(ws + OFF_R1);            // bf16 input (early)
  short* WP16  = (short*)(ws + OFF_SO);            // conv_pre weights (early)
  short* WT16  = (short*)(ws + OFF_K);             // gate weights (late)
  // app1
  short* V1b   = (short*)(ws + OFF_R2);            // R2 lower
  short* VT1b  = (short*)(ws + OFF_R3);            // R3 lower
  short* OW1   = (short*)(ws + OFF_R1);            // R1 lower
  short* OH1   = (short*)(ws + OFF_R2);            // R2 lower
  // app2 (fused producer)
  short* V2b   = (short*)(ws + OFF_R2) + 8388608;  // R2 upper
  short* VT2b  = (short*)(ws + OFF_R1) + 8388608;  // R1 upper
  short* OW2   = (short*)(ws + OFF_R0);            // R0 lower
  short* OH2   = (short*)(ws + OFF_R2);            // R2 lower
  short* XB16  = (short*)(ws + OFF_R1);            // R1 lower
  // gates
  short* G0b = (short*)(ws + OFF_R0);
  short* G1b = (short*)(ws + OFF_R0) + 8388608;
  short* G2b = (short*)(ws + OFF_R2);
  short* G3b = (short*)(ws + OFF_R2) + 8388608;
  float* out = (float*)d_out;

  const dim3 gTile(64, D, B), gAtt(32, D, B);

  // stage 1: conv_pre via MFMA: x -> bf16 pos-major -> X1 (fp32) in R0
  k_wp <<<dim3(12),  dim3(256), 0, stream>>>(w_pre, WP16);
  k_x16<<<gTile,     dim3(256), 0, stream>>>(x, XB0);
  k_conv_pre16<<<dim3(16, D, B), dim3(256), 0, stream>>>(
      XB0, WP16, bnpg, bnpb, bnpm, bnpv, R0);

  // attention application 1 (mask on outer)
  k_qkv<<<gTile, dim3(256), 0, stream>>>(R0, wq, wk, wv, Kb, KTb, QTb, V1b, VT1b);
  k_att_row<false><<<gAtt, dim3(256), 0, stream>>>(R0, OW1, Kb, V1b, SI, wq);
  k_att_col<false><<<gAtt, dim3(256), 0, stream>>>(KTb, QTb, VT1b, OH1, SO);
  // fused: combine app1 + projections for app2 (Yt->R3, K/KT/QT, V2b/VT2b)
  k_comb_qkv<<<gTile, dim3(256), 0, stream>>>(
      R0, OW1, OH1, SI, SO, gamma, wq, wk, wv,
      R3, Kb, KTb, QTb, V2b, VT2b);

  // attention application 2 (transposed layout; mask on inner): x=R3
  k_att_row<true><<<gAtt, dim3(256), 0, stream>>>(R3, OW2, Kb, V2b, SI, wq);
  k_att_col<true><<<gAtt, dim3(256), 0, stream>>>(KTb, QTb, VT2b, OH2, SO);
  k_comb_bf<<<gTile, dim3(256), 0, stream>>>(R3, OW2, OH2, SI, SO, gamma, XB16);

  // bf16 gate weights (K region free now)
  k_wt<<<dim3(112), dim3(256), 0, stream>>>(w_gate, WT16);

  // stage 3: conv_gate via MFMA -> bf16 gates (G0,G1 in R0; G2,G3 in R2)
  k_gates<<<dim3(64, D, B), dim3(256), 0, stream>>>(XB16, WT16, G0b, G1b, G2b, G3b);

  // stage 4: BN + activations + SRU scan -> out
  k_scan<<<dim3(2048), dim3(256), 0, stream>>>(G0b, G1b, G2b, G3b, bng, bnb, bnm, bnv, out);
}

// Round 22
// 276.057 us; speedup vs baseline: 2.3539x; 1.0147x over previous
//
#include <hip/hip_runtime.h>
#include <math.h>

// Problem constants
namespace {
constexpr int B = 2, C = 16, D = 16, H = 128, W = 128;
constexpr int HW   = H * W;        // 16384
constexpr int DHW  = D * HW;       // 262144
constexpr int CDHW = C * DHW;      // 4194304
constexpr float EPSBN = 1e-5f;

// workspace regions (floats). ws = 37,748,736 floats = 151 MB
constexpr long long OFF_R0  = 0;
constexpr long long OFF_R1  = 8388608;
constexpr long long OFF_K   = 16777216;  // K / WT16 (bf16 gate weights)
constexpr long long OFF_KT  = 17825792;
constexpr long long OFF_QT  = 18874368;
constexpr long long OFF_MST = 19922944;  // s_inner (I,O); 0.5M used
constexpr long long OFF_SO  = 20447232;  // s_outer (I,O); 0.5M used; WP16 early
constexpr long long OFF_R2  = 20971520;
constexpr long long OFF_R3  = 29360128;
}

using frag_ab = __attribute__((ext_vector_type(8))) short;  // 8 bf16
using frag_cd = __attribute__((ext_vector_type(4))) float;  // 4 f32

__device__ __forceinline__ unsigned short f2bf(float f) {
  unsigned u = __float_as_uint(f);
  u = (u + 0x7FFF + ((u >> 16) & 1)) >> 16;   // RNE
  return (unsigned short)u;
}
__device__ __forceinline__ float bf2f(short s) {
  return __uint_as_float(((unsigned)(unsigned short)s) << 16);
}
__device__ __forceinline__ unsigned cvt_pk_bf16(float lo, float hi) {
  unsigned r;
  asm volatile("v_cvt_pk_bf16_f32 %0, %1, %2" : "=v"(r) : "v"(lo), "v"(hi));
  return r;
}

// ---------------------------------------------------------------------------
// K_x16: cast input x (fp32, c-major) -> bf16 [pos][16c]. grid(64, D, B).
// ---------------------------------------------------------------------------
__global__ __launch_bounds__(256) void k_x16(
    const float* __restrict__ x, short* __restrict__ XB0)
{
  const int tid = threadIdx.x;
  const int tile = blockIdx.x, d = blockIdx.y, b = blockIdx.z;
  const int h0 = (tile >> 3) * 16, w0 = (tile & 7) * 16;
  const long long xbase = (long long)b * CDHW + (long long)d * HW;
  const int th = tid >> 4, tw = tid & 15;

  float v[16];
  #pragma unroll
  for (int c = 0; c < 16; ++c)
    v[c] = x[xbase + (long long)c * DHW + (h0 + th) * 128 + (w0 + tw)];

  unsigned pk[8];
  #pragma unroll
  for (int c = 0; c < 8; ++c)
    pk[c] = (unsigned)f2bf(v[2 * c]) | ((unsigned)f2bf(v[2 * c + 1]) << 16);
  short* dst = XB0 + ((long long)(b * D + d) * HW + (h0 + th) * 128 + (w0 + tw)) * 16;
  *(uint4*)(dst)     = make_uint4(pk[0], pk[1], pk[2], pk[3]);
  *(uint4*)(dst + 8) = make_uint4(pk[4], pk[5], pk[6], pk[7]);
}

// ---------------------------------------------------------------------------
// K_wp: pack conv_pre weights -> bf16 per-half layout.
// ---------------------------------------------------------------------------
__global__ __launch_bounds__(256) void k_wp(
    const float* __restrict__ wp, short* __restrict__ WP16)
{
  const int idx = blockIdx.x * 256 + threadIdx.x;   // < 3072
  if (idx >= 2 * 16 * 96) return;
  const int u = idx / 96;            // half*16 + co
  const int k = idx - u * 96;
  const int ks = k >> 5, rem = k & 31;
  const int t = rem >> 3, c8 = rem & 7;
  const int tap = ks * 4 + t;
  const int half = u >> 4, co = u & 15;
  const int cin = half * 8 + c8;
  float v = (tap < 9) ? wp[co * 144 + cin * 9 + tap] : 0.f;
  WP16[idx] = (short)f2bf(v);
}

// ---------------------------------------------------------------------------
// K1 v4: conv_pre via MFMA, cin-halves sequential, ASYNC-STAGE split:
// half-1 global loads issued into registers before half-0's MFMA loop.
// ---------------------------------------------------------------------------
__global__ __launch_bounds__(256) void k_conv_pre16(
    const short* __restrict__ XB0, const short* __restrict__ WP16,
    const float* __restrict__ bg, const float* __restrict__ bb,
    const float* __restrict__ bm, const float* __restrict__ bv,
    float* __restrict__ X1)
{
  __shared__ short xls[10 * 132 * 8];   // 21.1 KB
  const int tid = threadIdx.x;
  const int rg = blockIdx.x;
  const int d = blockIdx.y, b = blockIdx.z;
  const int h0 = rg * 8;

  const int lane = tid & 63;
  const int wv   = tid >> 6;
  const int p    = lane & 15;
  const int chunk = lane >> 4;

  const short* xb0 = XB0 + (long long)(b * D + d) * HW * 16;
  const frag_ab zero8 = {0, 0, 0, 0, 0, 0, 0, 0};

  // per-thread staging offsets (element index in shorts; -1 = OOB)
  int goff[6];
  #pragma unroll
  for (int it = 0; it < 6; ++it) {
    const int idx = it * 256 + tid;
    goff[it] = -1;
    if (idx < 1320) {
      const int row = idx / 132, col = idx - row * 132;
      const int gh = h0 - 1 + row, gw = col - 1;
      if (gh >= 0 && gh < H && gw >= 0 && gw < W)
        goff[it] = (gh * 128 + gw) * 16;
    }
  }

  frag_cd acc[2][8];
  #pragma unroll
  for (int r2 = 0; r2 < 2; ++r2)
    #pragma unroll
    for (int pg = 0; pg < 8; ++pg)
      acc[r2][pg] = (frag_cd){0.f, 0.f, 0.f, 0.f};

  int offs[3];
  #pragma unroll
  for (int s = 0; s < 3; ++s) {
    int tap = s * 4 + chunk;
    if (tap > 8) tap = 0;
    const int kh = (tap * 11) >> 5;
    const int kw = tap - kh * 3;
    offs[s] = ((2 * wv + kh) * 132 + p + kw) * 8;
  }

  frag_ab st[6];
  // half 0: load -> regs -> LDS
  #pragma unroll
  for (int it = 0; it < 6; ++it)
    st[it] = (goff[it] >= 0) ? *(const frag_ab*)(xb0 + goff[it]) : zero8;
  #pragma unroll
  for (int it = 0; it < 6; ++it) {
    const int idx = it * 256 + tid;
    if (idx < 1320) *(frag_ab*)&xls[idx * 8] = st[it];
  }
  __syncthreads();

  // issue half-1 loads early (hide under half-0 MFMAs)
  #pragma unroll
  for (int it = 0; it < 6; ++it)
    st[it] = (goff[it] >= 0) ? *(const frag_ab*)(xb0 + goff[it] + 8) : zero8;

  // half 0 compute
  {
    frag_ab a[3];
    const short* wl = WP16 + p * 96 + chunk * 8;
    #pragma unroll
    for (int s = 0; s < 3; ++s) a[s] = *(const frag_ab*)(wl + s * 32);
    #pragma unroll
    for (int s = 0; s < 3; ++s) {
      const frag_ab av = a[s];
      const int base0 = offs[s];
      #pragma unroll
      for (int pg = 0; pg < 8; ++pg) {
        frag_ab b0 = *(const frag_ab*)&xls[base0 + pg * 128];
        acc[0][pg] = __builtin_amdgcn_mfma_f32_16x16x32_bf16(av, b0, acc[0][pg], 0, 0, 0);
        frag_ab b1 = *(const frag_ab*)&xls[base0 + 1056 + pg * 128];
        acc[1][pg] = __builtin_amdgcn_mfma_f32_16x16x32_bf16(av, b1, acc[1][pg], 0, 0, 0);
      }
    }
  }
  __syncthreads();

  // half 1: write staged regs, compute
  #pragma unroll
  for (int it = 0; it < 6; ++it) {
    const int idx = it * 256 + tid;
    if (idx < 1320) *(frag_ab*)&xls[idx * 8] = st[it];
  }
  __syncthreads();
  {
    frag_ab a[3];
    const short* wl = WP16 + (16 + p) * 96 + chunk * 8;
    #pragma unroll
    for (int s = 0; s < 3; ++s) a[s] = *(const frag_ab*)(wl + s * 32);
    #pragma unroll
    for (int s = 0; s < 3; ++s) {
      const frag_ab av = a[s];
      const int base0 = offs[s];
      #pragma unroll
      for (int pg = 0; pg < 8; ++pg) {
        frag_ab b0 = *(const frag_ab*)&xls[base0 + pg * 128];
        acc[0][pg] = __builtin_amdgcn_mfma_f32_16x16x32_bf16(av, b0, acc[0][pg], 0, 0, 0);
        frag_ab b1 = *(const frag_ab*)&xls[base0 + 1056 + pg * 128];
        acc[1][pg] = __builtin_amdgcn_mfma_f32_16x16x32_bf16(av, b1, acc[1][pg], 0, 0, 0);
      }
    }
  }

  float sc4[4], bi4[4];
  #pragma unroll
  for (int reg = 0; reg < 4; ++reg) {
    const int co = chunk * 4 + reg;
    float s = bg[co] * rsqrtf(bv[co] + EPSBN);
    sc4[reg] = s;
    bi4[reg] = bb[co] - bm[co] * s;
  }
  const long long xbase = (long long)b * CDHW + (long long)d * HW;
  #pragma unroll
  for (int r2 = 0; r2 < 2; ++r2) {
    const int row = h0 + 2 * wv + r2;
    #pragma unroll
    for (int pg = 0; pg < 8; ++pg)
      #pragma unroll
      for (int reg = 0; reg < 4; ++reg) {
        const int co = chunk * 4 + reg;
        float v = fmaxf(fmaf(acc[r2][pg][reg], sc4[reg], bi4[reg]), 0.f);
        X1[xbase + (long long)co * DHW + row * 128 + pg * 16 + p] = v;
      }
  }
}

// ---------------------------------------------------------------------------
// K2: projections (app1 only). V/VT stored bf16.
// ---------------------------------------------------------------------------
__global__ __launch_bounds__(256) void k_qkv(
    const float* __restrict__ xin, const float* __restrict__ wq,
    const float* __restrict__ wk, const float* __restrict__ wv,
    float* __restrict__ Kp, float* __restrict__ KTp, float* __restrict__ QTp,
    short* __restrict__ Vp16, short* __restrict__ VTp16)
{
  const int tid = threadIdx.x;
  const int tile = blockIdx.x, d = blockIdx.y, b = blockIdx.z;
  const int h0 = (tile >> 3) * 16, w0 = (tile & 7) * 16;
  const int ty = tid >> 4, tx = tid & 15;
  const int h = h0 + ty, w = w0 + tx;

  const float* xb = xin + (long long)b * CDHW + (long long)d * HW + h * 128 + w;
  float xv[16];
  #pragma unroll
  for (int c = 0; c < 16; ++c) xv[c] = xb[(long long)c * DHW];

  float q0 = 0, q1 = 0, k0 = 0, k1 = 0, v[16];
  #pragma unroll
  for (int c = 0; c < 16; ++c) {
    q0 = fmaf(wq[c], xv[c], q0);
    q1 = fmaf(wq[16 + c], xv[c], q1);
    k0 = fmaf(wk[c], xv[c], k0);
    k1 = fmaf(wk[16 + c], xv[c], k1);
  }
  #pragma unroll
  for (int o = 0; o < 16; ++o) {
    float a = 0;
    #pragma unroll
    for (int c = 0; c < 16; ++c) a = fmaf(wv[o * 16 + c], xv[c], a);
    v[o] = a;
  }

  const int sl = b * 16 + d;
  const long long base2 = (long long)(sl * 2) * HW;
  const long long baseV = (long long)(sl * 16) * HW;
  const int hw = h * 128 + w;
  Kp[base2 + hw] = k0;
  Kp[base2 + HW + hw] = k1;
  #pragma unroll
  for (int o = 0; o < 16; ++o)
    Vp16[baseV + (long long)o * HW + hw] = (short)f2bf(v[o]);

  __shared__ float lsk[2][16][17];
  __shared__ float lsq[2][16][17];
  __shared__ float lsv[16][16][17];
  lsk[0][ty][tx] = k0; lsk[1][ty][tx] = k1;
  lsq[0][ty][tx] = q0; lsq[1][ty][tx] = q1;
  #pragma unroll
  for (int o = 0; o < 16; ++o) lsv[o][ty][tx] = v[o];
  __syncthreads();

  const int wh = (w0 + ty) * 128 + (h0 + tx);
  KTp[base2 + wh]      = lsk[0][tx][ty];
  KTp[base2 + HW + wh] = lsk[1][tx][ty];
  QTp[base2 + wh]      = lsq[0][tx][ty];
  QTp[base2 + HW + wh] = lsq[1][tx][ty];
  #pragma unroll
  for (int o = 0; o < 16; ++o)
    VTp16[baseV + (long long)o * HW + wh] = (short)f2bf(lsv[o][tx][ty]);
}

// ---------------------------------------------------------------------------
// K3 v7: INNER direction via MFMA. OWn stored bf16 [pos][16c].
// ---------------------------------------------------------------------------
template<bool MASK_INNER>
__global__ __launch_bounds__(256) void k_att_row(
    const float* __restrict__ xin, short* __restrict__ OWn16,
    const float* __restrict__ Kp, const short* __restrict__ Vp16,
    float* __restrict__ Sip, const float* __restrict__ wq)
{
  __shared__ float kr2[4][128][2];
  __shared__ float q0l[4][128], q1l[4][128];
  __shared__ __align__(16) short v16[4][16][136];
  const int tid = threadIdx.x;
  const int o0 = blockIdx.x * 4, d = blockIdx.y, b = blockIdx.z;
  const int sl = b * 16 + d;
  const long long base2 = (long long)(sl * 2) * HW;
  const long long baseV = (long long)(sl * 16) * HW;
  const long long baseM = (long long)sl * HW;
  const int hi = tid >> 6;
  const int L  = tid & 63;
  const int p  = L & 15;
  const int chunk = L >> 4;
  const int orow = o0 + hi;
  const long long xbase = (long long)b * CDHW + (long long)d * HW;

  for (int kk = tid; kk < 1024; kk += 256) {
    int col = kk & 127;
    int t = kk >> 7;
    int r2 = t >> 1, o = t & 1;
    kr2[r2][col][o] = Kp[base2 + (long long)o * HW + (o0 + r2) * 128 + col];
  }
  for (int idx = tid; idx < 2048; idx += 256) {
    int v4 = idx & 31;
    int t = idx >> 5;
    int c = t & 15, r2 = t >> 4;
    *(uint2*)&v16[r2][c][v4 * 4] =
        *(const uint2*)&Vp16[baseV + (long long)c * HW + (o0 + r2) * 128 + v4 * 4];
  }
  {
    float q0a = 0.f, q0b = 0.f, q1a = 0.f, q1b = 0.f;
    #pragma unroll
    for (int c = 0; c < 16; ++c) {
      const float w0 = wq[c], w1 = wq[16 + c];
      float xa = xin[xbase + (long long)c * DHW + orow * 128 + L];
      float xb2 = xin[xbase + (long long)c * DHW + orow * 128 + L + 64];
      q0a = fmaf(w0, xa, q0a);  q1a = fmaf(w1, xa, q1a);
      q0b = fmaf(w0, xb2, q0b); q1b = fmaf(w1, xb2, q1b);
    }
    q0l[hi][L] = q0a; q0l[hi][L + 64] = q0b;
    q1l[hi][L] = q1a; q1l[hi][L + 64] = q1b;
  }
  __syncthreads();

  float q0r[8], q1r[8];
  #pragma unroll
  for (int ti = 0; ti < 8; ++ti) {
    q0r[ti] = q0l[hi][ti * 16 + p];
    q1r[ti] = q1l[hi][ti * 16 + p];
  }

  frag_cd acc[8];
  #pragma unroll
  for (int ti = 0; ti < 8; ++ti) acc[ti] = (frag_cd){0.f, 0.f, 0.f, 0.f};
  float ssum[8] = {0.f, 0.f, 0.f, 0.f, 0.f, 0.f, 0.f, 0.f};

  #pragma unroll
  for (int ks = 0; ks < 4; ++ks) {
    const int vb = ks * 32 + chunk * 8;
    float2 kv[8];
    const float* kvp = &kr2[hi][vb][0];
    *(float4*)&kv[0] = *(const float4*)(kvp);
    *(float4*)&kv[2] = *(const float4*)(kvp + 4);
    *(float4*)&kv[4] = *(const float4*)(kvp + 8);
    *(float4*)&kv[6] = *(const float4*)(kvp + 12);
    frag_ab bfrag = *(const frag_ab*)&v16[hi][p][vb];

    #pragma unroll
    for (int ti = 0; ti < 8; ++ti) {
      float pv[8];
      #pragma unroll
      for (int j = 0; j < 8; ++j) {
        float e = fmaf(q0r[ti], kv[j].x, q1r[ti] * kv[j].y);
        pv[j] = __expf(e);
      }
      if constexpr (MASK_INNER) {
        const int dj = ti * 16 + p - vb;
        #pragma unroll
        for (int j = 0; j < 8; ++j)
          if (j == dj) pv[j] = 0.f;
      }
      float lsum = 0.f;
      #pragma unroll
      for (int j = 0; j < 8; ++j) lsum += pv[j];
      ssum[ti] += lsum;

      union { frag_ab f; unsigned u[4]; } cv;
      cv.u[0] = cvt_pk_bf16(pv[0], pv[1]);
      cv.u[1] = cvt_pk_bf16(pv[2], pv[3]);
      cv.u[2] = cvt_pk_bf16(pv[4], pv[5]);
      cv.u[3] = cvt_pk_bf16(pv[6], pv[7]);
      acc[ti] = __builtin_amdgcn_mfma_f32_16x16x32_bf16(cv.f, bfrag, acc[ti], 0, 0, 0);
    }
  }

  #pragma unroll
  for (int ti = 0; ti < 8; ++ti) {
    ssum[ti] += __shfl_xor(ssum[ti], 16);
    ssum[ti] += __shfl_xor(ssum[ti], 32);
  }
  if (L < 16) {
    #pragma unroll
    for (int ti = 0; ti < 8; ++ti)
      Sip[baseM + (ti * 16 + L) * 128 + orow] = ssum[ti];
  }

  short* ob = OWn16 + ((long long)(b * D + d) * HW + orow * 128) * 16;
  #pragma unroll
  for (int ti = 0; ti < 8; ++ti)
    #pragma unroll
    for (int reg = 0; reg < 4; ++reg)
      ob[(ti * 16 + chunk * 4 + reg) * 16 + p] = (short)f2bf(acc[ti][reg]);
}

// ---------------------------------------------------------------------------
// K4 v7: OUTER direction via MFMA. OHn stored bf16 [pos][16c].
// ---------------------------------------------------------------------------
template<bool MASK_INNER>
__global__ __launch_bounds__(256) void k_att_col(
    const float* __restrict__ KTp, const float* __restrict__ QTp,
    const short* __restrict__ VTp16, short* __restrict__ OHn16,
    float* __restrict__ Sop)
{
  __shared__ float kr2[4][128][2];
  __shared__ __align__(16) short v16[4][16][136];
  const int tid = threadIdx.x;
  const int i0 = blockIdx.x * 4, d = blockIdx.y, b = blockIdx.z;
  const int sl = b * 16 + d;
  const long long base2 = (long long)(sl * 2) * HW;
  const long long baseV = (long long)(sl * 16) * HW;
  const long long baseS = (long long)sl * HW;
  const int hi = tid >> 6;
  const int L  = tid & 63;
  const int p  = L & 15;
  const int chunk = L >> 4;
  const int icol = i0 + hi;

  for (int kk = tid; kk < 1024; kk += 256) {
    int col = kk & 127;
    int t = kk >> 7;
    int r2 = t >> 1, o = t & 1;
    kr2[r2][col][o] = KTp[base2 + (long long)o * HW + (i0 + r2) * 128 + col];
  }
  for (int idx = tid; idx < 2048; idx += 256) {
    int j4 = idx & 31;
    int t = idx >> 5;
    int c = t & 15, r2 = t >> 4;
    *(uint2*)&v16[r2][c][j4 * 4] =
        *(const uint2*)&VTp16[baseV + (long long)c * HW + (i0 + r2) * 128 + j4 * 4];
  }
  __syncthreads();

  float q0r[8], q1r[8];
  #pragma unroll
  for (int ti = 0; ti < 8; ++ti) {
    q0r[ti] = QTp[base2 + icol * 128 + ti * 16 + p];
    q1r[ti] = QTp[base2 + HW + icol * 128 + ti * 16 + p];
  }

  frag_cd acc[8];
  #pragma unroll
  for (int ti = 0; ti < 8; ++ti) acc[ti] = (frag_cd){0.f, 0.f, 0.f, 0.f};
  float ssum[8] = {0.f, 0.f, 0.f, 0.f, 0.f, 0.f, 0.f, 0.f};

  #pragma unroll
  for (int ks = 0; ks < 4; ++ks) {
    const int vb = ks * 32 + chunk * 8;
    float2 kv[8];
    const float* kvp = &kr2[hi][vb][0];
    *(float4*)&kv[0] = *(const float4*)(kvp);
    *(float4*)&kv[2] = *(const float4*)(kvp + 4);
    *(float4*)&kv[4] = *(const float4*)(kvp + 8);
    *(float4*)&kv[6] = *(const float4*)(kvp + 12);
    frag_ab bfrag = *(const frag_ab*)&v16[hi][p][vb];

    #pragma unroll
    for (int ti = 0; ti < 8; ++ti) {
      float pv[8];
      #pragma unroll
      for (int j = 0; j < 8; ++j) {
        float e = fmaf(q0r[ti], kv[j].x, q1r[ti] * kv[j].y);
        pv[j] = __expf(e);
      }
      if constexpr (!MASK_INNER) {
        const int dj = ti * 16 + p - vb;    // mask j == orr
        #pragma unroll
        for (int j = 0; j < 8; ++j)
          if (j == dj) pv[j] = 0.f;
      }
      float lsum = 0.f;
      #pragma unroll
      for (int j = 0; j < 8; ++j) lsum += pv[j];
      ssum[ti] += lsum;

      union { frag_ab f; unsigned u[4]; } cv;
      cv.u[0] = cvt_pk_bf16(pv[0], pv[1]);
      cv.u[1] = cvt_pk_bf16(pv[2], pv[3]);
      cv.u[2] = cvt_pk_bf16(pv[4], pv[5]);
      cv.u[3] = cvt_pk_bf16(pv[6], pv[7]);
      acc[ti] = __builtin_amdgcn_mfma_f32_16x16x32_bf16(cv.f, bfrag, acc[ti], 0, 0, 0);
    }
  }

  #pragma unroll
  for (int ti = 0; ti < 8; ++ti) {
    ssum[ti] += __shfl_xor(ssum[ti], 16);
    ssum[ti] += __shfl_xor(ssum[ti], 32);
  }
  if (L < 16) {
    #pragma unroll
    for (int ti = 0; ti < 8; ++ti)
      Sop[baseS + icol * 128 + ti * 16 + L] = ssum[ti];
  }

  short* ob = OHn16 + ((long long)(b * D + d) * HW + icol * 128) * 16;
  #pragma unroll
  for (int ti = 0; ti < 8; ++ti)
    #pragma unroll
    for (int reg = 0; reg < 4; ++reg)
      ob[(ti * 16 + chunk * 4 + reg) * 16 + p] = (short)f2bf(acc[ti][reg]);
}

// ---------------------------------------------------------------------------
// K_comb_qkv: app1 combine + app2 projections, fused.
// ---------------------------------------------------------------------------
__global__ __launch_bounds__(256) void k_comb_qkv(
    const float* __restrict__ Xn, const short* __restrict__ OWn16,
    const short* __restrict__ OHn16, const float* __restrict__ Sip,
    const float* __restrict__ Sop, const float* __restrict__ gp,
    const float* __restrict__ wq, const float* __restrict__ wk,
    const float* __restrict__ wv,
    float* __restrict__ Yt, float* __restrict__ Kp, float* __restrict__ KTp,
    float* __restrict__ QTp, short* __restrict__ Vp16, short* __restrict__ VTp16)
{
  __shared__ float xs[16][16][17];    // x tile; later reused for v transpose
  __shared__ float ows[16][16][17];
  __shared__ float lsk[2][16][17], lsq[2][16][17];
  const int tid = threadIdx.x;
  const int tile = blockIdx.x, d = blockIdx.y, b = blockIdx.z;
  const int o0 = (tile >> 3) * 16, i0 = (tile & 7) * 16;
  const int sl = b * 16 + d;
  const long long baseM = (long long)sl * HW;
  const long long base2 = (long long)(sl * 2) * HW;
  const long long baseV = (long long)(sl * 16) * HW;
  const long long xbase = (long long)b * CDHW + (long long)d * HW;

  const int to = tid >> 4, ti = tid & 15;
  #pragma unroll
  for (int c = 0; c < 16; ++c) {
    const long long src = xbase + (long long)c * DHW + (o0 + to) * 128 + (i0 + ti);
    xs[c][to][ti] = Xn[src];
  }
  {
    const short* osrc = OWn16 + ((long long)(b * D + d) * HW + (o0 + to) * 128 + (i0 + ti)) * 16;
    frag_ab f0 = *(const frag_ab*)(osrc);
    frag_ab f1 = *(const frag_ab*)(osrc + 8);
    #pragma unroll
    for (int c = 0; c < 8; ++c) {
      ows[c][to][ti]     = bf2f(f0[c]);
      ows[c + 8][to][ti] = bf2f(f1[c]);
    }
  }
  __syncthreads();

  const int ti2 = tid >> 4, to2 = tid & 15;
  const int i = i0 + ti2, o = o0 + to2;
  const float si = Sip[baseM + i * 128 + o];
  const float so = Sop[baseM + i * 128 + o];
  const float gi = gp[0] / (si + so);

  float oh[16];
  {
    const short* osrc = OHn16 + ((long long)(b * D + d) * HW + i * 128 + o) * 16;
    frag_ab f0 = *(const frag_ab*)(osrc);
    frag_ab f1 = *(const frag_ab*)(osrc + 8);
    #pragma unroll
    for (int c = 0; c < 8; ++c) { oh[c] = bf2f(f0[c]); oh[c + 8] = bf2f(f1[c]); }
  }

  float res[16];
  #pragma unroll
  for (int c = 0; c < 16; ++c)
    res[c] = fmaf(gi, ows[c][to2][ti2] + oh[c], xs[c][to2][ti2]);

  // Yt (fp32, app2's normal-layout input)
  #pragma unroll
  for (int c = 0; c < 16; ++c)
    Yt[xbase + (long long)c * DHW + i * 128 + o] = res[c];

  // projections of res (app2 frame pixel (h=i, w=o))
  float q0 = 0, q1 = 0, k0 = 0, k1 = 0, v[16];
  #pragma unroll
  for (int c = 0; c < 16; ++c) {
    q0 = fmaf(wq[c], res[c], q0);
    q1 = fmaf(wq[16 + c], res[c], q1);
    k0 = fmaf(wk[c], res[c], k0);
    k1 = fmaf(wk[16 + c], res[c], k1);
  }
  #pragma unroll
  for (int oo = 0; oo < 16; ++oo) {
    float a = 0;
    #pragma unroll
    for (int c = 0; c < 16; ++c) a = fmaf(wv[oo * 16 + c], res[c], a);
    v[oo] = a;
  }

  const int hw = i * 128 + o;
  Kp[base2 + hw] = k0;
  Kp[base2 + HW + hw] = k1;
  #pragma unroll
  for (int oo = 0; oo < 16; ++oo)
    Vp16[baseV + (long long)oo * HW + hw] = (short)f2bf(v[oo]);

  // transposed outputs
  lsk[0][to2][ti2] = k0; lsk[1][to2][ti2] = k1;
  lsq[0][to2][ti2] = q0; lsq[1][to2][ti2] = q1;
  __syncthreads();

  #pragma unroll
  for (int c = 0; c < 16; ++c) xs[c][to2][ti2] = v[c];

  {
    const int a = tid >> 4, bb2 = tid & 15;
    const long long wh = (long long)(o0 + a) * 128 + (i0 + bb2);
    KTp[base2 + wh]      = lsk[0][a][bb2];
    KTp[base2 + HW + wh] = lsk[1][a][bb2];
    QTp[base2 + wh]      = lsq[0][a][bb2];
    QTp[base2 + HW + wh] = lsq[1][a][bb2];
  }
  __syncthreads();
  {
    const int a = tid >> 4, bb2 = tid & 15;
    const long long wh = (long long)(o0 + a) * 128 + (i0 + bb2);
    #pragma unroll
    for (int c = 0; c < 16; ++c)
      VTp16[baseV + (long long)c * HW + wh] = (short)f2bf(xs[c][a][bb2]);
  }
}

// ---------------------------------------------------------------------------
// K_comb (app2 final): bf16 OW/OH inputs; writes bf16 [pos][16c] Xb16.
// ---------------------------------------------------------------------------
__global__ __launch_bounds__(256) void k_comb_bf(
    const float* __restrict__ Xn, const short* __restrict__ OWn16,
    const short* __restrict__ OHn16, const float* __restrict__ Sip,
    const float* __restrict__ Sop, const float* __restrict__ gp,
    short* __restrict__ Xb16)
{
  __shared__ float xs[16][16][17], ows[16][16][17];
  const int tid = threadIdx.x;
  const int tile = blockIdx.x, d = blockIdx.y, b = blockIdx.z;
  const int o0 = (tile >> 3) * 16, i0 = (tile & 7) * 16;
  const int sl = b * 16 + d;
  const long long baseM = (long long)sl * HW;
  const long long xbase = (long long)b * CDHW + (long long)d * HW;

  const int to = tid >> 4, ti = tid & 15;
  #pragma unroll
  for (int c = 0; c < 16; ++c) {
    const long long src = xbase + (long long)c * DHW + (o0 + to) * 128 + (i0 + ti);
    xs[c][to][ti] = Xn[src];
  }
  {
    const short* osrc = OWn16 + ((long long)(b * D + d) * HW + (o0 + to) * 128 + (i0 + ti)) * 16;
    frag_ab f0 = *(const frag_ab*)(osrc);
    frag_ab f1 = *(const frag_ab*)(osrc + 8);
    #pragma unroll
    for (int c = 0; c < 8; ++c) {
      ows[c][to][ti]     = bf2f(f0[c]);
      ows[c + 8][to][ti] = bf2f(f1[c]);
    }
  }
  __syncthreads();

  const int ti2 = tid >> 4, to2 = tid & 15;
  const int i = i0 + ti2, o = o0 + to2;
  const float si = Sip[baseM + i * 128 + o];
  const float so = Sop[baseM + i * 128 + o];
  const float gi = gp[0] / (si + so);

  float oh[16];
  {
    const short* osrc = OHn16 + ((long long)(b * D + d) * HW + i * 128 + o) * 16;
    frag_ab f0 = *(const frag_ab*)(osrc);
    frag_ab f1 = *(const frag_ab*)(osrc + 8);
    #pragma unroll
    for (int c = 0; c < 8; ++c) { oh[c] = bf2f(f0[c]); oh[c + 8] = bf2f(f1[c]); }
  }

  float res[16];
  #pragma unroll
  for (int c = 0; c < 16; ++c)
    res[c] = fmaf(gi, ows[c][to2][ti2] + oh[c], xs[c][to2][ti2]);

  unsigned pk[8];
  #pragma unroll
  for (int c = 0; c < 8; ++c)
    pk[c] = (unsigned)f2bf(res[2 * c]) | ((unsigned)f2bf(res[2 * c + 1]) << 16);
  short* dst = Xb16 + ((long long)(b * D + d) * HW + i * 128 + o) * 16;
  *(uint4*)(dst)     = make_uint4(pk[0], pk[1], pk[2], pk[3]);
  *(uint4*)(dst + 8) = make_uint4(pk[4], pk[5], pk[6], pk[7]);
}

// ---------------------------------------------------------------------------
// K_wt: pack gate weights -> bf16 per-half layout.
// ---------------------------------------------------------------------------
__global__ __launch_bounds__(256) void k_wt(
    const float* __restrict__ wg, short* __restrict__ WT16)
{
  const int idx = blockIdx.x * 256 + threadIdx.x;   // < 28672
  if (idx >= 2 * 64 * 224) return;
  const int u = idx / 224;           // half*64 + co
  const int k = idx - u * 224;
  const int ks = k >> 5, rem = k & 31;
  const int t = rem >> 3, c8 = rem & 7;
  const int tap = ks * 4 + t;
  const int half = u >> 6, co = u & 63;
  const int cin = half * 8 + c8;
  float v = (tap < 27) ? wg[co * 432 + cin * 27 + tap] : 0.f;
  WT16[idx] = (short)f2bf(v);
}

// ---------------------------------------------------------------------------
// K5a v3: conv_gate via MFMA, cin-halves sequential, ASYNC-STAGE split.
// Gates stored bf16.
// ---------------------------------------------------------------------------
__global__ __launch_bounds__(256) void k_gates(
    const short* __restrict__ XB16, const short* __restrict__ WT16,
    short* __restrict__ g0, short* __restrict__ g1,
    short* __restrict__ g2, short* __restrict__ g3)
{
  __shared__ short xls[1584 * 8];       // 25.3 KB
  const int tid = threadIdx.x;
  const int rp = blockIdx.x;
  const int d = blockIdx.y, b = blockIdx.z;
  const int h0 = rp * 2;

  const int lane = tid & 63;
  const int og   = tid >> 6;
  const int p    = lane & 15;
  const int chunk = lane >> 4;

  const short* xb = XB16 + (long long)(b * D) * HW * 16;
  const frag_ab zero8 = {0, 0, 0, 0, 0, 0, 0, 0};

  // per-thread staging offsets (shorts; -1 = OOB)
  int goff[7];
  #pragma unroll
  for (int it = 0; it < 7; ++it) {
    const int idx = it * 256 + tid;
    goff[it] = -1;
    if (idx < 1584) {
      const int kd = idx / 528;
      const int rem = idx - kd * 528;
      const int rr = rem / 132;
      const int col = rem - rr * 132;
      const int dd = d - 1 + kd, gh = h0 - 1 + rr, gw = col - 1;
      if (dd >= 0 && dd < D && gh >= 0 && gh < H && gw >= 0 && gw < W)
        goff[it] = (int)(((long long)dd * HW + gh * W + gw) * 16);
    }
  }

  frag_cd acc[2][8];
  #pragma unroll
  for (int r2 = 0; r2 < 2; ++r2)
    #pragma unroll
    for (int pg = 0; pg < 8; ++pg)
      acc[r2][pg] = (frag_cd){0.f, 0.f, 0.f, 0.f};

  int offs[7];
  #pragma unroll
  for (int s = 0; s < 7; ++s) {
    int tap = s * 4 + chunk;
    if (tap > 26) tap = 0;
    const int kd = (tap * 57) >> 9;
    const int rem = tap - kd * 9;
    const int kh = (rem * 11) >> 5;
    const int kw = rem - kh * 3;
    offs[s] = ((kd * 4 + kh) * 132 + p + kw) * 8;
  }

  frag_ab st[7];
  // half 0: load -> regs -> LDS
  #pragma unroll
  for (int it = 0; it < 7; ++it)
    st[it] = (goff[it] >= 0) ? *(const frag_ab*)(xb + goff[it]) : zero8;
  #pragma unroll
  for (int it = 0; it < 7; ++it) {
    const int idx = it * 256 + tid;
    if (idx < 1584) *(frag_ab*)&xls[idx * 8] = st[it];
  }
  __syncthreads();

  // issue half-1 loads early (hide under half-0 MFMAs)
  #pragma unroll
  for (int it = 0; it < 7; ++it)
    st[it] = (goff[it] >= 0) ? *(const frag_ab*)(xb + goff[it] + 8) : zero8;

  // half 0 compute
  {
    frag_ab a[7];
    const short* wl = WT16 + (og * 16 + p) * 224 + chunk * 8;
    #pragma unroll
    for (int s = 0; s < 7; ++s) a[s] = *(const frag_ab*)(wl + s * 32);
    #pragma unroll
    for (int s = 0; s < 7; ++s) {
      const frag_ab av = a[s];
      const int base0 = offs[s];
      #pragma unroll
      for (int pg = 0; pg < 8; ++pg) {
        frag_ab b0 = *(const frag_ab*)&xls[base0 + pg * 128];
        acc[0][pg] = __builtin_amdgcn_mfma_f32_16x16x32_bf16(av, b0, acc[0][pg], 0, 0, 0);
        frag_ab b1 = *(const frag_ab*)&xls[base0 + 1056 + pg * 128];
        acc[1][pg] = __builtin_amdgcn_mfma_f32_16x16x32_bf16(av, b1, acc[1][pg], 0, 0, 0);
      }
    }
  }
  __syncthreads();

  // half 1: write staged regs, compute
  #pragma unroll
  for (int it = 0; it < 7; ++it) {
    const int idx = it * 256 + tid;
    if (idx < 1584) *(frag_ab*)&xls[idx * 8] = st[it];
  }
  __syncthreads();
  {
    frag_ab a[7];
    const short* wl = WT16 + (64 + og * 16 + p) * 224 + chunk * 8;
    #pragma unroll
    for (int s = 0; s < 7; ++s) a[s] = *(const frag_ab*)(wl + s * 32);
    #pragma unroll
    for (int s = 0; s < 7; ++s) {
      const frag_ab av = a[s];
      const int base0 = offs[s];
      #pragma unroll
      for (int pg = 0; pg < 8; ++pg) {
        frag_ab b0 = *(const frag_ab*)&xls[base0 + pg * 128];
        acc[0][pg] = __builtin_amdgcn_mfma_f32_16x16x32_bf16(av, b0, acc[0][pg], 0, 0, 0);
        frag_ab b1 = *(const frag_ab*)&xls[base0 + 1056 + pg * 128];
        acc[1][pg] = __builtin_amdgcn_mfma_f32_16x16x32_bf16(av, b1, acc[1][pg], 0, 0, 0);
      }
    }
  }

  short* gbuf = (og == 0) ? g0 : (og == 1) ? g1 : (og == 2) ? g2 : g3;
  const long long base = (long long)b * CDHW + (long long)d * HW + h0 * W;
  #pragma unroll
  for (int r2 = 0; r2 < 2; ++r2)
    #pragma unroll
    for (int pg = 0; pg < 8; ++pg)
      #pragma unroll
      for (int reg = 0; reg < 4; ++reg) {
        const int cc = chunk * 4 + reg;
        gbuf[base + (long long)cc * DHW + r2 * W + pg * 16 + p] =
            (short)f2bf(acc[r2][pg][reg]);
      }
}

// ---------------------------------------------------------------------------
// K5b: BN + activations + SRU scan over D. Gates read as bf16.
// ---------------------------------------------------------------------------
__global__ __launch_bounds__(256) void k_scan(
    const short* __restrict__ g0, const short* __restrict__ g1,
    const short* __restrict__ g2, const short* __restrict__ g3,
    const float* __restrict__ bg, const float* __restrict__ bb,
    const float* __restrict__ bm, const float* __restrict__ bv,
    float* __restrict__ out)
{
  const int g = blockIdx.x * 256 + threadIdx.x;   // 0 .. 524287
  const int hw = g & 16383;
  const int cc = (g >> 14) & 15;
  const int b  = g >> 18;

  float sc[4], bi[4];
  #pragma unroll
  for (int gg = 0; gg < 4; ++gg) {
    int ch = gg * 16 + cc;
    float s = bg[ch] * rsqrtf(bv[ch] + EPSBN);
    sc[gg] = s;
    bi[gg] = bb[ch] - bm[ch] * s;
  }

  const long long base = (long long)b * CDHW + (long long)cc * DHW + hw;
  float Ct = 0.f;
  for (int d = 0; d < D; ++d) {
    const long long idx = base + (long long)d * HW;
    float wx = tanhf(fmaf(bf2f(g0[idx]), sc[0], bi[0]));
    float ft = 1.f / (1.f + __expf(-fmaf(bf2f(g1[idx]), sc[1], bi[1])));
    float rt = 1.f / (1.f + __expf(-fmaf(bf2f(g2[idx]), sc[2], bi[2])));
    float xg = tanhf(fmaf(bf2f(g3[idx]), sc[3], bi[3]));
    Ct = (d == 0) ? (1.f - ft) : fmaf(ft, Ct, (1.f - ft) * wx);
    out[idx] = fmaf(rt, Ct, (1.f - rt) * xg);
  }
}

// ---------------------------------------------------------------------------
extern "C" void kernel_launch(void* const* d_in, const int* in_sizes, int n_in,
                              void* d_out, int out_size, void* d_ws, size_t ws_size,
                              hipStream_t stream) {
  const float* x      = (const float*)d_in[0];
  const float* w_pre  = (const float*)d_in[1];
  const float* bnpg   = (const float*)d_in[2];
  const float* bnpb   = (const float*)d_in[3];
  const float* bnpm   = (const float*)d_in[4];
  const float* bnpv   = (const float*)d_in[5];
  const float* wq     = (const float*)d_in[6];
  const float* wk     = (const float*)d_in[7];
  const float* wv     = (const float*)d_in[8];
  const float* gamma  = (const float*)d_in[9];
  const float* w_gate = (const float*)d_in[10];
  const float* bng    = (const float*)d_in[11];
  const float* bnb    = (const float*)d_in[12];
  const float* bnm    = (const float*)d_in[13];
  const float* bnv    = (const float*)d_in[14];

  float* ws  = (float*)d_ws;
  float* R0  = ws + OFF_R0;
  float* R3  = ws + OFF_R3;
  float* Kb  = ws + OFF_K;
  float* KTb = ws + OFF_KT;
  float* QTb = ws + OFF_QT;
  float* SI  = ws + OFF_MST;
  float* SO  = ws + OFF_SO;

  short* XB0   = (short*)(ws + OFF_R1);            // bf16 input (early)
  short* WP16  = (short*)(ws + OFF_SO);            // conv_pre weights (early)
  short* WT16  = (short*)(ws + OFF_K);             // gate weights (late)
  // app1
  short* V1b   = (short*)(ws + OFF_R2);            // R2 lower
  short* VT1b  = (short*)(ws + OFF_R3);            // R3 lower
  short* OW1   = (short*)(ws + OFF_R1);            // R1 lower
  short* OH1   = (short*)(ws + OFF_R2);            // R2 lower
  // app2 (fused producer)
  short* V2b   = (short*)(ws + OFF_R2) + 8388608;  // R2 upper
  short* VT2b  = (short*)(ws + OFF_R1) + 8388608;  // R1 upper
  short* OW2   = (short*)(ws + OFF_R0);            // R0 lower
  short* OH2   = (short*)(ws + OFF_R2);            // R2 lower
  short* XB16  = (short*)(ws + OFF_R1);            // R1 lower
  // gates
  short* G0b = (short*)(ws + OFF_R0);
  short* G1b = (short*)(ws + OFF_R0) + 8388608;
  short* G2b = (short*)(ws + OFF_R2);
  short* G3b = (short*)(ws + OFF_R2) + 8388608;
  float* out = (float*)d_out;

  const dim3 gTile(64, D, B), gAtt(32, D, B);

  // stage 1: conv_pre via MFMA: x -> bf16 pos-major -> X1 (fp32) in R0
  k_wp <<<dim3(12),  dim3(256), 0, stream>>>(w_pre, WP16);
  k_x16<<<gTile,     dim3(256), 0, stream>>>(x, XB0);
  k_conv_pre16<<<dim3(16, D, B), dim3(256), 0, stream>>>(
      XB0, WP16, bnpg, bnpb, bnpm, bnpv, R0);

  // attention application 1 (mask on outer)
  k_qkv<<<gTile, dim3(256), 0, stream>>>(R0, wq, wk, wv, Kb, KTb, QTb, V1b, VT1b);
  k_att_row<false><<<gAtt, dim3(256), 0, stream>>>(R0, OW1, Kb, V1b, SI, wq);
  k_att_col<false><<<gAtt, dim3(256), 0, stream>>>(KTb, QTb, VT1b, OH1, SO);
  // fused: combine app1 + projections for app2 (Yt->R3, K/KT/QT, V2b/VT2b)
  k_comb_qkv<<<gTile, dim3(256), 0, stream>>>(
      R0, OW1, OH1, SI, SO, gamma, wq, wk, wv,
      R3, Kb, KTb, QTb, V2b, VT2b);

  // attention application 2 (transposed layout; mask on inner): x=R3
  k_att_row<true><<<gAtt, dim3(256), 0, stream>>>(R3, OW2, Kb, V2b, SI, wq);
  k_att_col<true><<<gAtt, dim3(256), 0, stream>>>(KTb, QTb, VT2b, OH2, SO);
  k_comb_bf<<<gTile, dim3(256), 0, stream>>>(R3, OW2, OH2, SI, SO, gamma, XB16);

  // bf16 gate weights (K region free now)
  k_wt<<<dim3(112), dim3(256), 0, stream>>>(w_gate, WT16);

  // stage 3: conv_gate via MFMA -> bf16 gates (G0,G1 in R0; G2,G3 in R2)
  k_gates<<<dim3(64, D, B), dim3(256), 0, stream>>>(XB16, WT16, G0b, G1b, G2b, G3b);

  // stage 4: BN + activations + SRU scan -> out
  k_scan<<<dim3(2048), dim3(256), 0, stream>>>(G0b, G1b, G2b, G3b, bng, bnb, bnm, bnv, out);
}